// Round 4
// baseline (658.183 us; speedup 1.0000x reference)
//
#include <hip/hip_runtime.h>
#include <hip/hip_bf16.h>
#include <math.h>

typedef __hip_bfloat16 bf16;
typedef __attribute__((ext_vector_type(8))) short short8v;   // 8 bf16 (4 VGPRs)
typedef __attribute__((ext_vector_type(4))) short short4v;   // 4 bf16 (2 VGPRs)
typedef __attribute__((ext_vector_type(4))) float float4v;   // 4 fp32 acc
#define MFMA16 __builtin_amdgcn_mfma_f32_16x16x32_bf16

__device__ __forceinline__ float us2f(unsigned short u) {
  union { unsigned u; float f; } c; c.u = ((unsigned)u) << 16; return c.f;
}
__device__ __forceinline__ unsigned short f2us(float f) {
  return __bfloat16_as_ushort(__float2bfloat16(f));
}

// fp32 x . fp32 w, K % 8 == 0, 16B-aligned
__device__ __forceinline__ float dot_ff(const float* __restrict__ x,
                                        const float* __restrict__ w, int K) {
  const float4* xp = reinterpret_cast<const float4*>(x);
  const float4* wp = reinterpret_cast<const float4*>(w);
  float acc = 0.f;
  const int n = K >> 2;
  for (int i = 0; i < n; ++i) {
    float4 a = xp[i], b = wp[i];
    acc += a.x*b.x + a.y*b.y + a.z*b.z + a.w*b.w;
  }
  return acc;
}

__device__ __forceinline__ float sigm(float x) { return 1.f / (1.f + expf(-x)); }

// ---------------------------------------------------------------------------
__global__ void k_canary(float* __restrict__ out) {
  out[blockIdx.x * 256 + threadIdx.x] = 100.0f;
}

// ---------------------------------------------------------------------------
// One-shot: convert MFMA-consumed weights AND the emb table to bf16 in ws.
// embb: 49689*128 = 6,360,192 elems, 4/thread -> grid 6212.
// ---------------------------------------------------------------------------
__global__ __launch_bounds__(256) void k_cvt(
    const float* __restrict__ a_in_w, const float* __restrict__ t_in_w,
    const float* __restrict__ t_out_w, const float* __restrict__ t_ff1w,
    const float* __restrict__ t_ff2w, const float* __restrict__ a_out_w,
    const float* __restrict__ emb,
    unsigned short* __restrict__ awb, unsigned short* __restrict__ twb,
    unsigned short* __restrict__ pwb, unsigned short* __restrict__ f1wb,
    unsigned short* __restrict__ f2wb, unsigned short* __restrict__ awb2,
    unsigned short* __restrict__ embb)
{
  int i = blockIdx.x * 256 + threadIdx.x;
  if (i < 1590048) {                                  // embb, 4 elems/thread
    float4 e4 = *reinterpret_cast<const float4*>(emb + (size_t)i * 4);
    short4v s; s[0] = f2us(e4.x); s[1] = f2us(e4.y); s[2] = f2us(e4.z); s[3] = f2us(e4.w);
    *reinterpret_cast<short4v*>(embb + (size_t)i * 4) = s;
  }
  if (i < 49152)  awb[i] = f2us(a_in_w[i]);
  if (i < 786432) twb[i] = f2us(t_in_w[i]);
  if (i < 262144) pwb[i] = f2us(t_out_w[i]);
  if (i < 524288) f1wb[i] = f2us(t_ff1w[i]);
  if (i < 524288) f2wb[i] = f2us(t_ff2w[i]);
  if (i < 16384)  awb2[i] = f2us(a_out_w[i]);
}

// ---------------------------------------------------------------------------
// GRU weight prep: row-major bf16 copies. whhb [dir][768][256],
// wihb [dir][768][128] (for gi GEMM).
// ---------------------------------------------------------------------------
__global__ __launch_bounds__(256) void k_gru_wb(
    const float* __restrict__ wih_f, const float* __restrict__ whh_f,
    const float* __restrict__ wih_b, const float* __restrict__ whh_b,
    unsigned short* __restrict__ whhb, unsigned short* __restrict__ wihb)
{
  int i = blockIdx.x * 256 + threadIdx.x;   // < 393216
  if (i >= 393216) return;
  int dir = i / 196608, r = i % 196608;
  whhb[i] = f2us((dir ? whh_b : whh_f)[r]);
  if (r < 98304) wihb[dir * 98304 + r] = f2us((dir ? wih_b : wih_f)[r]);
}

// ---------------------------------------------------------------------------
// Stage 1: embed (bf16 table) + per-order MHA + proj-then-mean.
// QKV MFMA -> fused scores/softmax/PV (wave = head, barrier-free) ->
// out-proj MFMA + shfl mean -> bf16 oe write. 4 barriers total.
// LDS: ids 128 + xs 8704 (P overlay) + qb 8704 (O overlay) + kb 8704
//      + vT 10240 = 36,480 B -> 4 blocks/CU.
// ---------------------------------------------------------------------------
__global__ __launch_bounds__(256, 4) void k_order_attn(
    const int* __restrict__ oh, const unsigned short* __restrict__ embb,
    const unsigned short* __restrict__ awb, const float* __restrict__ in_b,
    const unsigned short* __restrict__ awb2, const float* __restrict__ out_b,
    unsigned short* __restrict__ oeb)
{
  const int bo = blockIdx.x;            // 0..8191
  const int tid = threadIdx.x;
  __shared__ int ids[32];
  __shared__ alignas(16) unsigned short xs[32 * 136];     // x bf16; P [128][32] overlays
  __shared__ alignas(16) unsigned short qb[32 * 136];     // q bf16; O bf16 overlays
  __shared__ alignas(16) unsigned short kb[32 * 136];
  __shared__ alignas(16) unsigned short vT[128 * 40];     // V^T bf16: vT[d][k]
  unsigned short* pb = xs;                                // P overlay (8192 <= 8704)
  unsigned short* ob = qb;                                // O overlay

  const int lane = tid & 63, wave = tid >> 6;
  const int l15 = lane & 15, quad = lane >> 4;

  if (tid < 32) ids[tid] = oh[bo * 32 + tid];
  __syncthreads();
  for (int i = tid; i < 512; i += 256) {                  // bf16 gather, 16B/lane
    int t = i >> 4, c8 = (i & 15) << 3;
    *reinterpret_cast<short8v*>(xs + t * 136 + c8) =
        *reinterpret_cast<const short8v*>(embb + (size_t)ids[t] * 128 + c8);
  }
  __syncthreads();
  // ---- QKV MFMA: qkv[t][j] = x[t][.] . w[j][.] ----
  {
    short8v af[2][4];
#pragma unroll
    for (int mt = 0; mt < 2; ++mt)
#pragma unroll
      for (int kc = 0; kc < 4; ++kc)
        af[mt][kc] = *reinterpret_cast<const short8v*>(
            xs + (mt * 16 + l15) * 136 + kc * 32 + quad * 8);
    for (int ni = 0; ni < 6; ++ni) {
      const int j = (wave + ni * 4) * 16 + l15;
      const unsigned short* wrow = awb + (size_t)j * 128;
      float4v acc0 = {0.f, 0.f, 0.f, 0.f}, acc1 = {0.f, 0.f, 0.f, 0.f};
#pragma unroll
      for (int kc = 0; kc < 4; ++kc) {
        short8v bfr = *reinterpret_cast<const short8v*>(wrow + kc * 32 + quad * 8);
        acc0 = MFMA16(af[0][kc], bfr, acc0, 0, 0, 0);
        acc1 = MFMA16(af[1][kc], bfr, acc1, 0, 0, 0);
      }
      const float bj = in_b[j];
      const int jj = j & 127;
      if (j < 256) {
        unsigned short* dst = (j < 128) ? qb : kb;
#pragma unroll
        for (int r = 0; r < 4; ++r) {
          int t0 = quad * 4 + r;
          dst[t0 * 136 + jj] = f2us(acc0[r] + bj);
          dst[(t0 + 16) * 136 + jj] = f2us(acc1[r] + bj);
        }
      } else {                                            // V transposed: vT[d][k]
        short4v s0, s1;
#pragma unroll
        for (int r = 0; r < 4; ++r) { s0[r] = f2us(acc0[r] + bj); s1[r] = f2us(acc1[r] + bj); }
        *reinterpret_cast<short4v*>(vT + jj * 40 + quad * 4) = s0;
        *reinterpret_cast<short4v*>(vT + jj * 40 + 16 + quad * 4) = s1;
      }
    }
  }
  __syncthreads();
  // ---- FUSED: scores + softmax + PV + O write (wave = head h) ----
  {
    const int h = wave;
    const float scale1 = 0.17677669529663687f;            // 1/sqrt(32)
    short8v qf[2], kf[2];
#pragma unroll
    for (int mt = 0; mt < 2; ++mt)
      qf[mt] = *reinterpret_cast<const short8v*>(qb + (mt * 16 + l15) * 136 + h * 32 + quad * 8);
#pragma unroll
    for (int nt = 0; nt < 2; ++nt)
      kf[nt] = *reinterpret_cast<const short8v*>(kb + (nt * 16 + l15) * 136 + h * 32 + quad * 8);
    float4v sacc[2][2];
#pragma unroll
    for (int mt = 0; mt < 2; ++mt)
#pragma unroll
      for (int nt = 0; nt < 2; ++nt) {
        sacc[mt][nt] = (float4v){0.f, 0.f, 0.f, 0.f};
        sacc[mt][nt] = MFMA16(qf[mt], kf[nt], sacc[mt][nt], 0, 0, 0);
      }
    float inv_reg[2][4];
#pragma unroll
    for (int mt = 0; mt < 2; ++mt)
#pragma unroll
      for (int r = 0; r < 4; ++r) {
        float s0 = sacc[mt][0][r] * scale1;
        float s1 = sacc[mt][1][r] * scale1;
        float mx = fmaxf(s0, s1);
        mx = fmaxf(mx, __shfl_xor(mx, 1));
        mx = fmaxf(mx, __shfl_xor(mx, 2));
        mx = fmaxf(mx, __shfl_xor(mx, 4));
        mx = fmaxf(mx, __shfl_xor(mx, 8));
        float e0 = expf(s0 - mx), e1 = expf(s1 - mx);
        float sm = e0 + e1;
        sm += __shfl_xor(sm, 1);
        sm += __shfl_xor(sm, 2);
        sm += __shfl_xor(sm, 4);
        sm += __shfl_xor(sm, 8);
        inv_reg[mt][r] = 1.f / sm;
        int row = h * 32 + mt * 16 + quad * 4 + r;
        pb[row * 32 + l15] = f2us(e0);
        pb[row * 32 + 16 + l15] = f2us(e1);
      }
    // PV (reads only this wave's P rows / vT stripe -> no barrier needed)
    short8v pf[2], vf[2];
#pragma unroll
    for (int mt = 0; mt < 2; ++mt)
      pf[mt] = *reinterpret_cast<const short8v*>(pb + (h * 32 + mt * 16 + l15) * 32 + quad * 8);
#pragma unroll
    for (int nt = 0; nt < 2; ++nt)
      vf[nt] = *reinterpret_cast<const short8v*>(vT + (h * 32 + nt * 16 + l15) * 40 + quad * 8);
    float4v oacc[2][2];
#pragma unroll
    for (int mt = 0; mt < 2; ++mt)
#pragma unroll
      for (int nt = 0; nt < 2; ++nt) {
        oacc[mt][nt] = (float4v){0.f, 0.f, 0.f, 0.f};
        oacc[mt][nt] = MFMA16(pf[mt], vf[nt], oacc[mt][nt], 0, 0, 0);
      }
    // write O bf16 into ob (qb overlay): only this wave's head-col stripe
#pragma unroll
    for (int mt = 0; mt < 2; ++mt)
#pragma unroll
      for (int r = 0; r < 4; ++r) {
        int t = mt * 16 + quad * 4 + r;
        float inv = inv_reg[mt][r];
#pragma unroll
        for (int nt = 0; nt < 2; ++nt)
          ob[t * 136 + h * 32 + nt * 16 + l15] = f2us(oacc[mt][nt][r] * inv);
      }
  }
  __syncthreads();
  // ---- out-proj MFMA: proj[t][j] = O[t][.] . W[j][.]; then mean over t ----
  {
    float4v acc[2][2];
#pragma unroll
    for (int mt = 0; mt < 2; ++mt)
#pragma unroll
      for (int nt = 0; nt < 2; ++nt) acc[mt][nt] = (float4v){0.f, 0.f, 0.f, 0.f};
#pragma unroll
    for (int kc = 0; kc < 4; ++kc) {
      short8v af0 = *reinterpret_cast<const short8v*>(ob + l15 * 136 + kc * 32 + quad * 8);
      short8v af1 = *reinterpret_cast<const short8v*>(ob + (16 + l15) * 136 + kc * 32 + quad * 8);
#pragma unroll
      for (int nt = 0; nt < 2; ++nt) {
        int j = (wave * 2 + nt) * 16 + l15;
        short8v bfr = *reinterpret_cast<const short8v*>(awb2 + (size_t)j * 128 + kc * 32 + quad * 8);
        acc[0][nt] = MFMA16(af0, bfr, acc[0][nt], 0, 0, 0);
        acc[1][nt] = MFMA16(af1, bfr, acc[1][nt], 0, 0, 0);
      }
    }
#pragma unroll
    for (int nt = 0; nt < 2; ++nt) {
      float part = 0.f;
#pragma unroll
      for (int mt = 0; mt < 2; ++mt)
#pragma unroll
        for (int r = 0; r < 4; ++r) part += acc[mt][nt][r];
      part += __shfl_xor(part, 16);
      part += __shfl_xor(part, 32);
      if (quad == 0) {
        int j = (wave * 2 + nt) * 16 + l15;
        oeb[(size_t)bo * 128 + j] = f2us(part * (1.f / 32.f) + out_b[j]);
      }
    }
  }
}

// ---------------------------------------------------------------------------
// gi GEMM (MFMA): gi[8192][1536] bf16 = oe @ wih^T (both dirs). oe is bf16.
// ---------------------------------------------------------------------------
__global__ __launch_bounds__(256, 2) void k_gru_gi(
    const unsigned short* __restrict__ oeb, const unsigned short* __restrict__ wihb,
    unsigned short* __restrict__ gi)
{
  const int row0 = blockIdx.x * 32, tid = threadIdx.x;
  __shared__ alignas(16) unsigned short xs[32 * 136];
  for (int i = tid; i < 512; i += 256) {
    int t = i >> 4, c8 = (i & 15) << 3;
    *reinterpret_cast<short8v*>(xs + t * 136 + c8) =
        *reinterpret_cast<const short8v*>(oeb + (size_t)(row0 + t) * 128 + c8);
  }
  __syncthreads();
  const int lane = tid & 63, wave = tid >> 6;
  const int l15 = lane & 15, quad = lane >> 4;
  short8v af[2][4];
#pragma unroll
  for (int mt = 0; mt < 2; ++mt)
#pragma unroll
    for (int kc = 0; kc < 4; ++kc)
      af[mt][kc] = *reinterpret_cast<const short8v*>(
          xs + (mt * 16 + l15) * 136 + kc * 32 + quad * 8);
  for (int ni = 0; ni < 24; ++ni) {
    int col = (wave + ni * 4) * 16 + l15;
    const unsigned short* wrow = wihb + (size_t)col * 128;
    float4v a0 = {0.f,0.f,0.f,0.f}, a1 = {0.f,0.f,0.f,0.f};
#pragma unroll
    for (int kc = 0; kc < 4; ++kc) {
      short8v bfr = *reinterpret_cast<const short8v*>(wrow + kc * 32 + quad * 8);
      a0 = MFMA16(af[0][kc], bfr, a0, 0, 0, 0);
      a1 = MFMA16(af[1][kc], bfr, a1, 0, 0, 0);
    }
#pragma unroll
    for (int r = 0; r < 4; ++r) {
      gi[(size_t)(row0 + quad * 4 + r) * 1536 + col] = f2us(a0[r]);
      gi[(size_t)(row0 + quad * 4 + r + 16) * 1536 + col] = f2us(a1[r]);
    }
  }
}

// ---------------------------------------------------------------------------
// GRU recurrence via MFMA. 2 batches/block, grid (128,2) = 256 blocks,
// 512 threads (8 waves). whh register-resident. gi for step s+1 prefetched
// into registers before the barrier. LDS: hb 8448 + pg 6176 = 14,624 B.
// ---------------------------------------------------------------------------
__global__ __launch_bounds__(512, 2) void k_gru_rec(
    const unsigned short* __restrict__ gi, const unsigned short* __restrict__ whhb,
    const float* __restrict__ bih_f, const float* __restrict__ bhh_f,
    const float* __restrict__ bih_b, const float* __restrict__ bhh_b,
    float* __restrict__ g)
{
  const int b0 = blockIdx.x * 2, dir = blockIdx.y;
  const int tid = threadIdx.x;           // 0..511
  const unsigned short* wb = whhb + (size_t)dir * 196608;   // [768][256] bf16
  const float* bih = dir ? bih_b : bih_f;
  const float* bhh = dir ? bhh_b : bhh_f;
  __shared__ alignas(16) unsigned short hb[16 * 264];   // h bf16 (A operand)
  __shared__ float pg[2 * 772];                         // gh fp32 (rows 0-1)
  const int lane = tid & 63, wave = tid >> 6;
  const int l15 = lane & 15, quad = lane >> 4;
  const int j = tid & 255, mb = tid >> 8;               // pointwise: (m=mb, j)
  const float bir = bih[j], biz = bih[256 + j], bin_ = bih[512 + j];
  const float bhr = bhh[j], bhz = bhh[256 + j], bhn  = bhh[512 + j];
  short8v wf[6][8];
  int cols[6];
#pragma unroll
  for (int ni = 0; ni < 6; ++ni) {
    cols[ni] = (wave + ni * 8) * 16 + l15;
#pragma unroll
    for (int kc = 0; kc < 8; ++kc)
      wf[ni][kc] = *reinterpret_cast<const short8v*>(
          wb + (size_t)cols[ni] * 256 + kc * 32 + quad * 8);
  }
  for (int i = tid; i < 16 * 264; i += 512) hb[i] = 0;
  int tcur = dir ? 31 : 0;
  size_t gbase = ((size_t)(b0 + mb) * 32 + tcur) * 1536 + dir * 768;
  float gr = us2f(gi[gbase + j]);
  float gz = us2f(gi[gbase + 256 + j]);
  float gn = us2f(gi[gbase + 512 + j]);
  __syncthreads();
  for (int s = 0; s < 32; ++s) {
    float4v acc[6];
#pragma unroll
    for (int ni = 0; ni < 6; ++ni) acc[ni] = (float4v){0.f, 0.f, 0.f, 0.f};
#pragma unroll
    for (int kc = 0; kc < 8; ++kc) {
      short8v af = *reinterpret_cast<const short8v*>(hb + l15 * 264 + kc * 32 + quad * 8);
#pragma unroll
      for (int ni = 0; ni < 6; ++ni)
        acc[ni] = MFMA16(af, wf[ni][kc], acc[ni], 0, 0, 0);
    }
    if (quad == 0) {
#pragma unroll
      for (int ni = 0; ni < 6; ++ni) {
        pg[cols[ni]] = acc[ni][0];
        pg[772 + cols[ni]] = acc[ni][1];
      }
    }
    float gr2 = 0.f, gz2 = 0.f, gn2 = 0.f;
    if (s < 31) {
      int t2 = dir ? (30 - s) : (s + 1);
      size_t gb2 = ((size_t)(b0 + mb) * 32 + t2) * 1536 + dir * 768;
      gr2 = us2f(gi[gb2 + j]);
      gz2 = us2f(gi[gb2 + 256 + j]);
      gn2 = us2f(gi[gb2 + 512 + j]);
    }
    __syncthreads();
    {
      const int tt = dir ? (31 - s) : s;
      float hprev = us2f(hb[mb * 264 + j]);
      float r = sigm(gr + bir + pg[mb * 772 + j] + bhr);
      float z = sigm(gz + biz + pg[mb * 772 + 256 + j] + bhz);
      float n = tanhf(gn + bin_ + r * (pg[mb * 772 + 512 + j] + bhn));
      float nh = (1.f - z) * n + z * hprev;
      hb[mb * 264 + j] = f2us(nh);
      g[((size_t)(b0 + mb) * 32 + tt) * 512 + dir * 256 + j] = nh;
    }
    gr = gr2; gz = gz2; gn = gn2;
    __syncthreads();
  }
}

// ---------------------------------------------------------------------------
// Stage 3 fused attention, one block per (b, head). x staged in K=256
// halves -> LDS 44,544 B -> 3 blocks/CU. QKV/scores/PV on MFMA.
// ---------------------------------------------------------------------------
#define XS2_STR 264

__global__ __launch_bounds__(256, 3) void k_mha2f(
    const float* __restrict__ g, const unsigned short* __restrict__ twb,
    const float* __restrict__ Bv, float* __restrict__ attn)
{
  const int b = blockIdx.x, h = blockIdx.y, tid = threadIdx.x;
  __shared__ alignas(16) unsigned short xs2[32 * XS2_STR]; // x half; sc+pb overlay
  __shared__ alignas(16) unsigned short qk[2 * 32 * 136];
  __shared__ alignas(16) unsigned short vT[128 * 40];      // vT[d][k]
  unsigned short* qs = qk;
  unsigned short* ks = qk + 32 * 136;
  float* sc = reinterpret_cast<float*>(xs2);               // [32][33]; col 32 = 1/sum
  unsigned short* pb = xs2 + 2112;                         // P bf16 [32][32]
  const int lane = tid & 63, wave = tid >> 6;
  const int l15 = lane & 15, quad = lane >> 4;

  int wrowi[6];
#pragma unroll
  for (int ni = 0; ni < 6; ++ni) {
    int idx = (wave + ni * 4) * 16 + l15;
    int m = idx >> 7, dd = idx & 127;
    wrowi[ni] = m * 512 + h * 128 + dd;
  }
  float4v acc[6][2];
#pragma unroll
  for (int ni = 0; ni < 6; ++ni)
#pragma unroll
    for (int mt = 0; mt < 2; ++mt) acc[ni][mt] = (float4v){0.f, 0.f, 0.f, 0.f};

  for (int half = 0; half < 2; ++half) {
    __syncthreads();
    for (int i = tid; i < 2048; i += 256) {
      int t = i >> 6, c4 = (i & 63) << 2;
      float4 e4 = *reinterpret_cast<const float4*>(
          g + (size_t)b * 16384 + t * 512 + half * 256 + c4);
      short4v s; s[0] = f2us(e4.x); s[1] = f2us(e4.y); s[2] = f2us(e4.z); s[3] = f2us(e4.w);
      *reinterpret_cast<short4v*>(xs2 + t * XS2_STR + c4) = s;
    }
    __syncthreads();
    for (int kl = 0; kl < 2; ++kl) {
      const int kg = half * 2 + kl;
      short8v af[2][4];
#pragma unroll
      for (int mt = 0; mt < 2; ++mt)
#pragma unroll
        for (int u = 0; u < 4; ++u)
          af[mt][u] = *reinterpret_cast<const short8v*>(
              xs2 + (mt * 16 + l15) * XS2_STR + kl * 128 + u * 32 + quad * 8);
#pragma unroll
      for (int ni = 0; ni < 6; ++ni) {
        const unsigned short* wrow = twb + (size_t)wrowi[ni] * 512 + kg * 128;
#pragma unroll
        for (int u = 0; u < 4; ++u) {
          short8v bfr = *reinterpret_cast<const short8v*>(wrow + u * 32 + quad * 8);
          acc[ni][0] = MFMA16(af[0][u], bfr, acc[ni][0], 0, 0, 0);
          acc[ni][1] = MFMA16(af[1][u], bfr, acc[ni][1], 0, 0, 0);
        }
      }
    }
  }
#pragma unroll
  for (int ni = 0; ni < 6; ++ni) {
    int idx = (wave + ni * 4) * 16 + l15;
    int m = idx >> 7, dd = idx & 127;
    float bj = Bv[wrowi[ni]];
    if (m < 2) {
      unsigned short* dst = (m == 0) ? qs : ks;
#pragma unroll
      for (int r = 0; r < 4; ++r) {
        int t0 = quad * 4 + r;
        dst[t0 * 136 + dd] = f2us(acc[ni][0][r] + bj);
        dst[(t0 + 16) * 136 + dd] = f2us(acc[ni][1][r] + bj);
      }
    } else {
      short4v s0, s1;
#pragma unroll
      for (int r = 0; r < 4; ++r) { s0[r] = f2us(acc[ni][0][r] + bj); s1[r] = f2us(acc[ni][1][r] + bj); }
      *reinterpret_cast<short4v*>(vT + dd * 40 + quad * 4) = s0;
      *reinterpret_cast<short4v*>(vT + dd * 40 + 16 + quad * 4) = s1;
    }
  }
  __syncthreads();
  // ---- scores MFMA ----
  {
    const float scale2 = 0.08838834764831845f;            // 1/sqrt(128)
    const int mt = wave >> 1, nt = wave & 1;
    float4v a = {0.f, 0.f, 0.f, 0.f};
#pragma unroll
    for (int kc = 0; kc < 4; ++kc) {
      short8v qf = *reinterpret_cast<const short8v*>(qs + (mt * 16 + l15) * 136 + kc * 32 + quad * 8);
      short8v kf = *reinterpret_cast<const short8v*>(ks + (nt * 16 + l15) * 136 + kc * 32 + quad * 8);
      a = MFMA16(qf, kf, a, 0, 0, 0);
    }
#pragma unroll
    for (int r = 0; r < 4; ++r)
      sc[(mt * 16 + quad * 4 + r) * 33 + nt * 16 + l15] = a[r] * scale2;
  }
  __syncthreads();
  // ---- softmax rows: 4 lanes/row, shfl-reduce; bf16 unnormalized P ----
  if (tid < 128) {
    int row = tid >> 2, seg = tid & 3;
    float* srow = sc + row * 33;
    float mx = srow[seg * 8];
#pragma unroll
    for (int c = 1; c < 8; ++c) mx = fmaxf(mx, srow[seg * 8 + c]);
    mx = fmaxf(mx, __shfl_xor(mx, 1));
    mx = fmaxf(mx, __shfl_xor(mx, 2));
    float s = 0.f;
    short8v pv;
#pragma unroll
    for (int c = 0; c < 8; ++c) {
      float e = expf(srow[seg * 8 + c] - mx);
      s += e; pv[c] = f2us(e);
    }
    *reinterpret_cast<short8v*>(pb + row * 32 + seg * 8) = pv;
    s += __shfl_xor(s, 1);
    s += __shfl_xor(s, 2);
    if (seg == 0) srow[32] = 1.f / s;
  }
  __syncthreads();
  // ---- PV MFMA ----
  {
    short8v pf[2], vf[2];
#pragma unroll
    for (int mt = 0; mt < 2; ++mt)
      pf[mt] = *reinterpret_cast<const short8v*>(pb + (mt * 16 + l15) * 32 + quad * 8);
#pragma unroll
    for (int ntl = 0; ntl < 2; ++ntl)
      vf[ntl] = *reinterpret_cast<const short8v*>(vT + ((2 * wave + ntl) * 16 + l15) * 40 + quad * 8);
    float4v oacc[2][2];
#pragma unroll
    for (int mt = 0; mt < 2; ++mt)
#pragma unroll
      for (int ntl = 0; ntl < 2; ++ntl) {
        oacc[mt][ntl] = (float4v){0.f, 0.f, 0.f, 0.f};
        oacc[mt][ntl] = MFMA16(pf[mt], vf[ntl], oacc[mt][ntl], 0, 0, 0);
      }
#pragma unroll
    for (int mt = 0; mt < 2; ++mt)
#pragma unroll
      for (int r = 0; r < 4; ++r) {
        int q = mt * 16 + quad * 4 + r;
        float inv = sc[q * 33 + 32];
#pragma unroll
        for (int ntl = 0; ntl < 2; ++ntl)
          attn[((size_t)b * 32 + q) * 512 + h * 128 + (2 * wave + ntl) * 16 + l15] =
              oacc[mt][ntl][r] * inv;
      }
  }
}

// ---------------------------------------------------------------------------
// proj GEMM via MFMA (M=16/block, N=512, K=512) + bias + residual + LN.
// ---------------------------------------------------------------------------
__global__ __launch_bounds__(256, 2) void k_projln_mfma(
    const float* __restrict__ X, const unsigned short* __restrict__ Wb,
    const float* __restrict__ bias, const float* __restrict__ res,
    const float* __restrict__ gam, const float* __restrict__ bet,
    float* __restrict__ Y)
{
  const int row0 = blockIdx.x * 16, tid = threadIdx.x;
  __shared__ alignas(16) unsigned short xs[16 * 520];
  __shared__ float ys[16 * 516];
  for (int i = tid; i < 16 * 512; i += 256) {
    int t = i >> 9, c = i & 511;
    xs[t * 520 + c] = f2us(X[(size_t)(row0 + t) * 512 + c]);
  }
  __syncthreads();
  {
    const int lane = tid & 63, wave = tid >> 6;
    const int l15 = lane & 15, quad = lane >> 4;
    short8v af[16];
#pragma unroll
    for (int kc = 0; kc < 16; ++kc)
      af[kc] = *reinterpret_cast<const short8v*>(xs + l15 * 520 + kc * 32 + quad * 8);
    for (int ni = 0; ni < 8; ++ni) {
      int col = (wave + ni * 4) * 16 + l15;
      const unsigned short* wrow = Wb + (size_t)col * 512;
      float4v acc = {0.f,0.f,0.f,0.f};
#pragma unroll
      for (int kc = 0; kc < 16; ++kc) {
        short8v bfr = *reinterpret_cast<const short8v*>(wrow + kc * 32 + quad * 8);
        acc = MFMA16(af[kc], bfr, acc, 0, 0, 0);
      }
      float bj = bias[col];
#pragma unroll
      for (int r = 0; r < 4; ++r)
        ys[(quad * 4 + r) * 516 + col] = acc[r] + bj;
    }
  }
  __syncthreads();
  for (int i = tid; i < 16 * 512; i += 256) {
    int t = i >> 9, c = i & 511;
    ys[t * 516 + c] += res[(size_t)(row0 + t) * 512 + c];
  }
  __syncthreads();
  {
    int row = tid >> 4, l16 = tid & 15;
    const float* yr = ys + row * 516;
    float part = 0.f;
#pragma unroll
    for (int k = 0; k < 32; ++k) part += yr[l16 + 16 * k];
#pragma unroll
    for (int off = 8; off; off >>= 1) part += __shfl_xor(part, off, 16);
    float mean = part * (1.f / 512.f);
    float var = 0.f;
#pragma unroll
    for (int k = 0; k < 32; ++k) { float d = yr[l16 + 16 * k] - mean; var += d * d; }
#pragma unroll
    for (int off = 8; off; off >>= 1) var += __shfl_xor(var, off, 16);
    float rs = rsqrtf(var * (1.f / 512.f) + 1e-5f);
    for (int k = 0; k < 32; ++k) {
      int c = l16 + 16 * k;
      Y[(size_t)(row0 + row) * 512 + c] = (yr[c] - mean) * rs * gam[c] + bet[c];
    }
  }
}

// ---------------------------------------------------------------------------
// FUSED ff1+relu+ff2+residual+LN (M=16/block). f1 (16x1024 bf16) lives in
// LDS; ys fp32 overlays f1 after the last MFMA that reads it.
// LDS: xs 16,640 + f1L 33,024 = 49,664 B -> 3 blocks/CU.
// ---------------------------------------------------------------------------
__global__ __launch_bounds__(256, 3) void k_ffln(
    const float* __restrict__ X, const unsigned short* __restrict__ W1,
    const float* __restrict__ b1, const unsigned short* __restrict__ W2,
    const float* __restrict__ b2, const float* __restrict__ res,
    const float* __restrict__ gam, const float* __restrict__ bet,
    float* __restrict__ Y)
{
  const int row0 = blockIdx.x * 16, tid = threadIdx.x;
  __shared__ alignas(16) unsigned short xs[16 * 520];
  __shared__ alignas(16) unsigned short f1L[16 * 1032];   // ys [16][516] fp32 overlays
  float* ys = reinterpret_cast<float*>(f1L);
  const int lane = tid & 63, wave = tid >> 6;
  const int l15 = lane & 15, quad = lane >> 4;
  for (int i = tid; i < 16 * 512; i += 256) {
    int t = i >> 9, c = i & 511;
    xs[t * 520 + c] = f2us(X[(size_t)(row0 + t) * 512 + c]);
  }
  __syncthreads();
  // ff1: N=1024, K=512 -> relu -> f1L bf16
  {
    short8v af[16];
#pragma unroll
    for (int kc = 0; kc < 16; ++kc)
      af[kc] = *reinterpret_cast<const short8v*>(xs + l15 * 520 + kc * 32 + quad * 8);
    for (int ni = 0; ni < 16; ++ni) {
      int col = (wave + ni * 4) * 16 + l15;
      const unsigned short* wrow = W1 + (size_t)col * 512;
      float4v acc = {0.f,0.f,0.f,0.f};
#pragma unroll
      for (int kc = 0; kc < 16; ++kc) {
        short8v bfr = *reinterpret_cast<const short8v*>(wrow + kc * 32 + quad * 8);
        acc = MFMA16(af[kc], bfr, acc, 0, 0, 0);
      }
      float bj = b1[col];
#pragma unroll
      for (int r = 0; r < 4; ++r)
        f1L[(quad * 4 + r) * 1032 + col] = f2us(fmaxf(acc[r] + bj, 0.f));
    }
  }
  __syncthreads();
  // ff2: N=512, K=1024 from f1L
  float4v acc2[8];
#pragma unroll
  for (int ni = 0; ni < 8; ++ni) acc2[ni] = (float4v){0.f,0.f,0.f,0.f};
  for (int half = 0; half < 2; ++half) {
    short8v af[16];
#pragma unroll
    for (int kc = 0; kc < 16; ++kc)
      af[kc] = *reinterpret_cast<const short8v*>(
          f1L + l15 * 1032 + half * 512 + kc * 32 + quad * 8);
#pragma unroll
    for (int ni = 0; ni < 8; ++ni) {
      int col = (wave + ni * 4) * 16 + l15;
      const unsigned short* wrow = W2 + (size_t)col * 1024 + half * 512;
#pragma unroll
      for (int kc = 0; kc < 16; ++kc) {
        short8v bfr = *reinterpret_cast<const short8v*>(wrow + kc * 32 + quad * 8);
        acc2[ni] = MFMA16(af[kc], bfr, acc2[ni], 0, 0, 0);
      }
    }
  }
  __syncthreads();                                        // f1L dead -> ys
  for (int ni = 0; ni < 8; ++ni) {
    int col = (wave + ni * 4) * 16 + l15;
    float bj = b2[col];
#pragma unroll
    for (int r = 0; r < 4; ++r)
      ys[(quad * 4 + r) * 516 + col] = acc2[ni][r] + bj;
  }
  __syncthreads();
  for (int i = tid; i < 16 * 512; i += 256) {
    int t = i >> 9, c = i & 511;
    ys[t * 516 + c] += res[(size_t)(row0 + t) * 512 + c];
  }
  __syncthreads();
  {
    int row = tid >> 4, l16 = tid & 15;
    const float* yr = ys + row * 516;
    float part = 0.f;
#pragma unroll
    for (int k = 0; k < 32; ++k) part += yr[l16 + 16 * k];
#pragma unroll
    for (int off = 8; off; off >>= 1) part += __shfl_xor(part, off, 16);
    float mean = part * (1.f / 512.f);
    float var = 0.f;
#pragma unroll
    for (int k = 0; k < 32; ++k) { float d = yr[l16 + 16 * k] - mean; var += d * d; }
#pragma unroll
    for (int off = 8; off; off >>= 1) var += __shfl_xor(var, off, 16);
    float rs = rsqrtf(var * (1.f / 512.f) + 1e-5f);
    for (int k = 0; k < 32; ++k) {
      int c = l16 + 16 * k;
      Y[(size_t)(row0 + row) * 512 + c] = (yr[c] - mean) * rs * gam[c] + bet[c];
    }
  }
}

// ---------------------------------------------------------------------------
// Final: mean-pool, temporal MLP, concat, classifier, LN, relu -> fp32
// ---------------------------------------------------------------------------
__global__ __launch_bounds__(256) void k_final(
    const float* __restrict__ g2,
    const float* __restrict__ db, const float* __restrict__ dsl,
    const float* __restrict__ te1_w, const float* __restrict__ te1_b,
    const float* __restrict__ l1g, const float* __restrict__ l1b,
    const float* __restrict__ te2_w, const float* __restrict__ te2_b,
    const float* __restrict__ l2g, const float* __restrict__ l2b,
    const float* __restrict__ c_w, const float* __restrict__ c_b,
    const float* __restrict__ clg, const float* __restrict__ clb,
    float* __restrict__ out)
{
  const int b = blockIdx.x, tid = threadIdx.x;
  __shared__ float cat[640];
  __shared__ float t1[64];
  __shared__ float t2[128];
  __shared__ float pre[256];
  __shared__ float red[256];
  __shared__ float st[2];
  for (int i = tid; i < 512; i += 256) {
    float acc = 0.f;
#pragma unroll
    for (int t = 0; t < 32; ++t) acc += g2[((size_t)b * 32 + t) * 512 + i];
    cat[i] = acc * (1.f / 32.f);
  }
  if (tid == 0) {
    float s = 0.f;
    for (int i = 0; i < 31; ++i) s += db[b * 31 + i];
    st[0] = s / 31.f;
    st[1] = dsl[b];
  }
  __syncthreads();
  const float f0 = st[0], f1v = st[1];
  if (tid < 64)
    t1[tid] = f0 * te1_w[tid * 2] + f1v * te1_w[tid * 2 + 1] + te1_b[tid];
  __syncthreads();
  if (tid == 0) {
    float m = 0.f; for (int i = 0; i < 64; ++i) m += t1[i]; m *= (1.f / 64.f);
    float v = 0.f; for (int i = 0; i < 64; ++i) { float d = t1[i] - m; v += d * d; }
    st[0] = m; st[1] = rsqrtf(v * (1.f / 64.f) + 1e-5f);
  }
  __syncthreads();
  if (tid < 64) {
    float v = (t1[tid] - st[0]) * st[1] * l1g[tid] + l1b[tid];
    t1[tid] = fmaxf(v, 0.f);
  }
  __syncthreads();
  if (tid < 128)
    t2[tid] = dot_ff(t1, te2_w + (size_t)tid * 64, 64) + te2_b[tid];
  __syncthreads();
  if (tid == 0) {
    float m = 0.f; for (int i = 0; i < 128; ++i) m += t2[i]; m *= (1.f / 128.f);
    float v = 0.f; for (int i = 0; i < 128; ++i) { float d = t2[i] - m; v += d * d; }
    st[0] = m; st[1] = rsqrtf(v * (1.f / 128.f) + 1e-5f);
  }
  __syncthreads();
  if (tid < 128) {
    float v = (t2[tid] - st[0]) * st[1] * l2g[tid] + l2b[tid];
    cat[512 + tid] = fmaxf(v, 0.f);
  }
  __syncthreads();
  pre[tid] = dot_ff(cat, c_w + (size_t)tid * 640, 640) + c_b[tid];
  red[tid] = pre[tid];
  __syncthreads();
  for (int s = 128; s > 0; s >>= 1) { if (tid < s) red[tid] += red[tid + s]; __syncthreads(); }
  const float m = red[0] * (1.f / 256.f);
  __syncthreads();
  const float d = pre[tid] - m;
  red[tid] = d * d;
  __syncthreads();
  for (int s = 128; s > 0; s >>= 1) { if (tid < s) red[tid] += red[tid + s]; __syncthreads(); }
  const float rs = rsqrtf(red[0] * (1.f / 256.f) + 1e-5f);
  float v = d * rs * clg[tid] + clb[tid];
  out[(size_t)b * 256 + tid] = fmaxf(v, 0.f);
}

// ---------------------------------------------------------------------------
extern "C" void kernel_launch(void* const* d_in, const int* in_sizes, int n_in,
                              void* d_out, int out_size, void* d_ws, size_t ws_size,
                              hipStream_t stream) {
  (void)in_sizes; (void)n_in; (void)out_size; (void)ws_size;
  const int*   oh     = (const int*)  d_in[0];
  const float* db     = (const float*)d_in[1];
  const float* dsl    = (const float*)d_in[2];
  const float* emb    = (const float*)d_in[3];
  const float* a_in_w = (const float*)d_in[4];
  const float* a_in_b = (const float*)d_in[5];
  const float* a_out_w= (const float*)d_in[6];
  const float* a_out_b= (const float*)d_in[7];
  const float* wih_f  = (const float*)d_in[8];
  const float* whh_f  = (const float*)d_in[9];
  const float* bih_f  = (const float*)d_in[10];
  const float* bhh_f  = (const float*)d_in[11];
  const float* wih_b  = (const float*)d_in[12];
  const float* whh_b  = (const float*)d_in[13];
  const float* bih_b  = (const float*)d_in[14];
  const float* bhh_b  = (const float*)d_in[15];
  const float* t_in_w = (const float*)d_in[16];
  const float* t_in_b = (const float*)d_in[17];
  const float* t_out_w= (const float*)d_in[18];
  const float* t_out_b= (const float*)d_in[19];
  const float* t_ln1g = (const float*)d_in[20];
  const float* t_ln1b = (const float*)d_in[21];
  const float* t_ff1w = (const float*)d_in[22];
  const float* t_ff1b = (const float*)d_in[23];
  const float* t_ff2w = (const float*)d_in[24];
  const float* t_ff2b = (const float*)d_in[25];
  const float* t_ln2g = (const float*)d_in[26];
  const float* t_ln2b = (const float*)d_in[27];
  const float* te1_w  = (const float*)d_in[28];
  const float* te1_b  = (const float*)d_in[29];
  const float* tl1g   = (const float*)d_in[30];
  const float* tl1b   = (const float*)d_in[31];
  const float* te2_w  = (const float*)d_in[32];
  const float* te2_b  = (const float*)d_in[33];
  const float* tl2g   = (const float*)d_in[34];
  const float* tl2b   = (const float*)d_in[35];
  const float* c_w    = (const float*)d_in[36];
  const float* c_b    = (const float*)d_in[37];
  const float* clng   = (const float*)d_in[38];
  const float* clnb   = (const float*)d_in[39];

  float* ws = (float*)d_ws;
  // Workspace (float slots), max index 17,391,616 (~69.6 MB):
  //   A [0,        524288):  oeb bf16 [8192][128]
  //   B [1048576,  5242880): embb bf16 [49689*128] (dead after order_attn)
  //                          -> g fp32 (gru_rec) -> g2 fp32 (ffln, over g)
  //   C [5242880,  9437184): attn fp32; g1 = LN out in-place
  //   D [9437184,  9633792): whhb bf16 [2][768][256]
  //   D2[9633792,  9732096): wihb bf16 [2][768][128]
  //   D3[9732096,  9740288): awb2 bf16 [128*128]
  //   E [10027008,10051584): awb bf16 [384*128]
  //   F [10051584,10444800): twb bf16 [1536*512]
  //   G [10444800,10575872): pwb bf16 [512*512]
  //   G2[10575872,10838016): f1wb bf16 [1024*512]
  //   G3[10838016,11100160): f2wb bf16 [512*1024]
  //   H [11100160,17391616): gi bf16 [8192*1536]
  unsigned short* oeb = (unsigned short*)ws;
  unsigned short* embb= (unsigned short*)(ws + 1048576);
  float* g    = ws + 1048576;
  float* attn = ws + 5242880;
  float* g1   = attn;                                   // in-place
  float* g2   = ws + 1048576;                           // over dead g/embb
  unsigned short* whhb = (unsigned short*)(ws + 9437184);
  unsigned short* wihb = (unsigned short*)(ws + 9633792);
  unsigned short* awb2 = (unsigned short*)(ws + 9732096);
  unsigned short* awb  = (unsigned short*)(ws + 10027008);
  unsigned short* twb  = (unsigned short*)(ws + 10051584);
  unsigned short* pwb  = (unsigned short*)(ws + 10444800);
  unsigned short* f1wb = (unsigned short*)(ws + 10575872);
  unsigned short* f2wb = (unsigned short*)(ws + 10838016);
  unsigned short* gi   = (unsigned short*)(ws + 11100160);

  k_canary<<<256, 256, 0, stream>>>((float*)d_out);
  k_cvt<<<6212, 256, 0, stream>>>(a_in_w, t_in_w, t_out_w, t_ff1w, t_ff2w, a_out_w,
                                  emb, awb, twb, pwb, f1wb, f2wb, awb2, embb);
  k_gru_wb<<<1536, 256, 0, stream>>>(wih_f, whh_f, wih_b, whh_b, whhb, wihb);
  k_order_attn<<<8192, 256, 0, stream>>>(oh, embb, awb, a_in_b, awb2, a_out_b, oeb);
  k_gru_gi<<<256, 256, 0, stream>>>(oeb, wihb, gi);
  k_gru_rec<<<dim3(128, 2), 512, 0, stream>>>(gi, whhb, bih_f, bhh_f, bih_b, bhh_b, g);
  k_mha2f<<<dim3(256, 4), 256, 0, stream>>>(g, twb, t_in_b, attn);
  k_projln_mfma<<<512, 256, 0, stream>>>(attn, pwb, t_out_b, g, t_ln1g, t_ln1b, g1);
  k_ffln<<<512, 256, 0, stream>>>(g1, f1wb, t_ff1b, f2wb, t_ff2b, g1,
                                  t_ln2g, t_ln2b, g2);
  k_final<<<256, 256, 0, stream>>>(g2, db, dsl, te1_w, te1_b, tl1g, tl1b,
                                   te2_w, te2_b, tl2g, tl2b, c_w, c_b, clng, clnb,
                                   (float*)d_out);
}

// Round 5
// 648.032 us; speedup vs baseline: 1.0157x; 1.0157x over previous
//
#include <hip/hip_runtime.h>
#include <hip/hip_bf16.h>
#include <math.h>

typedef __hip_bfloat16 bf16;
typedef __attribute__((ext_vector_type(8))) short short8v;   // 8 bf16 (4 VGPRs)
typedef __attribute__((ext_vector_type(4))) short short4v;   // 4 bf16 (2 VGPRs)
typedef __attribute__((ext_vector_type(4))) float float4v;   // 4 fp32 acc
#define MFMA16 __builtin_amdgcn_mfma_f32_16x16x32_bf16

__device__ __forceinline__ float us2f(unsigned short u) {
  union { unsigned u; float f; } c; c.u = ((unsigned)u) << 16; return c.f;
}
__device__ __forceinline__ unsigned short f2us(float f) {
  return __bfloat16_as_ushort(__float2bfloat16(f));
}

// fp32 x . fp32 w, K % 8 == 0, 16B-aligned
__device__ __forceinline__ float dot_ff(const float* __restrict__ x,
                                        const float* __restrict__ w, int K) {
  const float4* xp = reinterpret_cast<const float4*>(x);
  const float4* wp = reinterpret_cast<const float4*>(w);
  float acc = 0.f;
  const int n = K >> 2;
  for (int i = 0; i < n; ++i) {
    float4 a = xp[i], b = wp[i];
    acc += a.x*b.x + a.y*b.y + a.z*b.z + a.w*b.w;
  }
  return acc;
}

__device__ __forceinline__ float sigm(float x) { return 1.f / (1.f + expf(-x)); }

// ---------------------------------------------------------------------------
__global__ void k_canary(float* __restrict__ out) {
  out[blockIdx.x * 256 + threadIdx.x] = 100.0f;
}

// ---------------------------------------------------------------------------
// One-shot: convert MFMA-consumed weights AND the emb table to bf16 in ws.
// ---------------------------------------------------------------------------
__global__ __launch_bounds__(256) void k_cvt(
    const float* __restrict__ a_in_w, const float* __restrict__ t_in_w,
    const float* __restrict__ t_out_w, const float* __restrict__ t_ff1w,
    const float* __restrict__ t_ff2w, const float* __restrict__ a_out_w,
    const float* __restrict__ emb,
    unsigned short* __restrict__ awb, unsigned short* __restrict__ twb,
    unsigned short* __restrict__ pwb, unsigned short* __restrict__ f1wb,
    unsigned short* __restrict__ f2wb, unsigned short* __restrict__ awb2,
    unsigned short* __restrict__ embb)
{
  int i = blockIdx.x * 256 + threadIdx.x;
  if (i < 1590048) {                                  // embb, 4 elems/thread
    float4 e4 = *reinterpret_cast<const float4*>(emb + (size_t)i * 4);
    short4v s; s[0] = f2us(e4.x); s[1] = f2us(e4.y); s[2] = f2us(e4.z); s[3] = f2us(e4.w);
    *reinterpret_cast<short4v*>(embb + (size_t)i * 4) = s;
  }
  if (i < 49152)  awb[i] = f2us(a_in_w[i]);
  if (i < 786432) twb[i] = f2us(t_in_w[i]);
  if (i < 262144) pwb[i] = f2us(t_out_w[i]);
  if (i < 524288) f1wb[i] = f2us(t_ff1w[i]);
  if (i < 524288) f2wb[i] = f2us(t_ff2w[i]);
  if (i < 16384)  awb2[i] = f2us(a_out_w[i]);
}

// ---------------------------------------------------------------------------
// GRU weight prep: row-major bf16 copies. whhb [dir][768][256],
// wihb [dir][768][128] (for gi GEMM).
// ---------------------------------------------------------------------------
__global__ __launch_bounds__(256) void k_gru_wb(
    const float* __restrict__ wih_f, const float* __restrict__ whh_f,
    const float* __restrict__ wih_b, const float* __restrict__ whh_b,
    unsigned short* __restrict__ whhb, unsigned short* __restrict__ wihb)
{
  int i = blockIdx.x * 256 + threadIdx.x;   // < 393216
  if (i >= 393216) return;
  int dir = i / 196608, r = i % 196608;
  whhb[i] = f2us((dir ? whh_b : whh_f)[r]);
  if (r < 98304) wihb[dir * 98304 + r] = f2us((dir ? wih_b : wih_f)[r]);
}

// ---------------------------------------------------------------------------
// Stage 1: embed + per-order MHA + proj-then-mean. A-fragments loaded
// DIRECTLY from the bf16 emb table (per-lane data, no LDS staging, no
// gather barrier). QKV MFMA -> fused scores/softmax/PV (wave = head,
// barrier-free) -> out-proj MFMA + shfl mean. 2 barriers total.
// LDS: pb 8192 + qb 8704 (O overlay) + kb 8704 + vT 10240 = 35,840 B
// -> 4 blocks/CU.
// ---------------------------------------------------------------------------
__global__ __launch_bounds__(256, 4) void k_order_attn(
    const int* __restrict__ oh, const unsigned short* __restrict__ embb,
    const unsigned short* __restrict__ awb, const float* __restrict__ in_b,
    const unsigned short* __restrict__ awb2, const float* __restrict__ out_b,
    unsigned short* __restrict__ oeb)
{
  const int bo = blockIdx.x;            // 0..8191
  const int tid = threadIdx.x;
  __shared__ alignas(16) unsigned short pb[128 * 32];     // P bf16
  __shared__ alignas(16) unsigned short qb[32 * 136];     // q bf16; O overlays
  __shared__ alignas(16) unsigned short kb[32 * 136];
  __shared__ alignas(16) unsigned short vT[128 * 40];     // V^T bf16: vT[d][k]
  unsigned short* ob = qb;                                // O overlay

  const int lane = tid & 63, wave = tid >> 6;
  const int l15 = lane & 15, quad = lane >> 4;

  // per-lane token ids for rows l15 and 16+l15; direct global A-frag loads
  const int id0 = oh[bo * 32 + l15];
  const int id1 = oh[bo * 32 + 16 + l15];
  short8v af[2][4];
#pragma unroll
  for (int kc = 0; kc < 4; ++kc) {
    af[0][kc] = *reinterpret_cast<const short8v*>(
        embb + (size_t)id0 * 128 + kc * 32 + quad * 8);
    af[1][kc] = *reinterpret_cast<const short8v*>(
        embb + (size_t)id1 * 128 + kc * 32 + quad * 8);
  }
  // ---- QKV MFMA: qkv[t][j] = x[t][.] . w[j][.] ----
  for (int ni = 0; ni < 6; ++ni) {
    const int j = (wave + ni * 4) * 16 + l15;
    const unsigned short* wrow = awb + (size_t)j * 128;
    float4v acc0 = {0.f, 0.f, 0.f, 0.f}, acc1 = {0.f, 0.f, 0.f, 0.f};
#pragma unroll
    for (int kc = 0; kc < 4; ++kc) {
      short8v bfr = *reinterpret_cast<const short8v*>(wrow + kc * 32 + quad * 8);
      acc0 = MFMA16(af[0][kc], bfr, acc0, 0, 0, 0);
      acc1 = MFMA16(af[1][kc], bfr, acc1, 0, 0, 0);
    }
    const float bj = in_b[j];
    const int jj = j & 127;
    if (j < 256) {
      unsigned short* dst = (j < 128) ? qb : kb;
#pragma unroll
      for (int r = 0; r < 4; ++r) {
        int t0 = quad * 4 + r;
        dst[t0 * 136 + jj] = f2us(acc0[r] + bj);
        dst[(t0 + 16) * 136 + jj] = f2us(acc1[r] + bj);
      }
    } else {                                              // V transposed: vT[d][k]
      short4v s0, s1;
#pragma unroll
      for (int r = 0; r < 4; ++r) { s0[r] = f2us(acc0[r] + bj); s1[r] = f2us(acc1[r] + bj); }
      *reinterpret_cast<short4v*>(vT + jj * 40 + quad * 4) = s0;
      *reinterpret_cast<short4v*>(vT + jj * 40 + 16 + quad * 4) = s1;
    }
  }
  __syncthreads();
  // ---- FUSED: scores + softmax + PV + O write (wave = head h) ----
  {
    const int h = wave;
    const float scale1 = 0.17677669529663687f;            // 1/sqrt(32)
    short8v qf[2], kf[2];
#pragma unroll
    for (int mt = 0; mt < 2; ++mt)
      qf[mt] = *reinterpret_cast<const short8v*>(qb + (mt * 16 + l15) * 136 + h * 32 + quad * 8);
#pragma unroll
    for (int nt = 0; nt < 2; ++nt)
      kf[nt] = *reinterpret_cast<const short8v*>(kb + (nt * 16 + l15) * 136 + h * 32 + quad * 8);
    float4v sacc[2][2];
#pragma unroll
    for (int mt = 0; mt < 2; ++mt)
#pragma unroll
      for (int nt = 0; nt < 2; ++nt) {
        sacc[mt][nt] = (float4v){0.f, 0.f, 0.f, 0.f};
        sacc[mt][nt] = MFMA16(qf[mt], kf[nt], sacc[mt][nt], 0, 0, 0);
      }
    float inv_reg[2][4];
#pragma unroll
    for (int mt = 0; mt < 2; ++mt)
#pragma unroll
      for (int r = 0; r < 4; ++r) {
        float s0 = sacc[mt][0][r] * scale1;
        float s1 = sacc[mt][1][r] * scale1;
        float mx = fmaxf(s0, s1);
        mx = fmaxf(mx, __shfl_xor(mx, 1));
        mx = fmaxf(mx, __shfl_xor(mx, 2));
        mx = fmaxf(mx, __shfl_xor(mx, 4));
        mx = fmaxf(mx, __shfl_xor(mx, 8));
        float e0 = expf(s0 - mx), e1 = expf(s1 - mx);
        float sm = e0 + e1;
        sm += __shfl_xor(sm, 1);
        sm += __shfl_xor(sm, 2);
        sm += __shfl_xor(sm, 4);
        sm += __shfl_xor(sm, 8);
        inv_reg[mt][r] = 1.f / sm;
        int row = h * 32 + mt * 16 + quad * 4 + r;
        pb[row * 32 + l15] = f2us(e0);
        pb[row * 32 + 16 + l15] = f2us(e1);
      }
    // PV (reads only this wave's P rows / vT stripe -> no barrier needed)
    short8v pf[2], vf[2];
#pragma unroll
    for (int mt = 0; mt < 2; ++mt)
      pf[mt] = *reinterpret_cast<const short8v*>(pb + (h * 32 + mt * 16 + l15) * 32 + quad * 8);
#pragma unroll
    for (int nt = 0; nt < 2; ++nt)
      vf[nt] = *reinterpret_cast<const short8v*>(vT + (h * 32 + nt * 16 + l15) * 40 + quad * 8);
    float4v oacc[2][2];
#pragma unroll
    for (int mt = 0; mt < 2; ++mt)
#pragma unroll
      for (int nt = 0; nt < 2; ++nt) {
        oacc[mt][nt] = (float4v){0.f, 0.f, 0.f, 0.f};
        oacc[mt][nt] = MFMA16(pf[mt], vf[nt], oacc[mt][nt], 0, 0, 0);
      }
    // write O bf16 into ob (qb overlay): only this wave's head-col stripe
#pragma unroll
    for (int mt = 0; mt < 2; ++mt)
#pragma unroll
      for (int r = 0; r < 4; ++r) {
        int t = mt * 16 + quad * 4 + r;
        float inv = inv_reg[mt][r];
#pragma unroll
        for (int nt = 0; nt < 2; ++nt)
          ob[t * 136 + h * 32 + nt * 16 + l15] = f2us(oacc[mt][nt][r] * inv);
      }
  }
  __syncthreads();
  // ---- out-proj MFMA: proj[t][j] = O[t][.] . W[j][.]; then mean over t ----
  {
    float4v acc[2][2];
#pragma unroll
    for (int mt = 0; mt < 2; ++mt)
#pragma unroll
      for (int nt = 0; nt < 2; ++nt) acc[mt][nt] = (float4v){0.f, 0.f, 0.f, 0.f};
#pragma unroll
    for (int kc = 0; kc < 4; ++kc) {
      short8v af0 = *reinterpret_cast<const short8v*>(ob + l15 * 136 + kc * 32 + quad * 8);
      short8v af1 = *reinterpret_cast<const short8v*>(ob + (16 + l15) * 136 + kc * 32 + quad * 8);
#pragma unroll
      for (int nt = 0; nt < 2; ++nt) {
        int j = (wave * 2 + nt) * 16 + l15;
        short8v bfr = *reinterpret_cast<const short8v*>(awb2 + (size_t)j * 128 + kc * 32 + quad * 8);
        acc[0][nt] = MFMA16(af0, bfr, acc[0][nt], 0, 0, 0);
        acc[1][nt] = MFMA16(af1, bfr, acc[1][nt], 0, 0, 0);
      }
    }
#pragma unroll
    for (int nt = 0; nt < 2; ++nt) {
      float part = 0.f;
#pragma unroll
      for (int mt = 0; mt < 2; ++mt)
#pragma unroll
        for (int r = 0; r < 4; ++r) part += acc[mt][nt][r];
      part += __shfl_xor(part, 16);
      part += __shfl_xor(part, 32);
      if (quad == 0) {
        int j = (wave * 2 + nt) * 16 + l15;
        oeb[(size_t)bo * 128 + j] = f2us(part * (1.f / 32.f) + out_b[j]);
      }
    }
  }
}

// ---------------------------------------------------------------------------
// gi GEMM (MFMA): gi[8192][1536] bf16 = oe @ wih^T (both dirs). oe is bf16.
// ---------------------------------------------------------------------------
__global__ __launch_bounds__(256, 2) void k_gru_gi(
    const unsigned short* __restrict__ oeb, const unsigned short* __restrict__ wihb,
    unsigned short* __restrict__ gi)
{
  const int row0 = blockIdx.x * 32, tid = threadIdx.x;
  __shared__ alignas(16) unsigned short xs[32 * 136];
  for (int i = tid; i < 512; i += 256) {
    int t = i >> 4, c8 = (i & 15) << 3;
    *reinterpret_cast<short8v*>(xs + t * 136 + c8) =
        *reinterpret_cast<const short8v*>(oeb + (size_t)(row0 + t) * 128 + c8);
  }
  __syncthreads();
  const int lane = tid & 63, wave = tid >> 6;
  const int l15 = lane & 15, quad = lane >> 4;
  short8v af[2][4];
#pragma unroll
  for (int mt = 0; mt < 2; ++mt)
#pragma unroll
    for (int kc = 0; kc < 4; ++kc)
      af[mt][kc] = *reinterpret_cast<const short8v*>(
          xs + (mt * 16 + l15) * 136 + kc * 32 + quad * 8);
  for (int ni = 0; ni < 24; ++ni) {
    int col = (wave + ni * 4) * 16 + l15;
    const unsigned short* wrow = wihb + (size_t)col * 128;
    float4v a0 = {0.f,0.f,0.f,0.f}, a1 = {0.f,0.f,0.f,0.f};
#pragma unroll
    for (int kc = 0; kc < 4; ++kc) {
      short8v bfr = *reinterpret_cast<const short8v*>(wrow + kc * 32 + quad * 8);
      a0 = MFMA16(af[0][kc], bfr, a0, 0, 0, 0);
      a1 = MFMA16(af[1][kc], bfr, a1, 0, 0, 0);
    }
#pragma unroll
    for (int r = 0; r < 4; ++r) {
      gi[(size_t)(row0 + quad * 4 + r) * 1536 + col] = f2us(a0[r]);
      gi[(size_t)(row0 + quad * 4 + r + 16) * 1536 + col] = f2us(a1[r]);
    }
  }
}

// ---------------------------------------------------------------------------
// GRU recurrence via MFMA. 2 batches/block, grid (128,2) = 256 blocks,
// 512 threads (8 waves). whh register-resident. gi for step s+1 prefetched
// into registers before the barrier. LDS: hb 8448 + pg 6176 = 14,624 B.
// ---------------------------------------------------------------------------
__global__ __launch_bounds__(512, 2) void k_gru_rec(
    const unsigned short* __restrict__ gi, const unsigned short* __restrict__ whhb,
    const float* __restrict__ bih_f, const float* __restrict__ bhh_f,
    const float* __restrict__ bih_b, const float* __restrict__ bhh_b,
    float* __restrict__ g)
{
  const int b0 = blockIdx.x * 2, dir = blockIdx.y;
  const int tid = threadIdx.x;           // 0..511
  const unsigned short* wb = whhb + (size_t)dir * 196608;   // [768][256] bf16
  const float* bih = dir ? bih_b : bih_f;
  const float* bhh = dir ? bhh_b : bhh_f;
  __shared__ alignas(16) unsigned short hb[16 * 264];   // h bf16 (A operand)
  __shared__ float pg[2 * 772];                         // gh fp32 (rows 0-1)
  const int lane = tid & 63, wave = tid >> 6;
  const int l15 = lane & 15, quad = lane >> 4;
  const int j = tid & 255, mb = tid >> 8;               // pointwise: (m=mb, j)
  const float bir = bih[j], biz = bih[256 + j], bin_ = bih[512 + j];
  const float bhr = bhh[j], bhz = bhh[256 + j], bhn  = bhh[512 + j];
  short8v wf[6][8];
  int cols[6];
#pragma unroll
  for (int ni = 0; ni < 6; ++ni) {
    cols[ni] = (wave + ni * 8) * 16 + l15;
#pragma unroll
    for (int kc = 0; kc < 8; ++kc)
      wf[ni][kc] = *reinterpret_cast<const short8v*>(
          wb + (size_t)cols[ni] * 256 + kc * 32 + quad * 8);
  }
  for (int i = tid; i < 16 * 264; i += 512) hb[i] = 0;
  int tcur = dir ? 31 : 0;
  size_t gbase = ((size_t)(b0 + mb) * 32 + tcur) * 1536 + dir * 768;
  float gr = us2f(gi[gbase + j]);
  float gz = us2f(gi[gbase + 256 + j]);
  float gn = us2f(gi[gbase + 512 + j]);
  __syncthreads();
  for (int s = 0; s < 32; ++s) {
    float4v acc[6];
#pragma unroll
    for (int ni = 0; ni < 6; ++ni) acc[ni] = (float4v){0.f, 0.f, 0.f, 0.f};
#pragma unroll
    for (int kc = 0; kc < 8; ++kc) {
      short8v af = *reinterpret_cast<const short8v*>(hb + l15 * 264 + kc * 32 + quad * 8);
#pragma unroll
      for (int ni = 0; ni < 6; ++ni)
        acc[ni] = MFMA16(af, wf[ni][kc], acc[ni], 0, 0, 0);
    }
    if (quad == 0) {
#pragma unroll
      for (int ni = 0; ni < 6; ++ni) {
        pg[cols[ni]] = acc[ni][0];
        pg[772 + cols[ni]] = acc[ni][1];
      }
    }
    float gr2 = 0.f, gz2 = 0.f, gn2 = 0.f;
    if (s < 31) {
      int t2 = dir ? (30 - s) : (s + 1);
      size_t gb2 = ((size_t)(b0 + mb) * 32 + t2) * 1536 + dir * 768;
      gr2 = us2f(gi[gb2 + j]);
      gz2 = us2f(gi[gb2 + 256 + j]);
      gn2 = us2f(gi[gb2 + 512 + j]);
    }
    __syncthreads();
    {
      const int tt = dir ? (31 - s) : s;
      float hprev = us2f(hb[mb * 264 + j]);
      float r = sigm(gr + bir + pg[mb * 772 + j] + bhr);
      float z = sigm(gz + biz + pg[mb * 772 + 256 + j] + bhz);
      float n = tanhf(gn + bin_ + r * (pg[mb * 772 + 512 + j] + bhn));
      float nh = (1.f - z) * n + z * hprev;
      hb[mb * 264 + j] = f2us(nh);
      g[((size_t)(b0 + mb) * 32 + tt) * 512 + dir * 256 + j] = nh;
    }
    gr = gr2; gz = gz2; gn = gn2;
    __syncthreads();
  }
}

// ---------------------------------------------------------------------------
// Stage 3 fused attention, one block per (b, head). x staged in K=256
// halves -> LDS 44,544 B -> 3 blocks/CU. QKV/scores/PV on MFMA.
// ---------------------------------------------------------------------------
#define XS2_STR 264

__global__ __launch_bounds__(256, 3) void k_mha2f(
    const float* __restrict__ g, const unsigned short* __restrict__ twb,
    const float* __restrict__ Bv, float* __restrict__ attn)
{
  const int b = blockIdx.x, h = blockIdx.y, tid = threadIdx.x;
  __shared__ alignas(16) unsigned short xs2[32 * XS2_STR]; // x half; sc+pb overlay
  __shared__ alignas(16) unsigned short qk[2 * 32 * 136];
  __shared__ alignas(16) unsigned short vT[128 * 40];      // vT[d][k]
  unsigned short* qs = qk;
  unsigned short* ks = qk + 32 * 136;
  float* sc = reinterpret_cast<float*>(xs2);               // [32][33]; col 32 = 1/sum
  unsigned short* pb = xs2 + 2112;                         // P bf16 [32][32]
  const int lane = tid & 63, wave = tid >> 6;
  const int l15 = lane & 15, quad = lane >> 4;

  int wrowi[6];
#pragma unroll
  for (int ni = 0; ni < 6; ++ni) {
    int idx = (wave + ni * 4) * 16 + l15;
    int m = idx >> 7, dd = idx & 127;
    wrowi[ni] = m * 512 + h * 128 + dd;
  }
  float4v acc[6][2];
#pragma unroll
  for (int ni = 0; ni < 6; ++ni)
#pragma unroll
    for (int mt = 0; mt < 2; ++mt) acc[ni][mt] = (float4v){0.f, 0.f, 0.f, 0.f};

  for (int half = 0; half < 2; ++half) {
    __syncthreads();
    for (int i = tid; i < 2048; i += 256) {
      int t = i >> 6, c4 = (i & 63) << 2;
      float4 e4 = *reinterpret_cast<const float4*>(
          g + (size_t)b * 16384 + t * 512 + half * 256 + c4);
      short4v s; s[0] = f2us(e4.x); s[1] = f2us(e4.y); s[2] = f2us(e4.z); s[3] = f2us(e4.w);
      *reinterpret_cast<short4v*>(xs2 + t * XS2_STR + c4) = s;
    }
    __syncthreads();
    for (int kl = 0; kl < 2; ++kl) {
      const int kg = half * 2 + kl;
      short8v af[2][4];
#pragma unroll
      for (int mt = 0; mt < 2; ++mt)
#pragma unroll
        for (int u = 0; u < 4; ++u)
          af[mt][u] = *reinterpret_cast<const short8v*>(
              xs2 + (mt * 16 + l15) * XS2_STR + kl * 128 + u * 32 + quad * 8);
#pragma unroll
      for (int ni = 0; ni < 6; ++ni) {
        const unsigned short* wrow = twb + (size_t)wrowi[ni] * 512 + kg * 128;
#pragma unroll
        for (int u = 0; u < 4; ++u) {
          short8v bfr = *reinterpret_cast<const short8v*>(wrow + u * 32 + quad * 8);
          acc[ni][0] = MFMA16(af[0][u], bfr, acc[ni][0], 0, 0, 0);
          acc[ni][1] = MFMA16(af[1][u], bfr, acc[ni][1], 0, 0, 0);
        }
      }
    }
  }
#pragma unroll
  for (int ni = 0; ni < 6; ++ni) {
    int idx = (wave + ni * 4) * 16 + l15;
    int m = idx >> 7, dd = idx & 127;
    float bj = Bv[wrowi[ni]];
    if (m < 2) {
      unsigned short* dst = (m == 0) ? qs : ks;
#pragma unroll
      for (int r = 0; r < 4; ++r) {
        int t0 = quad * 4 + r;
        dst[t0 * 136 + dd] = f2us(acc[ni][0][r] + bj);
        dst[(t0 + 16) * 136 + dd] = f2us(acc[ni][1][r] + bj);
      }
    } else {
      short4v s0, s1;
#pragma unroll
      for (int r = 0; r < 4; ++r) { s0[r] = f2us(acc[ni][0][r] + bj); s1[r] = f2us(acc[ni][1][r] + bj); }
      *reinterpret_cast<short4v*>(vT + dd * 40 + quad * 4) = s0;
      *reinterpret_cast<short4v*>(vT + dd * 40 + 16 + quad * 4) = s1;
    }
  }
  __syncthreads();
  // ---- scores MFMA ----
  {
    const float scale2 = 0.08838834764831845f;            // 1/sqrt(128)
    const int mt = wave >> 1, nt = wave & 1;
    float4v a = {0.f, 0.f, 0.f, 0.f};
#pragma unroll
    for (int kc = 0; kc < 4; ++kc) {
      short8v qf = *reinterpret_cast<const short8v*>(qs + (mt * 16 + l15) * 136 + kc * 32 + quad * 8);
      short8v kf = *reinterpret_cast<const short8v*>(ks + (nt * 16 + l15) * 136 + kc * 32 + quad * 8);
      a = MFMA16(qf, kf, a, 0, 0, 0);
    }
#pragma unroll
    for (int r = 0; r < 4; ++r)
      sc[(mt * 16 + quad * 4 + r) * 33 + nt * 16 + l15] = a[r] * scale2;
  }
  __syncthreads();
  // ---- softmax rows: 4 lanes/row, shfl-reduce; bf16 unnormalized P ----
  if (tid < 128) {
    int row = tid >> 2, seg = tid & 3;
    float* srow = sc + row * 33;
    float mx = srow[seg * 8];
#pragma unroll
    for (int c = 1; c < 8; ++c) mx = fmaxf(mx, srow[seg * 8 + c]);
    mx = fmaxf(mx, __shfl_xor(mx, 1));
    mx = fmaxf(mx, __shfl_xor(mx, 2));
    float s = 0.f;
    short8v pv;
#pragma unroll
    for (int c = 0; c < 8; ++c) {
      float e = expf(srow[seg * 8 + c] - mx);
      s += e; pv[c] = f2us(e);
    }
    *reinterpret_cast<short8v*>(pb + row * 32 + seg * 8) = pv;
    s += __shfl_xor(s, 1);
    s += __shfl_xor(s, 2);
    if (seg == 0) srow[32] = 1.f / s;
  }
  __syncthreads();
  // ---- PV MFMA ----
  {
    short8v pf[2], vf[2];
#pragma unroll
    for (int mt = 0; mt < 2; ++mt)
      pf[mt] = *reinterpret_cast<const short8v*>(pb + (mt * 16 + l15) * 32 + quad * 8);
#pragma unroll
    for (int ntl = 0; ntl < 2; ++ntl)
      vf[ntl] = *reinterpret_cast<const short8v*>(vT + ((2 * wave + ntl) * 16 + l15) * 40 + quad * 8);
    float4v oacc[2][2];
#pragma unroll
    for (int mt = 0; mt < 2; ++mt)
#pragma unroll
      for (int ntl = 0; ntl < 2; ++ntl) {
        oacc[mt][ntl] = (float4v){0.f, 0.f, 0.f, 0.f};
        oacc[mt][ntl] = MFMA16(pf[mt], vf[ntl], oacc[mt][ntl], 0, 0, 0);
      }
#pragma unroll
    for (int mt = 0; mt < 2; ++mt)
#pragma unroll
      for (int r = 0; r < 4; ++r) {
        int q = mt * 16 + quad * 4 + r;
        float inv = sc[q * 33 + 32];
#pragma unroll
        for (int ntl = 0; ntl < 2; ++ntl)
          attn[((size_t)b * 32 + q) * 512 + h * 128 + (2 * wave + ntl) * 16 + l15] =
              oacc[mt][ntl][r] * inv;
      }
  }
}

// ---------------------------------------------------------------------------
// proj GEMM via MFMA (M=16/block, N=512, K=512) + bias + residual + LN.
// ---------------------------------------------------------------------------
__global__ __launch_bounds__(256, 2) void k_projln_mfma(
    const float* __restrict__ X, const unsigned short* __restrict__ Wb,
    const float* __restrict__ bias, const float* __restrict__ res,
    const float* __restrict__ gam, const float* __restrict__ bet,
    float* __restrict__ Y)
{
  const int row0 = blockIdx.x * 16, tid = threadIdx.x;
  __shared__ alignas(16) unsigned short xs[16 * 520];
  __shared__ float ys[16 * 516];
  for (int i = tid; i < 16 * 512; i += 256) {
    int t = i >> 9, c = i & 511;
    xs[t * 520 + c] = f2us(X[(size_t)(row0 + t) * 512 + c]);
  }
  __syncthreads();
  {
    const int lane = tid & 63, wave = tid >> 6;
    const int l15 = lane & 15, quad = lane >> 4;
    short8v af[16];
#pragma unroll
    for (int kc = 0; kc < 16; ++kc)
      af[kc] = *reinterpret_cast<const short8v*>(xs + l15 * 520 + kc * 32 + quad * 8);
    for (int ni = 0; ni < 8; ++ni) {
      int col = (wave + ni * 4) * 16 + l15;
      const unsigned short* wrow = Wb + (size_t)col * 512;
      float4v acc = {0.f,0.f,0.f,0.f};
#pragma unroll
      for (int kc = 0; kc < 16; ++kc) {
        short8v bfr = *reinterpret_cast<const short8v*>(wrow + kc * 32 + quad * 8);
        acc = MFMA16(af[kc], bfr, acc, 0, 0, 0);
      }
      float bj = bias[col];
#pragma unroll
      for (int r = 0; r < 4; ++r)
        ys[(quad * 4 + r) * 516 + col] = acc[r] + bj;
    }
  }
  __syncthreads();
  for (int i = tid; i < 16 * 512; i += 256) {
    int t = i >> 9, c = i & 511;
    ys[t * 516 + c] += res[(size_t)(row0 + t) * 512 + c];
  }
  __syncthreads();
  {
    int row = tid >> 4, l16 = tid & 15;
    const float* yr = ys + row * 516;
    float part = 0.f;
#pragma unroll
    for (int k = 0; k < 32; ++k) part += yr[l16 + 16 * k];
#pragma unroll
    for (int off = 8; off; off >>= 1) part += __shfl_xor(part, off, 16);
    float mean = part * (1.f / 512.f);
    float var = 0.f;
#pragma unroll
    for (int k = 0; k < 32; ++k) { float d = yr[l16 + 16 * k] - mean; var += d * d; }
#pragma unroll
    for (int off = 8; off; off >>= 1) var += __shfl_xor(var, off, 16);
    float rs = rsqrtf(var * (1.f / 512.f) + 1e-5f);
    for (int k = 0; k < 32; ++k) {
      int c = l16 + 16 * k;
      Y[(size_t)(row0 + row) * 512 + c] = (yr[c] - mean) * rs * gam[c] + bet[c];
    }
  }
}

// ---------------------------------------------------------------------------
// FUSED ff1+relu+ff2+residual+LN (M=16/block), register-pressure-managed:
// ff2 holds only acc2[8] and reloads the A-frag per k-chunk from LDS.
// Y written in-place over X/res (rows are block-private; reads precede
// writes). LDS: xs 16,640 + f1L 33,024 = 49,664 B -> 3 blocks/CU.
// ---------------------------------------------------------------------------
__global__ __launch_bounds__(256, 2) void k_ffln(
    const float* __restrict__ X, const unsigned short* __restrict__ W1,
    const float* __restrict__ b1, const unsigned short* __restrict__ W2,
    const float* __restrict__ b2, const float* __restrict__ res,
    const float* __restrict__ gam, const float* __restrict__ bet,
    float* __restrict__ Y)
{
  const int row0 = blockIdx.x * 16, tid = threadIdx.x;
  __shared__ alignas(16) unsigned short xs[16 * 520];
  __shared__ alignas(16) unsigned short f1L[16 * 1032];   // ys [16][516] fp32 overlays
  float* ys = reinterpret_cast<float*>(f1L);
  const int lane = tid & 63, wave = tid >> 6;
  const int l15 = lane & 15, quad = lane >> 4;
  for (int i = tid; i < 16 * 512; i += 256) {
    int t = i >> 9, c = i & 511;
    xs[t * 520 + c] = f2us(X[(size_t)(row0 + t) * 512 + c]);
  }
  __syncthreads();
  // ff1: N=1024, K=512 -> relu -> f1L bf16 (reload A per kc: low pressure)
  for (int ni = 0; ni < 16; ++ni) {
    int col = (wave + ni * 4) * 16 + l15;
    const unsigned short* wrow = W1 + (size_t)col * 512;
    float4v acc = {0.f,0.f,0.f,0.f};
#pragma unroll
    for (int kc = 0; kc < 16; ++kc) {
      short8v a = *reinterpret_cast<const short8v*>(xs + l15 * 520 + kc * 32 + quad * 8);
      short8v bfr = *reinterpret_cast<const short8v*>(wrow + kc * 32 + quad * 8);
      acc = MFMA16(a, bfr, acc, 0, 0, 0);
    }
    float bj = b1[col];
#pragma unroll
    for (int r = 0; r < 4; ++r)
      f1L[(quad * 4 + r) * 1032 + col] = f2us(fmaxf(acc[r] + bj, 0.f));
  }
  __syncthreads();
  // ff2: N=512, K=1024 from f1L; hold acc2[8] only, reload A per kc
  float4v acc2[8];
#pragma unroll
  for (int ni = 0; ni < 8; ++ni) acc2[ni] = (float4v){0.f,0.f,0.f,0.f};
  int cols2[8];
#pragma unroll
  for (int ni = 0; ni < 8; ++ni) cols2[ni] = (wave + ni * 4) * 16 + l15;
  for (int half = 0; half < 2; ++half) {
    for (int kc = 0; kc < 16; ++kc) {
      short8v a = *reinterpret_cast<const short8v*>(
          f1L + l15 * 1032 + half * 512 + kc * 32 + quad * 8);
#pragma unroll
      for (int ni = 0; ni < 8; ++ni) {
        short8v bfr = *reinterpret_cast<const short8v*>(
            W2 + (size_t)cols2[ni] * 1024 + half * 512 + kc * 32 + quad * 8);
        acc2[ni] = MFMA16(a, bfr, acc2[ni], 0, 0, 0);
      }
    }
  }
  __syncthreads();                                        // f1L dead -> ys
  for (int ni = 0; ni < 8; ++ni) {
    int col = cols2[ni];
    float bj = b2[col];
#pragma unroll
    for (int r = 0; r < 4; ++r)
      ys[(quad * 4 + r) * 516 + col] = acc2[ni][r] + bj;
  }
  __syncthreads();
  for (int i = tid; i < 16 * 512; i += 256) {
    int t = i >> 9, c = i & 511;
    ys[t * 516 + c] += res[(size_t)(row0 + t) * 512 + c];
  }
  __syncthreads();
  {
    int row = tid >> 4, l16 = tid & 15;
    const float* yr = ys + row * 516;
    float part = 0.f;
#pragma unroll
    for (int k = 0; k < 32; ++k) part += yr[l16 + 16 * k];
#pragma unroll
    for (int off = 8; off; off >>= 1) part += __shfl_xor(part, off, 16);
    float mean = part * (1.f / 512.f);
    float var = 0.f;
#pragma unroll
    for (int k = 0; k < 32; ++k) { float d = yr[l16 + 16 * k] - mean; var += d * d; }
#pragma unroll
    for (int off = 8; off; off >>= 1) var += __shfl_xor(var, off, 16);
    float rs = rsqrtf(var * (1.f / 512.f) + 1e-5f);
    for (int k = 0; k < 32; ++k) {
      int c = l16 + 16 * k;
      Y[(size_t)(row0 + row) * 512 + c] = (yr[c] - mean) * rs * gam[c] + bet[c];
    }
  }
}

// ---------------------------------------------------------------------------
// Final: mean-pool, temporal MLP, concat, classifier, LN, relu -> fp32
// ---------------------------------------------------------------------------
__global__ __launch_bounds__(256) void k_final(
    const float* __restrict__ g2,
    const float* __restrict__ db, const float* __restrict__ dsl,
    const float* __restrict__ te1_w, const float* __restrict__ te1_b,
    const float* __restrict__ l1g, const float* __restrict__ l1b,
    const float* __restrict__ te2_w, const float* __restrict__ te2_b,
    const float* __restrict__ l2g, const float* __restrict__ l2b,
    const float* __restrict__ c_w, const float* __restrict__ c_b,
    const float* __restrict__ clg, const float* __restrict__ clb,
    float* __restrict__ out)
{
  const int b = blockIdx.x, tid = threadIdx.x;
  __shared__ float cat[640];
  __shared__ float t1[64];
  __shared__ float t2[128];
  __shared__ float pre[256];
  __shared__ float red[256];
  __shared__ float st[2];
  for (int i = tid; i < 512; i += 256) {
    float acc = 0.f;
#pragma unroll
    for (int t = 0; t < 32; ++t) acc += g2[((size_t)b * 32 + t) * 512 + i];
    cat[i] = acc * (1.f / 32.f);
  }
  if (tid == 0) {
    float s = 0.f;
    for (int i = 0; i < 31; ++i) s += db[b * 31 + i];
    st[0] = s / 31.f;
    st[1] = dsl[b];
  }
  __syncthreads();
  const float f0 = st[0], f1v = st[1];
  if (tid < 64)
    t1[tid] = f0 * te1_w[tid * 2] + f1v * te1_w[tid * 2 + 1] + te1_b[tid];
  __syncthreads();
  if (tid == 0) {
    float m = 0.f; for (int i = 0; i < 64; ++i) m += t1[i]; m *= (1.f / 64.f);
    float v = 0.f; for (int i = 0; i < 64; ++i) { float d = t1[i] - m; v += d * d; }
    st[0] = m; st[1] = rsqrtf(v * (1.f / 64.f) + 1e-5f);
  }
  __syncthreads();
  if (tid < 64) {
    float v = (t1[tid] - st[0]) * st[1] * l1g[tid] + l1b[tid];
    t1[tid] = fmaxf(v, 0.f);
  }
  __syncthreads();
  if (tid < 128)
    t2[tid] = dot_ff(t1, te2_w + (size_t)tid * 64, 64) + te2_b[tid];
  __syncthreads();
  if (tid == 0) {
    float m = 0.f; for (int i = 0; i < 128; ++i) m += t2[i]; m *= (1.f / 128.f);
    float v = 0.f; for (int i = 0; i < 128; ++i) { float d = t2[i] - m; v += d * d; }
    st[0] = m; st[1] = rsqrtf(v * (1.f / 128.f) + 1e-5f);
  }
  __syncthreads();
  if (tid < 128) {
    float v = (t2[tid] - st[0]) * st[1] * l2g[tid] + l2b[tid];
    cat[512 + tid] = fmaxf(v, 0.f);
  }
  __syncthreads();
  pre[tid] = dot_ff(cat, c_w + (size_t)tid * 640, 640) + c_b[tid];
  red[tid] = pre[tid];
  __syncthreads();
  for (int s = 128; s > 0; s >>= 1) { if (tid < s) red[tid] += red[tid + s]; __syncthreads(); }
  const float m = red[0] * (1.f / 256.f);
  __syncthreads();
  const float d = pre[tid] - m;
  red[tid] = d * d;
  __syncthreads();
  for (int s = 128; s > 0; s >>= 1) { if (tid < s) red[tid] += red[tid + s]; __syncthreads(); }
  const float rs = rsqrtf(red[0] * (1.f / 256.f) + 1e-5f);
  float v = d * rs * clg[tid] + clb[tid];
  out[(size_t)b * 256 + tid] = fmaxf(v, 0.f);
}

// ---------------------------------------------------------------------------
extern "C" void kernel_launch(void* const* d_in, const int* in_sizes, int n_in,
                              void* d_out, int out_size, void* d_ws, size_t ws_size,
                              hipStream_t stream) {
  (void)in_sizes; (void)n_in; (void)out_size; (void)ws_size;
  const int*   oh     = (const int*)  d_in[0];
  const float* db     = (const float*)d_in[1];
  const float* dsl    = (const float*)d_in[2];
  const float* emb    = (const float*)d_in[3];
  const float* a_in_w = (const float*)d_in[4];
  const float* a_in_b = (const float*)d_in[5];
  const float* a_out_w= (const float*)d_in[6];
  const float* a_out_b= (const float*)d_in[7];
  const float* wih_f  = (const float*)d_in[8];
  const float* whh_f  = (const float*)d_in[9];
  const float* bih_f  = (const float*)d_in[10];
  const float* bhh_f  = (const float*)d_in[11];
  const float* wih_b  = (const float*)d_in[12];
  const float* whh_b  = (const float*)d_in[13];
  const float* bih_b  = (const float*)d_in[14];
  const float* bhh_b  = (const float*)d_in[15];
  const float* t_in_w = (const float*)d_in[16];
  const float* t_in_b = (const float*)d_in[17];
  const float* t_out_w= (const float*)d_in[18];
  const float* t_out_b= (const float*)d_in[19];
  const float* t_ln1g = (const float*)d_in[20];
  const float* t_ln1b = (const float*)d_in[21];
  const float* t_ff1w = (const float*)d_in[22];
  const float* t_ff1b = (const float*)d_in[23];
  const float* t_ff2w = (const float*)d_in[24];
  const float* t_ff2b = (const float*)d_in[25];
  const float* t_ln2g = (const float*)d_in[26];
  const float* t_ln2b = (const float*)d_in[27];
  const float* te1_w  = (const float*)d_in[28];
  const float* te1_b  = (const float*)d_in[29];
  const float* tl1g   = (const float*)d_in[30];
  const float* tl1b   = (const float*)d_in[31];
  const float* te2_w  = (const float*)d_in[32];
  const float* te2_b  = (const float*)d_in[33];
  const float* tl2g   = (const float*)d_in[34];
  const float* tl2b   = (const float*)d_in[35];
  const float* c_w    = (const float*)d_in[36];
  const float* c_b    = (const float*)d_in[37];
  const float* clng   = (const float*)d_in[38];
  const float* clnb   = (const float*)d_in[39];

  float* ws = (float*)d_ws;
  // Workspace (float slots), max index 17,391,616 (~69.6 MB):
  //   A [0,        524288):  oeb bf16 [8192][128]
  //   B [1048576,  5242880): embb bf16 (dead after order_attn) -> g fp32
  //   C [5242880,  9437184): attn fp32; g1 LN in-place; g2 ffln in-place
  //   D [9437184,  9633792): whhb bf16 [2][768][256]
  //   D2[9633792,  9732096): wihb bf16 [2][768][128]
  //   D3[9732096,  9740288): awb2 bf16 [128*128]
  //   E [10027008,10051584): awb bf16 [384*128]
  //   F [10051584,10444800): twb bf16 [1536*512]
  //   G [10444800,10575872): pwb bf16 [512*512]
  //   G2[10575872,10838016): f1wb bf16 [1024*512]
  //   G3[10838016,11100160): f2wb bf16 [512*1024]
  //   H [11100160,17391616): gi bf16 [8192*1536]
  unsigned short* oeb = (unsigned short*)ws;
  unsigned short* embb= (unsigned short*)(ws + 1048576);
  float* g    = ws + 1048576;                           // over dead embb
  float* attn = ws + 5242880;
  float* g1   = attn;                                   // in-place LN out
  float* g2   = attn;                                   // in-place ffln out
  unsigned short* whhb = (unsigned short*)(ws + 9437184);
  unsigned short* wihb = (unsigned short*)(ws + 9633792);
  unsigned short* awb2 = (unsigned short*)(ws + 9732096);
  unsigned short* awb  = (unsigned short*)(ws + 10027008);
  unsigned short* twb  = (unsigned short*)(ws + 10051584);
  unsigned short* pwb  = (unsigned short*)(ws + 10444800);
  unsigned short* f1wb = (unsigned short*)(ws + 10575872);
  unsigned short* f2wb = (unsigned short*)(ws + 10838016);
  unsigned short* gi   = (unsigned short*)(ws + 11100160);

  k_canary<<<256, 256, 0, stream>>>((float*)d_out);
  k_cvt<<<6212, 256, 0, stream>>>(a_in_w, t_in_w, t_out_w, t_ff1w, t_ff2w, a_out_w,
                                  emb, awb, twb, pwb, f1wb, f2wb, awb2, embb);
  k_gru_wb<<<1536, 256, 0, stream>>>(wih_f, whh_f, wih_b, whh_b, whhb, wihb);
  k_order_attn<<<8192, 256, 0, stream>>>(oh, embb, awb, a_in_b, awb2, a_out_b, oeb);
  k_gru_gi<<<256, 256, 0, stream>>>(oeb, wihb, gi);
  k_gru_rec<<<dim3(128, 2), 512, 0, stream>>>(gi, whhb, bih_f, bhh_f, bih_b, bhh_b, g);
  k_mha2f<<<dim3(256, 4), 256, 0, stream>>>(g, twb, t_in_b, attn);
  k_projln_mfma<<<512, 256, 0, stream>>>(attn, pwb, t_out_b, g, t_ln1g, t_ln1b, g1);
  k_ffln<<<512, 256, 0, stream>>>(g1, f1wb, t_ff1b, f2wb, t_ff2b, g1,
                                  t_ln2g, t_ln2b, g2);
  k_final<<<256, 256, 0, stream>>>(g2, db, dsl, te1_w, te1_b, tl1g, tl1b,
                                   te2_w, te2_b, tl2g, tl2b, c_w, c_b, clng, clnb,
                                   (float*)d_out);
}

// Round 6
// 623.336 us; speedup vs baseline: 1.0559x; 1.0396x over previous
//
#include <hip/hip_runtime.h>
#include <hip/hip_bf16.h>
#include <math.h>

typedef __hip_bfloat16 bf16;
typedef __attribute__((ext_vector_type(8))) short short8v;   // 8 bf16 (4 VGPRs)
typedef __attribute__((ext_vector_type(4))) short short4v;   // 4 bf16 (2 VGPRs)
typedef __attribute__((ext_vector_type(4))) float float4v;   // 4 fp32 acc
#define MFMA16 __builtin_amdgcn_mfma_f32_16x16x32_bf16

__device__ __forceinline__ float us2f(unsigned short u) {
  union { unsigned u; float f; } c; c.u = ((unsigned)u) << 16; return c.f;
}
__device__ __forceinline__ unsigned short f2us(float f) {
  return __bfloat16_as_ushort(__float2bfloat16(f));
}

// fp32 x . fp32 w, K % 8 == 0, 16B-aligned
__device__ __forceinline__ float dot_ff(const float* __restrict__ x,
                                        const float* __restrict__ w, int K) {
  const float4* xp = reinterpret_cast<const float4*>(x);
  const float4* wp = reinterpret_cast<const float4*>(w);
  float acc = 0.f;
  const int n = K >> 2;
  for (int i = 0; i < n; ++i) {
    float4 a = xp[i], b = wp[i];
    acc += a.x*b.x + a.y*b.y + a.z*b.z + a.w*b.w;
  }
  return acc;
}

__device__ __forceinline__ float sigm(float x) { return 1.f / (1.f + expf(-x)); }

// ---------------------------------------------------------------------------
__global__ void k_canary(float* __restrict__ out) {
  out[blockIdx.x * 256 + threadIdx.x] = 100.0f;
}

// ---------------------------------------------------------------------------
// One-shot: convert MFMA-consumed weights AND the emb table to bf16 in ws.
// ---------------------------------------------------------------------------
__global__ __launch_bounds__(256) void k_cvt(
    const float* __restrict__ a_in_w, const float* __restrict__ t_in_w,
    const float* __restrict__ t_out_w, const float* __restrict__ t_ff1w,
    const float* __restrict__ t_ff2w, const float* __restrict__ a_out_w,
    const float* __restrict__ emb,
    unsigned short* __restrict__ awb, unsigned short* __restrict__ twb,
    unsigned short* __restrict__ pwb, unsigned short* __restrict__ f1wb,
    unsigned short* __restrict__ f2wb, unsigned short* __restrict__ awb2,
    unsigned short* __restrict__ embb)
{
  int i = blockIdx.x * 256 + threadIdx.x;
  if (i < 1590048) {                                  // embb, 4 elems/thread
    float4 e4 = *reinterpret_cast<const float4*>(emb + (size_t)i * 4);
    short4v s; s[0] = f2us(e4.x); s[1] = f2us(e4.y); s[2] = f2us(e4.z); s[3] = f2us(e4.w);
    *reinterpret_cast<short4v*>(embb + (size_t)i * 4) = s;
  }
  if (i < 49152)  awb[i] = f2us(a_in_w[i]);
  if (i < 786432) twb[i] = f2us(t_in_w[i]);
  if (i < 262144) pwb[i] = f2us(t_out_w[i]);
  if (i < 524288) f1wb[i] = f2us(t_ff1w[i]);
  if (i < 524288) f2wb[i] = f2us(t_ff2w[i]);
  if (i < 16384)  awb2[i] = f2us(a_out_w[i]);
}

// ---------------------------------------------------------------------------
// GRU weight prep: row-major bf16 copies. whhb [dir][768][256],
// wihb [dir][768][128] (for gi GEMM).
// ---------------------------------------------------------------------------
__global__ __launch_bounds__(256) void k_gru_wb(
    const float* __restrict__ wih_f, const float* __restrict__ whh_f,
    const float* __restrict__ wih_b, const float* __restrict__ whh_b,
    unsigned short* __restrict__ whhb, unsigned short* __restrict__ wihb)
{
  int i = blockIdx.x * 256 + threadIdx.x;   // < 393216
  if (i >= 393216) return;
  int dir = i / 196608, r = i % 196608;
  whhb[i] = f2us((dir ? whh_b : whh_f)[r]);
  if (r < 98304) wihb[dir * 98304 + r] = f2us((dir ? wih_b : wih_f)[r]);
}

// ---------------------------------------------------------------------------
// Stage 1: embed + per-order MHA + proj-then-mean. Staged bf16 gather
// (R4-proven). LDS overlays for 5 blocks/CU:
//   regA 10,240 B: xs [32][136] (gather->A-frags) THEN vT [128][40]
//   qb   8,704 B: q  THEN O
//   kb   8,704 B: k  THEN P [128][32]
// Total 27,648 B -> 5 blocks/CU (20 waves). 5 barriers.
// ---------------------------------------------------------------------------
__global__ __launch_bounds__(256, 5) void k_order_attn(
    const int* __restrict__ oh, const unsigned short* __restrict__ embb,
    const unsigned short* __restrict__ awb, const float* __restrict__ in_b,
    const unsigned short* __restrict__ awb2, const float* __restrict__ out_b,
    unsigned short* __restrict__ oeb)
{
  const int bo = blockIdx.x;            // 0..8191
  const int tid = threadIdx.x;
  __shared__ alignas(16) unsigned short regA[128 * 40];   // xs -> vT
  __shared__ alignas(16) unsigned short qb[32 * 136];     // q -> O
  __shared__ alignas(16) unsigned short kb[32 * 136];     // k -> P
  unsigned short* xs = regA;
  unsigned short* vT = regA;
  unsigned short* ob = qb;
  unsigned short* pb = kb;

  const int lane = tid & 63, wave = tid >> 6;
  const int l15 = lane & 15, quad = lane >> 4;

  // staged bf16 gather, 16B/lane (coalesced per row-chunk)
  for (int i = tid; i < 512; i += 256) {
    int t = i >> 4, c8 = (i & 15) << 3;
    int id = oh[bo * 32 + t];
    *reinterpret_cast<short8v*>(xs + t * 136 + c8) =
        *reinterpret_cast<const short8v*>(embb + (size_t)id * 128 + c8);
  }
  __syncthreads();
  short8v af[2][4];
#pragma unroll
  for (int mt = 0; mt < 2; ++mt)
#pragma unroll
    for (int kc = 0; kc < 4; ++kc)
      af[mt][kc] = *reinterpret_cast<const short8v*>(
          xs + (mt * 16 + l15) * 136 + kc * 32 + quad * 8);
  __syncthreads();                       // xs dead -> vT region writable
  // ---- QKV MFMA: qkv[t][j] = x[t][.] . w[j][.] ----
  for (int ni = 0; ni < 6; ++ni) {
    const int j = (wave + ni * 4) * 16 + l15;
    const unsigned short* wrow = awb + (size_t)j * 128;
    float4v acc0 = {0.f, 0.f, 0.f, 0.f}, acc1 = {0.f, 0.f, 0.f, 0.f};
#pragma unroll
    for (int kc = 0; kc < 4; ++kc) {
      short8v bfr = *reinterpret_cast<const short8v*>(wrow + kc * 32 + quad * 8);
      acc0 = MFMA16(af[0][kc], bfr, acc0, 0, 0, 0);
      acc1 = MFMA16(af[1][kc], bfr, acc1, 0, 0, 0);
    }
    const float bj = in_b[j];
    const int jj = j & 127;
    if (j < 256) {
      unsigned short* dst = (j < 128) ? qb : kb;
#pragma unroll
      for (int r = 0; r < 4; ++r) {
        int t0 = quad * 4 + r;
        dst[t0 * 136 + jj] = f2us(acc0[r] + bj);
        dst[(t0 + 16) * 136 + jj] = f2us(acc1[r] + bj);
      }
    } else {                              // V transposed: vT[d][k] over xs
      short4v s0, s1;
#pragma unroll
      for (int r = 0; r < 4; ++r) { s0[r] = f2us(acc0[r] + bj); s1[r] = f2us(acc1[r] + bj); }
      *reinterpret_cast<short4v*>(vT + jj * 40 + quad * 4) = s0;
      *reinterpret_cast<short4v*>(vT + jj * 40 + 16 + quad * 4) = s1;
    }
  }
  __syncthreads();
  // ---- FUSED: scores + softmax + PV + O write (wave = head h) ----
  {
    const int h = wave;
    const float scale1 = 0.17677669529663687f;            // 1/sqrt(32)
    short8v qf[2], kf[2];
#pragma unroll
    for (int mt = 0; mt < 2; ++mt)
      qf[mt] = *reinterpret_cast<const short8v*>(qb + (mt * 16 + l15) * 136 + h * 32 + quad * 8);
#pragma unroll
    for (int nt = 0; nt < 2; ++nt)
      kf[nt] = *reinterpret_cast<const short8v*>(kb + (nt * 16 + l15) * 136 + h * 32 + quad * 8);
    float4v sacc[2][2];
#pragma unroll
    for (int mt = 0; mt < 2; ++mt)
#pragma unroll
      for (int nt = 0; nt < 2; ++nt) {
        sacc[mt][nt] = (float4v){0.f, 0.f, 0.f, 0.f};
        sacc[mt][nt] = MFMA16(qf[mt], kf[nt], sacc[mt][nt], 0, 0, 0);
      }
    __syncthreads();                     // qb/kb reg-reads done -> P/O writes ok
    float inv_reg[2][4];
#pragma unroll
    for (int mt = 0; mt < 2; ++mt)
#pragma unroll
      for (int r = 0; r < 4; ++r) {
        float s0 = sacc[mt][0][r] * scale1;
        float s1 = sacc[mt][1][r] * scale1;
        float mx = fmaxf(s0, s1);
        mx = fmaxf(mx, __shfl_xor(mx, 1));
        mx = fmaxf(mx, __shfl_xor(mx, 2));
        mx = fmaxf(mx, __shfl_xor(mx, 4));
        mx = fmaxf(mx, __shfl_xor(mx, 8));
        float e0 = expf(s0 - mx), e1 = expf(s1 - mx);
        float sm = e0 + e1;
        sm += __shfl_xor(sm, 1);
        sm += __shfl_xor(sm, 2);
        sm += __shfl_xor(sm, 4);
        sm += __shfl_xor(sm, 8);
        inv_reg[mt][r] = 1.f / sm;
        int row = h * 32 + mt * 16 + quad * 4 + r;
        pb[row * 32 + l15] = f2us(e0);
        pb[row * 32 + 16 + l15] = f2us(e1);
      }
    // PV (reads only this wave's P rows / vT stripe)
    short8v pf[2], vf[2];
#pragma unroll
    for (int mt = 0; mt < 2; ++mt)
      pf[mt] = *reinterpret_cast<const short8v*>(pb + (h * 32 + mt * 16 + l15) * 32 + quad * 8);
#pragma unroll
    for (int nt = 0; nt < 2; ++nt)
      vf[nt] = *reinterpret_cast<const short8v*>(vT + (h * 32 + nt * 16 + l15) * 40 + quad * 8);
    float4v oacc[2][2];
#pragma unroll
    for (int mt = 0; mt < 2; ++mt)
#pragma unroll
      for (int nt = 0; nt < 2; ++nt) {
        oacc[mt][nt] = (float4v){0.f, 0.f, 0.f, 0.f};
        oacc[mt][nt] = MFMA16(pf[mt], vf[nt], oacc[mt][nt], 0, 0, 0);
      }
    // write O bf16 into ob (qb overlay): this wave's head-col stripe
#pragma unroll
    for (int mt = 0; mt < 2; ++mt)
#pragma unroll
      for (int r = 0; r < 4; ++r) {
        int t = mt * 16 + quad * 4 + r;
        float inv = inv_reg[mt][r];
#pragma unroll
        for (int nt = 0; nt < 2; ++nt)
          ob[t * 136 + h * 32 + nt * 16 + l15] = f2us(oacc[mt][nt][r] * inv);
      }
  }
  __syncthreads();
  // ---- out-proj MFMA: proj[t][j] = O[t][.] . W[j][.]; then mean over t ----
  {
    float4v acc[2][2];
#pragma unroll
    for (int mt = 0; mt < 2; ++mt)
#pragma unroll
      for (int nt = 0; nt < 2; ++nt) acc[mt][nt] = (float4v){0.f, 0.f, 0.f, 0.f};
#pragma unroll
    for (int kc = 0; kc < 4; ++kc) {
      short8v af0 = *reinterpret_cast<const short8v*>(ob + l15 * 136 + kc * 32 + quad * 8);
      short8v af1 = *reinterpret_cast<const short8v*>(ob + (16 + l15) * 136 + kc * 32 + quad * 8);
#pragma unroll
      for (int nt = 0; nt < 2; ++nt) {
        int j = (wave * 2 + nt) * 16 + l15;
        short8v bfr = *reinterpret_cast<const short8v*>(awb2 + (size_t)j * 128 + kc * 32 + quad * 8);
        acc[0][nt] = MFMA16(af0, bfr, acc[0][nt], 0, 0, 0);
        acc[1][nt] = MFMA16(af1, bfr, acc[1][nt], 0, 0, 0);
      }
    }
#pragma unroll
    for (int nt = 0; nt < 2; ++nt) {
      float part = 0.f;
#pragma unroll
      for (int mt = 0; mt < 2; ++mt)
#pragma unroll
        for (int r = 0; r < 4; ++r) part += acc[mt][nt][r];
      part += __shfl_xor(part, 16);
      part += __shfl_xor(part, 32);
      if (quad == 0) {
        int j = (wave * 2 + nt) * 16 + l15;
        oeb[(size_t)bo * 128 + j] = f2us(part * (1.f / 32.f) + out_b[j]);
      }
    }
  }
}

// ---------------------------------------------------------------------------
// gi GEMM (MFMA): gi[8192][1536] bf16 = oe @ wih^T (both dirs). oe is bf16.
// ---------------------------------------------------------------------------
__global__ __launch_bounds__(256, 2) void k_gru_gi(
    const unsigned short* __restrict__ oeb, const unsigned short* __restrict__ wihb,
    unsigned short* __restrict__ gi)
{
  const int row0 = blockIdx.x * 32, tid = threadIdx.x;
  __shared__ alignas(16) unsigned short xs[32 * 136];
  for (int i = tid; i < 512; i += 256) {
    int t = i >> 4, c8 = (i & 15) << 3;
    *reinterpret_cast<short8v*>(xs + t * 136 + c8) =
        *reinterpret_cast<const short8v*>(oeb + (size_t)(row0 + t) * 128 + c8);
  }
  __syncthreads();
  const int lane = tid & 63, wave = tid >> 6;
  const int l15 = lane & 15, quad = lane >> 4;
  short8v af[2][4];
#pragma unroll
  for (int mt = 0; mt < 2; ++mt)
#pragma unroll
    for (int kc = 0; kc < 4; ++kc)
      af[mt][kc] = *reinterpret_cast<const short8v*>(
          xs + (mt * 16 + l15) * 136 + kc * 32 + quad * 8);
  for (int ni = 0; ni < 24; ++ni) {
    int col = (wave + ni * 4) * 16 + l15;
    const unsigned short* wrow = wihb + (size_t)col * 128;
    float4v a0 = {0.f,0.f,0.f,0.f}, a1 = {0.f,0.f,0.f,0.f};
#pragma unroll
    for (int kc = 0; kc < 4; ++kc) {
      short8v bfr = *reinterpret_cast<const short8v*>(wrow + kc * 32 + quad * 8);
      a0 = MFMA16(af[0][kc], bfr, a0, 0, 0, 0);
      a1 = MFMA16(af[1][kc], bfr, a1, 0, 0, 0);
    }
#pragma unroll
    for (int r = 0; r < 4; ++r) {
      gi[(size_t)(row0 + quad * 4 + r) * 1536 + col] = f2us(a0[r]);
      gi[(size_t)(row0 + quad * 4 + r + 16) * 1536 + col] = f2us(a1[r]);
    }
  }
}

// ---------------------------------------------------------------------------
// GRU recurrence via MFMA. 2 batches/block, grid (128,2) = 256 blocks,
// 512 threads (8 waves). whh register-resident. gi for step s+1 prefetched
// into registers before the barrier. LDS: hb 8448 + pg 6176 = 14,624 B.
// ---------------------------------------------------------------------------
__global__ __launch_bounds__(512, 2) void k_gru_rec(
    const unsigned short* __restrict__ gi, const unsigned short* __restrict__ whhb,
    const float* __restrict__ bih_f, const float* __restrict__ bhh_f,
    const float* __restrict__ bih_b, const float* __restrict__ bhh_b,
    float* __restrict__ g)
{
  const int b0 = blockIdx.x * 2, dir = blockIdx.y;
  const int tid = threadIdx.x;           // 0..511
  const unsigned short* wb = whhb + (size_t)dir * 196608;   // [768][256] bf16
  const float* bih = dir ? bih_b : bih_f;
  const float* bhh = dir ? bhh_b : bhh_f;
  __shared__ alignas(16) unsigned short hb[16 * 264];   // h bf16 (A operand)
  __shared__ float pg[2 * 772];                         // gh fp32 (rows 0-1)
  const int lane = tid & 63, wave = tid >> 6;
  const int l15 = lane & 15, quad = lane >> 4;
  const int j = tid & 255, mb = tid >> 8;               // pointwise: (m=mb, j)
  const float bir = bih[j], biz = bih[256 + j], bin_ = bih[512 + j];
  const float bhr = bhh[j], bhz = bhh[256 + j], bhn  = bhh[512 + j];
  short8v wf[6][8];
  int cols[6];
#pragma unroll
  for (int ni = 0; ni < 6; ++ni) {
    cols[ni] = (wave + ni * 8) * 16 + l15;
#pragma unroll
    for (int kc = 0; kc < 8; ++kc)
      wf[ni][kc] = *reinterpret_cast<const short8v*>(
          wb + (size_t)cols[ni] * 256 + kc * 32 + quad * 8);
  }
  for (int i = tid; i < 16 * 264; i += 512) hb[i] = 0;
  int tcur = dir ? 31 : 0;
  size_t gbase = ((size_t)(b0 + mb) * 32 + tcur) * 1536 + dir * 768;
  float gr = us2f(gi[gbase + j]);
  float gz = us2f(gi[gbase + 256 + j]);
  float gn = us2f(gi[gbase + 512 + j]);
  __syncthreads();
  for (int s = 0; s < 32; ++s) {
    float4v acc[6];
#pragma unroll
    for (int ni = 0; ni < 6; ++ni) acc[ni] = (float4v){0.f, 0.f, 0.f, 0.f};
#pragma unroll
    for (int kc = 0; kc < 8; ++kc) {
      short8v af = *reinterpret_cast<const short8v*>(hb + l15 * 264 + kc * 32 + quad * 8);
#pragma unroll
      for (int ni = 0; ni < 6; ++ni)
        acc[ni] = MFMA16(af, wf[ni][kc], acc[ni], 0, 0, 0);
    }
    if (quad == 0) {
#pragma unroll
      for (int ni = 0; ni < 6; ++ni) {
        pg[cols[ni]] = acc[ni][0];
        pg[772 + cols[ni]] = acc[ni][1];
      }
    }
    float gr2 = 0.f, gz2 = 0.f, gn2 = 0.f;
    if (s < 31) {
      int t2 = dir ? (30 - s) : (s + 1);
      size_t gb2 = ((size_t)(b0 + mb) * 32 + t2) * 1536 + dir * 768;
      gr2 = us2f(gi[gb2 + j]);
      gz2 = us2f(gi[gb2 + 256 + j]);
      gn2 = us2f(gi[gb2 + 512 + j]);
    }
    __syncthreads();
    {
      const int tt = dir ? (31 - s) : s;
      float hprev = us2f(hb[mb * 264 + j]);
      float r = sigm(gr + bir + pg[mb * 772 + j] + bhr);
      float z = sigm(gz + biz + pg[mb * 772 + 256 + j] + bhz);
      float n = tanhf(gn + bin_ + r * (pg[mb * 772 + 512 + j] + bhn));
      float nh = (1.f - z) * n + z * hprev;
      hb[mb * 264 + j] = f2us(nh);
      g[((size_t)(b0 + mb) * 32 + tt) * 512 + dir * 256 + j] = nh;
    }
    gr = gr2; gz = gz2; gn = gn2;
    __syncthreads();
  }
}

// ---------------------------------------------------------------------------
// Stage 3 fused attention, one block per (b, head). x staged in K=128
// quarter-chunks (xs3 8,704 B) -> LDS 36,352 B -> 4 blocks/CU.
// QKV/scores/PV on MFMA; sc+pb overlay xs3 after staging is done.
// ---------------------------------------------------------------------------
__global__ __launch_bounds__(256, 4) void k_mha2f(
    const float* __restrict__ g, const unsigned short* __restrict__ twb,
    const float* __restrict__ Bv, float* __restrict__ attn)
{
  const int b = blockIdx.x, h = blockIdx.y, tid = threadIdx.x;
  __shared__ alignas(16) unsigned short xs3[32 * 136];     // x chunk; sc+pb overlay
  __shared__ alignas(16) unsigned short qk[2 * 32 * 136];
  __shared__ alignas(16) unsigned short vT[128 * 40];      // vT[d][k]
  unsigned short* qs = qk;
  unsigned short* ks = qk + 32 * 136;
  float* sc = reinterpret_cast<float*>(xs3);               // [32][33]; col 32 = 1/sum
  unsigned short* pb = xs3 + 2112;                         // P bf16 [32][32]
  const int lane = tid & 63, wave = tid >> 6;
  const int l15 = lane & 15, quad = lane >> 4;

  int wrowi[6];
#pragma unroll
  for (int ni = 0; ni < 6; ++ni) {
    int idx = (wave + ni * 4) * 16 + l15;
    int m = idx >> 7, dd = idx & 127;
    wrowi[ni] = m * 512 + h * 128 + dd;
  }
  float4v acc[6][2];
#pragma unroll
  for (int ni = 0; ni < 6; ++ni)
#pragma unroll
    for (int mt = 0; mt < 2; ++mt) acc[ni][mt] = (float4v){0.f, 0.f, 0.f, 0.f};

  for (int ck = 0; ck < 4; ++ck) {
    __syncthreads();
    for (int i = tid; i < 1024; i += 256) {                // x quarter load
      int t = i >> 5, c4 = (i & 31) << 2;
      float4 e4 = *reinterpret_cast<const float4*>(
          g + (size_t)b * 16384 + t * 512 + ck * 128 + c4);
      short4v s; s[0] = f2us(e4.x); s[1] = f2us(e4.y); s[2] = f2us(e4.z); s[3] = f2us(e4.w);
      *reinterpret_cast<short4v*>(xs3 + t * 136 + c4) = s;
    }
    __syncthreads();
    short8v af2[2][4];
#pragma unroll
    for (int mt = 0; mt < 2; ++mt)
#pragma unroll
      for (int u = 0; u < 4; ++u)
        af2[mt][u] = *reinterpret_cast<const short8v*>(
            xs3 + (mt * 16 + l15) * 136 + u * 32 + quad * 8);
#pragma unroll
    for (int ni = 0; ni < 6; ++ni) {
      const unsigned short* wrow = twb + (size_t)wrowi[ni] * 512 + ck * 128;
#pragma unroll
      for (int u = 0; u < 4; ++u) {
        short8v bfr = *reinterpret_cast<const short8v*>(wrow + u * 32 + quad * 8);
        acc[ni][0] = MFMA16(af2[0][u], bfr, acc[ni][0], 0, 0, 0);
        acc[ni][1] = MFMA16(af2[1][u], bfr, acc[ni][1], 0, 0, 0);
      }
    }
  }
  __syncthreads();
#pragma unroll
  for (int ni = 0; ni < 6; ++ni) {
    int idx = (wave + ni * 4) * 16 + l15;
    int m = idx >> 7, dd = idx & 127;
    float bj = Bv[wrowi[ni]];
    if (m < 2) {
      unsigned short* dst = (m == 0) ? qs : ks;
#pragma unroll
      for (int r = 0; r < 4; ++r) {
        int t0 = quad * 4 + r;
        dst[t0 * 136 + dd] = f2us(acc[ni][0][r] + bj);
        dst[(t0 + 16) * 136 + dd] = f2us(acc[ni][1][r] + bj);
      }
    } else {
      short4v s0, s1;
#pragma unroll
      for (int r = 0; r < 4; ++r) { s0[r] = f2us(acc[ni][0][r] + bj); s1[r] = f2us(acc[ni][1][r] + bj); }
      *reinterpret_cast<short4v*>(vT + dd * 40 + quad * 4) = s0;
      *reinterpret_cast<short4v*>(vT + dd * 40 + 16 + quad * 4) = s1;
    }
  }
  __syncthreads();
  // ---- scores MFMA ----
  {
    const float scale2 = 0.08838834764831845f;            // 1/sqrt(128)
    const int mt = wave >> 1, nt = wave & 1;
    float4v a = {0.f, 0.f, 0.f, 0.f};
#pragma unroll
    for (int kc = 0; kc < 4; ++kc) {
      short8v qf = *reinterpret_cast<const short8v*>(qs + (mt * 16 + l15) * 136 + kc * 32 + quad * 8);
      short8v kf = *reinterpret_cast<const short8v*>(ks + (nt * 16 + l15) * 136 + kc * 32 + quad * 8);
      a = MFMA16(qf, kf, a, 0, 0, 0);
    }
#pragma unroll
    for (int r = 0; r < 4; ++r)
      sc[(mt * 16 + quad * 4 + r) * 33 + nt * 16 + l15] = a[r] * scale2;
  }
  __syncthreads();
  // ---- softmax rows: 4 lanes/row, shfl-reduce; bf16 unnormalized P ----
  if (tid < 128) {
    int row = tid >> 2, seg = tid & 3;
    float* srow = sc + row * 33;
    float mx = srow[seg * 8];
#pragma unroll
    for (int c = 1; c < 8; ++c) mx = fmaxf(mx, srow[seg * 8 + c]);
    mx = fmaxf(mx, __shfl_xor(mx, 1));
    mx = fmaxf(mx, __shfl_xor(mx, 2));
    float s = 0.f;
    short8v pv;
#pragma unroll
    for (int c = 0; c < 8; ++c) {
      float e = expf(srow[seg * 8 + c] - mx);
      s += e; pv[c] = f2us(e);
    }
    *reinterpret_cast<short8v*>(pb + row * 32 + seg * 8) = pv;
    s += __shfl_xor(s, 1);
    s += __shfl_xor(s, 2);
    if (seg == 0) srow[32] = 1.f / s;
  }
  __syncthreads();
  // ---- PV MFMA ----
  {
    short8v pf[2], vf[2];
#pragma unroll
    for (int mt = 0; mt < 2; ++mt)
      pf[mt] = *reinterpret_cast<const short8v*>(pb + (mt * 16 + l15) * 32 + quad * 8);
#pragma unroll
    for (int ntl = 0; ntl < 2; ++ntl)
      vf[ntl] = *reinterpret_cast<const short8v*>(vT + ((2 * wave + ntl) * 16 + l15) * 40 + quad * 8);
    float4v oacc[2][2];
#pragma unroll
    for (int mt = 0; mt < 2; ++mt)
#pragma unroll
      for (int ntl = 0; ntl < 2; ++ntl) {
        oacc[mt][ntl] = (float4v){0.f, 0.f, 0.f, 0.f};
        oacc[mt][ntl] = MFMA16(pf[mt], vf[ntl], oacc[mt][ntl], 0, 0, 0);
      }
#pragma unroll
    for (int mt = 0; mt < 2; ++mt)
#pragma unroll
      for (int r = 0; r < 4; ++r) {
        int q = mt * 16 + quad * 4 + r;
        float inv = sc[q * 33 + 32];
#pragma unroll
        for (int ntl = 0; ntl < 2; ++ntl)
          attn[((size_t)b * 32 + q) * 512 + h * 128 + (2 * wave + ntl) * 16 + l15] =
              oacc[mt][ntl][r] * inv;
      }
  }
}

// ---------------------------------------------------------------------------
// proj GEMM via MFMA (M=16/block, N=512, K=512) + bias + residual + LN.
// ---------------------------------------------------------------------------
__global__ __launch_bounds__(256, 2) void k_projln_mfma(
    const float* __restrict__ X, const unsigned short* __restrict__ Wb,
    const float* __restrict__ bias, const float* __restrict__ res,
    const float* __restrict__ gam, const float* __restrict__ bet,
    float* __restrict__ Y)
{
  const int row0 = blockIdx.x * 16, tid = threadIdx.x;
  __shared__ alignas(16) unsigned short xs[16 * 520];
  __shared__ float ys[16 * 516];
  for (int i = tid; i < 16 * 512; i += 256) {
    int t = i >> 9, c = i & 511;
    xs[t * 520 + c] = f2us(X[(size_t)(row0 + t) * 512 + c]);
  }
  __syncthreads();
  {
    const int lane = tid & 63, wave = tid >> 6;
    const int l15 = lane & 15, quad = lane >> 4;
    short8v af[16];
#pragma unroll
    for (int kc = 0; kc < 16; ++kc)
      af[kc] = *reinterpret_cast<const short8v*>(xs + l15 * 520 + kc * 32 + quad * 8);
    for (int ni = 0; ni < 8; ++ni) {
      int col = (wave + ni * 4) * 16 + l15;
      const unsigned short* wrow = Wb + (size_t)col * 512;
      float4v acc = {0.f,0.f,0.f,0.f};
#pragma unroll
      for (int kc = 0; kc < 16; ++kc) {
        short8v bfr = *reinterpret_cast<const short8v*>(wrow + kc * 32 + quad * 8);
        acc = MFMA16(af[kc], bfr, acc, 0, 0, 0);
      }
      float bj = bias[col];
#pragma unroll
      for (int r = 0; r < 4; ++r)
        ys[(quad * 4 + r) * 516 + col] = acc[r] + bj;
    }
  }
  __syncthreads();
  for (int i = tid; i < 16 * 512; i += 256) {
    int t = i >> 9, c = i & 511;
    ys[t * 516 + c] += res[(size_t)(row0 + t) * 512 + c];
  }
  __syncthreads();
  {
    int row = tid >> 4, l16 = tid & 15;
    const float* yr = ys + row * 516;
    float part = 0.f;
#pragma unroll
    for (int k = 0; k < 32; ++k) part += yr[l16 + 16 * k];
#pragma unroll
    for (int off = 8; off; off >>= 1) part += __shfl_xor(part, off, 16);
    float mean = part * (1.f / 512.f);
    float var = 0.f;
#pragma unroll
    for (int k = 0; k < 32; ++k) { float d = yr[l16 + 16 * k] - mean; var += d * d; }
#pragma unroll
    for (int off = 8; off; off >>= 1) var += __shfl_xor(var, off, 16);
    float rs = rsqrtf(var * (1.f / 512.f) + 1e-5f);
    for (int k = 0; k < 32; ++k) {
      int c = l16 + 16 * k;
      Y[(size_t)(row0 + row) * 512 + c] = (yr[c] - mean) * rs * gam[c] + bet[c];
    }
  }
}

// ---------------------------------------------------------------------------
// FUSED ff1+relu+ff2+residual+LN (M=16/block), register-pressure-managed:
// both GEMM phases reload the A-frag per k-chunk from LDS. In-place Y.
// LDS: xs 16,640 + f1L 33,024 = 49,664 B.
// ---------------------------------------------------------------------------
__global__ __launch_bounds__(256, 2) void k_ffln(
    const float* __restrict__ X, const unsigned short* __restrict__ W1,
    const float* __restrict__ b1, const unsigned short* __restrict__ W2,
    const float* __restrict__ b2, const float* __restrict__ res,
    const float* __restrict__ gam, const float* __restrict__ bet,
    float* __restrict__ Y)
{
  const int row0 = blockIdx.x * 16, tid = threadIdx.x;
  __shared__ alignas(16) unsigned short xs[16 * 520];
  __shared__ alignas(16) unsigned short f1L[16 * 1032];   // ys [16][516] fp32 overlays
  float* ys = reinterpret_cast<float*>(f1L);
  const int lane = tid & 63, wave = tid >> 6;
  const int l15 = lane & 15, quad = lane >> 4;
  for (int i = tid; i < 16 * 512; i += 256) {
    int t = i >> 9, c = i & 511;
    xs[t * 520 + c] = f2us(X[(size_t)(row0 + t) * 512 + c]);
  }
  __syncthreads();
  // ff1: N=1024, K=512 -> relu -> f1L bf16 (reload A per kc: low pressure)
  for (int ni = 0; ni < 16; ++ni) {
    int col = (wave + ni * 4) * 16 + l15;
    const unsigned short* wrow = W1 + (size_t)col * 512;
    float4v acc = {0.f,0.f,0.f,0.f};
#pragma unroll
    for (int kc = 0; kc < 16; ++kc) {
      short8v a = *reinterpret_cast<const short8v*>(xs + l15 * 520 + kc * 32 + quad * 8);
      short8v bfr = *reinterpret_cast<const short8v*>(wrow + kc * 32 + quad * 8);
      acc = MFMA16(a, bfr, acc, 0, 0, 0);
    }
    float bj = b1[col];
#pragma unroll
    for (int r = 0; r < 4; ++r)
      f1L[(quad * 4 + r) * 1032 + col] = f2us(fmaxf(acc[r] + bj, 0.f));
  }
  __syncthreads();
  // ff2: N=512, K=1024 from f1L; hold acc2[8] only, reload A per kc
  float4v acc2[8];
#pragma unroll
  for (int ni = 0; ni < 8; ++ni) acc2[ni] = (float4v){0.f,0.f,0.f,0.f};
  int cols2[8];
#pragma unroll
  for (int ni = 0; ni < 8; ++ni) cols2[ni] = (wave + ni * 4) * 16 + l15;
  for (int half = 0; half < 2; ++half) {
    for (int kc = 0; kc < 16; ++kc) {
      short8v a = *reinterpret_cast<const short8v*>(
          f1L + l15 * 1032 + half * 512 + kc * 32 + quad * 8);
#pragma unroll
      for (int ni = 0; ni < 8; ++ni) {
        short8v bfr = *reinterpret_cast<const short8v*>(
            W2 + (size_t)cols2[ni] * 1024 + half * 512 + kc * 32 + quad * 8);
        acc2[ni] = MFMA16(a, bfr, acc2[ni], 0, 0, 0);
      }
    }
  }
  __syncthreads();                                        // f1L dead -> ys
  for (int ni = 0; ni < 8; ++ni) {
    int col = cols2[ni];
    float bj = b2[col];
#pragma unroll
    for (int r = 0; r < 4; ++r)
      ys[(quad * 4 + r) * 516 + col] = acc2[ni][r] + bj;
  }
  __syncthreads();
  for (int i = tid; i < 16 * 512; i += 256) {
    int t = i >> 9, c = i & 511;
    ys[t * 516 + c] += res[(size_t)(row0 + t) * 512 + c];
  }
  __syncthreads();
  {
    int row = tid >> 4, l16 = tid & 15;
    const float* yr = ys + row * 516;
    float part = 0.f;
#pragma unroll
    for (int k = 0; k < 32; ++k) part += yr[l16 + 16 * k];
#pragma unroll
    for (int off = 8; off; off >>= 1) part += __shfl_xor(part, off, 16);
    float mean = part * (1.f / 512.f);
    float var = 0.f;
#pragma unroll
    for (int k = 0; k < 32; ++k) { float d = yr[l16 + 16 * k] - mean; var += d * d; }
#pragma unroll
    for (int off = 8; off; off >>= 1) var += __shfl_xor(var, off, 16);
    float rs = rsqrtf(var * (1.f / 512.f) + 1e-5f);
    for (int k = 0; k < 32; ++k) {
      int c = l16 + 16 * k;
      Y[(size_t)(row0 + row) * 512 + c] = (yr[c] - mean) * rs * gam[c] + bet[c];
    }
  }
}

// ---------------------------------------------------------------------------
// Final: mean-pool, temporal MLP, concat, classifier, LN, relu -> fp32
// ---------------------------------------------------------------------------
__global__ __launch_bounds__(256) void k_final(
    const float* __restrict__ g2,
    const float* __restrict__ db, const float* __restrict__ dsl,
    const float* __restrict__ te1_w, const float* __restrict__ te1_b,
    const float* __restrict__ l1g, const float* __restrict__ l1b,
    const float* __restrict__ te2_w, const float* __restrict__ te2_b,
    const float* __restrict__ l2g, const float* __restrict__ l2b,
    const float* __restrict__ c_w, const float* __restrict__ c_b,
    const float* __restrict__ clg, const float* __restrict__ clb,
    float* __restrict__ out)
{
  const int b = blockIdx.x, tid = threadIdx.x;
  __shared__ float cat[640];
  __shared__ float t1[64];
  __shared__ float t2[128];
  __shared__ float pre[256];
  __shared__ float red[256];
  __shared__ float st[2];
  for (int i = tid; i < 512; i += 256) {
    float acc = 0.f;
#pragma unroll
    for (int t = 0; t < 32; ++t) acc += g2[((size_t)b * 32 + t) * 512 + i];
    cat[i] = acc * (1.f / 32.f);
  }
  if (tid == 0) {
    float s = 0.f;
    for (int i = 0; i < 31; ++i) s += db[b * 31 + i];
    st[0] = s / 31.f;
    st[1] = dsl[b];
  }
  __syncthreads();
  const float f0 = st[0], f1v = st[1];
  if (tid < 64)
    t1[tid] = f0 * te1_w[tid * 2] + f1v * te1_w[tid * 2 + 1] + te1_b[tid];
  __syncthreads();
  if (tid == 0) {
    float m = 0.f; for (int i = 0; i < 64; ++i) m += t1[i]; m *= (1.f / 64.f);
    float v = 0.f; for (int i = 0; i < 64; ++i) { float d = t1[i] - m; v += d * d; }
    st[0] = m; st[1] = rsqrtf(v * (1.f / 64.f) + 1e-5f);
  }
  __syncthreads();
  if (tid < 64) {
    float v = (t1[tid] - st[0]) * st[1] * l1g[tid] + l1b[tid];
    t1[tid] = fmaxf(v, 0.f);
  }
  __syncthreads();
  if (tid < 128)
    t2[tid] = dot_ff(t1, te2_w + (size_t)tid * 64, 64) + te2_b[tid];
  __syncthreads();
  if (tid == 0) {
    float m = 0.f; for (int i = 0; i < 128; ++i) m += t2[i]; m *= (1.f / 128.f);
    float v = 0.f; for (int i = 0; i < 128; ++i) { float d = t2[i] - m; v += d * d; }
    st[0] = m; st[1] = rsqrtf(v * (1.f / 128.f) + 1e-5f);
  }
  __syncthreads();
  if (tid < 128) {
    float v = (t2[tid] - st[0]) * st[1] * l2g[tid] + l2b[tid];
    cat[512 + tid] = fmaxf(v, 0.f);
  }
  __syncthreads();
  pre[tid] = dot_ff(cat, c_w + (size_t)tid * 640, 640) + c_b[tid];
  red[tid] = pre[tid];
  __syncthreads();
  for (int s = 128; s > 0; s >>= 1) { if (tid < s) red[tid] += red[tid + s]; __syncthreads(); }
  const float m = red[0] * (1.f / 256.f);
  __syncthreads();
  const float d = pre[tid] - m;
  red[tid] = d * d;
  __syncthreads();
  for (int s = 128; s > 0; s >>= 1) { if (tid < s) red[tid] += red[tid + s]; __syncthreads(); }
  const float rs = rsqrtf(red[0] * (1.f / 256.f) + 1e-5f);
  float v = d * rs * clg[tid] + clb[tid];
  out[(size_t)b * 256 + tid] = fmaxf(v, 0.f);
}

// ---------------------------------------------------------------------------
extern "C" void kernel_launch(void* const* d_in, const int* in_sizes, int n_in,
                              void* d_out, int out_size, void* d_ws, size_t ws_size,
                              hipStream_t stream) {
  (void)in_sizes; (void)n_in; (void)out_size; (void)ws_size;
  const int*   oh     = (const int*)  d_in[0];
  const float* db     = (const float*)d_in[1];
  const float* dsl    = (const float*)d_in[2];
  const float* emb    = (const float*)d_in[3];
  const float* a_in_w = (const float*)d_in[4];
  const float* a_in_b = (const float*)d_in[5];
  const float* a_out_w= (const float*)d_in[6];
  const float* a_out_b= (const float*)d_in[7];
  const float* wih_f  = (const float*)d_in[8];
  const float* whh_f  = (const float*)d_in[9];
  const float* bih_f  = (const float*)d_in[10];
  const float* bhh_f  = (const float*)d_in[11];
  const float* wih_b  = (const float*)d_in[12];
  const float* whh_b  = (const float*)d_in[13];
  const float* bih_b  = (const float*)d_in[14];
  const float* bhh_b  = (const float*)d_in[15];
  const float* t_in_w = (const float*)d_in[16];
  const float* t_in_b = (const float*)d_in[17];
  const float* t_out_w= (const float*)d_in[18];
  const float* t_out_b= (const float*)d_in[19];
  const float* t_ln1g = (const float*)d_in[20];
  const float* t_ln1b = (const float*)d_in[21];
  const float* t_ff1w = (const float*)d_in[22];
  const float* t_ff1b = (const float*)d_in[23];
  const float* t_ff2w = (const float*)d_in[24];
  const float* t_ff2b = (const float*)d_in[25];
  const float* t_ln2g = (const float*)d_in[26];
  const float* t_ln2b = (const float*)d_in[27];
  const float* te1_w  = (const float*)d_in[28];
  const float* te1_b  = (const float*)d_in[29];
  const float* tl1g   = (const float*)d_in[30];
  const float* tl1b   = (const float*)d_in[31];
  const float* te2_w  = (const float*)d_in[32];
  const float* te2_b  = (const float*)d_in[33];
  const float* tl2g   = (const float*)d_in[34];
  const float* tl2b   = (const float*)d_in[35];
  const float* c_w    = (const float*)d_in[36];
  const float* c_b    = (const float*)d_in[37];
  const float* clng   = (const float*)d_in[38];
  const float* clnb   = (const float*)d_in[39];

  float* ws = (float*)d_ws;
  // Workspace (float slots), max index 17,391,616 (~69.6 MB):
  //   A [0,        524288):  oeb bf16 [8192][128]
  //   B [1048576,  5242880): embb bf16 (dead after order_attn) -> g fp32
  //   C [5242880,  9437184): attn fp32; g1 LN in-place; g2 ffln in-place
  //   D [9437184,  9633792): whhb bf16 [2][768][256]
  //   D2[9633792,  9732096): wihb bf16 [2][768][128]
  //   D3[9732096,  9740288): awb2 bf16 [128*128]
  //   E [10027008,10051584): awb bf16 [384*128]
  //   F [10051584,10444800): twb bf16 [1536*512]
  //   G [10444800,10575872): pwb bf16 [512*512]
  //   G2[10575872,10838016): f1wb bf16 [1024*512]
  //   G3[10838016,11100160): f2wb bf16 [512*1024]
  //   H [11100160,17391616): gi bf16 [8192*1536]
  unsigned short* oeb = (unsigned short*)ws;
  unsigned short* embb= (unsigned short*)(ws + 1048576);
  float* g    = ws + 1048576;                           // over dead embb
  float* attn = ws + 5242880;
  float* g1   = attn;                                   // in-place LN out
  float* g2   = attn;                                   // in-place ffln out
  unsigned short* whhb = (unsigned short*)(ws + 9437184);
  unsigned short* wihb = (unsigned short*)(ws + 9633792);
  unsigned short* awb2 = (unsigned short*)(ws + 9732096);
  unsigned short* awb  = (unsigned short*)(ws + 10027008);
  unsigned short* twb  = (unsigned short*)(ws + 10051584);
  unsigned short* pwb  = (unsigned short*)(ws + 10444800);
  unsigned short* f1wb = (unsigned short*)(ws + 10575872);
  unsigned short* f2wb = (unsigned short*)(ws + 10838016);
  unsigned short* gi   = (unsigned short*)(ws + 11100160);

  k_canary<<<256, 256, 0, stream>>>((float*)d_out);
  k_cvt<<<6212, 256, 0, stream>>>(a_in_w, t_in_w, t_out_w, t_ff1w, t_ff2w, a_out_w,
                                  emb, awb, twb, pwb, f1wb, f2wb, awb2, embb);
  k_gru_wb<<<1536, 256, 0, stream>>>(wih_f, whh_f, wih_b, whh_b, whhb, wihb);
  k_order_attn<<<8192, 256, 0, stream>>>(oh, embb, awb, a_in_b, awb2, a_out_b, oeb);
  k_gru_gi<<<256, 256, 0, stream>>>(oeb, wihb, gi);
  k_gru_rec<<<dim3(128, 2), 512, 0, stream>>>(gi, whhb, bih_f, bhh_f, bih_b, bhh_b, g);
  k_mha2f<<<dim3(256, 4), 256, 0, stream>>>(g, twb, t_in_b, attn);
  k_projln_mfma<<<512, 256, 0, stream>>>(attn, pwb, t_out_b, g, t_ln1g, t_ln1b, g1);
  k_ffln<<<512, 256, 0, stream>>>(g1, f1wb, t_ff1b, f2wb, t_ff2b, g1,
                                  t_ln2g, t_ln2b, g2);
  k_final<<<256, 256, 0, stream>>>(g2, db, dsl, te1_w, te1_b, tl1g, tl1b,
                                   te2_w, te2_b, tl2g, tl2b, c_w, c_b, clng, clnb,
                                   (float*)d_out);
}

// Round 7
// 617.721 us; speedup vs baseline: 1.0655x; 1.0091x over previous
//
#include <hip/hip_runtime.h>
#include <hip/hip_bf16.h>
#include <math.h>

typedef __hip_bfloat16 bf16;
typedef __attribute__((ext_vector_type(8))) short short8v;   // 8 bf16 (4 VGPRs)
typedef __attribute__((ext_vector_type(4))) short short4v;   // 4 bf16 (2 VGPRs)
typedef __attribute__((ext_vector_type(4))) float float4v;   // 4 fp32 acc
#define MFMA16 __builtin_amdgcn_mfma_f32_16x16x32_bf16

__device__ __forceinline__ float us2f(unsigned short u) {
  union { unsigned u; float f; } c; c.u = ((unsigned)u) << 16; return c.f;
}
__device__ __forceinline__ unsigned short f2us(float f) {
  return __bfloat16_as_ushort(__float2bfloat16(f));
}

// fp32 x . fp32 w, K % 8 == 0, 16B-aligned
__device__ __forceinline__ float dot_ff(const float* __restrict__ x,
                                        const float* __restrict__ w, int K) {
  const float4* xp = reinterpret_cast<const float4*>(x);
  const float4* wp = reinterpret_cast<const float4*>(w);
  float acc = 0.f;
  const int n = K >> 2;
  for (int i = 0; i < n; ++i) {
    float4 a = xp[i], b = wp[i];
    acc += a.x*b.x + a.y*b.y + a.z*b.z + a.w*b.w;
  }
  return acc;
}

__device__ __forceinline__ float sigm(float x) { return 1.f / (1.f + expf(-x)); }

// ---------------------------------------------------------------------------
__global__ void k_canary(float* __restrict__ out) {
  out[blockIdx.x * 256 + threadIdx.x] = 100.0f;
}

// ---------------------------------------------------------------------------
// One-shot: convert MFMA-consumed weights AND the emb table to bf16 in ws.
// ---------------------------------------------------------------------------
__global__ __launch_bounds__(256) void k_cvt(
    const float* __restrict__ a_in_w, const float* __restrict__ t_in_w,
    const float* __restrict__ t_out_w, const float* __restrict__ t_ff1w,
    const float* __restrict__ t_ff2w, const float* __restrict__ a_out_w,
    const float* __restrict__ emb,
    unsigned short* __restrict__ awb, unsigned short* __restrict__ twb,
    unsigned short* __restrict__ pwb, unsigned short* __restrict__ f1wb,
    unsigned short* __restrict__ f2wb, unsigned short* __restrict__ awb2,
    unsigned short* __restrict__ embb)
{
  int i = blockIdx.x * 256 + threadIdx.x;
  if (i < 1590048) {                                  // embb, 4 elems/thread
    float4 e4 = *reinterpret_cast<const float4*>(emb + (size_t)i * 4);
    short4v s; s[0] = f2us(e4.x); s[1] = f2us(e4.y); s[2] = f2us(e4.z); s[3] = f2us(e4.w);
    *reinterpret_cast<short4v*>(embb + (size_t)i * 4) = s;
  }
  if (i < 49152)  awb[i] = f2us(a_in_w[i]);
  if (i < 786432) twb[i] = f2us(t_in_w[i]);
  if (i < 262144) pwb[i] = f2us(t_out_w[i]);
  if (i < 524288) f1wb[i] = f2us(t_ff1w[i]);
  if (i < 524288) f2wb[i] = f2us(t_ff2w[i]);
  if (i < 16384)  awb2[i] = f2us(a_out_w[i]);
}

// ---------------------------------------------------------------------------
// GRU weight prep: row-major bf16 copies. whhb [dir][768][256],
// wihb [dir][768][128] (for gi GEMM).
// ---------------------------------------------------------------------------
__global__ __launch_bounds__(256) void k_gru_wb(
    const float* __restrict__ wih_f, const float* __restrict__ whh_f,
    const float* __restrict__ wih_b, const float* __restrict__ whh_b,
    unsigned short* __restrict__ whhb, unsigned short* __restrict__ wihb)
{
  int i = blockIdx.x * 256 + threadIdx.x;   // < 393216
  if (i >= 393216) return;
  int dir = i / 196608, r = i % 196608;
  whhb[i] = f2us((dir ? whh_b : whh_f)[r]);
  if (r < 98304) wihb[dir * 98304 + r] = f2us((dir ? wih_b : wih_f)[r]);
}

// ---------------------------------------------------------------------------
// Stage 1: embed + per-order MHA + proj-then-mean. Staged bf16 gather.
// Softmax: no-max exp (scores std ~0.33, bounded) + row-sums via
// MFMA(P, ones) -- zero cross-lane shuffles. LDS overlays (5 blocks/CU):
//   regA 10,240 B: xs [32][136] -> vT [128][40]
//   qb   8,704 B: q -> O;  kb 8,704 B: k -> P [128][32]
// Total 27,648 B. 5 barriers.
// ---------------------------------------------------------------------------
__global__ __launch_bounds__(256, 5) void k_order_attn(
    const int* __restrict__ oh, const unsigned short* __restrict__ embb,
    const unsigned short* __restrict__ awb, const float* __restrict__ in_b,
    const unsigned short* __restrict__ awb2, const float* __restrict__ out_b,
    unsigned short* __restrict__ oeb)
{
  const int bo = blockIdx.x;            // 0..8191
  const int tid = threadIdx.x;
  __shared__ alignas(16) unsigned short regA[128 * 40];   // xs -> vT
  __shared__ alignas(16) unsigned short qb[32 * 136];     // q -> O
  __shared__ alignas(16) unsigned short kb[32 * 136];     // k -> P
  unsigned short* xs = regA;
  unsigned short* vT = regA;
  unsigned short* ob = qb;
  unsigned short* pb = kb;

  const int lane = tid & 63, wave = tid >> 6;
  const int l15 = lane & 15, quad = lane >> 4;

  // staged bf16 gather, 16B/lane (coalesced per row-chunk)
  for (int i = tid; i < 512; i += 256) {
    int t = i >> 4, c8 = (i & 15) << 3;
    int id = oh[bo * 32 + t];
    *reinterpret_cast<short8v*>(xs + t * 136 + c8) =
        *reinterpret_cast<const short8v*>(embb + (size_t)id * 128 + c8);
  }
  __syncthreads();
  short8v af[2][4];
#pragma unroll
  for (int mt = 0; mt < 2; ++mt)
#pragma unroll
    for (int kc = 0; kc < 4; ++kc)
      af[mt][kc] = *reinterpret_cast<const short8v*>(
          xs + (mt * 16 + l15) * 136 + kc * 32 + quad * 8);
  __syncthreads();                       // xs dead -> vT region writable
  // ---- QKV MFMA: qkv[t][j] = x[t][.] . w[j][.] ----
  for (int ni = 0; ni < 6; ++ni) {
    const int j = (wave + ni * 4) * 16 + l15;
    const unsigned short* wrow = awb + (size_t)j * 128;
    float4v acc0 = {0.f, 0.f, 0.f, 0.f}, acc1 = {0.f, 0.f, 0.f, 0.f};
#pragma unroll
    for (int kc = 0; kc < 4; ++kc) {
      short8v bfr = *reinterpret_cast<const short8v*>(wrow + kc * 32 + quad * 8);
      acc0 = MFMA16(af[0][kc], bfr, acc0, 0, 0, 0);
      acc1 = MFMA16(af[1][kc], bfr, acc1, 0, 0, 0);
    }
    const float bj = in_b[j];
    const int jj = j & 127;
    if (j < 256) {
      unsigned short* dst = (j < 128) ? qb : kb;
#pragma unroll
      for (int r = 0; r < 4; ++r) {
        int t0 = quad * 4 + r;
        dst[t0 * 136 + jj] = f2us(acc0[r] + bj);
        dst[(t0 + 16) * 136 + jj] = f2us(acc1[r] + bj);
      }
    } else {                              // V transposed: vT[d][k] over xs
      short4v s0, s1;
#pragma unroll
      for (int r = 0; r < 4; ++r) { s0[r] = f2us(acc0[r] + bj); s1[r] = f2us(acc1[r] + bj); }
      *reinterpret_cast<short4v*>(vT + jj * 40 + quad * 4) = s0;
      *reinterpret_cast<short4v*>(vT + jj * 40 + 16 + quad * 4) = s1;
    }
  }
  __syncthreads();
  // ---- FUSED: scores + exp + PV + ones-rowsum + O write (wave = head) ----
  {
    const int h = wave;
    const float scale1 = 0.17677669529663687f;            // 1/sqrt(32)
    short8v qf[2], kf[2];
#pragma unroll
    for (int mt = 0; mt < 2; ++mt)
      qf[mt] = *reinterpret_cast<const short8v*>(qb + (mt * 16 + l15) * 136 + h * 32 + quad * 8);
#pragma unroll
    for (int nt = 0; nt < 2; ++nt)
      kf[nt] = *reinterpret_cast<const short8v*>(kb + (nt * 16 + l15) * 136 + h * 32 + quad * 8);
    float4v sacc[2][2];
#pragma unroll
    for (int mt = 0; mt < 2; ++mt)
#pragma unroll
      for (int nt = 0; nt < 2; ++nt) {
        sacc[mt][nt] = (float4v){0.f, 0.f, 0.f, 0.f};
        sacc[mt][nt] = MFMA16(qf[mt], kf[nt], sacc[mt][nt], 0, 0, 0);
      }
    __syncthreads();                     // all kb reg-reads done -> P writes ok
    // P = exp(s) (no max subtraction: |s| <~ 2, safe)
#pragma unroll
    for (int mt = 0; mt < 2; ++mt)
#pragma unroll
      for (int r = 0; r < 4; ++r) {
        float e0 = expf(sacc[mt][0][r] * scale1);
        float e1 = expf(sacc[mt][1][r] * scale1);
        int row = h * 32 + mt * 16 + quad * 4 + r;
        pb[row * 32 + l15] = f2us(e0);
        pb[row * 32 + 16 + l15] = f2us(e1);
      }
    // ones fragment for rowsum MFMA
    short8v ones;
#pragma unroll
    for (int i = 0; i < 8; ++i) ones[i] = (short)0x3F80;  // bf16 1.0
    // PV (same-wave LDS write->read; in-order LDS pipe per wave)
    short8v pf[2], vf[2];
#pragma unroll
    for (int mt = 0; mt < 2; ++mt)
      pf[mt] = *reinterpret_cast<const short8v*>(pb + (h * 32 + mt * 16 + l15) * 32 + quad * 8);
    float4v sums[2];
#pragma unroll
    for (int mt = 0; mt < 2; ++mt) {
      sums[mt] = (float4v){0.f, 0.f, 0.f, 0.f};
      sums[mt] = MFMA16(pf[mt], ones, sums[mt], 0, 0, 0);  // rowsums in C layout
    }
#pragma unroll
    for (int nt = 0; nt < 2; ++nt)
      vf[nt] = *reinterpret_cast<const short8v*>(vT + (h * 32 + nt * 16 + l15) * 40 + quad * 8);
    float4v oacc[2][2];
#pragma unroll
    for (int mt = 0; mt < 2; ++mt)
#pragma unroll
      for (int nt = 0; nt < 2; ++nt) {
        oacc[mt][nt] = (float4v){0.f, 0.f, 0.f, 0.f};
        oacc[mt][nt] = MFMA16(pf[mt], vf[nt], oacc[mt][nt], 0, 0, 0);
      }
    // write O bf16 into ob (qb overlay): this wave's head-col stripe
#pragma unroll
    for (int mt = 0; mt < 2; ++mt)
#pragma unroll
      for (int r = 0; r < 4; ++r) {
        int t = mt * 16 + quad * 4 + r;
        float inv = 1.f / sums[mt][r];
#pragma unroll
        for (int nt = 0; nt < 2; ++nt)
          ob[t * 136 + h * 32 + nt * 16 + l15] = f2us(oacc[mt][nt][r] * inv);
      }
  }
  __syncthreads();
  // ---- out-proj MFMA: proj[t][j] = O[t][.] . W[j][.]; then mean over t ----
  {
    float4v acc[2][2];
#pragma unroll
    for (int mt = 0; mt < 2; ++mt)
#pragma unroll
      for (int nt = 0; nt < 2; ++nt) acc[mt][nt] = (float4v){0.f, 0.f, 0.f, 0.f};
#pragma unroll
    for (int kc = 0; kc < 4; ++kc) {
      short8v af0 = *reinterpret_cast<const short8v*>(ob + l15 * 136 + kc * 32 + quad * 8);
      short8v af1 = *reinterpret_cast<const short8v*>(ob + (16 + l15) * 136 + kc * 32 + quad * 8);
#pragma unroll
      for (int nt = 0; nt < 2; ++nt) {
        int j = (wave * 2 + nt) * 16 + l15;
        short8v bfr = *reinterpret_cast<const short8v*>(awb2 + (size_t)j * 128 + kc * 32 + quad * 8);
        acc[0][nt] = MFMA16(af0, bfr, acc[0][nt], 0, 0, 0);
        acc[1][nt] = MFMA16(af1, bfr, acc[1][nt], 0, 0, 0);
      }
    }
#pragma unroll
    for (int nt = 0; nt < 2; ++nt) {
      float part = 0.f;
#pragma unroll
      for (int mt = 0; mt < 2; ++mt)
#pragma unroll
        for (int r = 0; r < 4; ++r) part += acc[mt][nt][r];
      part += __shfl_xor(part, 16);
      part += __shfl_xor(part, 32);
      if (quad == 0) {
        int j = (wave * 2 + nt) * 16 + l15;
        oeb[(size_t)bo * 128 + j] = f2us(part * (1.f / 32.f) + out_b[j]);
      }
    }
  }
}

// ---------------------------------------------------------------------------
// gi GEMM (MFMA): gi[8192][1536] bf16 = oe @ wih^T (both dirs). oe is bf16.
// ---------------------------------------------------------------------------
__global__ __launch_bounds__(256, 2) void k_gru_gi(
    const unsigned short* __restrict__ oeb, const unsigned short* __restrict__ wihb,
    unsigned short* __restrict__ gi)
{
  const int row0 = blockIdx.x * 32, tid = threadIdx.x;
  __shared__ alignas(16) unsigned short xs[32 * 136];
  for (int i = tid; i < 512; i += 256) {
    int t = i >> 4, c8 = (i & 15) << 3;
    *reinterpret_cast<short8v*>(xs + t * 136 + c8) =
        *reinterpret_cast<const short8v*>(oeb + (size_t)(row0 + t) * 128 + c8);
  }
  __syncthreads();
  const int lane = tid & 63, wave = tid >> 6;
  const int l15 = lane & 15, quad = lane >> 4;
  short8v af[2][4];
#pragma unroll
  for (int mt = 0; mt < 2; ++mt)
#pragma unroll
    for (int kc = 0; kc < 4; ++kc)
      af[mt][kc] = *reinterpret_cast<const short8v*>(
          xs + (mt * 16 + l15) * 136 + kc * 32 + quad * 8);
  for (int ni = 0; ni < 24; ++ni) {
    int col = (wave + ni * 4) * 16 + l15;
    const unsigned short* wrow = wihb + (size_t)col * 128;
    float4v a0 = {0.f,0.f,0.f,0.f}, a1 = {0.f,0.f,0.f,0.f};
#pragma unroll
    for (int kc = 0; kc < 4; ++kc) {
      short8v bfr = *reinterpret_cast<const short8v*>(wrow + kc * 32 + quad * 8);
      a0 = MFMA16(af[0][kc], bfr, a0, 0, 0, 0);
      a1 = MFMA16(af[1][kc], bfr, a1, 0, 0, 0);
    }
#pragma unroll
    for (int r = 0; r < 4; ++r) {
      gi[(size_t)(row0 + quad * 4 + r) * 1536 + col] = f2us(a0[r]);
      gi[(size_t)(row0 + quad * 4 + r + 16) * 1536 + col] = f2us(a1[r]);
    }
  }
}

// ---------------------------------------------------------------------------
// GRU recurrence via MFMA. 2 batches/block, grid (128,2) = 256 blocks,
// 512 threads (8 waves). whh register-resident. gi for step s+1 prefetched
// into registers before the barrier. LDS: hb 8448 + pg 6176 = 14,624 B.
// ---------------------------------------------------------------------------
__global__ __launch_bounds__(512, 2) void k_gru_rec(
    const unsigned short* __restrict__ gi, const unsigned short* __restrict__ whhb,
    const float* __restrict__ bih_f, const float* __restrict__ bhh_f,
    const float* __restrict__ bih_b, const float* __restrict__ bhh_b,
    float* __restrict__ g)
{
  const int b0 = blockIdx.x * 2, dir = blockIdx.y;
  const int tid = threadIdx.x;           // 0..511
  const unsigned short* wb = whhb + (size_t)dir * 196608;   // [768][256] bf16
  const float* bih = dir ? bih_b : bih_f;
  const float* bhh = dir ? bhh_b : bhh_f;
  __shared__ alignas(16) unsigned short hb[16 * 264];   // h bf16 (A operand)
  __shared__ float pg[2 * 772];                         // gh fp32 (rows 0-1)
  const int lane = tid & 63, wave = tid >> 6;
  const int l15 = lane & 15, quad = lane >> 4;
  const int j = tid & 255, mb = tid >> 8;               // pointwise: (m=mb, j)
  const float bir = bih[j], biz = bih[256 + j], bin_ = bih[512 + j];
  const float bhr = bhh[j], bhz = bhh[256 + j], bhn  = bhh[512 + j];
  short8v wf[6][8];
  int cols[6];
#pragma unroll
  for (int ni = 0; ni < 6; ++ni) {
    cols[ni] = (wave + ni * 8) * 16 + l15;
#pragma unroll
    for (int kc = 0; kc < 8; ++kc)
      wf[ni][kc] = *reinterpret_cast<const short8v*>(
          wb + (size_t)cols[ni] * 256 + kc * 32 + quad * 8);
  }
  for (int i = tid; i < 16 * 264; i += 512) hb[i] = 0;
  int tcur = dir ? 31 : 0;
  size_t gbase = ((size_t)(b0 + mb) * 32 + tcur) * 1536 + dir * 768;
  float gr = us2f(gi[gbase + j]);
  float gz = us2f(gi[gbase + 256 + j]);
  float gn = us2f(gi[gbase + 512 + j]);
  __syncthreads();
  for (int s = 0; s < 32; ++s) {
    float4v acc[6];
#pragma unroll
    for (int ni = 0; ni < 6; ++ni) acc[ni] = (float4v){0.f, 0.f, 0.f, 0.f};
#pragma unroll
    for (int kc = 0; kc < 8; ++kc) {
      short8v af = *reinterpret_cast<const short8v*>(hb + l15 * 264 + kc * 32 + quad * 8);
#pragma unroll
      for (int ni = 0; ni < 6; ++ni)
        acc[ni] = MFMA16(af, wf[ni][kc], acc[ni], 0, 0, 0);
    }
    if (quad == 0) {
#pragma unroll
      for (int ni = 0; ni < 6; ++ni) {
        pg[cols[ni]] = acc[ni][0];
        pg[772 + cols[ni]] = acc[ni][1];
      }
    }
    float gr2 = 0.f, gz2 = 0.f, gn2 = 0.f;
    if (s < 31) {
      int t2 = dir ? (30 - s) : (s + 1);
      size_t gb2 = ((size_t)(b0 + mb) * 32 + t2) * 1536 + dir * 768;
      gr2 = us2f(gi[gb2 + j]);
      gz2 = us2f(gi[gb2 + 256 + j]);
      gn2 = us2f(gi[gb2 + 512 + j]);
    }
    __syncthreads();
    {
      const int tt = dir ? (31 - s) : s;
      float hprev = us2f(hb[mb * 264 + j]);
      float r = sigm(gr + bir + pg[mb * 772 + j] + bhr);
      float z = sigm(gz + biz + pg[mb * 772 + 256 + j] + bhz);
      float n = tanhf(gn + bin_ + r * (pg[mb * 772 + 512 + j] + bhn));
      float nh = (1.f - z) * n + z * hprev;
      hb[mb * 264 + j] = f2us(nh);
      g[((size_t)(b0 + mb) * 32 + tt) * 512 + dir * 256 + j] = nh;
    }
    gr = gr2; gz = gz2; gn = gn2;
    __syncthreads();
  }
}

// ---------------------------------------------------------------------------
// Stage 3 fused attention, one block per (b, head). x staged in K=128
// quarter-chunks (xs3 8,704 B) -> LDS 36,352 B -> 4 blocks/CU.
// Softmax phase DELETED: scores phase writes P = exp(s) bf16 directly;
// PV phase computes row-sums via MFMA(P, ones). No sc buffer.
// ---------------------------------------------------------------------------
__global__ __launch_bounds__(256, 4) void k_mha2f(
    const float* __restrict__ g, const unsigned short* __restrict__ twb,
    const float* __restrict__ Bv, float* __restrict__ attn)
{
  const int b = blockIdx.x, h = blockIdx.y, tid = threadIdx.x;
  __shared__ alignas(16) unsigned short xs3[32 * 136];     // x chunk; P overlay
  __shared__ alignas(16) unsigned short qk[2 * 32 * 136];
  __shared__ alignas(16) unsigned short vT[128 * 40];      // vT[d][k]
  unsigned short* qs = qk;
  unsigned short* ks = qk + 32 * 136;
  unsigned short* pb = xs3;                                // P bf16 [32][32]
  const int lane = tid & 63, wave = tid >> 6;
  const int l15 = lane & 15, quad = lane >> 4;

  int wrowi[6];
#pragma unroll
  for (int ni = 0; ni < 6; ++ni) {
    int idx = (wave + ni * 4) * 16 + l15;
    int m = idx >> 7, dd = idx & 127;
    wrowi[ni] = m * 512 + h * 128 + dd;
  }
  float4v acc[6][2];
#pragma unroll
  for (int ni = 0; ni < 6; ++ni)
#pragma unroll
    for (int mt = 0; mt < 2; ++mt) acc[ni][mt] = (float4v){0.f, 0.f, 0.f, 0.f};

  for (int ck = 0; ck < 4; ++ck) {
    __syncthreads();
    for (int i = tid; i < 1024; i += 256) {                // x quarter load
      int t = i >> 5, c4 = (i & 31) << 2;
      float4 e4 = *reinterpret_cast<const float4*>(
          g + (size_t)b * 16384 + t * 512 + ck * 128 + c4);
      short4v s; s[0] = f2us(e4.x); s[1] = f2us(e4.y); s[2] = f2us(e4.z); s[3] = f2us(e4.w);
      *reinterpret_cast<short4v*>(xs3 + t * 136 + c4) = s;
    }
    __syncthreads();
    short8v af2[2][4];
#pragma unroll
    for (int mt = 0; mt < 2; ++mt)
#pragma unroll
      for (int u = 0; u < 4; ++u)
        af2[mt][u] = *reinterpret_cast<const short8v*>(
            xs3 + (mt * 16 + l15) * 136 + u * 32 + quad * 8);
#pragma unroll
    for (int ni = 0; ni < 6; ++ni) {
      const unsigned short* wrow = twb + (size_t)wrowi[ni] * 512 + ck * 128;
#pragma unroll
      for (int u = 0; u < 4; ++u) {
        short8v bfr = *reinterpret_cast<const short8v*>(wrow + u * 32 + quad * 8);
        acc[ni][0] = MFMA16(af2[0][u], bfr, acc[ni][0], 0, 0, 0);
        acc[ni][1] = MFMA16(af2[1][u], bfr, acc[ni][1], 0, 0, 0);
      }
    }
  }
  __syncthreads();                                         // xs3 reads done
#pragma unroll
  for (int ni = 0; ni < 6; ++ni) {
    int idx = (wave + ni * 4) * 16 + l15;
    int m = idx >> 7, dd = idx & 127;
    float bj = Bv[wrowi[ni]];
    if (m < 2) {
      unsigned short* dst = (m == 0) ? qs : ks;
#pragma unroll
      for (int r = 0; r < 4; ++r) {
        int t0 = quad * 4 + r;
        dst[t0 * 136 + dd] = f2us(acc[ni][0][r] + bj);
        dst[(t0 + 16) * 136 + dd] = f2us(acc[ni][1][r] + bj);
      }
    } else {
      short4v s0, s1;
#pragma unroll
      for (int r = 0; r < 4; ++r) { s0[r] = f2us(acc[ni][0][r] + bj); s1[r] = f2us(acc[ni][1][r] + bj); }
      *reinterpret_cast<short4v*>(vT + dd * 40 + quad * 4) = s0;
      *reinterpret_cast<short4v*>(vT + dd * 40 + 16 + quad * 4) = s1;
    }
  }
  __syncthreads();
  // ---- scores MFMA -> P = exp(s) bf16 directly (no max: |s| <~ 7) ----
  {
    const float scale2 = 0.08838834764831845f;            // 1/sqrt(128)
    const int mt = wave >> 1, nt = wave & 1;
    float4v a = {0.f, 0.f, 0.f, 0.f};
#pragma unroll
    for (int kc = 0; kc < 4; ++kc) {
      short8v qf = *reinterpret_cast<const short8v*>(qs + (mt * 16 + l15) * 136 + kc * 32 + quad * 8);
      short8v kf = *reinterpret_cast<const short8v*>(ks + (nt * 16 + l15) * 136 + kc * 32 + quad * 8);
      a = MFMA16(qf, kf, a, 0, 0, 0);
    }
#pragma unroll
    for (int r = 0; r < 4; ++r) {
      int row = mt * 16 + quad * 4 + r;
      pb[row * 32 + nt * 16 + l15] = f2us(expf(a[r] * scale2));
    }
  }
  __syncthreads();
  // ---- PV MFMA + ones-rowsum; scale by 1/sum in epilogue ----
  {
    short8v ones;
#pragma unroll
    for (int i = 0; i < 8; ++i) ones[i] = (short)0x3F80;  // bf16 1.0
    short8v pf[2], vf[2];
#pragma unroll
    for (int mt = 0; mt < 2; ++mt)
      pf[mt] = *reinterpret_cast<const short8v*>(pb + (mt * 16 + l15) * 32 + quad * 8);
    float4v sums[2];
#pragma unroll
    for (int mt = 0; mt < 2; ++mt) {
      sums[mt] = (float4v){0.f, 0.f, 0.f, 0.f};
      sums[mt] = MFMA16(pf[mt], ones, sums[mt], 0, 0, 0);
    }
#pragma unroll
    for (int ntl = 0; ntl < 2; ++ntl)
      vf[ntl] = *reinterpret_cast<const short8v*>(vT + ((2 * wave + ntl) * 16 + l15) * 40 + quad * 8);
    float4v oacc[2][2];
#pragma unroll
    for (int mt = 0; mt < 2; ++mt)
#pragma unroll
      for (int ntl = 0; ntl < 2; ++ntl) {
        oacc[mt][ntl] = (float4v){0.f, 0.f, 0.f, 0.f};
        oacc[mt][ntl] = MFMA16(pf[mt], vf[ntl], oacc[mt][ntl], 0, 0, 0);
      }
#pragma unroll
    for (int mt = 0; mt < 2; ++mt)
#pragma unroll
      for (int r = 0; r < 4; ++r) {
        int q = mt * 16 + quad * 4 + r;
        float inv = 1.f / sums[mt][r];
#pragma unroll
        for (int ntl = 0; ntl < 2; ++ntl)
          attn[((size_t)b * 32 + q) * 512 + h * 128 + (2 * wave + ntl) * 16 + l15] =
              oacc[mt][ntl][r] * inv;
      }
  }
}

// ---------------------------------------------------------------------------
// proj GEMM via MFMA (M=16/block, N=512, K=512) + bias + residual + LN.
// ---------------------------------------------------------------------------
__global__ __launch_bounds__(256, 2) void k_projln_mfma(
    const float* __restrict__ X, const unsigned short* __restrict__ Wb,
    const float* __restrict__ bias, const float* __restrict__ res,
    const float* __restrict__ gam, const float* __restrict__ bet,
    float* __restrict__ Y)
{
  const int row0 = blockIdx.x * 16, tid = threadIdx.x;
  __shared__ alignas(16) unsigned short xs[16 * 520];
  __shared__ float ys[16 * 516];
  for (int i = tid; i < 16 * 512; i += 256) {
    int t = i >> 9, c = i & 511;
    xs[t * 520 + c] = f2us(X[(size_t)(row0 + t) * 512 + c]);
  }
  __syncthreads();
  {
    const int lane = tid & 63, wave = tid >> 6;
    const int l15 = lane & 15, quad = lane >> 4;
    short8v af[16];
#pragma unroll
    for (int kc = 0; kc < 16; ++kc)
      af[kc] = *reinterpret_cast<const short8v*>(xs + l15 * 520 + kc * 32 + quad * 8);
    for (int ni = 0; ni < 8; ++ni) {
      int col = (wave + ni * 4) * 16 + l15;
      const unsigned short* wrow = Wb + (size_t)col * 512;
      float4v acc = {0.f,0.f,0.f,0.f};
#pragma unroll
      for (int kc = 0; kc < 16; ++kc) {
        short8v bfr = *reinterpret_cast<const short8v*>(wrow + kc * 32 + quad * 8);
        acc = MFMA16(af[kc], bfr, acc, 0, 0, 0);
      }
      float bj = bias[col];
#pragma unroll
      for (int r = 0; r < 4; ++r)
        ys[(quad * 4 + r) * 516 + col] = acc[r] + bj;
    }
  }
  __syncthreads();
  for (int i = tid; i < 16 * 512; i += 256) {
    int t = i >> 9, c = i & 511;
    ys[t * 516 + c] += res[(size_t)(row0 + t) * 512 + c];
  }
  __syncthreads();
  {
    int row = tid >> 4, l16 = tid & 15;
    const float* yr = ys + row * 516;
    float part = 0.f;
#pragma unroll
    for (int k = 0; k < 32; ++k) part += yr[l16 + 16 * k];
#pragma unroll
    for (int off = 8; off; off >>= 1) part += __shfl_xor(part, off, 16);
    float mean = part * (1.f / 512.f);
    float var = 0.f;
#pragma unroll
    for (int k = 0; k < 32; ++k) { float d = yr[l16 + 16 * k] - mean; var += d * d; }
#pragma unroll
    for (int off = 8; off; off >>= 1) var += __shfl_xor(var, off, 16);
    float rs = rsqrtf(var * (1.f / 512.f) + 1e-5f);
    for (int k = 0; k < 32; ++k) {
      int c = l16 + 16 * k;
      Y[(size_t)(row0 + row) * 512 + c] = (yr[c] - mean) * rs * gam[c] + bet[c];
    }
  }
}

// ---------------------------------------------------------------------------
// FUSED ff1+relu+ff2+residual+LN (M=16/block), register-pressure-managed:
// both GEMM phases reload the A-frag per k-chunk from LDS. In-place Y.
// LDS: xs 16,640 + f1L 33,024 = 49,664 B.
// ---------------------------------------------------------------------------
__global__ __launch_bounds__(256, 2) void k_ffln(
    const float* __restrict__ X, const unsigned short* __restrict__ W1,
    const float* __restrict__ b1, const unsigned short* __restrict__ W2,
    const float* __restrict__ b2, const float* __restrict__ res,
    const float* __restrict__ gam, const float* __restrict__ bet,
    float* __restrict__ Y)
{
  const int row0 = blockIdx.x * 16, tid = threadIdx.x;
  __shared__ alignas(16) unsigned short xs[16 * 520];
  __shared__ alignas(16) unsigned short f1L[16 * 1032];   // ys [16][516] fp32 overlays
  float* ys = reinterpret_cast<float*>(f1L);
  const int lane = tid & 63, wave = tid >> 6;
  const int l15 = lane & 15, quad = lane >> 4;
  for (int i = tid; i < 16 * 512; i += 256) {
    int t = i >> 9, c = i & 511;
    xs[t * 520 + c] = f2us(X[(size_t)(row0 + t) * 512 + c]);
  }
  __syncthreads();
  // ff1: N=1024, K=512 -> relu -> f1L bf16 (reload A per kc: low pressure)
  for (int ni = 0; ni < 16; ++ni) {
    int col = (wave + ni * 4) * 16 + l15;
    const unsigned short* wrow = W1 + (size_t)col * 512;
    float4v acc = {0.f,0.f,0.f,0.f};
#pragma unroll
    for (int kc = 0; kc < 16; ++kc) {
      short8v a = *reinterpret_cast<const short8v*>(xs + l15 * 520 + kc * 32 + quad * 8);
      short8v bfr = *reinterpret_cast<const short8v*>(wrow + kc * 32 + quad * 8);
      acc = MFMA16(a, bfr, acc, 0, 0, 0);
    }
    float bj = b1[col];
#pragma unroll
    for (int r = 0; r < 4; ++r)
      f1L[(quad * 4 + r) * 1032 + col] = f2us(fmaxf(acc[r] + bj, 0.f));
  }
  __syncthreads();
  // ff2: N=512, K=1024 from f1L; hold acc2[8] only, reload A per kc
  float4v acc2[8];
#pragma unroll
  for (int ni = 0; ni < 8; ++ni) acc2[ni] = (float4v){0.f,0.f,0.f,0.f};
  int cols2[8];
#pragma unroll
  for (int ni = 0; ni < 8; ++ni) cols2[ni] = (wave + ni * 4) * 16 + l15;
  for (int half = 0; half < 2; ++half) {
    for (int kc = 0; kc < 16; ++kc) {
      short8v a = *reinterpret_cast<const short8v*>(
          f1L + l15 * 1032 + half * 512 + kc * 32 + quad * 8);
#pragma unroll
      for (int ni = 0; ni < 8; ++ni) {
        short8v bfr = *reinterpret_cast<const short8v*>(
            W2 + (size_t)cols2[ni] * 1024 + half * 512 + kc * 32 + quad * 8);
        acc2[ni] = MFMA16(a, bfr, acc2[ni], 0, 0, 0);
      }
    }
  }
  __syncthreads();                                        // f1L dead -> ys
  for (int ni = 0; ni < 8; ++ni) {
    int col = cols2[ni];
    float bj = b2[col];
#pragma unroll
    for (int r = 0; r < 4; ++r)
      ys[(quad * 4 + r) * 516 + col] = acc2[ni][r] + bj;
  }
  __syncthreads();
  for (int i = tid; i < 16 * 512; i += 256) {
    int t = i >> 9, c = i & 511;
    ys[t * 516 + c] += res[(size_t)(row0 + t) * 512 + c];
  }
  __syncthreads();
  {
    int row = tid >> 4, l16 = tid & 15;
    const float* yr = ys + row * 516;
    float part = 0.f;
#pragma unroll
    for (int k = 0; k < 32; ++k) part += yr[l16 + 16 * k];
#pragma unroll
    for (int off = 8; off; off >>= 1) part += __shfl_xor(part, off, 16);
    float mean = part * (1.f / 512.f);
    float var = 0.f;
#pragma unroll
    for (int k = 0; k < 32; ++k) { float d = yr[l16 + 16 * k] - mean; var += d * d; }
#pragma unroll
    for (int off = 8; off; off >>= 1) var += __shfl_xor(var, off, 16);
    float rs = rsqrtf(var * (1.f / 512.f) + 1e-5f);
    for (int k = 0; k < 32; ++k) {
      int c = l16 + 16 * k;
      Y[(size_t)(row0 + row) * 512 + c] = (yr[c] - mean) * rs * gam[c] + bet[c];
    }
  }
}

// ---------------------------------------------------------------------------
// Final: mean-pool, temporal MLP, concat, classifier, LN, relu -> fp32
// ---------------------------------------------------------------------------
__global__ __launch_bounds__(256) void k_final(
    const float* __restrict__ g2,
    const float* __restrict__ db, const float* __restrict__ dsl,
    const float* __restrict__ te1_w, const float* __restrict__ te1_b,
    const float* __restrict__ l1g, const float* __restrict__ l1b,
    const float* __restrict__ te2_w, const float* __restrict__ te2_b,
    const float* __restrict__ l2g, const float* __restrict__ l2b,
    const float* __restrict__ c_w, const float* __restrict__ c_b,
    const float* __restrict__ clg, const float* __restrict__ clb,
    float* __restrict__ out)
{
  const int b = blockIdx.x, tid = threadIdx.x;
  __shared__ float cat[640];
  __shared__ float t1[64];
  __shared__ float t2[128];
  __shared__ float pre[256];
  __shared__ float red[256];
  __shared__ float st[2];
  for (int i = tid; i < 512; i += 256) {
    float acc = 0.f;
#pragma unroll
    for (int t = 0; t < 32; ++t) acc += g2[((size_t)b * 32 + t) * 512 + i];
    cat[i] = acc * (1.f / 32.f);
  }
  if (tid == 0) {
    float s = 0.f;
    for (int i = 0; i < 31; ++i) s += db[b * 31 + i];
    st[0] = s / 31.f;
    st[1] = dsl[b];
  }
  __syncthreads();
  const float f0 = st[0], f1v = st[1];
  if (tid < 64)
    t1[tid] = f0 * te1_w[tid * 2] + f1v * te1_w[tid * 2 + 1] + te1_b[tid];
  __syncthreads();
  if (tid == 0) {
    float m = 0.f; for (int i = 0; i < 64; ++i) m += t1[i]; m *= (1.f / 64.f);
    float v = 0.f; for (int i = 0; i < 64; ++i) { float d = t1[i] - m; v += d * d; }
    st[0] = m; st[1] = rsqrtf(v * (1.f / 64.f) + 1e-5f);
  }
  __syncthreads();
  if (tid < 64) {
    float v = (t1[tid] - st[0]) * st[1] * l1g[tid] + l1b[tid];
    t1[tid] = fmaxf(v, 0.f);
  }
  __syncthreads();
  if (tid < 128)
    t2[tid] = dot_ff(t1, te2_w + (size_t)tid * 64, 64) + te2_b[tid];
  __syncthreads();
  if (tid == 0) {
    float m = 0.f; for (int i = 0; i < 128; ++i) m += t2[i]; m *= (1.f / 128.f);
    float v = 0.f; for (int i = 0; i < 128; ++i) { float d = t2[i] - m; v += d * d; }
    st[0] = m; st[1] = rsqrtf(v * (1.f / 128.f) + 1e-5f);
  }
  __syncthreads();
  if (tid < 128) {
    float v = (t2[tid] - st[0]) * st[1] * l2g[tid] + l2b[tid];
    cat[512 + tid] = fmaxf(v, 0.f);
  }
  __syncthreads();
  pre[tid] = dot_ff(cat, c_w + (size_t)tid * 640, 640) + c_b[tid];
  red[tid] = pre[tid];
  __syncthreads();
  for (int s = 128; s > 0; s >>= 1) { if (tid < s) red[tid] += red[tid + s]; __syncthreads(); }
  const float m = red[0] * (1.f / 256.f);
  __syncthreads();
  const float d = pre[tid] - m;
  red[tid] = d * d;
  __syncthreads();
  for (int s = 128; s > 0; s >>= 1) { if (tid < s) red[tid] += red[tid + s]; __syncthreads(); }
  const float rs = rsqrtf(red[0] * (1.f / 256.f) + 1e-5f);
  float v = d * rs * clg[tid] + clb[tid];
  out[(size_t)b * 256 + tid] = fmaxf(v, 0.f);
}

// ---------------------------------------------------------------------------
extern "C" void kernel_launch(void* const* d_in, const int* in_sizes, int n_in,
                              void* d_out, int out_size, void* d_ws, size_t ws_size,
                              hipStream_t stream) {
  (void)in_sizes; (void)n_in; (void)out_size; (void)ws_size;
  const int*   oh     = (const int*)  d_in[0];
  const float* db     = (const float*)d_in[1];
  const float* dsl    = (const float*)d_in[2];
  const float* emb    = (const float*)d_in[3];
  const float* a_in_w = (const float*)d_in[4];
  const float* a_in_b = (const float*)d_in[5];
  const float* a_out_w= (const float*)d_in[6];
  const float* a_out_b= (const float*)d_in[7];
  const float* wih_f  = (const float*)d_in[8];
  const float* whh_f  = (const float*)d_in[9];
  const float* bih_f  = (const float*)d_in[10];
  const float* bhh_f  = (const float*)d_in[11];
  const float* wih_b  = (const float*)d_in[12];
  const float* whh_b  = (const float*)d_in[13];
  const float* bih_b  = (const float*)d_in[14];
  const float* bhh_b  = (const float*)d_in[15];
  const float* t_in_w = (const float*)d_in[16];
  const float* t_in_b = (const float*)d_in[17];
  const float* t_out_w= (const float*)d_in[18];
  const float* t_out_b= (const float*)d_in[19];
  const float* t_ln1g = (const float*)d_in[20];
  const float* t_ln1b = (const float*)d_in[21];
  const float* t_ff1w = (const float*)d_in[22];
  const float* t_ff1b = (const float*)d_in[23];
  const float* t_ff2w = (const float*)d_in[24];
  const float* t_ff2b = (const float*)d_in[25];
  const float* t_ln2g = (const float*)d_in[26];
  const float* t_ln2b = (const float*)d_in[27];
  const float* te1_w  = (const float*)d_in[28];
  const float* te1_b  = (const float*)d_in[29];
  const float* tl1g   = (const float*)d_in[30];
  const float* tl1b   = (const float*)d_in[31];
  const float* te2_w  = (const float*)d_in[32];
  const float* te2_b  = (const float*)d_in[33];
  const float* tl2g   = (const float*)d_in[34];
  const float* tl2b   = (const float*)d_in[35];
  const float* c_w    = (const float*)d_in[36];
  const float* c_b    = (const float*)d_in[37];
  const float* clng   = (const float*)d_in[38];
  const float* clnb   = (const float*)d_in[39];

  float* ws = (float*)d_ws;
  // Workspace (float slots), max index 17,391,616 (~69.6 MB):
  //   A [0,        524288):  oeb bf16 [8192][128]
  //   B [1048576,  5242880): embb bf16 (dead after order_attn) -> g fp32
  //   C [5242880,  9437184): attn fp32; g1 LN in-place; g2 ffln in-place
  //   D [9437184,  9633792): whhb bf16 [2][768][256]
  //   D2[9633792,  9732096): wihb bf16 [2][768][128]
  //   D3[9732096,  9740288): awb2 bf16 [128*128]
  //   E [10027008,10051584): awb bf16 [384*128]
  //   F [10051584,10444800): twb bf16 [1536*512]
  //   G [10444800,10575872): pwb bf16 [512*512]
  //   G2[10575872,10838016): f1wb bf16 [1024*512]
  //   G3[10838016,11100160): f2wb bf16 [512*1024]
  //   H [11100160,17391616): gi bf16 [8192*1536]
  unsigned short* oeb = (unsigned short*)ws;
  unsigned short* embb= (unsigned short*)(ws + 1048576);
  float* g    = ws + 1048576;                           // over dead embb
  float* attn = ws + 5242880;
  float* g1   = attn;                                   // in-place LN out
  float* g2   = attn;                                   // in-place ffln out
  unsigned short* whhb = (unsigned short*)(ws + 9437184);
  unsigned short* wihb = (unsigned short*)(ws + 9633792);
  unsigned short* awb2 = (unsigned short*)(ws + 9732096);
  unsigned short* awb  = (unsigned short*)(ws + 10027008);
  unsigned short* twb  = (unsigned short*)(ws + 10051584);
  unsigned short* pwb  = (unsigned short*)(ws + 10444800);
  unsigned short* f1wb = (unsigned short*)(ws + 10575872);
  unsigned short* f2wb = (unsigned short*)(ws + 10838016);
  unsigned short* gi   = (unsigned short*)(ws + 11100160);

  k_canary<<<256, 256, 0, stream>>>((float*)d_out);
  k_cvt<<<6212, 256, 0, stream>>>(a_in_w, t_in_w, t_out_w, t_ff1w, t_ff2w, a_out_w,
                                  emb, awb, twb, pwb, f1wb, f2wb, awb2, embb);
  k_gru_wb<<<1536, 256, 0, stream>>>(wih_f, whh_f, wih_b, whh_b, whhb, wihb);
  k_order_attn<<<8192, 256, 0, stream>>>(oh, embb, awb, a_in_b, awb2, a_out_b, oeb);
  k_gru_gi<<<256, 256, 0, stream>>>(oeb, wihb, gi);
  k_gru_rec<<<dim3(128, 2), 512, 0, stream>>>(gi, whhb, bih_f, bhh_f, bih_b, bhh_b, g);
  k_mha2f<<<dim3(256, 4), 256, 0, stream>>>(g, twb, t_in_b, attn);
  k_projln_mfma<<<512, 256, 0, stream>>>(attn, pwb, t_out_b, g, t_ln1g, t_ln1b, g1);
  k_ffln<<<512, 256, 0, stream>>>(g1, f1wb, t_ff1b, f2wb, t_ff2b, g1,
                                  t_ln2g, t_ln2b, g2);
  k_final<<<256, 256, 0, stream>>>(g2, db, dsl, te1_w, te1_b, tl1g, tl1b,
                                   te2_w, te2_b, tl2g, tl2b, c_w, c_b, clng, clnb,
                                   (float*)d_out);
}

// Round 10
// 616.551 us; speedup vs baseline: 1.0675x; 1.0019x over previous
//
#include <hip/hip_runtime.h>
#include <hip/hip_bf16.h>
#include <math.h>

typedef __hip_bfloat16 bf16;
typedef __attribute__((ext_vector_type(8))) short short8v;   // 8 bf16 (4 VGPRs)
typedef __attribute__((ext_vector_type(4))) short short4v;   // 4 bf16 (2 VGPRs)
typedef __attribute__((ext_vector_type(4))) float float4v;   // 4 fp32 acc
#define MFMA16 __builtin_amdgcn_mfma_f32_16x16x32_bf16

__device__ __forceinline__ float us2f(unsigned short u) {
  union { unsigned u; float f; } c; c.u = ((unsigned)u) << 16; return c.f;
}
__device__ __forceinline__ unsigned short f2us(float f) {
  return __bfloat16_as_ushort(__float2bfloat16(f));
}

// fp32 x . fp32 w, K % 8 == 0, 16B-aligned
__device__ __forceinline__ float dot_ff(const float* __restrict__ x,
                                        const float* __restrict__ w, int K) {
  const float4* xp = reinterpret_cast<const float4*>(x);
  const float4* wp = reinterpret_cast<const float4*>(w);
  float acc = 0.f;
  const int n = K >> 2;
  for (int i = 0; i < n; ++i) {
    float4 a = xp[i], b = wp[i];
    acc += a.x*b.x + a.y*b.y + a.z*b.z + a.w*b.w;
  }
  return acc;
}

// native-exp sigmoid / tanh (clamped; serial-path hot in GRU)
__device__ __forceinline__ float sigm(float x) { return 1.f / (1.f + __expf(-x)); }
__device__ __forceinline__ float tanh_fast(float x) {
  x = fminf(fmaxf(x, -15.f), 15.f);
  float e = __expf(2.f * x);
  return (e - 1.f) / (e + 1.f);
}

// ---------------------------------------------------------------------------
__global__ void k_canary(float* __restrict__ out) {
  out[blockIdx.x * 256 + threadIdx.x] = 100.0f;
}

// ---------------------------------------------------------------------------
// One-shot: convert MFMA-consumed weights AND the emb table to bf16 in ws.
// ---------------------------------------------------------------------------
__global__ __launch_bounds__(256) void k_cvt(
    const float* __restrict__ a_in_w, const float* __restrict__ t_in_w,
    const float* __restrict__ t_out_w, const float* __restrict__ t_ff1w,
    const float* __restrict__ t_ff2w, const float* __restrict__ a_out_w,
    const float* __restrict__ emb,
    unsigned short* __restrict__ awb, unsigned short* __restrict__ twb,
    unsigned short* __restrict__ pwb, unsigned short* __restrict__ f1wb,
    unsigned short* __restrict__ f2wb, unsigned short* __restrict__ awb2,
    unsigned short* __restrict__ embb)
{
  int i = blockIdx.x * 256 + threadIdx.x;
  if (i < 1590048) {                                  // embb, 4 elems/thread
    float4 e4 = *reinterpret_cast<const float4*>(emb + (size_t)i * 4);
    short4v s; s[0] = f2us(e4.x); s[1] = f2us(e4.y); s[2] = f2us(e4.z); s[3] = f2us(e4.w);
    *reinterpret_cast<short4v*>(embb + (size_t)i * 4) = s;
  }
  if (i < 49152)  awb[i] = f2us(a_in_w[i]);
  if (i < 786432) twb[i] = f2us(t_in_w[i]);
  if (i < 262144) pwb[i] = f2us(t_out_w[i]);
  if (i < 524288) f1wb[i] = f2us(t_ff1w[i]);
  if (i < 524288) f2wb[i] = f2us(t_ff2w[i]);
  if (i < 16384)  awb2[i] = f2us(a_out_w[i]);
}

// ---------------------------------------------------------------------------
// GRU weight prep: row-major bf16 copies. whhb [dir][768][256],
// wihb [dir][768][128] (for gi GEMM).
// ---------------------------------------------------------------------------
__global__ __launch_bounds__(256) void k_gru_wb(
    const float* __restrict__ wih_f, const float* __restrict__ whh_f,
    const float* __restrict__ wih_b, const float* __restrict__ whh_b,
    unsigned short* __restrict__ whhb, unsigned short* __restrict__ wihb)
{
  int i = blockIdx.x * 256 + threadIdx.x;   // < 393216
  if (i >= 393216) return;
  int dir = i / 196608, r = i % 196608;
  whhb[i] = f2us((dir ? whh_b : whh_f)[r]);
  if (r < 98304) wihb[dir * 98304 + r] = f2us((dir ? wih_b : wih_f)[r]);
}

// ---------------------------------------------------------------------------
// Stage 1: embed + per-order MHA + proj-then-mean. Staged bf16 gather.
// Softmax: no-max native exp + row-sums via MFMA(P, ones).
// LDS overlays, 3 x 8,704 B = 26,112 B -> 6 blocks/CU (LDS-bound; VGPR 44
// is far under the waves=5 cap of 102, so launch_bounds(256,5) suffices):
//   regA: xs [32][136] -> vT [128][32] (stride 32)
//   qb:   q -> O;  kb: k -> P [128][32]
// ---------------------------------------------------------------------------
__global__ __launch_bounds__(256, 5) void k_order_attn(
    const int* __restrict__ oh, const unsigned short* __restrict__ embb,
    const unsigned short* __restrict__ awb, const float* __restrict__ in_b,
    const unsigned short* __restrict__ awb2, const float* __restrict__ out_b,
    unsigned short* __restrict__ oeb)
{
  const int bo = blockIdx.x;            // 0..8191
  const int tid = threadIdx.x;
  __shared__ alignas(16) unsigned short regA[32 * 136];   // xs -> vT[128][32]
  __shared__ alignas(16) unsigned short qb[32 * 136];     // q -> O
  __shared__ alignas(16) unsigned short kb[32 * 136];     // k -> P
  unsigned short* xs = regA;
  unsigned short* vT = regA;                              // stride 32
  unsigned short* ob = qb;
  unsigned short* pb = kb;

  const int lane = tid & 63, wave = tid >> 6;
  const int l15 = lane & 15, quad = lane >> 4;

  // staged bf16 gather, 16B/lane (coalesced per row-chunk)
  for (int i = tid; i < 512; i += 256) {
    int t = i >> 4, c8 = (i & 15) << 3;
    int id = oh[bo * 32 + t];
    *reinterpret_cast<short8v*>(xs + t * 136 + c8) =
        *reinterpret_cast<const short8v*>(embb + (size_t)id * 128 + c8);
  }
  __syncthreads();
  short8v af[2][4];
#pragma unroll
  for (int mt = 0; mt < 2; ++mt)
#pragma unroll
    for (int kc = 0; kc < 4; ++kc)
      af[mt][kc] = *reinterpret_cast<const short8v*>(
          xs + (mt * 16 + l15) * 136 + kc * 32 + quad * 8);
  __syncthreads();                       // xs dead -> vT region writable
  // ---- QKV MFMA: qkv[t][j] = x[t][.] . w[j][.] ----
  for (int ni = 0; ni < 6; ++ni) {
    const int j = (wave + ni * 4) * 16 + l15;
    const unsigned short* wrow = awb + (size_t)j * 128;
    float4v acc0 = {0.f, 0.f, 0.f, 0.f}, acc1 = {0.f, 0.f, 0.f, 0.f};
#pragma unroll
    for (int kc = 0; kc < 4; ++kc) {
      short8v bfr = *reinterpret_cast<const short8v*>(wrow + kc * 32 + quad * 8);
      acc0 = MFMA16(af[0][kc], bfr, acc0, 0, 0, 0);
      acc1 = MFMA16(af[1][kc], bfr, acc1, 0, 0, 0);
    }
    const float bj = in_b[j];
    const int jj = j & 127;
    if (j < 256) {
      unsigned short* dst = (j < 128) ? qb : kb;
#pragma unroll
      for (int r = 0; r < 4; ++r) {
        int t0 = quad * 4 + r;
        dst[t0 * 136 + jj] = f2us(acc0[r] + bj);
        dst[(t0 + 16) * 136 + jj] = f2us(acc1[r] + bj);
      }
    } else {                              // V transposed: vT[d][k], stride 32
      short4v s0, s1;
#pragma unroll
      for (int r = 0; r < 4; ++r) { s0[r] = f2us(acc0[r] + bj); s1[r] = f2us(acc1[r] + bj); }
      *reinterpret_cast<short4v*>(vT + jj * 32 + quad * 4) = s0;
      *reinterpret_cast<short4v*>(vT + jj * 32 + 16 + quad * 4) = s1;
    }
  }
  __syncthreads();
  // ---- FUSED: scores + exp + PV + ones-rowsum + O write (wave = head) ----
  {
    const int h = wave;
    const float scale1 = 0.17677669529663687f;            // 1/sqrt(32)
    short8v qf[2], kf[2];
#pragma unroll
    for (int mt = 0; mt < 2; ++mt)
      qf[mt] = *reinterpret_cast<const short8v*>(qb + (mt * 16 + l15) * 136 + h * 32 + quad * 8);
#pragma unroll
    for (int nt = 0; nt < 2; ++nt)
      kf[nt] = *reinterpret_cast<const short8v*>(kb + (nt * 16 + l15) * 136 + h * 32 + quad * 8);
    float4v sacc[2][2];
#pragma unroll
    for (int mt = 0; mt < 2; ++mt)
#pragma unroll
      for (int nt = 0; nt < 2; ++nt) {
        sacc[mt][nt] = (float4v){0.f, 0.f, 0.f, 0.f};
        sacc[mt][nt] = MFMA16(qf[mt], kf[nt], sacc[mt][nt], 0, 0, 0);
      }
    __syncthreads();                     // all qb/kb reg-reads done -> P/O writes ok
    // P = exp(s) (no max subtraction: |s| <~ 2, safe)
#pragma unroll
    for (int mt = 0; mt < 2; ++mt)
#pragma unroll
      for (int r = 0; r < 4; ++r) {
        float e0 = __expf(sacc[mt][0][r] * scale1);
        float e1 = __expf(sacc[mt][1][r] * scale1);
        int row = h * 32 + mt * 16 + quad * 4 + r;
        pb[row * 32 + l15] = f2us(e0);
        pb[row * 32 + 16 + l15] = f2us(e1);
      }
    // ones fragment for rowsum MFMA
    short8v ones;
#pragma unroll
    for (int i = 0; i < 8; ++i) ones[i] = (short)0x3F80;  // bf16 1.0
    // PV (same-wave LDS write->read; in-order LDS pipe per wave)
    short8v pf[2], vf[2];
#pragma unroll
    for (int mt = 0; mt < 2; ++mt)
      pf[mt] = *reinterpret_cast<const short8v*>(pb + (h * 32 + mt * 16 + l15) * 32 + quad * 8);
    float4v sums[2];
#pragma unroll
    for (int mt = 0; mt < 2; ++mt) {
      sums[mt] = (float4v){0.f, 0.f, 0.f, 0.f};
      sums[mt] = MFMA16(pf[mt], ones, sums[mt], 0, 0, 0);  // rowsums in C layout
    }
#pragma unroll
    for (int nt = 0; nt < 2; ++nt)
      vf[nt] = *reinterpret_cast<const short8v*>(vT + (h * 32 + nt * 16 + l15) * 32 + quad * 8);
    float4v oacc[2][2];
#pragma unroll
    for (int mt = 0; mt < 2; ++mt)
#pragma unroll
      for (int nt = 0; nt < 2; ++nt) {
        oacc[mt][nt] = (float4v){0.f, 0.f, 0.f, 0.f};
        oacc[mt][nt] = MFMA16(pf[mt], vf[nt], oacc[mt][nt], 0, 0, 0);
      }
    // write O bf16 into ob (qb overlay): this wave's head-col stripe
#pragma unroll
    for (int mt = 0; mt < 2; ++mt)
#pragma unroll
      for (int r = 0; r < 4; ++r) {
        int t = mt * 16 + quad * 4 + r;
        float inv = 1.f / sums[mt][r];
#pragma unroll
        for (int nt = 0; nt < 2; ++nt)
          ob[t * 136 + h * 32 + nt * 16 + l15] = f2us(oacc[mt][nt][r] * inv);
      }
  }
  __syncthreads();
  // ---- out-proj MFMA: proj[t][j] = O[t][.] . W[j][.]; then mean over t ----
  {
    float4v acc[2][2];
#pragma unroll
    for (int mt = 0; mt < 2; ++mt)
#pragma unroll
      for (int nt = 0; nt < 2; ++nt) acc[mt][nt] = (float4v){0.f, 0.f, 0.f, 0.f};
#pragma unroll
    for (int kc = 0; kc < 4; ++kc) {
      short8v af0 = *reinterpret_cast<const short8v*>(ob + l15 * 136 + kc * 32 + quad * 8);
      short8v af1 = *reinterpret_cast<const short8v*>(ob + (16 + l15) * 136 + kc * 32 + quad * 8);
#pragma unroll
      for (int nt = 0; nt < 2; ++nt) {
        int j = (wave * 2 + nt) * 16 + l15;
        short8v bfr = *reinterpret_cast<const short8v*>(awb2 + (size_t)j * 128 + kc * 32 + quad * 8);
        acc[0][nt] = MFMA16(af0, bfr, acc[0][nt], 0, 0, 0);
        acc[1][nt] = MFMA16(af1, bfr, acc[1][nt], 0, 0, 0);
      }
    }
#pragma unroll
    for (int nt = 0; nt < 2; ++nt) {
      float part = 0.f;
#pragma unroll
      for (int mt = 0; mt < 2; ++mt)
#pragma unroll
        for (int r = 0; r < 4; ++r) part += acc[mt][nt][r];
      part += __shfl_xor(part, 16);
      part += __shfl_xor(part, 32);
      if (quad == 0) {
        int j = (wave * 2 + nt) * 16 + l15;
        oeb[(size_t)bo * 128 + j] = f2us(part * (1.f / 32.f) + out_b[j]);
      }
    }
  }
}

// ---------------------------------------------------------------------------
// gi GEMM (MFMA): gi[8192][1536] bf16 = oe @ wih^T (both dirs). oe is bf16.
// ---------------------------------------------------------------------------
__global__ __launch_bounds__(256, 2) void k_gru_gi(
    const unsigned short* __restrict__ oeb, const unsigned short* __restrict__ wihb,
    unsigned short* __restrict__ gi)
{
  const int row0 = blockIdx.x * 32, tid = threadIdx.x;
  __shared__ alignas(16) unsigned short xs[32 * 136];
  for (int i = tid; i < 512; i += 256) {
    int t = i >> 4, c8 = (i & 15) << 3;
    *reinterpret_cast<short8v*>(xs + t * 136 + c8) =
        *reinterpret_cast<const short8v*>(oeb + (size_t)(row0 + t) * 128 + c8);
  }
  __syncthreads();
  const int lane = tid & 63, wave = tid >> 6;
  const int l15 = lane & 15, quad = lane >> 4;
  short8v af[2][4];
#pragma unroll
  for (int mt = 0; mt < 2; ++mt)
#pragma unroll
    for (int kc = 0; kc < 4; ++kc)
      af[mt][kc] = *reinterpret_cast<const short8v*>(
          xs + (mt * 16 + l15) * 136 + kc * 32 + quad * 8);
  for (int ni = 0; ni < 24; ++ni) {
    int col = (wave + ni * 4) * 16 + l15;
    const unsigned short* wrow = wihb + (size_t)col * 128;
    float4v a0 = {0.f,0.f,0.f,0.f}, a1 = {0.f,0.f,0.f,0.f};
#pragma unroll
    for (int kc = 0; kc < 4; ++kc) {
      short8v bfr = *reinterpret_cast<const short8v*>(wrow + kc * 32 + quad * 8);
      a0 = MFMA16(af[0][kc], bfr, a0, 0, 0, 0);
      a1 = MFMA16(af[1][kc], bfr, a1, 0, 0, 0);
    }
#pragma unroll
    for (int r = 0; r < 4; ++r) {
      gi[(size_t)(row0 + quad * 4 + r) * 1536 + col] = f2us(a0[r]);
      gi[(size_t)(row0 + quad * 4 + r + 16) * 1536 + col] = f2us(a1[r]);
    }
  }
}

// ---------------------------------------------------------------------------
// GRU recurrence via MFMA. 2 batches/block, grid (128,2) = 256 blocks,
// 512 threads (8 waves). whh register-resident. gi for step s+1 prefetched
// into registers before the barrier. Native-exp pointwise.
// LDS: hb 8448 + pg 6176 = 14,624 B.
// ---------------------------------------------------------------------------
__global__ __launch_bounds__(512, 2) void k_gru_rec(
    const unsigned short* __restrict__ gi, const unsigned short* __restrict__ whhb,
    const float* __restrict__ bih_f, const float* __restrict__ bhh_f,
    const float* __restrict__ bih_b, const float* __restrict__ bhh_b,
    float* __restrict__ g)
{
  const int b0 = blockIdx.x * 2, dir = blockIdx.y;
  const int tid = threadIdx.x;           // 0..511
  const unsigned short* wb = whhb + (size_t)dir * 196608;   // [768][256] bf16
  const float* bih = dir ? bih_b : bih_f;
  const float* bhh = dir ? bhh_b : bhh_f;
  __shared__ alignas(16) unsigned short hb[16 * 264];   // h bf16 (A operand)
  __shared__ float pg[2 * 772];                         // gh fp32 (rows 0-1)
  const int lane = tid & 63, wave = tid >> 6;
  const int l15 = lane & 15, quad = lane >> 4;
  const int j = tid & 255, mb = tid >> 8;               // pointwise: (m=mb, j)
  const float bir = bih[j], biz = bih[256 + j], bin_ = bih[512 + j];
  const float bhr = bhh[j], bhz = bhh[256 + j], bhn  = bhh[512 + j];
  short8v wf[6][8];
  int cols[6];
#pragma unroll
  for (int ni = 0; ni < 6; ++ni) {
    cols[ni] = (wave + ni * 8) * 16 + l15;
#pragma unroll
    for (int kc = 0; kc < 8; ++kc)
      wf[ni][kc] = *reinterpret_cast<const short8v*>(
          wb + (size_t)cols[ni] * 256 + kc * 32 + quad * 8);
  }
  for (int i = tid; i < 16 * 264; i += 512) hb[i] = 0;
  int tcur = dir ? 31 : 0;
  size_t gbase = ((size_t)(b0 + mb) * 32 + tcur) * 1536 + dir * 768;
  float gr = us2f(gi[gbase + j]);
  float gz = us2f(gi[gbase + 256 + j]);
  float gn = us2f(gi[gbase + 512 + j]);
  __syncthreads();
  for (int s = 0; s < 32; ++s) {
    float4v acc[6];
#pragma unroll
    for (int ni = 0; ni < 6; ++ni) acc[ni] = (float4v){0.f, 0.f, 0.f, 0.f};
#pragma unroll
    for (int kc = 0; kc < 8; ++kc) {
      short8v af = *reinterpret_cast<const short8v*>(hb + l15 * 264 + kc * 32 + quad * 8);
#pragma unroll
      for (int ni = 0; ni < 6; ++ni)
        acc[ni] = MFMA16(af, wf[ni][kc], acc[ni], 0, 0, 0);
    }
    if (quad == 0) {
#pragma unroll
      for (int ni = 0; ni < 6; ++ni) {
        pg[cols[ni]] = acc[ni][0];
        pg[772 + cols[ni]] = acc[ni][1];
      }
    }
    float gr2 = 0.f, gz2 = 0.f, gn2 = 0.f;
    if (s < 31) {
      int t2 = dir ? (30 - s) : (s + 1);
      size_t gb2 = ((size_t)(b0 + mb) * 32 + t2) * 1536 + dir * 768;
      gr2 = us2f(gi[gb2 + j]);
      gz2 = us2f(gi[gb2 + 256 + j]);
      gn2 = us2f(gi[gb2 + 512 + j]);
    }
    __syncthreads();
    {
      const int tt = dir ? (31 - s) : s;
      float hprev = us2f(hb[mb * 264 + j]);
      float r = sigm(gr + bir + pg[mb * 772 + j] + bhr);
      float z = sigm(gz + biz + pg[mb * 772 + 256 + j] + bhz);
      float n = tanh_fast(gn + bin_ + r * (pg[mb * 772 + 512 + j] + bhn));
      float nh = (1.f - z) * n + z * hprev;
      hb[mb * 264 + j] = f2us(nh);
      g[((size_t)(b0 + mb) * 32 + tt) * 512 + dir * 256 + j] = nh;
    }
    gr = gr2; gz = gz2; gn = gn2;
    __syncthreads();
  }
}

// ---------------------------------------------------------------------------
// Stage 3 fused attention, one block per (b, head). x staged in K=128
// quarter-chunks (xs3 8,704 B) -> LDS 36,352 B -> 4 blocks/CU.
// Scores phase writes P = exp(s) bf16 directly; PV computes row-sums via
// MFMA(P, ones). No sc buffer, no softmax phase.
// ---------------------------------------------------------------------------
__global__ __launch_bounds__(256, 4) void k_mha2f(
    const float* __restrict__ g, const unsigned short* __restrict__ twb,
    const float* __restrict__ Bv, float* __restrict__ attn)
{
  const int b = blockIdx.x, h = blockIdx.y, tid = threadIdx.x;
  __shared__ alignas(16) unsigned short xs3[32 * 136];     // x chunk; P overlay
  __shared__ alignas(16) unsigned short qk[2 * 32 * 136];
  __shared__ alignas(16) unsigned short vT[128 * 40];      // vT[d][k]
  unsigned short* qs = qk;
  unsigned short* ks = qk + 32 * 136;
  unsigned short* pb = xs3;                                // P bf16 [32][32]
  const int lane = tid & 63, wave = tid >> 6;
  const int l15 = lane & 15, quad = lane >> 4;

  int wrowi[6];
#pragma unroll
  for (int ni = 0; ni < 6; ++ni) {
    int idx = (wave + ni * 4) * 16 + l15;
    int m = idx >> 7, dd = idx & 127;
    wrowi[ni] = m * 512 + h * 128 + dd;
  }
  float4v acc[6][2];
#pragma unroll
  for (int ni = 0; ni < 6; ++ni)
#pragma unroll
    for (int mt = 0; mt < 2; ++mt) acc[ni][mt] = (float4v){0.f, 0.f, 0.f, 0.f};

  for (int ck = 0; ck < 4; ++ck) {
    __syncthreads();
    for (int i = tid; i < 1024; i += 256) {                // x quarter load
      int t = i >> 5, c4 = (i & 31) << 2;
      float4 e4 = *reinterpret_cast<const float4*>(
          g + (size_t)b * 16384 + t * 512 + ck * 128 + c4);
      short4v s; s[0] = f2us(e4.x); s[1] = f2us(e4.y); s[2] = f2us(e4.z); s[3] = f2us(e4.w);
      *reinterpret_cast<short4v*>(xs3 + t * 136 + c4) = s;
    }
    __syncthreads();
    short8v af2[2][4];
#pragma unroll
    for (int mt = 0; mt < 2; ++mt)
#pragma unroll
      for (int u = 0; u < 4; ++u)
        af2[mt][u] = *reinterpret_cast<const short8v*>(
            xs3 + (mt * 16 + l15) * 136 + u * 32 + quad * 8);
#pragma unroll
    for (int ni = 0; ni < 6; ++ni) {
      const unsigned short* wrow = twb + (size_t)wrowi[ni] * 512 + ck * 128;
#pragma unroll
      for (int u = 0; u < 4; ++u) {
        short8v bfr = *reinterpret_cast<const short8v*>(wrow + u * 32 + quad * 8);
        acc[ni][0] = MFMA16(af2[0][u], bfr, acc[ni][0], 0, 0, 0);
        acc[ni][1] = MFMA16(af2[1][u], bfr, acc[ni][1], 0, 0, 0);
      }
    }
  }
  __syncthreads();                                         // xs3 reads done
#pragma unroll
  for (int ni = 0; ni < 6; ++ni) {
    int idx = (wave + ni * 4) * 16 + l15;
    int m = idx >> 7, dd = idx & 127;
    float bj = Bv[wrowi[ni]];
    if (m < 2) {
      unsigned short* dst = (m == 0) ? qs : ks;
#pragma unroll
      for (int r = 0; r < 4; ++r) {
        int t0 = quad * 4 + r;
        dst[t0 * 136 + dd] = f2us(acc[ni][0][r] + bj);
        dst[(t0 + 16) * 136 + dd] = f2us(acc[ni][1][r] + bj);
      }
    } else {
      short4v s0, s1;
#pragma unroll
      for (int r = 0; r < 4; ++r) { s0[r] = f2us(acc[ni][0][r] + bj); s1[r] = f2us(acc[ni][1][r] + bj); }
      *reinterpret_cast<short4v*>(vT + dd * 40 + quad * 4) = s0;
      *reinterpret_cast<short4v*>(vT + dd * 40 + 16 + quad * 4) = s1;
    }
  }
  __syncthreads();
  // ---- scores MFMA -> P = exp(s) bf16 directly (no max: |s| <~ 7) ----
  {
    const float scale2 = 0.08838834764831845f;            // 1/sqrt(128)
    const int mt = wave >> 1, nt = wave & 1;
    float4v a = {0.f, 0.f, 0.f, 0.f};
#pragma unroll
    for (int kc = 0; kc < 4; ++kc) {
      short8v qf = *reinterpret_cast<const short8v*>(qs + (mt * 16 + l15) * 136 + kc * 32 + quad * 8);
      short8v kf = *reinterpret_cast<const short8v*>(ks + (nt * 16 + l15) * 136 + kc * 32 + quad * 8);
      a = MFMA16(qf, kf, a, 0, 0, 0);
    }
#pragma unroll
    for (int r = 0; r < 4; ++r) {
      int row = mt * 16 + quad * 4 + r;
      pb[row * 32 + nt * 16 + l15] = f2us(__expf(a[r] * scale2));
    }
  }
  __syncthreads();
  // ---- PV MFMA + ones-rowsum; scale by 1/sum in epilogue ----
  {
    short8v ones;
#pragma unroll
    for (int i = 0; i < 8; ++i) ones[i] = (short)0x3F80;  // bf16 1.0
    short8v pf[2], vf[2];
#pragma unroll
    for (int mt = 0; mt < 2; ++mt)
      pf[mt] = *reinterpret_cast<const short8v*>(pb + (mt * 16 + l15) * 32 + quad * 8);
    float4v sums[2];
#pragma unroll
    for (int mt = 0; mt < 2; ++mt) {
      sums[mt] = (float4v){0.f, 0.f, 0.f, 0.f};
      sums[mt] = MFMA16(pf[mt], ones, sums[mt], 0, 0, 0);
    }
#pragma unroll
    for (int ntl = 0; ntl < 2; ++ntl)
      vf[ntl] = *reinterpret_cast<const short8v*>(vT + ((2 * wave + ntl) * 16 + l15) * 40 + quad * 8);
    float4v oacc[2][2];
#pragma unroll
    for (int mt = 0; mt < 2; ++mt)
#pragma unroll
      for (int ntl = 0; ntl < 2; ++ntl) {
        oacc[mt][ntl] = (float4v){0.f, 0.f, 0.f, 0.f};
        oacc[mt][ntl] = MFMA16(pf[mt], vf[ntl], oacc[mt][ntl], 0, 0, 0);
      }
#pragma unroll
    for (int mt = 0; mt < 2; ++mt)
#pragma unroll
      for (int r = 0; r < 4; ++r) {
        int q = mt * 16 + quad * 4 + r;
        float inv = 1.f / sums[mt][r];
#pragma unroll
        for (int ntl = 0; ntl < 2; ++ntl)
          attn[((size_t)b * 32 + q) * 512 + h * 128 + (2 * wave + ntl) * 16 + l15] =
              oacc[mt][ntl][r] * inv;
      }
  }
}

// ---------------------------------------------------------------------------
// proj GEMM via MFMA (M=16/block, N=512, K=512) + bias + residual + LN.
// ---------------------------------------------------------------------------
__global__ __launch_bounds__(256, 2) void k_projln_mfma(
    const float* __restrict__ X, const unsigned short* __restrict__ Wb,
    const float* __restrict__ bias, const float* __restrict__ res,
    const float* __restrict__ gam, const float* __restrict__ bet,
    float* __restrict__ Y)
{
  const int row0 = blockIdx.x * 16, tid = threadIdx.x;
  __shared__ alignas(16) unsigned short xs[16 * 520];
  __shared__ float ys[16 * 516];
  for (int i = tid; i < 16 * 512; i += 256) {
    int t = i >> 9, c = i & 511;
    xs[t * 520 + c] = f2us(X[(size_t)(row0 + t) * 512 + c]);
  }
  __syncthreads();
  {
    const int lane = tid & 63, wave = tid >> 6;
    const int l15 = lane & 15, quad = lane >> 4;
    short8v af[16];
#pragma unroll
    for (int kc = 0; kc < 16; ++kc)
      af[kc] = *reinterpret_cast<const short8v*>(xs + l15 * 520 + kc * 32 + quad * 8);
    for (int ni = 0; ni < 8; ++ni) {
      int col = (wave + ni * 4) * 16 + l15;
      const unsigned short* wrow = Wb + (size_t)col * 512;
      float4v acc = {0.f,0.f,0.f,0.f};
#pragma unroll
      for (int kc = 0; kc < 16; ++kc) {
        short8v bfr = *reinterpret_cast<const short8v*>(wrow + kc * 32 + quad * 8);
        acc = MFMA16(af[kc], bfr, acc, 0, 0, 0);
      }
      float bj = bias[col];
#pragma unroll
      for (int r = 0; r < 4; ++r)
        ys[(quad * 4 + r) * 516 + col] = acc[r] + bj;
    }
  }
  __syncthreads();
  for (int i = tid; i < 16 * 512; i += 256) {
    int t = i >> 9, c = i & 511;
    ys[t * 516 + c] += res[(size_t)(row0 + t) * 512 + c];
  }
  __syncthreads();
  {
    int row = tid >> 4, l16 = tid & 15;
    const float* yr = ys + row * 516;
    float part = 0.f;
#pragma unroll
    for (int k = 0; k < 32; ++k) part += yr[l16 + 16 * k];
#pragma unroll
    for (int off = 8; off; off >>= 1) part += __shfl_xor(part, off, 16);
    float mean = part * (1.f / 512.f);
    float var = 0.f;
#pragma unroll
    for (int k = 0; k < 32; ++k) { float d = yr[l16 + 16 * k] - mean; var += d * d; }
#pragma unroll
    for (int off = 8; off; off >>= 1) var += __shfl_xor(var, off, 16);
    float rs = rsqrtf(var * (1.f / 512.f) + 1e-5f);
    for (int k = 0; k < 32; ++k) {
      int c = l16 + 16 * k;
      Y[(size_t)(row0 + row) * 512 + c] = (yr[c] - mean) * rs * gam[c] + bet[c];
    }
  }
}

// ---------------------------------------------------------------------------
// FUSED ff1+relu+ff2+residual+LN (M=16/block), register-pressure-managed:
// both GEMM phases reload the A-frag per k-chunk from LDS. In-place Y.
// LDS: xs 16,640 + f1L 33,024 = 49,664 B -> 3 blocks/CU.
// ---------------------------------------------------------------------------
__global__ __launch_bounds__(256, 3) void k_ffln(
    const float* __restrict__ X, const unsigned short* __restrict__ W1,
    const float* __restrict__ b1, const unsigned short* __restrict__ W2,
    const float* __restrict__ b2, const float* __restrict__ res,
    const float* __restrict__ gam, const float* __restrict__ bet,
    float* __restrict__ Y)
{
  const int row0 = blockIdx.x * 16, tid = threadIdx.x;
  __shared__ alignas(16) unsigned short xs[16 * 520];
  __shared__ alignas(16) unsigned short f1L[16 * 1032];   // ys [16][516] fp32 overlays
  float* ys = reinterpret_cast<float*>(f1L);
  const int lane = tid & 63, wave = tid >> 6;
  const int l15 = lane & 15, quad = lane >> 4;
  for (int i = tid; i < 16 * 512; i += 256) {
    int t = i >> 9, c = i & 511;
    xs[t * 520 + c] = f2us(X[(size_t)(row0 + t) * 512 + c]);
  }
  __syncthreads();
  // ff1: N=1024, K=512 -> relu -> f1L bf16 (reload A per kc: low pressure)
  for (int ni = 0; ni < 16; ++ni) {
    int col = (wave + ni * 4) * 16 + l15;
    const unsigned short* wrow = W1 + (size_t)col * 512;
    float4v acc = {0.f,0.f,0.f,0.f};
#pragma unroll
    for (int kc = 0; kc < 16; ++kc) {
      short8v a = *reinterpret_cast<const short8v*>(xs + l15 * 520 + kc * 32 + quad * 8);
      short8v bfr = *reinterpret_cast<const short8v*>(wrow + kc * 32 + quad * 8);
      acc = MFMA16(a, bfr, acc, 0, 0, 0);
    }
    float bj = b1[col];
#pragma unroll
    for (int r = 0; r < 4; ++r)
      f1L[(quad * 4 + r) * 1032 + col] = f2us(fmaxf(acc[r] + bj, 0.f));
  }
  __syncthreads();
  // ff2: N=512, K=1024 from f1L; hold acc2[8] only, reload A per kc
  float4v acc2[8];
#pragma unroll
  for (int ni = 0; ni < 8; ++ni) acc2[ni] = (float4v){0.f,0.f,0.f,0.f};
  int cols2[8];
#pragma unroll
  for (int ni = 0; ni < 8; ++ni) cols2[ni] = (wave + ni * 4) * 16 + l15;
  for (int half = 0; half < 2; ++half) {
    for (int kc = 0; kc < 16; ++kc) {
      short8v a = *reinterpret_cast<const short8v*>(
          f1L + l15 * 1032 + half * 512 + kc * 32 + quad * 8);
#pragma unroll
      for (int ni = 0; ni < 8; ++ni) {
        short8v bfr = *reinterpret_cast<const short8v*>(
            W2 + (size_t)cols2[ni] * 1024 + half * 512 + kc * 32 + quad * 8);
        acc2[ni] = MFMA16(a, bfr, acc2[ni], 0, 0, 0);
      }
    }
  }
  __syncthreads();                                        // f1L dead -> ys
  for (int ni = 0; ni < 8; ++ni) {
    int col = cols2[ni];
    float bj = b2[col];
#pragma unroll
    for (int r = 0; r < 4; ++r)
      ys[(quad * 4 + r) * 516 + col] = acc2[ni][r] + bj;
  }
  __syncthreads();
  for (int i = tid; i < 16 * 512; i += 256) {
    int t = i >> 9, c = i & 511;
    ys[t * 516 + c] += res[(size_t)(row0 + t) * 512 + c];
  }
  __syncthreads();
  {
    int row = tid >> 4, l16 = tid & 15;
    const float* yr = ys + row * 516;
    float part = 0.f;
#pragma unroll
    for (int k = 0; k < 32; ++k) part += yr[l16 + 16 * k];
#pragma unroll
    for (int off = 8; off; off >>= 1) part += __shfl_xor(part, off, 16);
    float mean = part * (1.f / 512.f);
    float var = 0.f;
#pragma unroll
    for (int k = 0; k < 32; ++k) { float d = yr[l16 + 16 * k] - mean; var += d * d; }
#pragma unroll
    for (int off = 8; off; off >>= 1) var += __shfl_xor(var, off, 16);
    float rs = rsqrtf(var * (1.f / 512.f) + 1e-5f);
    for (int k = 0; k < 32; ++k) {
      int c = l16 + 16 * k;
      Y[(size_t)(row0 + row) * 512 + c] = (yr[c] - mean) * rs * gam[c] + bet[c];
    }
  }
}

// ---------------------------------------------------------------------------
// Final: mean-pool, temporal MLP, concat, classifier, LN, relu -> fp32
// ---------------------------------------------------------------------------
__global__ __launch_bounds__(256) void k_final(
    const float* __restrict__ g2,
    const float* __restrict__ db, const float* __restrict__ dsl,
    const float* __restrict__ te1_w, const float* __restrict__ te1_b,
    const float* __restrict__ l1g, const float* __restrict__ l1b,
    const float* __restrict__ te2_w, const float* __restrict__ te2_b,
    const float* __restrict__ l2g, const float* __restrict__ l2b,
    const float* __restrict__ c_w, const float* __restrict__ c_b,
    const float* __restrict__ clg, const float* __restrict__ clb,
    float* __restrict__ out)
{
  const int b = blockIdx.x, tid = threadIdx.x;
  __shared__ float cat[640];
  __shared__ float t1[64];
  __shared__ float t2[128];
  __shared__ float pre[256];
  __shared__ float red[256];
  __shared__ float st[2];
  for (int i = tid; i < 512; i += 256) {
    float acc = 0.f;
#pragma unroll
    for (int t = 0; t < 32; ++t) acc += g2[((size_t)b * 32 + t) * 512 + i];
    cat[i] = acc * (1.f / 32.f);
  }
  if (tid == 0) {
    float s = 0.f;
    for (int i = 0; i < 31; ++i) s += db[b * 31 + i];
    st[0] = s / 31.f;
    st[1] = dsl[b];
  }
  __syncthreads();
  const float f0 = st[0], f1v = st[1];
  if (tid < 64)
    t1[tid] = f0 * te1_w[tid * 2] + f1v * te1_w[tid * 2 + 1] + te1_b[tid];
  __syncthreads();
  if (tid == 0) {
    float m = 0.f; for (int i = 0; i < 64; ++i) m += t1[i]; m *= (1.f / 64.f);
    float v = 0.f; for (int i = 0; i < 64; ++i) { float d = t1[i] - m; v += d * d; }
    st[0] = m; st[1] = rsqrtf(v * (1.f / 64.f) + 1e-5f);
  }
  __syncthreads();
  if (tid < 64) {
    float v = (t1[tid] - st[0]) * st[1] * l1g[tid] + l1b[tid];
    t1[tid] = fmaxf(v, 0.f);
  }
  __syncthreads();
  if (tid < 128)
    t2[tid] = dot_ff(t1, te2_w + (size_t)tid * 64, 64) + te2_b[tid];
  __syncthreads();
  if (tid == 0) {
    float m = 0.f; for (int i = 0; i < 128; ++i) m += t2[i]; m *= (1.f / 128.f);
    float v = 0.f; for (int i = 0; i < 128; ++i) { float d = t2[i] - m; v += d * d; }
    st[0] = m; st[1] = rsqrtf(v * (1.f / 128.f) + 1e-5f);
  }
  __syncthreads();
  if (tid < 128) {
    float v = (t2[tid] - st[0]) * st[1] * l2g[tid] + l2b[tid];
    cat[512 + tid] = fmaxf(v, 0.f);
  }
  __syncthreads();
  pre[tid] = dot_ff(cat, c_w + (size_t)tid * 640, 640) + c_b[tid];
  red[tid] = pre[tid];
  __syncthreads();
  for (int s = 128; s > 0; s >>= 1) { if (tid < s) red[tid] += red[tid + s]; __syncthreads(); }
  const float m = red[0] * (1.f / 256.f);
  __syncthreads();
  const float d = pre[tid] - m;
  red[tid] = d * d;
  __syncthreads();
  for (int s = 128; s > 0; s >>= 1) { if (tid < s) red[tid] += red[tid + s]; __syncthreads(); }
  const float rs = rsqrtf(red[0] * (1.f / 256.f) + 1e-5f);
  float v = d * rs * clg[tid] + clb[tid];
  out[(size_t)b * 256 + tid] = fmaxf(v, 0.f);
}

// ---------------------------------------------------------------------------
extern "C" void kernel_launch(void* const* d_in, const int* in_sizes, int n_in,
                              void* d_out, int out_size, void* d_ws, size_t ws_size,
                              hipStream_t stream) {
  (void)in_sizes; (void)n_in; (void)out_size; (void)ws_size;
  const int*   oh     = (const int*)  d_in[0];
  const float* db     = (const float*)d_in[1];
  const float* dsl    = (const float*)d_in[2];
  const float* emb    = (const float*)d_in[3];
  const float* a_in_w = (const float*)d_in[4];
  const float* a_in_b = (const float*)d_in[5];
  const float* a_out_w= (const float*)d_in[6];
  const float* a_out_b= (const float*)d_in[7];
  const float* wih_f  = (const float*)d_in[8];
  const float* whh_f  = (const float*)d_in[9];
  const float* bih_f  = (const float*)d_in[10];
  const float* bhh_f  = (const float*)d_in[11];
  const float* wih_b  = (const float*)d_in[12];
  const float* whh_b  = (const float*)d_in[13];
  const float* bih_b  = (const float*)d_in[14];
  const float* bhh_b  = (const float*)d_in[15];
  const float* t_in_w = (const float*)d_in[16];
  const float* t_in_b = (const float*)d_in[17];
  const float* t_out_w= (const float*)d_in[18];
  const float* t_out_b= (const float*)d_in[19];
  const float* t_ln1g = (const float*)d_in[20];
  const float* t_ln1b = (const float*)d_in[21];
  const float* t_ff1w = (const float*)d_in[22];
  const float* t_ff1b = (const float*)d_in[23];
  const float* t_ff2w = (const float*)d_in[24];
  const float* t_ff2b = (const float*)d_in[25];
  const float* t_ln2g = (const float*)d_in[26];
  const float* t_ln2b = (const float*)d_in[27];
  const float* te1_w  = (const float*)d_in[28];
  const float* te1_b  = (const float*)d_in[29];
  const float* tl1g   = (const float*)d_in[30];
  const float* tl1b   = (const float*)d_in[31];
  const float* te2_w  = (const float*)d_in[32];
  const float* te2_b  = (const float*)d_in[33];
  const float* tl2g   = (const float*)d_in[34];
  const float* tl2b   = (const float*)d_in[35];
  const float* c_w    = (const float*)d_in[36];
  const float* c_b    = (const float*)d_in[37];
  const float* clng   = (const float*)d_in[38];
  const float* clnb   = (const float*)d_in[39];

  float* ws = (float*)d_ws;
  // Workspace (float slots), max index 17,391,616 (~69.6 MB):
  //   A [0,        524288):  oeb bf16 [8192][128]
  //   B [1048576,  5242880): embb bf16 (dead after order_attn) -> g fp32
  //   C [5242880,  9437184): attn fp32; g1 LN in-place; g2 ffln in-place
  //   D [9437184,  9633792): whhb bf16 [2][768][256]
  //   D2[9633792,  9732096): wihb bf16 [2][768][128]
  //   D3[9732096,  9740288): awb2 bf16 [128*128]
  //   E [10027008,10051584): awb bf16 [384*128]
  //   F [10051584,10444800): twb bf16 [1536*512]
  //   G [10444800,10575872): pwb bf16 [512*512]
  //   G2[10575872,10838016): f1wb bf16 [1024*512]
  //   G3[10838016,11100160): f2wb bf16 [512*1024]
  //   H [11100160,17391616): gi bf16 [8192*1536]
  unsigned short* oeb = (unsigned short*)ws;
  unsigned short* embb= (unsigned short*)(ws + 1048576);
  float* g    = ws + 1048576;                           // over dead embb
  float* attn = ws + 5242880;
  float* g1   = attn;                                   // in-place LN out
  float* g2   = attn;                                   // in-place ffln out
  unsigned short* whhb = (unsigned short*)(ws + 9437184);
  unsigned short* wihb = (unsigned short*)(ws + 9633792);
  unsigned short* awb2 = (unsigned short*)(ws + 9732096);
  unsigned short* awb  = (unsigned short*)(ws + 10027008);
  unsigned short* twb  = (unsigned short*)(ws + 10051584);
  unsigned short* pwb  = (unsigned short*)(ws + 10444800);
  unsigned short* f1wb = (unsigned short*)(ws + 10575872);
  unsigned short* f2wb = (unsigned short*)(ws + 10838016);
  unsigned short* gi   = (unsigned short*)(ws + 11100160);

  k_canary<<<256, 256, 0, stream>>>((float*)d_out);
  k_cvt<<<6212, 256, 0, stream>>>(a_in_w, t_in_w, t_out_w, t_ff1w, t_ff2w, a_out_w,
                                  emb, awb, twb, pwb, f1wb, f2wb, awb2, embb);
  k_gru_wb<<<1536, 256, 0, stream>>>(wih_f, whh_f, wih_b, whh_b, whhb, wihb);
  k_order_attn<<<8192, 256, 0, stream>>>(oh, embb, awb, a_in_b, awb2, a_out_b, oeb);
  k_gru_gi<<<256, 256, 0, stream>>>(oeb, wihb, gi);
  k_gru_rec<<<dim3(128, 2), 512, 0, stream>>>(gi, whhb, bih_f, bhh_f, bih_b, bhh_b, g);
  k_mha2f<<<dim3(256, 4), 256, 0, stream>>>(g, twb, t_in_b, attn);
  k_projln_mfma<<<512, 256, 0, stream>>>(attn, pwb, t_out_b, g, t_ln1g, t_ln1b, g1);
  k_ffln<<<512, 256, 0, stream>>>(g1, f1wb, t_ff1b, f2wb, t_ff2b, g1,
                                  t_ln2g, t_ln2b, g2);
  k_final<<<256, 256, 0, stream>>>(g2, db, dsl, te1_w, te1_b, tl1g, tl1b,
                                   te2_w, te2_b, tl2g, tl2b, c_w, c_b, clng, clnb,
                                   (float*)d_out);
}

// Round 11
// 601.364 us; speedup vs baseline: 1.0945x; 1.0253x over previous
//
#include <hip/hip_runtime.h>
#include <hip/hip_bf16.h>
#include <math.h>

typedef __hip_bfloat16 bf16;
typedef __attribute__((ext_vector_type(8))) short short8v;   // 8 bf16 (4 VGPRs)
typedef __attribute__((ext_vector_type(4))) short short4v;   // 4 bf16 (2 VGPRs)
typedef __attribute__((ext_vector_type(4))) float float4v;   // 4 fp32 acc
#define MFMA16 __builtin_amdgcn_mfma_f32_16x16x32_bf16

__device__ __forceinline__ float us2f(unsigned short u) {
  union { unsigned u; float f; } c; c.u = ((unsigned)u) << 16; return c.f;
}
__device__ __forceinline__ unsigned short f2us(float f) {
  return __bfloat16_as_ushort(__float2bfloat16(f));
}

// fp32 x . fp32 w, K % 8 == 0, 16B-aligned
__device__ __forceinline__ float dot_ff(const float* __restrict__ x,
                                        const float* __restrict__ w, int K) {
  const float4* xp = reinterpret_cast<const float4*>(x);
  const float4* wp = reinterpret_cast<const float4*>(w);
  float acc = 0.f;
  const int n = K >> 2;
  for (int i = 0; i < n; ++i) {
    float4 a = xp[i], b = wp[i];
    acc += a.x*b.x + a.y*b.y + a.z*b.z + a.w*b.w;
  }
  return acc;
}

// native-exp sigmoid / tanh (clamped; serial-path hot in GRU)
__device__ __forceinline__ float sigm(float x) { return 1.f / (1.f + __expf(-x)); }
__device__ __forceinline__ float tanh_fast(float x) {
  x = fminf(fmaxf(x, -15.f), 15.f);
  float e = __expf(2.f * x);
  return (e - 1.f) / (e + 1.f);
}

// ---------------------------------------------------------------------------
__global__ void k_canary(float* __restrict__ out) {
  out[blockIdx.x * 256 + threadIdx.x] = 100.0f;
}

// ---------------------------------------------------------------------------
// One-shot: convert MFMA-consumed weights AND the emb table to bf16 in ws.
// ---------------------------------------------------------------------------
__global__ __launch_bounds__(256) void k_cvt(
    const float* __restrict__ a_in_w, const float* __restrict__ t_in_w,
    const float* __restrict__ t_out_w, const float* __restrict__ t_ff1w,
    const float* __restrict__ t_ff2w, const float* __restrict__ a_out_w,
    const float* __restrict__ emb,
    unsigned short* __restrict__ awb, unsigned short* __restrict__ twb,
    unsigned short* __restrict__ pwb, unsigned short* __restrict__ f1wb,
    unsigned short* __restrict__ f2wb, unsigned short* __restrict__ awb2,
    unsigned short* __restrict__ embb)
{
  int i = blockIdx.x * 256 + threadIdx.x;
  if (i < 1590048) {                                  // embb, 4 elems/thread
    float4 e4 = *reinterpret_cast<const float4*>(emb + (size_t)i * 4);
    short4v s; s[0] = f2us(e4.x); s[1] = f2us(e4.y); s[2] = f2us(e4.z); s[3] = f2us(e4.w);
    *reinterpret_cast<short4v*>(embb + (size_t)i * 4) = s;
  }
  if (i < 49152)  awb[i] = f2us(a_in_w[i]);
  if (i < 786432) twb[i] = f2us(t_in_w[i]);
  if (i < 262144) pwb[i] = f2us(t_out_w[i]);
  if (i < 524288) f1wb[i] = f2us(t_ff1w[i]);
  if (i < 524288) f2wb[i] = f2us(t_ff2w[i]);
  if (i < 16384)  awb2[i] = f2us(a_out_w[i]);
}

// ---------------------------------------------------------------------------
// GRU weight prep: row-major bf16 copies. whhb [dir][768][256],
// wihb [dir][768][128] (for gi GEMM).
// ---------------------------------------------------------------------------
__global__ __launch_bounds__(256) void k_gru_wb(
    const float* __restrict__ wih_f, const float* __restrict__ whh_f,
    const float* __restrict__ wih_b, const float* __restrict__ whh_b,
    unsigned short* __restrict__ whhb, unsigned short* __restrict__ wihb)
{
  int i = blockIdx.x * 256 + threadIdx.x;   // < 393216
  if (i >= 393216) return;
  int dir = i / 196608, r = i % 196608;
  whhb[i] = f2us((dir ? whh_b : whh_f)[r]);
  if (r < 98304) wihb[dir * 98304 + r] = f2us((dir ? wih_b : wih_f)[r]);
}

// ---------------------------------------------------------------------------
// Stage 1: embed + per-order MHA + proj-then-mean. Staged bf16 gather.
// Softmax: no-max native exp + row-sums via MFMA(P, ones).
// LDS overlays, 3 x 8,704 B = 26,112 B -> 6 blocks/CU (LDS-bound):
//   regA: xs [32][136] -> vT [128][32] (stride 32)
//   qb:   q -> O;  kb: k -> P [128][32]
// ---------------------------------------------------------------------------
__global__ __launch_bounds__(256, 5) void k_order_attn(
    const int* __restrict__ oh, const unsigned short* __restrict__ embb,
    const unsigned short* __restrict__ awb, const float* __restrict__ in_b,
    const unsigned short* __restrict__ awb2, const float* __restrict__ out_b,
    unsigned short* __restrict__ oeb)
{
  const int bo = blockIdx.x;            // 0..8191
  const int tid = threadIdx.x;
  __shared__ alignas(16) unsigned short regA[32 * 136];   // xs -> vT[128][32]
  __shared__ alignas(16) unsigned short qb[32 * 136];     // q -> O
  __shared__ alignas(16) unsigned short kb[32 * 136];     // k -> P
  unsigned short* xs = regA;
  unsigned short* vT = regA;                              // stride 32
  unsigned short* ob = qb;
  unsigned short* pb = kb;

  const int lane = tid & 63, wave = tid >> 6;
  const int l15 = lane & 15, quad = lane >> 4;

  // staged bf16 gather, 16B/lane (coalesced per row-chunk)
  for (int i = tid; i < 512; i += 256) {
    int t = i >> 4, c8 = (i & 15) << 3;
    int id = oh[bo * 32 + t];
    *reinterpret_cast<short8v*>(xs + t * 136 + c8) =
        *reinterpret_cast<const short8v*>(embb + (size_t)id * 128 + c8);
  }
  __syncthreads();
  short8v af[2][4];
#pragma unroll
  for (int mt = 0; mt < 2; ++mt)
#pragma unroll
    for (int kc = 0; kc < 4; ++kc)
      af[mt][kc] = *reinterpret_cast<const short8v*>(
          xs + (mt * 16 + l15) * 136 + kc * 32 + quad * 8);
  __syncthreads();                       // xs dead -> vT region writable
  // ---- QKV MFMA: qkv[t][j] = x[t][.] . w[j][.] ----
  for (int ni = 0; ni < 6; ++ni) {
    const int j = (wave + ni * 4) * 16 + l15;
    const unsigned short* wrow = awb + (size_t)j * 128;
    float4v acc0 = {0.f, 0.f, 0.f, 0.f}, acc1 = {0.f, 0.f, 0.f, 0.f};
#pragma unroll
    for (int kc = 0; kc < 4; ++kc) {
      short8v bfr = *reinterpret_cast<const short8v*>(wrow + kc * 32 + quad * 8);
      acc0 = MFMA16(af[0][kc], bfr, acc0, 0, 0, 0);
      acc1 = MFMA16(af[1][kc], bfr, acc1, 0, 0, 0);
    }
    const float bj = in_b[j];
    const int jj = j & 127;
    if (j < 256) {
      unsigned short* dst = (j < 128) ? qb : kb;
#pragma unroll
      for (int r = 0; r < 4; ++r) {
        int t0 = quad * 4 + r;
        dst[t0 * 136 + jj] = f2us(acc0[r] + bj);
        dst[(t0 + 16) * 136 + jj] = f2us(acc1[r] + bj);
      }
    } else {                              // V transposed: vT[d][k], stride 32
      short4v s0, s1;
#pragma unroll
      for (int r = 0; r < 4; ++r) { s0[r] = f2us(acc0[r] + bj); s1[r] = f2us(acc1[r] + bj); }
      *reinterpret_cast<short4v*>(vT + jj * 32 + quad * 4) = s0;
      *reinterpret_cast<short4v*>(vT + jj * 32 + 16 + quad * 4) = s1;
    }
  }
  __syncthreads();
  // ---- FUSED: scores + exp + PV + ones-rowsum + O write (wave = head) ----
  {
    const int h = wave;
    const float scale1 = 0.17677669529663687f;            // 1/sqrt(32)
    short8v qf[2], kf[2];
#pragma unroll
    for (int mt = 0; mt < 2; ++mt)
      qf[mt] = *reinterpret_cast<const short8v*>(qb + (mt * 16 + l15) * 136 + h * 32 + quad * 8);
#pragma unroll
    for (int nt = 0; nt < 2; ++nt)
      kf[nt] = *reinterpret_cast<const short8v*>(kb + (nt * 16 + l15) * 136 + h * 32 + quad * 8);
    float4v sacc[2][2];
#pragma unroll
    for (int mt = 0; mt < 2; ++mt)
#pragma unroll
      for (int nt = 0; nt < 2; ++nt) {
        sacc[mt][nt] = (float4v){0.f, 0.f, 0.f, 0.f};
        sacc[mt][nt] = MFMA16(qf[mt], kf[nt], sacc[mt][nt], 0, 0, 0);
      }
    __syncthreads();                     // all qb/kb reg-reads done -> P/O writes ok
    // P = exp(s) (no max subtraction: |s| <~ 2, safe)
#pragma unroll
    for (int mt = 0; mt < 2; ++mt)
#pragma unroll
      for (int r = 0; r < 4; ++r) {
        float e0 = __expf(sacc[mt][0][r] * scale1);
        float e1 = __expf(sacc[mt][1][r] * scale1);
        int row = h * 32 + mt * 16 + quad * 4 + r;
        pb[row * 32 + l15] = f2us(e0);
        pb[row * 32 + 16 + l15] = f2us(e1);
      }
    // ones fragment for rowsum MFMA
    short8v ones;
#pragma unroll
    for (int i = 0; i < 8; ++i) ones[i] = (short)0x3F80;  // bf16 1.0
    // PV (same-wave LDS write->read; in-order LDS pipe per wave)
    short8v pf[2], vf[2];
#pragma unroll
    for (int mt = 0; mt < 2; ++mt)
      pf[mt] = *reinterpret_cast<const short8v*>(pb + (h * 32 + mt * 16 + l15) * 32 + quad * 8);
    float4v sums[2];
#pragma unroll
    for (int mt = 0; mt < 2; ++mt) {
      sums[mt] = (float4v){0.f, 0.f, 0.f, 0.f};
      sums[mt] = MFMA16(pf[mt], ones, sums[mt], 0, 0, 0);  // rowsums in C layout
    }
#pragma unroll
    for (int nt = 0; nt < 2; ++nt)
      vf[nt] = *reinterpret_cast<const short8v*>(vT + (h * 32 + nt * 16 + l15) * 32 + quad * 8);
    float4v oacc[2][2];
#pragma unroll
    for (int mt = 0; mt < 2; ++mt)
#pragma unroll
      for (int nt = 0; nt < 2; ++nt) {
        oacc[mt][nt] = (float4v){0.f, 0.f, 0.f, 0.f};
        oacc[mt][nt] = MFMA16(pf[mt], vf[nt], oacc[mt][nt], 0, 0, 0);
      }
    // write O bf16 into ob (qb overlay): this wave's head-col stripe
#pragma unroll
    for (int mt = 0; mt < 2; ++mt)
#pragma unroll
      for (int r = 0; r < 4; ++r) {
        int t = mt * 16 + quad * 4 + r;
        float inv = 1.f / sums[mt][r];
#pragma unroll
        for (int nt = 0; nt < 2; ++nt)
          ob[t * 136 + h * 32 + nt * 16 + l15] = f2us(oacc[mt][nt][r] * inv);
      }
  }
  __syncthreads();
  // ---- out-proj MFMA: proj[t][j] = O[t][.] . W[j][.]; then mean over t ----
  {
    float4v acc[2][2];
#pragma unroll
    for (int mt = 0; mt < 2; ++mt)
#pragma unroll
      for (int nt = 0; nt < 2; ++nt) acc[mt][nt] = (float4v){0.f, 0.f, 0.f, 0.f};
#pragma unroll
    for (int kc = 0; kc < 4; ++kc) {
      short8v af0 = *reinterpret_cast<const short8v*>(ob + l15 * 136 + kc * 32 + quad * 8);
      short8v af1 = *reinterpret_cast<const short8v*>(ob + (16 + l15) * 136 + kc * 32 + quad * 8);
#pragma unroll
      for (int nt = 0; nt < 2; ++nt) {
        int j = (wave * 2 + nt) * 16 + l15;
        short8v bfr = *reinterpret_cast<const short8v*>(awb2 + (size_t)j * 128 + kc * 32 + quad * 8);
        acc[0][nt] = MFMA16(af0, bfr, acc[0][nt], 0, 0, 0);
        acc[1][nt] = MFMA16(af1, bfr, acc[1][nt], 0, 0, 0);
      }
    }
#pragma unroll
    for (int nt = 0; nt < 2; ++nt) {
      float part = 0.f;
#pragma unroll
      for (int mt = 0; mt < 2; ++mt)
#pragma unroll
        for (int r = 0; r < 4; ++r) part += acc[mt][nt][r];
      part += __shfl_xor(part, 16);
      part += __shfl_xor(part, 32);
      if (quad == 0) {
        int j = (wave * 2 + nt) * 16 + l15;
        oeb[(size_t)bo * 128 + j] = f2us(part * (1.f / 32.f) + out_b[j]);
      }
    }
  }
}

// ---------------------------------------------------------------------------
// gi GEMM (MFMA): gi[8192][1536] bf16 = oe @ wih^T (both dirs). oe is bf16.
// ---------------------------------------------------------------------------
__global__ __launch_bounds__(256, 2) void k_gru_gi(
    const unsigned short* __restrict__ oeb, const unsigned short* __restrict__ wihb,
    unsigned short* __restrict__ gi)
{
  const int row0 = blockIdx.x * 32, tid = threadIdx.x;
  __shared__ alignas(16) unsigned short xs[32 * 136];
  for (int i = tid; i < 512; i += 256) {
    int t = i >> 4, c8 = (i & 15) << 3;
    *reinterpret_cast<short8v*>(xs + t * 136 + c8) =
        *reinterpret_cast<const short8v*>(oeb + (size_t)(row0 + t) * 128 + c8);
  }
  __syncthreads();
  const int lane = tid & 63, wave = tid >> 6;
  const int l15 = lane & 15, quad = lane >> 4;
  short8v af[2][4];
#pragma unroll
  for (int mt = 0; mt < 2; ++mt)
#pragma unroll
    for (int kc = 0; kc < 4; ++kc)
      af[mt][kc] = *reinterpret_cast<const short8v*>(
          xs + (mt * 16 + l15) * 136 + kc * 32 + quad * 8);
  for (int ni = 0; ni < 24; ++ni) {
    int col = (wave + ni * 4) * 16 + l15;
    const unsigned short* wrow = wihb + (size_t)col * 128;
    float4v a0 = {0.f,0.f,0.f,0.f}, a1 = {0.f,0.f,0.f,0.f};
#pragma unroll
    for (int kc = 0; kc < 4; ++kc) {
      short8v bfr = *reinterpret_cast<const short8v*>(wrow + kc * 32 + quad * 8);
      a0 = MFMA16(af[0][kc], bfr, a0, 0, 0, 0);
      a1 = MFMA16(af[1][kc], bfr, a1, 0, 0, 0);
    }
#pragma unroll
    for (int r = 0; r < 4; ++r) {
      gi[(size_t)(row0 + quad * 4 + r) * 1536 + col] = f2us(a0[r]);
      gi[(size_t)(row0 + quad * 4 + r + 16) * 1536 + col] = f2us(a1[r]);
    }
  }
}

// ---------------------------------------------------------------------------
// GRU recurrence via MFMA. 2 batches/block, grid (128,2) = 256 blocks,
// 512 threads (8 waves). whh register-resident. gi for step s+1 prefetched
// into registers before the barrier. Native-exp pointwise.
// LDS: hb 8448 + pg 6176 = 14,624 B.
// ---------------------------------------------------------------------------
__global__ __launch_bounds__(512, 2) void k_gru_rec(
    const unsigned short* __restrict__ gi, const unsigned short* __restrict__ whhb,
    const float* __restrict__ bih_f, const float* __restrict__ bhh_f,
    const float* __restrict__ bih_b, const float* __restrict__ bhh_b,
    float* __restrict__ g)
{
  const int b0 = blockIdx.x * 2, dir = blockIdx.y;
  const int tid = threadIdx.x;           // 0..511
  const unsigned short* wb = whhb + (size_t)dir * 196608;   // [768][256] bf16
  const float* bih = dir ? bih_b : bih_f;
  const float* bhh = dir ? bhh_b : bhh_f;
  __shared__ alignas(16) unsigned short hb[16 * 264];   // h bf16 (A operand)
  __shared__ float pg[2 * 772];                         // gh fp32 (rows 0-1)
  const int lane = tid & 63, wave = tid >> 6;
  const int l15 = lane & 15, quad = lane >> 4;
  const int j = tid & 255, mb = tid >> 8;               // pointwise: (m=mb, j)
  const float bir = bih[j], biz = bih[256 + j], bin_ = bih[512 + j];
  const float bhr = bhh[j], bhz = bhh[256 + j], bhn  = bhh[512 + j];
  short8v wf[6][8];
  int cols[6];
#pragma unroll
  for (int ni = 0; ni < 6; ++ni) {
    cols[ni] = (wave + ni * 8) * 16 + l15;
#pragma unroll
    for (int kc = 0; kc < 8; ++kc)
      wf[ni][kc] = *reinterpret_cast<const short8v*>(
          wb + (size_t)cols[ni] * 256 + kc * 32 + quad * 8);
  }
  for (int i = tid; i < 16 * 264; i += 512) hb[i] = 0;
  int tcur = dir ? 31 : 0;
  size_t gbase = ((size_t)(b0 + mb) * 32 + tcur) * 1536 + dir * 768;
  float gr = us2f(gi[gbase + j]);
  float gz = us2f(gi[gbase + 256 + j]);
  float gn = us2f(gi[gbase + 512 + j]);
  __syncthreads();
  for (int s = 0; s < 32; ++s) {
    float4v acc[6];
#pragma unroll
    for (int ni = 0; ni < 6; ++ni) acc[ni] = (float4v){0.f, 0.f, 0.f, 0.f};
#pragma unroll
    for (int kc = 0; kc < 8; ++kc) {
      short8v af = *reinterpret_cast<const short8v*>(hb + l15 * 264 + kc * 32 + quad * 8);
#pragma unroll
      for (int ni = 0; ni < 6; ++ni)
        acc[ni] = MFMA16(af, wf[ni][kc], acc[ni], 0, 0, 0);
    }
    if (quad == 0) {
#pragma unroll
      for (int ni = 0; ni < 6; ++ni) {
        pg[cols[ni]] = acc[ni][0];
        pg[772 + cols[ni]] = acc[ni][1];
      }
    }
    float gr2 = 0.f, gz2 = 0.f, gn2 = 0.f;
    if (s < 31) {
      int t2 = dir ? (30 - s) : (s + 1);
      size_t gb2 = ((size_t)(b0 + mb) * 32 + t2) * 1536 + dir * 768;
      gr2 = us2f(gi[gb2 + j]);
      gz2 = us2f(gi[gb2 + 256 + j]);
      gn2 = us2f(gi[gb2 + 512 + j]);
    }
    __syncthreads();
    {
      const int tt = dir ? (31 - s) : s;
      float hprev = us2f(hb[mb * 264 + j]);
      float r = sigm(gr + bir + pg[mb * 772 + j] + bhr);
      float z = sigm(gz + biz + pg[mb * 772 + 256 + j] + bhz);
      float n = tanh_fast(gn + bin_ + r * (pg[mb * 772 + 512 + j] + bhn));
      float nh = (1.f - z) * n + z * hprev;
      hb[mb * 264 + j] = f2us(nh);
      g[((size_t)(b0 + mb) * 32 + tt) * 512 + dir * 256 + j] = nh;
    }
    gr = gr2; gz = gz2; gn = gn2;
    __syncthreads();
  }
}

// ---------------------------------------------------------------------------
// Stage 3 fused attention, one block per (b, head). x staged in K=128
// quarter-chunks (xs3 8,704 B) -> LDS 36,352 B -> 4 blocks/CU.
// Scores phase writes P = exp(s) bf16 directly; PV computes row-sums via
// MFMA(P, ones). No sc buffer, no softmax phase.
// ---------------------------------------------------------------------------
__global__ __launch_bounds__(256, 4) void k_mha2f(
    const float* __restrict__ g, const unsigned short* __restrict__ twb,
    const float* __restrict__ Bv, float* __restrict__ attn)
{
  const int b = blockIdx.x, h = blockIdx.y, tid = threadIdx.x;
  __shared__ alignas(16) unsigned short xs3[32 * 136];     // x chunk; P overlay
  __shared__ alignas(16) unsigned short qk[2 * 32 * 136];
  __shared__ alignas(16) unsigned short vT[128 * 40];      // vT[d][k]
  unsigned short* qs = qk;
  unsigned short* ks = qk + 32 * 136;
  unsigned short* pb = xs3;                                // P bf16 [32][32]
  const int lane = tid & 63, wave = tid >> 6;
  const int l15 = lane & 15, quad = lane >> 4;

  int wrowi[6];
#pragma unroll
  for (int ni = 0; ni < 6; ++ni) {
    int idx = (wave + ni * 4) * 16 + l15;
    int m = idx >> 7, dd = idx & 127;
    wrowi[ni] = m * 512 + h * 128 + dd;
  }
  float4v acc[6][2];
#pragma unroll
  for (int ni = 0; ni < 6; ++ni)
#pragma unroll
    for (int mt = 0; mt < 2; ++mt) acc[ni][mt] = (float4v){0.f, 0.f, 0.f, 0.f};

  for (int ck = 0; ck < 4; ++ck) {
    __syncthreads();
    for (int i = tid; i < 1024; i += 256) {                // x quarter load
      int t = i >> 5, c4 = (i & 31) << 2;
      float4 e4 = *reinterpret_cast<const float4*>(
          g + (size_t)b * 16384 + t * 512 + ck * 128 + c4);
      short4v s; s[0] = f2us(e4.x); s[1] = f2us(e4.y); s[2] = f2us(e4.z); s[3] = f2us(e4.w);
      *reinterpret_cast<short4v*>(xs3 + t * 136 + c4) = s;
    }
    __syncthreads();
    short8v af2[2][4];
#pragma unroll
    for (int mt = 0; mt < 2; ++mt)
#pragma unroll
      for (int u = 0; u < 4; ++u)
        af2[mt][u] = *reinterpret_cast<const short8v*>(
            xs3 + (mt * 16 + l15) * 136 + u * 32 + quad * 8);
#pragma unroll
    for (int ni = 0; ni < 6; ++ni) {
      const unsigned short* wrow = twb + (size_t)wrowi[ni] * 512 + ck * 128;
#pragma unroll
      for (int u = 0; u < 4; ++u) {
        short8v bfr = *reinterpret_cast<const short8v*>(wrow + u * 32 + quad * 8);
        acc[ni][0] = MFMA16(af2[0][u], bfr, acc[ni][0], 0, 0, 0);
        acc[ni][1] = MFMA16(af2[1][u], bfr, acc[ni][1], 0, 0, 0);
      }
    }
  }
  __syncthreads();                                         // xs3 reads done
#pragma unroll
  for (int ni = 0; ni < 6; ++ni) {
    int idx = (wave + ni * 4) * 16 + l15;
    int m = idx >> 7, dd = idx & 127;
    float bj = Bv[wrowi[ni]];
    if (m < 2) {
      unsigned short* dst = (m == 0) ? qs : ks;
#pragma unroll
      for (int r = 0; r < 4; ++r) {
        int t0 = quad * 4 + r;
        dst[t0 * 136 + dd] = f2us(acc[ni][0][r] + bj);
        dst[(t0 + 16) * 136 + dd] = f2us(acc[ni][1][r] + bj);
      }
    } else {
      short4v s0, s1;
#pragma unroll
      for (int r = 0; r < 4; ++r) { s0[r] = f2us(acc[ni][0][r] + bj); s1[r] = f2us(acc[ni][1][r] + bj); }
      *reinterpret_cast<short4v*>(vT + dd * 40 + quad * 4) = s0;
      *reinterpret_cast<short4v*>(vT + dd * 40 + 16 + quad * 4) = s1;
    }
  }
  __syncthreads();
  // ---- scores MFMA -> P = exp(s) bf16 directly (no max: |s| <~ 7) ----
  {
    const float scale2 = 0.08838834764831845f;            // 1/sqrt(128)
    const int mt = wave >> 1, nt = wave & 1;
    float4v a = {0.f, 0.f, 0.f, 0.f};
#pragma unroll
    for (int kc = 0; kc < 4; ++kc) {
      short8v qf = *reinterpret_cast<const short8v*>(qs + (mt * 16 + l15) * 136 + kc * 32 + quad * 8);
      short8v kf = *reinterpret_cast<const short8v*>(ks + (nt * 16 + l15) * 136 + kc * 32 + quad * 8);
      a = MFMA16(qf, kf, a, 0, 0, 0);
    }
#pragma unroll
    for (int r = 0; r < 4; ++r) {
      int row = mt * 16 + quad * 4 + r;
      pb[row * 32 + nt * 16 + l15] = f2us(__expf(a[r] * scale2));
    }
  }
  __syncthreads();
  // ---- PV MFMA + ones-rowsum; scale by 1/sum in epilogue ----
  {
    short8v ones;
#pragma unroll
    for (int i = 0; i < 8; ++i) ones[i] = (short)0x3F80;  // bf16 1.0
    short8v pf[2], vf[2];
#pragma unroll
    for (int mt = 0; mt < 2; ++mt)
      pf[mt] = *reinterpret_cast<const short8v*>(pb + (mt * 16 + l15) * 32 + quad * 8);
    float4v sums[2];
#pragma unroll
    for (int mt = 0; mt < 2; ++mt) {
      sums[mt] = (float4v){0.f, 0.f, 0.f, 0.f};
      sums[mt] = MFMA16(pf[mt], ones, sums[mt], 0, 0, 0);
    }
#pragma unroll
    for (int ntl = 0; ntl < 2; ++ntl)
      vf[ntl] = *reinterpret_cast<const short8v*>(vT + ((2 * wave + ntl) * 16 + l15) * 40 + quad * 8);
    float4v oacc[2][2];
#pragma unroll
    for (int mt = 0; mt < 2; ++mt)
#pragma unroll
      for (int ntl = 0; ntl < 2; ++ntl) {
        oacc[mt][ntl] = (float4v){0.f, 0.f, 0.f, 0.f};
        oacc[mt][ntl] = MFMA16(pf[mt], vf[ntl], oacc[mt][ntl], 0, 0, 0);
      }
#pragma unroll
    for (int mt = 0; mt < 2; ++mt)
#pragma unroll
      for (int r = 0; r < 4; ++r) {
        int q = mt * 16 + quad * 4 + r;
        float inv = 1.f / sums[mt][r];
#pragma unroll
        for (int ntl = 0; ntl < 2; ++ntl)
          attn[((size_t)b * 32 + q) * 512 + h * 128 + (2 * wave + ntl) * 16 + l15] =
              oacc[mt][ntl][r] * inv;
      }
  }
}

// ---------------------------------------------------------------------------
// proj GEMM via MFMA, 512 threads (8 waves): M=16, N=512, K=512.
// Per wave ni<4 covers 512 cols. Double occupancy vs 256-thread version
// (grid 512 = 2 blocks/CU; 16 waves/CU). + bias + residual + LN (32 thr/row).
// ---------------------------------------------------------------------------
__global__ __launch_bounds__(512, 2) void k_projln_mfma(
    const float* __restrict__ X, const unsigned short* __restrict__ Wb,
    const float* __restrict__ bias, const float* __restrict__ res,
    const float* __restrict__ gam, const float* __restrict__ bet,
    float* __restrict__ Y)
{
  const int row0 = blockIdx.x * 16, tid = threadIdx.x;
  __shared__ alignas(16) unsigned short xs[16 * 520];
  __shared__ float ys[16 * 516];
  for (int i = tid; i < 16 * 512; i += 512) {
    int t = i >> 9, c = i & 511;
    xs[t * 520 + c] = f2us(X[(size_t)(row0 + t) * 512 + c]);
  }
  __syncthreads();
  {
    const int lane = tid & 63, wave = tid >> 6;           // wave 0..7
    const int l15 = lane & 15, quad = lane >> 4;
    short8v af[16];
#pragma unroll
    for (int kc = 0; kc < 16; ++kc)
      af[kc] = *reinterpret_cast<const short8v*>(xs + l15 * 520 + kc * 32 + quad * 8);
    for (int ni = 0; ni < 4; ++ni) {
      int col = (wave + ni * 8) * 16 + l15;
      const unsigned short* wrow = Wb + (size_t)col * 512;
      float4v acc = {0.f,0.f,0.f,0.f};
#pragma unroll
      for (int kc = 0; kc < 16; ++kc) {
        short8v bfr = *reinterpret_cast<const short8v*>(wrow + kc * 32 + quad * 8);
        acc = MFMA16(af[kc], bfr, acc, 0, 0, 0);
      }
      float bj = bias[col];
#pragma unroll
      for (int r = 0; r < 4; ++r)
        ys[(quad * 4 + r) * 516 + col] = acc[r] + bj;
    }
  }
  __syncthreads();
  for (int i = tid; i < 16 * 512; i += 512) {
    int t = i >> 9, c = i & 511;
    ys[t * 516 + c] += res[(size_t)(row0 + t) * 512 + c];
  }
  __syncthreads();
  {
    int row = tid >> 5, l32 = tid & 31;                   // 32 threads/row
    const float* yr = ys + row * 516;
    float part = 0.f;
#pragma unroll
    for (int k = 0; k < 16; ++k) part += yr[l32 + 32 * k];
#pragma unroll
    for (int off = 16; off; off >>= 1) part += __shfl_xor(part, off, 32);
    float mean = part * (1.f / 512.f);
    float var = 0.f;
#pragma unroll
    for (int k = 0; k < 16; ++k) { float d = yr[l32 + 32 * k] - mean; var += d * d; }
#pragma unroll
    for (int off = 16; off; off >>= 1) var += __shfl_xor(var, off, 32);
    float rs = rsqrtf(var * (1.f / 512.f) + 1e-5f);
    for (int k = 0; k < 16; ++k) {
      int c = l32 + 32 * k;
      Y[(size_t)(row0 + row) * 512 + c] = (yr[c] - mean) * rs * gam[c] + bet[c];
    }
  }
}

// ---------------------------------------------------------------------------
// FUSED ff1+relu+ff2+residual+LN, 512 threads (8 waves): per-wave column
// work halves (ff1 ni<8, ff2 ni<4) -> 2x waves hide the global-B latency.
// In-place Y. LDS: xs 16,640 + f1L 33,024 = 49,664 B; grid 512 = 2/CU,
// 16 waves/CU.
// ---------------------------------------------------------------------------
__global__ __launch_bounds__(512, 2) void k_ffln(
    const float* __restrict__ X, const unsigned short* __restrict__ W1,
    const float* __restrict__ b1, const unsigned short* __restrict__ W2,
    const float* __restrict__ b2, const float* __restrict__ res,
    const float* __restrict__ gam, const float* __restrict__ bet,
    float* __restrict__ Y)
{
  const int row0 = blockIdx.x * 16, tid = threadIdx.x;
  __shared__ alignas(16) unsigned short xs[16 * 520];
  __shared__ alignas(16) unsigned short f1L[16 * 1032];   // ys [16][516] fp32 overlays
  float* ys = reinterpret_cast<float*>(f1L);
  const int lane = tid & 63, wave = tid >> 6;             // wave 0..7
  const int l15 = lane & 15, quad = lane >> 4;
  for (int i = tid; i < 16 * 512; i += 512) {
    int t = i >> 9, c = i & 511;
    xs[t * 520 + c] = f2us(X[(size_t)(row0 + t) * 512 + c]);
  }
  __syncthreads();
  // ff1: N=1024, K=512 -> relu -> f1L bf16 (8 waves x ni<8 x 16 = 1024 cols)
  for (int ni = 0; ni < 8; ++ni) {
    int col = (wave + ni * 8) * 16 + l15;
    const unsigned short* wrow = W1 + (size_t)col * 512;
    float4v acc = {0.f,0.f,0.f,0.f};
#pragma unroll
    for (int kc = 0; kc < 16; ++kc) {
      short8v a = *reinterpret_cast<const short8v*>(xs + l15 * 520 + kc * 32 + quad * 8);
      short8v bfr = *reinterpret_cast<const short8v*>(wrow + kc * 32 + quad * 8);
      acc = MFMA16(a, bfr, acc, 0, 0, 0);
    }
    float bj = b1[col];
#pragma unroll
    for (int r = 0; r < 4; ++r)
      f1L[(quad * 4 + r) * 1032 + col] = f2us(fmaxf(acc[r] + bj, 0.f));
  }
  __syncthreads();
  // ff2: N=512, K=1024 from f1L (8 waves x ni<4 x 16 = 512 cols)
  float4v acc2[4];
#pragma unroll
  for (int ni = 0; ni < 4; ++ni) acc2[ni] = (float4v){0.f,0.f,0.f,0.f};
  int cols2[4];
#pragma unroll
  for (int ni = 0; ni < 4; ++ni) cols2[ni] = (wave + ni * 8) * 16 + l15;
  for (int half = 0; half < 2; ++half) {
    for (int kc = 0; kc < 16; ++kc) {
      short8v a = *reinterpret_cast<const short8v*>(
          f1L + l15 * 1032 + half * 512 + kc * 32 + quad * 8);
#pragma unroll
      for (int ni = 0; ni < 4; ++ni) {
        short8v bfr = *reinterpret_cast<const short8v*>(
            W2 + (size_t)cols2[ni] * 1024 + half * 512 + kc * 32 + quad * 8);
        acc2[ni] = MFMA16(a, bfr, acc2[ni], 0, 0, 0);
      }
    }
  }
  __syncthreads();                                        // f1L dead -> ys
  for (int ni = 0; ni < 4; ++ni) {
    int col = cols2[ni];
    float bj = b2[col];
#pragma unroll
    for (int r = 0; r < 4; ++r)
      ys[(quad * 4 + r) * 516 + col] = acc2[ni][r] + bj;
  }
  __syncthreads();
  for (int i = tid; i < 16 * 512; i += 512) {
    int t = i >> 9, c = i & 511;
    ys[t * 516 + c] += res[(size_t)(row0 + t) * 512 + c];
  }
  __syncthreads();
  {
    int row = tid >> 5, l32 = tid & 31;                   // 32 threads/row
    const float* yr = ys + row * 516;
    float part = 0.f;
#pragma unroll
    for (int k = 0; k < 16; ++k) part += yr[l32 + 32 * k];
#pragma unroll
    for (int off = 16; off; off >>= 1) part += __shfl_xor(part, off, 32);
    float mean = part * (1.f / 512.f);
    float var = 0.f;
#pragma unroll
    for (int k = 0; k < 16; ++k) { float d = yr[l32 + 32 * k] - mean; var += d * d; }
#pragma unroll
    for (int off = 16; off; off >>= 1) var += __shfl_xor(var, off, 32);
    float rs = rsqrtf(var * (1.f / 512.f) + 1e-5f);
    for (int k = 0; k < 16; ++k) {
      int c = l32 + 32 * k;
      Y[(size_t)(row0 + row) * 512 + c] = (yr[c] - mean) * rs * gam[c] + bet[c];
    }
  }
}

// ---------------------------------------------------------------------------
// Final: mean-pool, temporal MLP, concat, classifier, LN, relu -> fp32
// ---------------------------------------------------------------------------
__global__ __launch_bounds__(256) void k_final(
    const float* __restrict__ g2,
    const float* __restrict__ db, const float* __restrict__ dsl,
    const float* __restrict__ te1_w, const float* __restrict__ te1_b,
    const float* __restrict__ l1g, const float* __restrict__ l1b,
    const float* __restrict__ te2_w, const float* __restrict__ te2_b,
    const float* __restrict__ l2g, const float* __restrict__ l2b,
    const float* __restrict__ c_w, const float* __restrict__ c_b,
    const float* __restrict__ clg, const float* __restrict__ clb,
    float* __restrict__ out)
{
  const int b = blockIdx.x, tid = threadIdx.x;
  __shared__ float cat[640];
  __shared__ float t1[64];
  __shared__ float t2[128];
  __shared__ float pre[256];
  __shared__ float red[256];
  __shared__ float st[2];
  for (int i = tid; i < 512; i += 256) {
    float acc = 0.f;
#pragma unroll
    for (int t = 0; t < 32; ++t) acc += g2[((size_t)b * 32 + t) * 512 + i];
    cat[i] = acc * (1.f / 32.f);
  }
  if (tid == 0) {
    float s = 0.f;
    for (int i = 0; i < 31; ++i) s += db[b * 31 + i];
    st[0] = s / 31.f;
    st[1] = dsl[b];
  }
  __syncthreads();
  const float f0 = st[0], f1v = st[1];
  if (tid < 64)
    t1[tid] = f0 * te1_w[tid * 2] + f1v * te1_w[tid * 2 + 1] + te1_b[tid];
  __syncthreads();
  if (tid == 0) {
    float m = 0.f; for (int i = 0; i < 64; ++i) m += t1[i]; m *= (1.f / 64.f);
    float v = 0.f; for (int i = 0; i < 64; ++i) { float d = t1[i] - m; v += d * d; }
    st[0] = m; st[1] = rsqrtf(v * (1.f / 64.f) + 1e-5f);
  }
  __syncthreads();
  if (tid < 64) {
    float v = (t1[tid] - st[0]) * st[1] * l1g[tid] + l1b[tid];
    t1[tid] = fmaxf(v, 0.f);
  }
  __syncthreads();
  if (tid < 128)
    t2[tid] = dot_ff(t1, te2_w + (size_t)tid * 64, 64) + te2_b[tid];
  __syncthreads();
  if (tid == 0) {
    float m = 0.f; for (int i = 0; i < 128; ++i) m += t2[i]; m *= (1.f / 128.f);
    float v = 0.f; for (int i = 0; i < 128; ++i) { float d = t2[i] - m; v += d * d; }
    st[0] = m; st[1] = rsqrtf(v * (1.f / 128.f) + 1e-5f);
  }
  __syncthreads();
  if (tid < 128) {
    float v = (t2[tid] - st[0]) * st[1] * l2g[tid] + l2b[tid];
    cat[512 + tid] = fmaxf(v, 0.f);
  }
  __syncthreads();
  pre[tid] = dot_ff(cat, c_w + (size_t)tid * 640, 640) + c_b[tid];
  red[tid] = pre[tid];
  __syncthreads();
  for (int s = 128; s > 0; s >>= 1) { if (tid < s) red[tid] += red[tid + s]; __syncthreads(); }
  const float m = red[0] * (1.f / 256.f);
  __syncthreads();
  const float d = pre[tid] - m;
  red[tid] = d * d;
  __syncthreads();
  for (int s = 128; s > 0; s >>= 1) { if (tid < s) red[tid] += red[tid + s]; __syncthreads(); }
  const float rs = rsqrtf(red[0] * (1.f / 256.f) + 1e-5f);
  float v = d * rs * clg[tid] + clb[tid];
  out[(size_t)b * 256 + tid] = fmaxf(v, 0.f);
}

// ---------------------------------------------------------------------------
extern "C" void kernel_launch(void* const* d_in, const int* in_sizes, int n_in,
                              void* d_out, int out_size, void* d_ws, size_t ws_size,
                              hipStream_t stream) {
  (void)in_sizes; (void)n_in; (void)out_size; (void)ws_size;
  const int*   oh     = (const int*)  d_in[0];
  const float* db     = (const float*)d_in[1];
  const float* dsl    = (const float*)d_in[2];
  const float* emb    = (const float*)d_in[3];
  const float* a_in_w = (const float*)d_in[4];
  const float* a_in_b = (const float*)d_in[5];
  const float* a_out_w= (const float*)d_in[6];
  const float* a_out_b= (const float*)d_in[7];
  const float* wih_f  = (const float*)d_in[8];
  const float* whh_f  = (const float*)d_in[9];
  const float* bih_f  = (const float*)d_in[10];
  const float* bhh_f  = (const float*)d_in[11];
  const float* wih_b  = (const float*)d_in[12];
  const float* whh_b  = (const float*)d_in[13];
  const float* bih_b  = (const float*)d_in[14];
  const float* bhh_b  = (const float*)d_in[15];
  const float* t_in_w = (const float*)d_in[16];
  const float* t_in_b = (const float*)d_in[17];
  const float* t_out_w= (const float*)d_in[18];
  const float* t_out_b= (const float*)d_in[19];
  const float* t_ln1g = (const float*)d_in[20];
  const float* t_ln1b = (const float*)d_in[21];
  const float* t_ff1w = (const float*)d_in[22];
  const float* t_ff1b = (const float*)d_in[23];
  const float* t_ff2w = (const float*)d_in[24];
  const float* t_ff2b = (const float*)d_in[25];
  const float* t_ln2g = (const float*)d_in[26];
  const float* t_ln2b = (const float*)d_in[27];
  const float* te1_w  = (const float*)d_in[28];
  const float* te1_b  = (const float*)d_in[29];
  const float* tl1g   = (const float*)d_in[30];
  const float* tl1b   = (const float*)d_in[31];
  const float* te2_w  = (const float*)d_in[32];
  const float* te2_b  = (const float*)d_in[33];
  const float* tl2g   = (const float*)d_in[34];
  const float* tl2b   = (const float*)d_in[35];
  const float* c_w    = (const float*)d_in[36];
  const float* c_b    = (const float*)d_in[37];
  const float* clng   = (const float*)d_in[38];
  const float* clnb   = (const float*)d_in[39];

  float* ws = (float*)d_ws;
  // Workspace (float slots), max index 17,391,616 (~69.6 MB):
  //   A [0,        524288):  oeb bf16 [8192][128]
  //   B [1048576,  5242880): embb bf16 (dead after order_attn) -> g fp32
  //   C [5242880,  9437184): attn fp32; g1 LN in-place; g2 ffln in-place
  //   D [9437184,  9633792): whhb bf16 [2][768][256]
  //   D2[9633792,  9732096): wihb bf16 [2][768][128]
  //   D3[9732096,  9740288): awb2 bf16 [128*128]
  //   E [10027008,10051584): awb bf16 [384*128]
  //   F [10051584,10444800): twb bf16 [1536*512]
  //   G [10444800,10575872): pwb bf16 [512*512]
  //   G2[10575872,10838016): f1wb bf16 [1024*512]
  //   G3[10838016,11100160): f2wb bf16 [512*1024]
  //   H [11100160,17391616): gi bf16 [8192*1536]
  unsigned short* oeb = (unsigned short*)ws;
  unsigned short* embb= (unsigned short*)(ws + 1048576);
  float* g    = ws + 1048576;                           // over dead embb
  float* attn = ws + 5242880;
  float* g1   = attn;                                   // in-place LN out
  float* g2   = attn;                                   // in-place ffln out
  unsigned short* whhb = (unsigned short*)(ws + 9437184);
  unsigned short* wihb = (unsigned short*)(ws + 9633792);
  unsigned short* awb2 = (unsigned short*)(ws + 9732096);
  unsigned short* awb  = (unsigned short*)(ws + 10027008);
  unsigned short* twb  = (unsigned short*)(ws + 10051584);
  unsigned short* pwb  = (unsigned short*)(ws + 10444800);
  unsigned short* f1wb = (unsigned short*)(ws + 10575872);
  unsigned short* f2wb = (unsigned short*)(ws + 10838016);
  unsigned short* gi   = (unsigned short*)(ws + 11100160);

  k_canary<<<256, 256, 0, stream>>>((float*)d_out);
  k_cvt<<<6212, 256, 0, stream>>>(a_in_w, t_in_w, t_out_w, t_ff1w, t_ff2w, a_out_w,
                                  emb, awb, twb, pwb, f1wb, f2wb, awb2, embb);
  k_gru_wb<<<1536, 256, 0, stream>>>(wih_f, whh_f, wih_b, whh_b, whhb, wihb);
  k_order_attn<<<8192, 256, 0, stream>>>(oh, embb, awb, a_in_b, awb2, a_out_b, oeb);
  k_gru_gi<<<256, 256, 0, stream>>>(oeb, wihb, gi);
  k_gru_rec<<<dim3(128, 2), 512, 0, stream>>>(gi, whhb, bih_f, bhh_f, bih_b, bhh_b, g);
  k_mha2f<<<dim3(256, 4), 256, 0, stream>>>(g, twb, t_in_b, attn);
  k_projln_mfma<<<512, 512, 0, stream>>>(attn, pwb, t_out_b, g, t_ln1g, t_ln1b, g1);
  k_ffln<<<512, 512, 0, stream>>>(g1, f1wb, t_ff1b, f2wb, t_ff2b, g1,
                                  t_ln2g, t_ln2b, g2);
  k_final<<<256, 256, 0, stream>>>(g2, db, dsl, te1_w, te1_b, tl1g, tl1b,
                                   te2_w, te2_b, tl2g, tl2b, c_w, c_b, clng, clnb,
                                   (float*)d_out);
}

// Round 12
// 575.131 us; speedup vs baseline: 1.1444x; 1.0456x over previous
//
#include <hip/hip_runtime.h>
#include <hip/hip_bf16.h>
#include <math.h>

typedef __hip_bfloat16 bf16;
typedef __attribute__((ext_vector_type(8))) short short8v;   // 8 bf16 (4 VGPRs)
typedef __attribute__((ext_vector_type(4))) short short4v;   // 4 bf16 (2 VGPRs)
typedef __attribute__((ext_vector_type(4))) float float4v;   // 4 fp32 acc
#define MFMA16 __builtin_amdgcn_mfma_f32_16x16x32_bf16

__device__ __forceinline__ float us2f(unsigned short u) {
  union { unsigned u; float f; } c; c.u = ((unsigned)u) << 16; return c.f;
}
__device__ __forceinline__ unsigned short f2us(float f) {
  return __bfloat16_as_ushort(__float2bfloat16(f));
}

// fp32 x . fp32 w, K % 8 == 0, 16B-aligned
__device__ __forceinline__ float dot_ff(const float* __restrict__ x,
                                        const float* __restrict__ w, int K) {
  const float4* xp = reinterpret_cast<const float4*>(x);
  const float4* wp = reinterpret_cast<const float4*>(w);
  float acc = 0.f;
  const int n = K >> 2;
  for (int i = 0; i < n; ++i) {
    float4 a = xp[i], b = wp[i];
    acc += a.x*b.x + a.y*b.y + a.z*b.z + a.w*b.w;
  }
  return acc;
}

// native-exp sigmoid / tanh (clamped; serial-path hot in GRU)
__device__ __forceinline__ float sigm(float x) { return 1.f / (1.f + __expf(-x)); }
__device__ __forceinline__ float tanh_fast(float x) {
  x = fminf(fmaxf(x, -15.f), 15.f);
  float e = __expf(2.f * x);
  return (e - 1.f) / (e + 1.f);
}

// ---------------------------------------------------------------------------
__global__ void k_canary(float* __restrict__ out) {
  out[blockIdx.x * 256 + threadIdx.x] = 100.0f;
}

// ---------------------------------------------------------------------------
// One-shot: convert MFMA-consumed weights to bf16 in ws.
// ---------------------------------------------------------------------------
__global__ __launch_bounds__(256) void k_cvt(
    const float* __restrict__ a_in_w, const float* __restrict__ t_in_w,
    const float* __restrict__ t_out_w, const float* __restrict__ t_ff1w,
    const float* __restrict__ t_ff2w, const float* __restrict__ a_out_w,
    unsigned short* __restrict__ awb, unsigned short* __restrict__ twb,
    unsigned short* __restrict__ pwb, unsigned short* __restrict__ f1wb,
    unsigned short* __restrict__ f2wb, unsigned short* __restrict__ awb2)
{
  int i = blockIdx.x * 256 + threadIdx.x;
  if (i < 49152)  awb[i] = f2us(a_in_w[i]);
  if (i < 786432) twb[i] = f2us(t_in_w[i]);
  if (i < 262144) pwb[i] = f2us(t_out_w[i]);
  if (i < 524288) f1wb[i] = f2us(t_ff1w[i]);
  if (i < 524288) f2wb[i] = f2us(t_ff2w[i]);
  if (i < 16384)  awb2[i] = f2us(a_out_w[i]);
}

// ---------------------------------------------------------------------------
// GRU weight prep: row-major bf16 copies. whhb [dir][768][256],
// wihb [dir][768][128] (for gi GEMM).
// ---------------------------------------------------------------------------
__global__ __launch_bounds__(256) void k_gru_wb(
    const float* __restrict__ wih_f, const float* __restrict__ whh_f,
    const float* __restrict__ wih_b, const float* __restrict__ whh_b,
    unsigned short* __restrict__ whhb, unsigned short* __restrict__ wihb)
{
  int i = blockIdx.x * 256 + threadIdx.x;   // < 393216
  if (i >= 393216) return;
  int dir = i / 196608, r = i % 196608;
  whhb[i] = f2us((dir ? whh_b : whh_f)[r]);
  if (r < 98304) wihb[dir * 98304 + r] = f2us((dir ? wih_b : wih_f)[r]);
}

// ---------------------------------------------------------------------------
// QKV precompute over the VOCAB (hoists the per-order QKV GEMM out of
// k_order_attn: QKV is a per-token linear map). qkt[49689][256] = q,k with
// bias; vt[49689][128] = v with bias. M=32 rows/block, grid 1553.
// Removes 786 MB of per-order weight re-streaming from L2.
// ---------------------------------------------------------------------------
__global__ __launch_bounds__(256, 2) void k_qkvpre(
    const float* __restrict__ emb, const unsigned short* __restrict__ awb,
    const float* __restrict__ in_b,
    unsigned short* __restrict__ qkt, unsigned short* __restrict__ vt)
{
  const int row0 = blockIdx.x * 32, tid = threadIdx.x;
  __shared__ alignas(16) unsigned short xs[32 * 136];
  for (int i = tid; i < 1024; i += 256) {
    int t = i >> 5, c4 = (i & 31) << 2;
    int grow = row0 + t; if (grow > 49688) grow = 49688;
    float4 e4 = *reinterpret_cast<const float4*>(emb + (size_t)grow * 128 + c4);
    short4v s; s[0] = f2us(e4.x); s[1] = f2us(e4.y); s[2] = f2us(e4.z); s[3] = f2us(e4.w);
    *reinterpret_cast<short4v*>(xs + t * 136 + c4) = s;
  }
  __syncthreads();
  const int lane = tid & 63, wave = tid >> 6;
  const int l15 = lane & 15, quad = lane >> 4;
  short8v af[2][4];
#pragma unroll
  for (int mt = 0; mt < 2; ++mt)
#pragma unroll
    for (int kc = 0; kc < 4; ++kc)
      af[mt][kc] = *reinterpret_cast<const short8v*>(
          xs + (mt * 16 + l15) * 136 + kc * 32 + quad * 8);
  for (int ni = 0; ni < 6; ++ni) {
    const int j = (wave + ni * 4) * 16 + l15;
    const unsigned short* wrow = awb + (size_t)j * 128;
    float4v acc0 = {0.f, 0.f, 0.f, 0.f}, acc1 = {0.f, 0.f, 0.f, 0.f};
#pragma unroll
    for (int kc = 0; kc < 4; ++kc) {
      short8v bfr = *reinterpret_cast<const short8v*>(wrow + kc * 32 + quad * 8);
      acc0 = MFMA16(af[0][kc], bfr, acc0, 0, 0, 0);
      acc1 = MFMA16(af[1][kc], bfr, acc1, 0, 0, 0);
    }
    const float bj = in_b[j];
#pragma unroll
    for (int r = 0; r < 4; ++r) {
      int g0 = row0 + quad * 4 + r, g1 = g0 + 16;
      if (j < 256) {
        if (g0 <= 49688) qkt[(size_t)g0 * 256 + j] = f2us(acc0[r] + bj);
        if (g1 <= 49688) qkt[(size_t)g1 * 256 + j] = f2us(acc1[r] + bj);
      } else {
        int jj = j - 256;
        if (g0 <= 49688) vt[(size_t)g0 * 128 + jj] = f2us(acc0[r] + bj);
        if (g1 <= 49688) vt[(size_t)g1 * 128 + jj] = f2us(acc1[r] + bj);
      }
    }
  }
}

// ---------------------------------------------------------------------------
// Stage 1: gather precomputed q/k/vT + fused attention + proj-then-mean.
// No QKV GEMM, no weight streaming. 3 barriers (+1 internal).
// LDS: qb 8704 (O overlay) + kb 8704 (P overlay) + vTb 8192 = 25,600 B
// -> 6 blocks/CU.
// ---------------------------------------------------------------------------
__global__ __launch_bounds__(256, 5) void k_order_attn(
    const int* __restrict__ oh, const unsigned short* __restrict__ qkt,
    const unsigned short* __restrict__ vt,
    const unsigned short* __restrict__ awb2, const float* __restrict__ out_b,
    unsigned short* __restrict__ oeb)
{
  const int bo = blockIdx.x;            // 0..8191
  const int tid = threadIdx.x;
  __shared__ alignas(16) unsigned short qb[32 * 136];     // q -> O
  __shared__ alignas(16) unsigned short kb[32 * 136];     // k -> P [128][32]
  __shared__ alignas(16) unsigned short vTb[128 * 32];    // vT[d][t]
  unsigned short* ob = qb;
  unsigned short* pb = kb;

  const int lane = tid & 63, wave = tid >> 6;
  const int l15 = lane & 15, quad = lane >> 4;

  // gather q,k (16B/lane, 512B contiguous per token)
  for (int i = tid; i < 1024; i += 256) {
    int t = i >> 5, c8 = (i & 31) << 3;
    int id = oh[bo * 32 + t];
    short8v v8 = *reinterpret_cast<const short8v*>(qkt + (size_t)id * 256 + c8);
    if (c8 < 128) *reinterpret_cast<short8v*>(qb + t * 136 + c8) = v8;
    else          *reinterpret_cast<short8v*>(kb + t * 136 + (c8 - 128)) = v8;
  }
  // gather v, transpose into vTb via scalar LDS scatter
  for (int i = tid; i < 512; i += 256) {
    int t = i >> 4, c8 = (i & 15) << 3;
    int id = oh[bo * 32 + t];
    short8v v8 = *reinterpret_cast<const short8v*>(vt + (size_t)id * 128 + c8);
#pragma unroll
    for (int j2 = 0; j2 < 8; ++j2) vTb[(c8 + j2) * 32 + t] = v8[j2];
  }
  __syncthreads();
  // ---- FUSED: scores + exp + PV + ones-rowsum + O write (wave = head) ----
  {
    const int h = wave;
    const float scale1 = 0.17677669529663687f;            // 1/sqrt(32)
    short8v qf[2], kf[2];
#pragma unroll
    for (int mt = 0; mt < 2; ++mt)
      qf[mt] = *reinterpret_cast<const short8v*>(qb + (mt * 16 + l15) * 136 + h * 32 + quad * 8);
#pragma unroll
    for (int nt = 0; nt < 2; ++nt)
      kf[nt] = *reinterpret_cast<const short8v*>(kb + (nt * 16 + l15) * 136 + h * 32 + quad * 8);
    float4v sacc[2][2];
#pragma unroll
    for (int mt = 0; mt < 2; ++mt)
#pragma unroll
      for (int nt = 0; nt < 2; ++nt) {
        sacc[mt][nt] = (float4v){0.f, 0.f, 0.f, 0.f};
        sacc[mt][nt] = MFMA16(qf[mt], kf[nt], sacc[mt][nt], 0, 0, 0);
      }
    __syncthreads();                     // all qb/kb reg-reads done -> P/O writes ok
    // P = exp(s) (no max subtraction: |s| <~ 2, safe)
#pragma unroll
    for (int mt = 0; mt < 2; ++mt)
#pragma unroll
      for (int r = 0; r < 4; ++r) {
        float e0 = __expf(sacc[mt][0][r] * scale1);
        float e1 = __expf(sacc[mt][1][r] * scale1);
        int row = h * 32 + mt * 16 + quad * 4 + r;
        pb[row * 32 + l15] = f2us(e0);
        pb[row * 32 + 16 + l15] = f2us(e1);
      }
    // ones fragment for rowsum MFMA
    short8v ones;
#pragma unroll
    for (int i = 0; i < 8; ++i) ones[i] = (short)0x3F80;  // bf16 1.0
    // PV (same-wave LDS write->read; in-order LDS pipe per wave)
    short8v pf[2], vf[2];
#pragma unroll
    for (int mt = 0; mt < 2; ++mt)
      pf[mt] = *reinterpret_cast<const short8v*>(pb + (h * 32 + mt * 16 + l15) * 32 + quad * 8);
    float4v sums[2];
#pragma unroll
    for (int mt = 0; mt < 2; ++mt) {
      sums[mt] = (float4v){0.f, 0.f, 0.f, 0.f};
      sums[mt] = MFMA16(pf[mt], ones, sums[mt], 0, 0, 0);  // rowsums in C layout
    }
#pragma unroll
    for (int nt = 0; nt < 2; ++nt)
      vf[nt] = *reinterpret_cast<const short8v*>(vTb + (h * 32 + nt * 16 + l15) * 32 + quad * 8);
    float4v oacc[2][2];
#pragma unroll
    for (int mt = 0; mt < 2; ++mt)
#pragma unroll
      for (int nt = 0; nt < 2; ++nt) {
        oacc[mt][nt] = (float4v){0.f, 0.f, 0.f, 0.f};
        oacc[mt][nt] = MFMA16(pf[mt], vf[nt], oacc[mt][nt], 0, 0, 0);
      }
    // write O bf16 into ob (qb overlay): this wave's head-col stripe
#pragma unroll
    for (int mt = 0; mt < 2; ++mt)
#pragma unroll
      for (int r = 0; r < 4; ++r) {
        int t = mt * 16 + quad * 4 + r;
        float inv = 1.f / sums[mt][r];
#pragma unroll
        for (int nt = 0; nt < 2; ++nt)
          ob[t * 136 + h * 32 + nt * 16 + l15] = f2us(oacc[mt][nt][r] * inv);
      }
  }
  __syncthreads();
  // ---- out-proj MFMA: proj[t][j] = O[t][.] . W[j][.]; then mean over t ----
  {
    float4v acc[2][2];
#pragma unroll
    for (int mt = 0; mt < 2; ++mt)
#pragma unroll
      for (int nt = 0; nt < 2; ++nt) acc[mt][nt] = (float4v){0.f, 0.f, 0.f, 0.f};
#pragma unroll
    for (int kc = 0; kc < 4; ++kc) {
      short8v af0 = *reinterpret_cast<const short8v*>(ob + l15 * 136 + kc * 32 + quad * 8);
      short8v af1 = *reinterpret_cast<const short8v*>(ob + (16 + l15) * 136 + kc * 32 + quad * 8);
#pragma unroll
      for (int nt = 0; nt < 2; ++nt) {
        int j = (wave * 2 + nt) * 16 + l15;
        short8v bfr = *reinterpret_cast<const short8v*>(awb2 + (size_t)j * 128 + kc * 32 + quad * 8);
        acc[0][nt] = MFMA16(af0, bfr, acc[0][nt], 0, 0, 0);
        acc[1][nt] = MFMA16(af1, bfr, acc[1][nt], 0, 0, 0);
      }
    }
#pragma unroll
    for (int nt = 0; nt < 2; ++nt) {
      float part = 0.f;
#pragma unroll
      for (int mt = 0; mt < 2; ++mt)
#pragma unroll
        for (int r = 0; r < 4; ++r) part += acc[mt][nt][r];
      part += __shfl_xor(part, 16);
      part += __shfl_xor(part, 32);
      if (quad == 0) {
        int j = (wave * 2 + nt) * 16 + l15;
        oeb[(size_t)bo * 128 + j] = f2us(part * (1.f / 32.f) + out_b[j]);
      }
    }
  }
}

// ---------------------------------------------------------------------------
// gi GEMM (MFMA): gi[8192][1536] bf16 = oe @ wih^T (both dirs). oe is bf16.
// ---------------------------------------------------------------------------
__global__ __launch_bounds__(256, 2) void k_gru_gi(
    const unsigned short* __restrict__ oeb, const unsigned short* __restrict__ wihb,
    unsigned short* __restrict__ gi)
{
  const int row0 = blockIdx.x * 32, tid = threadIdx.x;
  __shared__ alignas(16) unsigned short xs[32 * 136];
  for (int i = tid; i < 512; i += 256) {
    int t = i >> 4, c8 = (i & 15) << 3;
    *reinterpret_cast<short8v*>(xs + t * 136 + c8) =
        *reinterpret_cast<const short8v*>(oeb + (size_t)(row0 + t) * 128 + c8);
  }
  __syncthreads();
  const int lane = tid & 63, wave = tid >> 6;
  const int l15 = lane & 15, quad = lane >> 4;
  short8v af[2][4];
#pragma unroll
  for (int mt = 0; mt < 2; ++mt)
#pragma unroll
    for (int kc = 0; kc < 4; ++kc)
      af[mt][kc] = *reinterpret_cast<const short8v*>(
          xs + (mt * 16 + l15) * 136 + kc * 32 + quad * 8);
  for (int ni = 0; ni < 24; ++ni) {
    int col = (wave + ni * 4) * 16 + l15;
    const unsigned short* wrow = wihb + (size_t)col * 128;
    float4v a0 = {0.f,0.f,0.f,0.f}, a1 = {0.f,0.f,0.f,0.f};
#pragma unroll
    for (int kc = 0; kc < 4; ++kc) {
      short8v bfr = *reinterpret_cast<const short8v*>(wrow + kc * 32 + quad * 8);
      a0 = MFMA16(af[0][kc], bfr, a0, 0, 0, 0);
      a1 = MFMA16(af[1][kc], bfr, a1, 0, 0, 0);
    }
#pragma unroll
    for (int r = 0; r < 4; ++r) {
      gi[(size_t)(row0 + quad * 4 + r) * 1536 + col] = f2us(a0[r]);
      gi[(size_t)(row0 + quad * 4 + r + 16) * 1536 + col] = f2us(a1[r]);
    }
  }
}

// ---------------------------------------------------------------------------
// GRU recurrence via MFMA. 2 batches/block, grid (128,2) = 256 blocks,
// 512 threads (8 waves). whh register-resident. gi for step s+1 prefetched
// into registers before the barrier. Native-exp pointwise.
// LDS: hb 8448 + pg 6176 = 14,624 B.
// ---------------------------------------------------------------------------
__global__ __launch_bounds__(512, 2) void k_gru_rec(
    const unsigned short* __restrict__ gi, const unsigned short* __restrict__ whhb,
    const float* __restrict__ bih_f, const float* __restrict__ bhh_f,
    const float* __restrict__ bih_b, const float* __restrict__ bhh_b,
    float* __restrict__ g)
{
  const int b0 = blockIdx.x * 2, dir = blockIdx.y;
  const int tid = threadIdx.x;           // 0..511
  const unsigned short* wb = whhb + (size_t)dir * 196608;   // [768][256] bf16
  const float* bih = dir ? bih_b : bih_f;
  const float* bhh = dir ? bhh_b : bhh_f;
  __shared__ alignas(16) unsigned short hb[16 * 264];   // h bf16 (A operand)
  __shared__ float pg[2 * 772];                         // gh fp32 (rows 0-1)
  const int lane = tid & 63, wave = tid >> 6;
  const int l15 = lane & 15, quad = lane >> 4;
  const int j = tid & 255, mb = tid >> 8;               // pointwise: (m=mb, j)
  const float bir = bih[j], biz = bih[256 + j], bin_ = bih[512 + j];
  const float bhr = bhh[j], bhz = bhh[256 + j], bhn  = bhh[512 + j];
  short8v wf[6][8];
  int cols[6];
#pragma unroll
  for (int ni = 0; ni < 6; ++ni) {
    cols[ni] = (wave + ni * 8) * 16 + l15;
#pragma unroll
    for (int kc = 0; kc < 8; ++kc)
      wf[ni][kc] = *reinterpret_cast<const short8v*>(
          wb + (size_t)cols[ni] * 256 + kc * 32 + quad * 8);
  }
  for (int i = tid; i < 16 * 264; i += 512) hb[i] = 0;
  int tcur = dir ? 31 : 0;
  size_t gbase = ((size_t)(b0 + mb) * 32 + tcur) * 1536 + dir * 768;
  float gr = us2f(gi[gbase + j]);
  float gz = us2f(gi[gbase + 256 + j]);
  float gn = us2f(gi[gbase + 512 + j]);
  __syncthreads();
  for (int s = 0; s < 32; ++s) {
    float4v acc[6];
#pragma unroll
    for (int ni = 0; ni < 6; ++ni) acc[ni] = (float4v){0.f, 0.f, 0.f, 0.f};
#pragma unroll
    for (int kc = 0; kc < 8; ++kc) {
      short8v af = *reinterpret_cast<const short8v*>(hb + l15 * 264 + kc * 32 + quad * 8);
#pragma unroll
      for (int ni = 0; ni < 6; ++ni)
        acc[ni] = MFMA16(af, wf[ni][kc], acc[ni], 0, 0, 0);
    }
    if (quad == 0) {
#pragma unroll
      for (int ni = 0; ni < 6; ++ni) {
        pg[cols[ni]] = acc[ni][0];
        pg[772 + cols[ni]] = acc[ni][1];
      }
    }
    float gr2 = 0.f, gz2 = 0.f, gn2 = 0.f;
    if (s < 31) {
      int t2 = dir ? (30 - s) : (s + 1);
      size_t gb2 = ((size_t)(b0 + mb) * 32 + t2) * 1536 + dir * 768;
      gr2 = us2f(gi[gb2 + j]);
      gz2 = us2f(gi[gb2 + 256 + j]);
      gn2 = us2f(gi[gb2 + 512 + j]);
    }
    __syncthreads();
    {
      const int tt = dir ? (31 - s) : s;
      float hprev = us2f(hb[mb * 264 + j]);
      float r = sigm(gr + bir + pg[mb * 772 + j] + bhr);
      float z = sigm(gz + biz + pg[mb * 772 + 256 + j] + bhz);
      float n = tanh_fast(gn + bin_ + r * (pg[mb * 772 + 512 + j] + bhn));
      float nh = (1.f - z) * n + z * hprev;
      hb[mb * 264 + j] = f2us(nh);
      g[((size_t)(b0 + mb) * 32 + tt) * 512 + dir * 256 + j] = nh;
    }
    gr = gr2; gz = gz2; gn = gn2;
    __syncthreads();
  }
}

// ---------------------------------------------------------------------------
// Stage 3 fused attention, one block per (b, head). x staged in K=128
// quarter-chunks (xs3 8,704 B) -> LDS 36,352 B -> 4 blocks/CU.
// Scores phase writes P = exp(s) bf16 directly; PV computes row-sums via
// MFMA(P, ones). No sc buffer, no softmax phase.
// ---------------------------------------------------------------------------
__global__ __launch_bounds__(256, 4) void k_mha2f(
    const float* __restrict__ g, const unsigned short* __restrict__ twb,
    const float* __restrict__ Bv, float* __restrict__ attn)
{
  const int b = blockIdx.x, h = blockIdx.y, tid = threadIdx.x;
  __shared__ alignas(16) unsigned short xs3[32 * 136];     // x chunk; P overlay
  __shared__ alignas(16) unsigned short qk[2 * 32 * 136];
  __shared__ alignas(16) unsigned short vT[128 * 40];      // vT[d][k]
  unsigned short* qs = qk;
  unsigned short* ks = qk + 32 * 136;
  unsigned short* pb = xs3;                                // P bf16 [32][32]
  const int lane = tid & 63, wave = tid >> 6;
  const int l15 = lane & 15, quad = lane >> 4;

  int wrowi[6];
#pragma unroll
  for (int ni = 0; ni < 6; ++ni) {
    int idx = (wave + ni * 4) * 16 + l15;
    int m = idx >> 7, dd = idx & 127;
    wrowi[ni] = m * 512 + h * 128 + dd;
  }
  float4v acc[6][2];
#pragma unroll
  for (int ni = 0; ni < 6; ++ni)
#pragma unroll
    for (int mt = 0; mt < 2; ++mt) acc[ni][mt] = (float4v){0.f, 0.f, 0.f, 0.f};

  for (int ck = 0; ck < 4; ++ck) {
    __syncthreads();
    for (int i = tid; i < 1024; i += 256) {                // x quarter load
      int t = i >> 5, c4 = (i & 31) << 2;
      float4 e4 = *reinterpret_cast<const float4*>(
          g + (size_t)b * 16384 + t * 512 + ck * 128 + c4);
      short4v s; s[0] = f2us(e4.x); s[1] = f2us(e4.y); s[2] = f2us(e4.z); s[3] = f2us(e4.w);
      *reinterpret_cast<short4v*>(xs3 + t * 136 + c4) = s;
    }
    __syncthreads();
    short8v af2[2][4];
#pragma unroll
    for (int mt = 0; mt < 2; ++mt)
#pragma unroll
      for (int u = 0; u < 4; ++u)
        af2[mt][u] = *reinterpret_cast<const short8v*>(
            xs3 + (mt * 16 + l15) * 136 + u * 32 + quad * 8);
#pragma unroll
    for (int ni = 0; ni < 6; ++ni) {
      const unsigned short* wrow = twb + (size_t)wrowi[ni] * 512 + ck * 128;
#pragma unroll
      for (int u = 0; u < 4; ++u) {
        short8v bfr = *reinterpret_cast<const short8v*>(wrow + u * 32 + quad * 8);
        acc[ni][0] = MFMA16(af2[0][u], bfr, acc[ni][0], 0, 0, 0);
        acc[ni][1] = MFMA16(af2[1][u], bfr, acc[ni][1], 0, 0, 0);
      }
    }
  }
  __syncthreads();                                         // xs3 reads done
#pragma unroll
  for (int ni = 0; ni < 6; ++ni) {
    int idx = (wave + ni * 4) * 16 + l15;
    int m = idx >> 7, dd = idx & 127;
    float bj = Bv[wrowi[ni]];
    if (m < 2) {
      unsigned short* dst = (m == 0) ? qs : ks;
#pragma unroll
      for (int r = 0; r < 4; ++r) {
        int t0 = quad * 4 + r;
        dst[t0 * 136 + dd] = f2us(acc[ni][0][r] + bj);
        dst[(t0 + 16) * 136 + dd] = f2us(acc[ni][1][r] + bj);
      }
    } else {
      short4v s0, s1;
#pragma unroll
      for (int r = 0; r < 4; ++r) { s0[r] = f2us(acc[ni][0][r] + bj); s1[r] = f2us(acc[ni][1][r] + bj); }
      *reinterpret_cast<short4v*>(vT + dd * 40 + quad * 4) = s0;
      *reinterpret_cast<short4v*>(vT + dd * 40 + 16 + quad * 4) = s1;
    }
  }
  __syncthreads();
  // ---- scores MFMA -> P = exp(s) bf16 directly (no max: |s| <~ 7) ----
  {
    const float scale2 = 0.08838834764831845f;            // 1/sqrt(128)
    const int mt = wave >> 1, nt = wave & 1;
    float4v a = {0.f, 0.f, 0.f, 0.f};
#pragma unroll
    for (int kc = 0; kc < 4; ++kc) {
      short8v qf = *reinterpret_cast<const short8v*>(qs + (mt * 16 + l15) * 136 + kc * 32 + quad * 8);
      short8v kf = *reinterpret_cast<const short8v*>(ks + (nt * 16 + l15) * 136 + kc * 32 + quad * 8);
      a = MFMA16(qf, kf, a, 0, 0, 0);
    }
#pragma unroll
    for (int r = 0; r < 4; ++r) {
      int row = mt * 16 + quad * 4 + r;
      pb[row * 32 + nt * 16 + l15] = f2us(__expf(a[r] * scale2));
    }
  }
  __syncthreads();
  // ---- PV MFMA + ones-rowsum; scale by 1/sum in epilogue ----
  {
    short8v ones;
#pragma unroll
    for (int i = 0; i < 8; ++i) ones[i] = (short)0x3F80;  // bf16 1.0
    short8v pf[2], vf[2];
#pragma unroll
    for (int mt = 0; mt < 2; ++mt)
      pf[mt] = *reinterpret_cast<const short8v*>(pb + (mt * 16 + l15) * 32 + quad * 8);
    float4v sums[2];
#pragma unroll
    for (int mt = 0; mt < 2; ++mt) {
      sums[mt] = (float4v){0.f, 0.f, 0.f, 0.f};
      sums[mt] = MFMA16(pf[mt], ones, sums[mt], 0, 0, 0);
    }
#pragma unroll
    for (int ntl = 0; ntl < 2; ++ntl)
      vf[ntl] = *reinterpret_cast<const short8v*>(vT + ((2 * wave + ntl) * 16 + l15) * 40 + quad * 8);
    float4v oacc[2][2];
#pragma unroll
    for (int mt = 0; mt < 2; ++mt)
#pragma unroll
      for (int ntl = 0; ntl < 2; ++ntl) {
        oacc[mt][ntl] = (float4v){0.f, 0.f, 0.f, 0.f};
        oacc[mt][ntl] = MFMA16(pf[mt], vf[ntl], oacc[mt][ntl], 0, 0, 0);
      }
#pragma unroll
    for (int mt = 0; mt < 2; ++mt)
#pragma unroll
      for (int r = 0; r < 4; ++r) {
        int q = mt * 16 + quad * 4 + r;
        float inv = 1.f / sums[mt][r];
#pragma unroll
        for (int ntl = 0; ntl < 2; ++ntl)
          attn[((size_t)b * 32 + q) * 512 + h * 128 + (2 * wave + ntl) * 16 + l15] =
              oacc[mt][ntl][r] * inv;
      }
  }
}

// ---------------------------------------------------------------------------
// proj GEMM via MFMA, 512 threads (8 waves): M=16, N=512, K=512.
// + bias + residual + LN (32 thr/row).
// ---------------------------------------------------------------------------
__global__ __launch_bounds__(512, 2) void k_projln_mfma(
    const float* __restrict__ X, const unsigned short* __restrict__ Wb,
    const float* __restrict__ bias, const float* __restrict__ res,
    const float* __restrict__ gam, const float* __restrict__ bet,
    float* __restrict__ Y)
{
  const int row0 = blockIdx.x * 16, tid = threadIdx.x;
  __shared__ alignas(16) unsigned short xs[16 * 520];
  __shared__ float ys[16 * 516];
  for (int i = tid; i < 16 * 512; i += 512) {
    int t = i >> 9, c = i & 511;
    xs[t * 520 + c] = f2us(X[(size_t)(row0 + t) * 512 + c]);
  }
  __syncthreads();
  {
    const int lane = tid & 63, wave = tid >> 6;           // wave 0..7
    const int l15 = lane & 15, quad = lane >> 4;
    short8v af[16];
#pragma unroll
    for (int kc = 0; kc < 16; ++kc)
      af[kc] = *reinterpret_cast<const short8v*>(xs + l15 * 520 + kc * 32 + quad * 8);
    for (int ni = 0; ni < 4; ++ni) {
      int col = (wave + ni * 8) * 16 + l15;
      const unsigned short* wrow = Wb + (size_t)col * 512;
      float4v acc = {0.f,0.f,0.f,0.f};
#pragma unroll
      for (int kc = 0; kc < 16; ++kc) {
        short8v bfr = *reinterpret_cast<const short8v*>(wrow + kc * 32 + quad * 8);
        acc = MFMA16(af[kc], bfr, acc, 0, 0, 0);
      }
      float bj = bias[col];
#pragma unroll
      for (int r = 0; r < 4; ++r)
        ys[(quad * 4 + r) * 516 + col] = acc[r] + bj;
    }
  }
  __syncthreads();
  for (int i = tid; i < 16 * 512; i += 512) {
    int t = i >> 9, c = i & 511;
    ys[t * 516 + c] += res[(size_t)(row0 + t) * 512 + c];
  }
  __syncthreads();
  {
    int row = tid >> 5, l32 = tid & 31;                   // 32 threads/row
    const float* yr = ys + row * 516;
    float part = 0.f;
#pragma unroll
    for (int k = 0; k < 16; ++k) part += yr[l32 + 32 * k];
#pragma unroll
    for (int off = 16; off; off >>= 1) part += __shfl_xor(part, off, 32);
    float mean = part * (1.f / 512.f);
    float var = 0.f;
#pragma unroll
    for (int k = 0; k < 16; ++k) { float d = yr[l32 + 32 * k] - mean; var += d * d; }
#pragma unroll
    for (int off = 16; off; off >>= 1) var += __shfl_xor(var, off, 32);
    float rs = rsqrtf(var * (1.f / 512.f) + 1e-5f);
    for (int k = 0; k < 16; ++k) {
      int c = l32 + 32 * k;
      Y[(size_t)(row0 + row) * 512 + c] = (yr[c] - mean) * rs * gam[c] + bet[c];
    }
  }
}

// ---------------------------------------------------------------------------
// FUSED ff1+relu+ff2+residual+LN, 512 threads (8 waves). In-place Y.
// LDS: xs 16,640 + f1L 33,024 = 49,664 B.
// ---------------------------------------------------------------------------
__global__ __launch_bounds__(512, 2) void k_ffln(
    const float* __restrict__ X, const unsigned short* __restrict__ W1,
    const float* __restrict__ b1, const unsigned short* __restrict__ W2,
    const float* __restrict__ b2, const float* __restrict__ res,
    const float* __restrict__ gam, const float* __restrict__ bet,
    float* __restrict__ Y)
{
  const int row0 = blockIdx.x * 16, tid = threadIdx.x;
  __shared__ alignas(16) unsigned short xs[16 * 520];
  __shared__ alignas(16) unsigned short f1L[16 * 1032];   // ys [16][516] fp32 overlays
  float* ys = reinterpret_cast<float*>(f1L);
  const int lane = tid & 63, wave = tid >> 6;             // wave 0..7
  const int l15 = lane & 15, quad = lane >> 4;
  for (int i = tid; i < 16 * 512; i += 512) {
    int t = i >> 9, c = i & 511;
    xs[t * 520 + c] = f2us(X[(size_t)(row0 + t) * 512 + c]);
  }
  __syncthreads();
  // ff1: N=1024, K=512 -> relu -> f1L bf16 (8 waves x ni<8 x 16 = 1024 cols)
  for (int ni = 0; ni < 8; ++ni) {
    int col = (wave + ni * 8) * 16 + l15;
    const unsigned short* wrow = W1 + (size_t)col * 512;
    float4v acc = {0.f,0.f,0.f,0.f};
#pragma unroll
    for (int kc = 0; kc < 16; ++kc) {
      short8v a = *reinterpret_cast<const short8v*>(xs + l15 * 520 + kc * 32 + quad * 8);
      short8v bfr = *reinterpret_cast<const short8v*>(wrow + kc * 32 + quad * 8);
      acc = MFMA16(a, bfr, acc, 0, 0, 0);
    }
    float bj = b1[col];
#pragma unroll
    for (int r = 0; r < 4; ++r)
      f1L[(quad * 4 + r) * 1032 + col] = f2us(fmaxf(acc[r] + bj, 0.f));
  }
  __syncthreads();
  // ff2: N=512, K=1024 from f1L (8 waves x ni<4 x 16 = 512 cols)
  float4v acc2[4];
#pragma unroll
  for (int ni = 0; ni < 4; ++ni) acc2[ni] = (float4v){0.f,0.f,0.f,0.f};
  int cols2[4];
#pragma unroll
  for (int ni = 0; ni < 4; ++ni) cols2[ni] = (wave + ni * 8) * 16 + l15;
  for (int half = 0; half < 2; ++half) {
    for (int kc = 0; kc < 16; ++kc) {
      short8v a = *reinterpret_cast<const short8v*>(
          f1L + l15 * 1032 + half * 512 + kc * 32 + quad * 8);
#pragma unroll
      for (int ni = 0; ni < 4; ++ni) {
        short8v bfr = *reinterpret_cast<const short8v*>(
            W2 + (size_t)cols2[ni] * 1024 + half * 512 + kc * 32 + quad * 8);
        acc2[ni] = MFMA16(a, bfr, acc2[ni], 0, 0, 0);
      }
    }
  }
  __syncthreads();                                        // f1L dead -> ys
  for (int ni = 0; ni < 4; ++ni) {
    int col = cols2[ni];
    float bj = b2[col];
#pragma unroll
    for (int r = 0; r < 4; ++r)
      ys[(quad * 4 + r) * 516 + col] = acc2[ni][r] + bj;
  }
  __syncthreads();
  for (int i = tid; i < 16 * 512; i += 512) {
    int t = i >> 9, c = i & 511;
    ys[t * 516 + c] += res[(size_t)(row0 + t) * 512 + c];
  }
  __syncthreads();
  {
    int row = tid >> 5, l32 = tid & 31;                   // 32 threads/row
    const float* yr = ys + row * 516;
    float part = 0.f;
#pragma unroll
    for (int k = 0; k < 16; ++k) part += yr[l32 + 32 * k];
#pragma unroll
    for (int off = 16; off; off >>= 1) part += __shfl_xor(part, off, 32);
    float mean = part * (1.f / 512.f);
    float var = 0.f;
#pragma unroll
    for (int k = 0; k < 16; ++k) { float d = yr[l32 + 32 * k] - mean; var += d * d; }
#pragma unroll
    for (int off = 16; off; off >>= 1) var += __shfl_xor(var, off, 32);
    float rs = rsqrtf(var * (1.f / 512.f) + 1e-5f);
    for (int k = 0; k < 16; ++k) {
      int c = l32 + 32 * k;
      Y[(size_t)(row0 + row) * 512 + c] = (yr[c] - mean) * rs * gam[c] + bet[c];
    }
  }
}

// ---------------------------------------------------------------------------
// Final: mean-pool, temporal MLP, concat, classifier, LN, relu -> fp32
// ---------------------------------------------------------------------------
__global__ __launch_bounds__(256) void k_final(
    const float* __restrict__ g2,
    const float* __restrict__ db, const float* __restrict__ dsl,
    const float* __restrict__ te1_w, const float* __restrict__ te1_b,
    const float* __restrict__ l1g, const float* __restrict__ l1b,
    const float* __restrict__ te2_w, const float* __restrict__ te2_b,
    const float* __restrict__ l2g, const float* __restrict__ l2b,
    const float* __restrict__ c_w, const float* __restrict__ c_b,
    const float* __restrict__ clg, const float* __restrict__ clb,
    float* __restrict__ out)
{
  const int b = blockIdx.x, tid = threadIdx.x;
  __shared__ float cat[640];
  __shared__ float t1[64];
  __shared__ float t2[128];
  __shared__ float pre[256];
  __shared__ float red[256];
  __shared__ float st[2];
  for (int i = tid; i < 512; i += 256) {
    float acc = 0.f;
#pragma unroll
    for (int t = 0; t < 32; ++t) acc += g2[((size_t)b * 32 + t) * 512 + i];
    cat[i] = acc * (1.f / 32.f);
  }
  if (tid == 0) {
    float s = 0.f;
    for (int i = 0; i < 31; ++i) s += db[b * 31 + i];
    st[0] = s / 31.f;
    st[1] = dsl[b];
  }
  __syncthreads();
  const float f0 = st[0], f1v = st[1];
  if (tid < 64)
    t1[tid] = f0 * te1_w[tid * 2] + f1v * te1_w[tid * 2 + 1] + te1_b[tid];
  __syncthreads();
  if (tid == 0) {
    float m = 0.f; for (int i = 0; i < 64; ++i) m += t1[i]; m *= (1.f / 64.f);
    float v = 0.f; for (int i = 0; i < 64; ++i) { float d = t1[i] - m; v += d * d; }
    st[0] = m; st[1] = rsqrtf(v * (1.f / 64.f) + 1e-5f);
  }
  __syncthreads();
  if (tid < 64) {
    float v = (t1[tid] - st[0]) * st[1] * l1g[tid] + l1b[tid];
    t1[tid] = fmaxf(v, 0.f);
  }
  __syncthreads();
  if (tid < 128)
    t2[tid] = dot_ff(t1, te2_w + (size_t)tid * 64, 64) + te2_b[tid];
  __syncthreads();
  if (tid == 0) {
    float m = 0.f; for (int i = 0; i < 128; ++i) m += t2[i]; m *= (1.f / 128.f);
    float v = 0.f; for (int i = 0; i < 128; ++i) { float d = t2[i] - m; v += d * d; }
    st[0] = m; st[1] = rsqrtf(v * (1.f / 128.f) + 1e-5f);
  }
  __syncthreads();
  if (tid < 128) {
    float v = (t2[tid] - st[0]) * st[1] * l2g[tid] + l2b[tid];
    cat[512 + tid] = fmaxf(v, 0.f);
  }
  __syncthreads();
  pre[tid] = dot_ff(cat, c_w + (size_t)tid * 640, 640) + c_b[tid];
  red[tid] = pre[tid];
  __syncthreads();
  for (int s = 128; s > 0; s >>= 1) { if (tid < s) red[tid] += red[tid + s]; __syncthreads(); }
  const float m = red[0] * (1.f / 256.f);
  __syncthreads();
  const float d = pre[tid] - m;
  red[tid] = d * d;
  __syncthreads();
  for (int s = 128; s > 0; s >>= 1) { if (tid < s) red[tid] += red[tid + s]; __syncthreads(); }
  const float rs = rsqrtf(red[0] * (1.f / 256.f) + 1e-5f);
  float v = d * rs * clg[tid] + clb[tid];
  out[(size_t)b * 256 + tid] = fmaxf(v, 0.f);
}

// ---------------------------------------------------------------------------
extern "C" void kernel_launch(void* const* d_in, const int* in_sizes, int n_in,
                              void* d_out, int out_size, void* d_ws, size_t ws_size,
                              hipStream_t stream) {
  (void)in_sizes; (void)n_in; (void)out_size; (void)ws_size;
  const int*   oh     = (const int*)  d_in[0];
  const float* db     = (const float*)d_in[1];
  const float* dsl    = (const float*)d_in[2];
  const float* emb    = (const float*)d_in[3];
  const float* a_in_w = (const float*)d_in[4];
  const float* a_in_b = (const float*)d_in[5];
  const float* a_out_w= (const float*)d_in[6];
  const float* a_out_b= (const float*)d_in[7];
  const float* wih_f  = (const float*)d_in[8];
  const float* whh_f  = (const float*)d_in[9];
  const float* bih_f  = (const float*)d_in[10];
  const float* bhh_f  = (const float*)d_in[11];
  const float* wih_b  = (const float*)d_in[12];
  const float* whh_b  = (const float*)d_in[13];
  const float* bih_b  = (const float*)d_in[14];
  const float* bhh_b  = (const float*)d_in[15];
  const float* t_in_w = (const float*)d_in[16];
  const float* t_in_b = (const float*)d_in[17];
  const float* t_out_w= (const float*)d_in[18];
  const float* t_out_b= (const float*)d_in[19];
  const float* t_ln1g = (const float*)d_in[20];
  const float* t_ln1b = (const float*)d_in[21];
  const float* t_ff1w = (const float*)d_in[22];
  const float* t_ff1b = (const float*)d_in[23];
  const float* t_ff2w = (const float*)d_in[24];
  const float* t_ff2b = (const float*)d_in[25];
  const float* t_ln2g = (const float*)d_in[26];
  const float* t_ln2b = (const float*)d_in[27];
  const float* te1_w  = (const float*)d_in[28];
  const float* te1_b  = (const float*)d_in[29];
  const float* tl1g   = (const float*)d_in[30];
  const float* tl1b   = (const float*)d_in[31];
  const float* te2_w  = (const float*)d_in[32];
  const float* te2_b  = (const float*)d_in[33];
  const float* tl2g   = (const float*)d_in[34];
  const float* tl2b   = (const float*)d_in[35];
  const float* c_w    = (const float*)d_in[36];
  const float* c_b    = (const float*)d_in[37];
  const float* clng   = (const float*)d_in[38];
  const float* clnb   = (const float*)d_in[39];

  float* ws = (float*)d_ws;
  // Workspace (float slots), max index 17,391,616 (~69.6 MB):
  //   A [0,        524288):  oeb bf16 [8192][128]
  //   B∪C [1048576, 7409664): qkt bf16 [49696][256] (dead after order_attn)
  //       then g fp32 [1048576,5242880) + attn/g1/g2 fp32 [5242880,9437184)
  //   D [9437184,  9633792): whhb bf16 [2][768][256]
  //   D2[9633792,  9732096): wihb bf16 [2][768][128]
  //   D3[9732096,  9740288): awb2 bf16 [128*128]
  //   E [10027008,10051584): awb bf16 [384*128]
  //   F [10051584,10444800): twb bf16 [1536*512]
  //   G [10444800,10575872): pwb bf16 [512*512]
  //   G2[10575872,10838016): f1wb bf16 [1024*512]
  //   G3[10838016,11100160): f2wb bf16 [512*1024]
  //   H [11100160,17391616): vt bf16 [49696][128] (dead after order_attn)
  //       then gi bf16 [8192*1536]
  unsigned short* oeb  = (unsigned short*)ws;
  unsigned short* qkt  = (unsigned short*)(ws + 1048576);
  float* g    = ws + 1048576;                           // over dead qkt
  float* attn = ws + 5242880;
  float* g1   = attn;                                   // in-place LN out
  float* g2   = attn;                                   // in-place ffln out
  unsigned short* whhb = (unsigned short*)(ws + 9437184);
  unsigned short* wihb = (unsigned short*)(ws + 9633792);
  unsigned short* awb2 = (unsigned short*)(ws + 9732096);
  unsigned short* awb  = (unsigned short*)(ws + 10027008);
  unsigned short* twb  = (unsigned short*)(ws + 10051584);
  unsigned short* pwb  = (unsigned short*)(ws + 10444800);
  unsigned short* f1wb = (unsigned short*)(ws + 10575872);
  unsigned short* f2wb = (unsigned short*)(ws + 10838016);
  unsigned short* vt   = (unsigned short*)(ws + 11100160);
  unsigned short* gi   = (unsigned short*)(ws + 11100160); // over dead vt

  k_canary<<<256, 256, 0, stream>>>((float*)d_out);
  k_cvt<<<3072, 256, 0, stream>>>(a_in_w, t_in_w, t_out_w, t_ff1w, t_ff2w, a_out_w,
                                  awb, twb, pwb, f1wb, f2wb, awb2);
  k_gru_wb<<<1536, 256, 0, stream>>>(wih_f, whh_f, wih_b, whh_b, whhb, wihb);
  k_qkvpre<<<1553, 256, 0, stream>>>(emb, awb, a_in_b, qkt, vt);
  k_order_attn<<<8192, 256, 0, stream>>>(oh, qkt, vt, awb2, a_out_b, oeb);
  k_gru_gi<<<256, 256, 0, stream>>>(oeb, wihb, gi);
  k_gru_rec<<<dim3(128, 2), 512, 0, stream>>>(gi, whhb, bih_f, bhh_f, bih_b, bhh_b, g);
  k_mha2f<<<dim3(256, 4), 256, 0, stream>>>(g, twb, t_in_b, attn);
  k_projln_mfma<<<512, 512, 0, stream>>>(attn, pwb, t_out_b, g, t_ln1g, t_ln1b, g1);
  k_ffln<<<512, 512, 0, stream>>>(g1, f1wb, t_ff1b, f2wb, t_ff2b, g1,
                                  t_ln2g, t_ln2b, g2);
  k_final<<<256, 256, 0, stream>>>(g2, db, dsl, te1_w, te1_b, tl1g, tl1b,
                                   te2_w, te2_b, tl2g, tl2b, c_w, c_b, clng, clnb,
                                   (float*)d_out);
}

// Round 13
// 571.767 us; speedup vs baseline: 1.1511x; 1.0059x over previous
//
#include <hip/hip_runtime.h>
#include <hip/hip_bf16.h>
#include <math.h>

typedef __hip_bfloat16 bf16;
typedef __attribute__((ext_vector_type(8))) short short8v;   // 8 bf16 (4 VGPRs)
typedef __attribute__((ext_vector_type(4))) short short4v;   // 4 bf16 (2 VGPRs)
typedef __attribute__((ext_vector_type(4))) float float4v;   // 4 fp32 acc
#define MFMA16 __builtin_amdgcn_mfma_f32_16x16x32_bf16

__device__ __forceinline__ float us2f(unsigned short u) {
  union { unsigned u; float f; } c; c.u = ((unsigned)u) << 16; return c.f;
}
__device__ __forceinline__ unsigned short f2us(float f) {
  return __bfloat16_as_ushort(__float2bfloat16(f));
}

// fp32 x . fp32 w, K % 8 == 0, 16B-aligned
__device__ __forceinline__ float dot_ff(const float* __restrict__ x,
                                        const float* __restrict__ w, int K) {
  const float4* xp = reinterpret_cast<const float4*>(x);
  const float4* wp = reinterpret_cast<const float4*>(w);
  float acc = 0.f;
  const int n = K >> 2;
  for (int i = 0; i < n; ++i) {
    float4 a = xp[i], b = wp[i];
    acc += a.x*b.x + a.y*b.y + a.z*b.z + a.w*b.w;
  }
  return acc;
}

// native-exp sigmoid / tanh (clamped; serial-path hot in GRU)
__device__ __forceinline__ float sigm(float x) { return 1.f / (1.f + __expf(-x)); }
__device__ __forceinline__ float tanh_fast(float x) {
  x = fminf(fmaxf(x, -15.f), 15.f);
  float e = __expf(2.f * x);
  return (e - 1.f) / (e + 1.f);
}

// ---------------------------------------------------------------------------
__global__ void k_canary(float* __restrict__ out) {
  out[blockIdx.x * 256 + threadIdx.x] = 100.0f;
}

// ---------------------------------------------------------------------------
// One-shot: convert MFMA-consumed weights to bf16 in ws.
// ---------------------------------------------------------------------------
__global__ __launch_bounds__(256) void k_cvt(
    const float* __restrict__ a_in_w, const float* __restrict__ t_in_w,
    const float* __restrict__ t_out_w, const float* __restrict__ t_ff1w,
    const float* __restrict__ t_ff2w, const float* __restrict__ a_out_w,
    unsigned short* __restrict__ awb, unsigned short* __restrict__ twb,
    unsigned short* __restrict__ pwb, unsigned short* __restrict__ f1wb,
    unsigned short* __restrict__ f2wb, unsigned short* __restrict__ awb2)
{
  int i = blockIdx.x * 256 + threadIdx.x;
  if (i < 49152)  awb[i] = f2us(a_in_w[i]);
  if (i < 786432) twb[i] = f2us(t_in_w[i]);
  if (i < 262144) pwb[i] = f2us(t_out_w[i]);
  if (i < 524288) f1wb[i] = f2us(t_ff1w[i]);
  if (i < 524288) f2wb[i] = f2us(t_ff2w[i]);
  if (i < 16384)  awb2[i] = f2us(a_out_w[i]);
}

// ---------------------------------------------------------------------------
// GRU weight prep: row-major bf16 copies. whhb [dir][768][256],
// wihb [dir][768][128] (for gi GEMM).
// ---------------------------------------------------------------------------
__global__ __launch_bounds__(256) void k_gru_wb(
    const float* __restrict__ wih_f, const float* __restrict__ whh_f,
    const float* __restrict__ wih_b, const float* __restrict__ whh_b,
    unsigned short* __restrict__ whhb, unsigned short* __restrict__ wihb)
{
  int i = blockIdx.x * 256 + threadIdx.x;   // < 393216
  if (i >= 393216) return;
  int dir = i / 196608, r = i % 196608;
  whhb[i] = f2us((dir ? whh_b : whh_f)[r]);
  if (r < 98304) wihb[dir * 98304 + r] = f2us((dir ? wih_b : wih_f)[r]);
}

// ---------------------------------------------------------------------------
// QKV precompute over the VOCAB. qkt[49689][256] = q,k with bias;
// vt[49689][128] = v with bias. M=32 rows/block, grid 1553.
// ---------------------------------------------------------------------------
__global__ __launch_bounds__(256, 2) void k_qkvpre(
    const float* __restrict__ emb, const unsigned short* __restrict__ awb,
    const float* __restrict__ in_b,
    unsigned short* __restrict__ qkt, unsigned short* __restrict__ vt)
{
  const int row0 = blockIdx.x * 32, tid = threadIdx.x;
  __shared__ alignas(16) unsigned short xs[32 * 136];
  for (int i = tid; i < 1024; i += 256) {
    int t = i >> 5, c4 = (i & 31) << 2;
    int grow = row0 + t; if (grow > 49688) grow = 49688;
    float4 e4 = *reinterpret_cast<const float4*>(emb + (size_t)grow * 128 + c4);
    short4v s; s[0] = f2us(e4.x); s[1] = f2us(e4.y); s[2] = f2us(e4.z); s[3] = f2us(e4.w);
    *reinterpret_cast<short4v*>(xs + t * 136 + c4) = s;
  }
  __syncthreads();
  const int lane = tid & 63, wave = tid >> 6;
  const int l15 = lane & 15, quad = lane >> 4;
  short8v af[2][4];
#pragma unroll
  for (int mt = 0; mt < 2; ++mt)
#pragma unroll
    for (int kc = 0; kc < 4; ++kc)
      af[mt][kc] = *reinterpret_cast<const short8v*>(
          xs + (mt * 16 + l15) * 136 + kc * 32 + quad * 8);
  for (int ni = 0; ni < 6; ++ni) {
    const int j = (wave + ni * 4) * 16 + l15;
    const unsigned short* wrow = awb + (size_t)j * 128;
    float4v acc0 = {0.f, 0.f, 0.f, 0.f}, acc1 = {0.f, 0.f, 0.f, 0.f};
#pragma unroll
    for (int kc = 0; kc < 4; ++kc) {
      short8v bfr = *reinterpret_cast<const short8v*>(wrow + kc * 32 + quad * 8);
      acc0 = MFMA16(af[0][kc], bfr, acc0, 0, 0, 0);
      acc1 = MFMA16(af[1][kc], bfr, acc1, 0, 0, 0);
    }
    const float bj = in_b[j];
#pragma unroll
    for (int r = 0; r < 4; ++r) {
      int g0 = row0 + quad * 4 + r, g1 = g0 + 16;
      if (j < 256) {
        if (g0 <= 49688) qkt[(size_t)g0 * 256 + j] = f2us(acc0[r] + bj);
        if (g1 <= 49688) qkt[(size_t)g1 * 256 + j] = f2us(acc1[r] + bj);
      } else {
        int jj = j - 256;
        if (g0 <= 49688) vt[(size_t)g0 * 128 + jj] = f2us(acc0[r] + bj);
        if (g1 <= 49688) vt[(size_t)g1 * 128 + jj] = f2us(acc1[r] + bj);
      }
    }
  }
}

// ---------------------------------------------------------------------------
// Stage 1: gather precomputed q/k/vT + fused attention + proj-then-mean.
// LDS: qb 8704 (O overlay) + kb 8704 (P overlay) + vTb 8192 = 25,600 B.
// ---------------------------------------------------------------------------
__global__ __launch_bounds__(256, 5) void k_order_attn(
    const int* __restrict__ oh, const unsigned short* __restrict__ qkt,
    const unsigned short* __restrict__ vt,
    const unsigned short* __restrict__ awb2, const float* __restrict__ out_b,
    unsigned short* __restrict__ oeb)
{
  const int bo = blockIdx.x;            // 0..8191
  const int tid = threadIdx.x;
  __shared__ alignas(16) unsigned short qb[32 * 136];     // q -> O
  __shared__ alignas(16) unsigned short kb[32 * 136];     // k -> P [128][32]
  __shared__ alignas(16) unsigned short vTb[128 * 32];    // vT[d][t]
  unsigned short* ob = qb;
  unsigned short* pb = kb;

  const int lane = tid & 63, wave = tid >> 6;
  const int l15 = lane & 15, quad = lane >> 4;

  // gather q,k (16B/lane, 512B contiguous per token)
  for (int i = tid; i < 1024; i += 256) {
    int t = i >> 5, c8 = (i & 31) << 3;
    int id = oh[bo * 32 + t];
    short8v v8 = *reinterpret_cast<const short8v*>(qkt + (size_t)id * 256 + c8);
    if (c8 < 128) *reinterpret_cast<short8v*>(qb + t * 136 + c8) = v8;
    else          *reinterpret_cast<short8v*>(kb + t * 136 + (c8 - 128)) = v8;
  }
  // gather v, transpose into vTb via scalar LDS scatter
  for (int i = tid; i < 512; i += 256) {
    int t = i >> 4, c8 = (i & 15) << 3;
    int id = oh[bo * 32 + t];
    short8v v8 = *reinterpret_cast<const short8v*>(vt + (size_t)id * 128 + c8);
#pragma unroll
    for (int j2 = 0; j2 < 8; ++j2) vTb[(c8 + j2) * 32 + t] = v8[j2];
  }
  __syncthreads();
  // ---- FUSED: scores + exp + PV + ones-rowsum + O write (wave = head) ----
  {
    const int h = wave;
    const float scale1 = 0.17677669529663687f;            // 1/sqrt(32)
    short8v qf[2], kf[2];
#pragma unroll
    for (int mt = 0; mt < 2; ++mt)
      qf[mt] = *reinterpret_cast<const short8v*>(qb + (mt * 16 + l15) * 136 + h * 32 + quad * 8);
#pragma unroll
    for (int nt = 0; nt < 2; ++nt)
      kf[nt] = *reinterpret_cast<const short8v*>(kb + (nt * 16 + l15) * 136 + h * 32 + quad * 8);
    float4v sacc[2][2];
#pragma unroll
    for (int mt = 0; mt < 2; ++mt)
#pragma unroll
      for (int nt = 0; nt < 2; ++nt) {
        sacc[mt][nt] = (float4v){0.f, 0.f, 0.f, 0.f};
        sacc[mt][nt] = MFMA16(qf[mt], kf[nt], sacc[mt][nt], 0, 0, 0);
      }
    __syncthreads();                     // all qb/kb reg-reads done -> P/O writes ok
    // P = exp(s) (no max subtraction: |s| <~ 2, safe)
#pragma unroll
    for (int mt = 0; mt < 2; ++mt)
#pragma unroll
      for (int r = 0; r < 4; ++r) {
        float e0 = __expf(sacc[mt][0][r] * scale1);
        float e1 = __expf(sacc[mt][1][r] * scale1);
        int row = h * 32 + mt * 16 + quad * 4 + r;
        pb[row * 32 + l15] = f2us(e0);
        pb[row * 32 + 16 + l15] = f2us(e1);
      }
    // ones fragment for rowsum MFMA
    short8v ones;
#pragma unroll
    for (int i = 0; i < 8; ++i) ones[i] = (short)0x3F80;  // bf16 1.0
    short8v pf[2], vf[2];
#pragma unroll
    for (int mt = 0; mt < 2; ++mt)
      pf[mt] = *reinterpret_cast<const short8v*>(pb + (h * 32 + mt * 16 + l15) * 32 + quad * 8);
    float4v sums[2];
#pragma unroll
    for (int mt = 0; mt < 2; ++mt) {
      sums[mt] = (float4v){0.f, 0.f, 0.f, 0.f};
      sums[mt] = MFMA16(pf[mt], ones, sums[mt], 0, 0, 0);  // rowsums in C layout
    }
#pragma unroll
    for (int nt = 0; nt < 2; ++nt)
      vf[nt] = *reinterpret_cast<const short8v*>(vTb + (h * 32 + nt * 16 + l15) * 32 + quad * 8);
    float4v oacc[2][2];
#pragma unroll
    for (int mt = 0; mt < 2; ++mt)
#pragma unroll
      for (int nt = 0; nt < 2; ++nt) {
        oacc[mt][nt] = (float4v){0.f, 0.f, 0.f, 0.f};
        oacc[mt][nt] = MFMA16(pf[mt], vf[nt], oacc[mt][nt], 0, 0, 0);
      }
    // write O bf16 into ob (qb overlay): this wave's head-col stripe
#pragma unroll
    for (int mt = 0; mt < 2; ++mt)
#pragma unroll
      for (int r = 0; r < 4; ++r) {
        int t = mt * 16 + quad * 4 + r;
        float inv = 1.f / sums[mt][r];
#pragma unroll
        for (int nt = 0; nt < 2; ++nt)
          ob[t * 136 + h * 32 + nt * 16 + l15] = f2us(oacc[mt][nt][r] * inv);
      }
  }
  __syncthreads();
  // ---- out-proj MFMA: proj[t][j] = O[t][.] . W[j][.]; then mean over t ----
  {
    float4v acc[2][2];
#pragma unroll
    for (int mt = 0; mt < 2; ++mt)
#pragma unroll
      for (int nt = 0; nt < 2; ++nt) acc[mt][nt] = (float4v){0.f, 0.f, 0.f, 0.f};
#pragma unroll
    for (int kc = 0; kc < 4; ++kc) {
      short8v af0 = *reinterpret_cast<const short8v*>(ob + l15 * 136 + kc * 32 + quad * 8);
      short8v af1 = *reinterpret_cast<const short8v*>(ob + (16 + l15) * 136 + kc * 32 + quad * 8);
#pragma unroll
      for (int nt = 0; nt < 2; ++nt) {
        int j = (wave * 2 + nt) * 16 + l15;
        short8v bfr = *reinterpret_cast<const short8v*>(awb2 + (size_t)j * 128 + kc * 32 + quad * 8);
        acc[0][nt] = MFMA16(af0, bfr, acc[0][nt], 0, 0, 0);
        acc[1][nt] = MFMA16(af1, bfr, acc[1][nt], 0, 0, 0);
      }
    }
#pragma unroll
    for (int nt = 0; nt < 2; ++nt) {
      float part = 0.f;
#pragma unroll
      for (int mt = 0; mt < 2; ++mt)
#pragma unroll
        for (int r = 0; r < 4; ++r) part += acc[mt][nt][r];
      part += __shfl_xor(part, 16);
      part += __shfl_xor(part, 32);
      if (quad == 0) {
        int j = (wave * 2 + nt) * 16 + l15;
        oeb[(size_t)bo * 128 + j] = f2us(part * (1.f / 32.f) + out_b[j]);
      }
    }
  }
}

// ---------------------------------------------------------------------------
// gi GEMM (MFMA): gi[8192][1536] bf16 = oe @ wih^T (both dirs). oe is bf16.
// ---------------------------------------------------------------------------
__global__ __launch_bounds__(256, 2) void k_gru_gi(
    const unsigned short* __restrict__ oeb, const unsigned short* __restrict__ wihb,
    unsigned short* __restrict__ gi)
{
  const int row0 = blockIdx.x * 32, tid = threadIdx.x;
  __shared__ alignas(16) unsigned short xs[32 * 136];
  for (int i = tid; i < 512; i += 256) {
    int t = i >> 4, c8 = (i & 15) << 3;
    *reinterpret_cast<short8v*>(xs + t * 136 + c8) =
        *reinterpret_cast<const short8v*>(oeb + (size_t)(row0 + t) * 128 + c8);
  }
  __syncthreads();
  const int lane = tid & 63, wave = tid >> 6;
  const int l15 = lane & 15, quad = lane >> 4;
  short8v af[2][4];
#pragma unroll
  for (int mt = 0; mt < 2; ++mt)
#pragma unroll
    for (int kc = 0; kc < 4; ++kc)
      af[mt][kc] = *reinterpret_cast<const short8v*>(
          xs + (mt * 16 + l15) * 136 + kc * 32 + quad * 8);
  for (int ni = 0; ni < 24; ++ni) {
    int col = (wave + ni * 4) * 16 + l15;
    const unsigned short* wrow = wihb + (size_t)col * 128;
    float4v a0 = {0.f,0.f,0.f,0.f}, a1 = {0.f,0.f,0.f,0.f};
#pragma unroll
    for (int kc = 0; kc < 4; ++kc) {
      short8v bfr = *reinterpret_cast<const short8v*>(wrow + kc * 32 + quad * 8);
      a0 = MFMA16(af[0][kc], bfr, a0, 0, 0, 0);
      a1 = MFMA16(af[1][kc], bfr, a1, 0, 0, 0);
    }
#pragma unroll
    for (int r = 0; r < 4; ++r) {
      gi[(size_t)(row0 + quad * 4 + r) * 1536 + col] = f2us(a0[r]);
      gi[(size_t)(row0 + quad * 4 + r + 16) * 1536 + col] = f2us(a1[r]);
    }
  }
}

// ---------------------------------------------------------------------------
// GRU recurrence via MFMA. 2 batches/block, grid (128,2) = 256 blocks,
// 512 threads (8 waves). whh register-resident. gi prefetched.
// LDS: hb 8448 + pg 6176 = 14,624 B.
// ---------------------------------------------------------------------------
__global__ __launch_bounds__(512, 2) void k_gru_rec(
    const unsigned short* __restrict__ gi, const unsigned short* __restrict__ whhb,
    const float* __restrict__ bih_f, const float* __restrict__ bhh_f,
    const float* __restrict__ bih_b, const float* __restrict__ bhh_b,
    float* __restrict__ g)
{
  const int b0 = blockIdx.x * 2, dir = blockIdx.y;
  const int tid = threadIdx.x;           // 0..511
  const unsigned short* wb = whhb + (size_t)dir * 196608;   // [768][256] bf16
  const float* bih = dir ? bih_b : bih_f;
  const float* bhh = dir ? bhh_b : bhh_f;
  __shared__ alignas(16) unsigned short hb[16 * 264];   // h bf16 (A operand)
  __shared__ float pg[2 * 772];                         // gh fp32 (rows 0-1)
  const int lane = tid & 63, wave = tid >> 6;
  const int l15 = lane & 15, quad = lane >> 4;
  const int j = tid & 255, mb = tid >> 8;               // pointwise: (m=mb, j)
  const float bir = bih[j], biz = bih[256 + j], bin_ = bih[512 + j];
  const float bhr = bhh[j], bhz = bhh[256 + j], bhn  = bhh[512 + j];
  short8v wf[6][8];
  int cols[6];
#pragma unroll
  for (int ni = 0; ni < 6; ++ni) {
    cols[ni] = (wave + ni * 8) * 16 + l15;
#pragma unroll
    for (int kc = 0; kc < 8; ++kc)
      wf[ni][kc] = *reinterpret_cast<const short8v*>(
          wb + (size_t)cols[ni] * 256 + kc * 32 + quad * 8);
  }
  for (int i = tid; i < 16 * 264; i += 512) hb[i] = 0;
  int tcur = dir ? 31 : 0;
  size_t gbase = ((size_t)(b0 + mb) * 32 + tcur) * 1536 + dir * 768;
  float gr = us2f(gi[gbase + j]);
  float gz = us2f(gi[gbase + 256 + j]);
  float gn = us2f(gi[gbase + 512 + j]);
  __syncthreads();
  for (int s = 0; s < 32; ++s) {
    float4v acc[6];
#pragma unroll
    for (int ni = 0; ni < 6; ++ni) acc[ni] = (float4v){0.f, 0.f, 0.f, 0.f};
#pragma unroll
    for (int kc = 0; kc < 8; ++kc) {
      short8v af = *reinterpret_cast<const short8v*>(hb + l15 * 264 + kc * 32 + quad * 8);
#pragma unroll
      for (int ni = 0; ni < 6; ++ni)
        acc[ni] = MFMA16(af, wf[ni][kc], acc[ni], 0, 0, 0);
    }
    if (quad == 0) {
#pragma unroll
      for (int ni = 0; ni < 6; ++ni) {
        pg[cols[ni]] = acc[ni][0];
        pg[772 + cols[ni]] = acc[ni][1];
      }
    }
    float gr2 = 0.f, gz2 = 0.f, gn2 = 0.f;
    if (s < 31) {
      int t2 = dir ? (30 - s) : (s + 1);
      size_t gb2 = ((size_t)(b0 + mb) * 32 + t2) * 1536 + dir * 768;
      gr2 = us2f(gi[gb2 + j]);
      gz2 = us2f(gi[gb2 + 256 + j]);
      gn2 = us2f(gi[gb2 + 512 + j]);
    }
    __syncthreads();
    {
      const int tt = dir ? (31 - s) : s;
      float hprev = us2f(hb[mb * 264 + j]);
      float r = sigm(gr + bir + pg[mb * 772 + j] + bhr);
      float z = sigm(gz + biz + pg[mb * 772 + 256 + j] + bhz);
      float n = tanh_fast(gn + bin_ + r * (pg[mb * 772 + 512 + j] + bhn));
      float nh = (1.f - z) * n + z * hprev;
      hb[mb * 264 + j] = f2us(nh);
      g[((size_t)(b0 + mb) * 32 + tt) * 512 + dir * 256 + j] = nh;
    }
    gr = gr2; gz = gz2; gn = gn2;
    __syncthreads();
  }
}

// ---------------------------------------------------------------------------
// Stage 3 fused attention, one block per (b, head). x staged in K=128
// quarter-chunks (xs3 8,704 B) -> LDS 36,352 B -> 4 blocks/CU.
// ---------------------------------------------------------------------------
__global__ __launch_bounds__(256, 4) void k_mha2f(
    const float* __restrict__ g, const unsigned short* __restrict__ twb,
    const float* __restrict__ Bv, float* __restrict__ attn)
{
  const int b = blockIdx.x, h = blockIdx.y, tid = threadIdx.x;
  __shared__ alignas(16) unsigned short xs3[32 * 136];     // x chunk; P overlay
  __shared__ alignas(16) unsigned short qk[2 * 32 * 136];
  __shared__ alignas(16) unsigned short vT[128 * 40];      // vT[d][k]
  unsigned short* qs = qk;
  unsigned short* ks = qk + 32 * 136;
  unsigned short* pb = xs3;                                // P bf16 [32][32]
  const int lane = tid & 63, wave = tid >> 6;
  const int l15 = lane & 15, quad = lane >> 4;

  int wrowi[6];
#pragma unroll
  for (int ni = 0; ni < 6; ++ni) {
    int idx = (wave + ni * 4) * 16 + l15;
    int m = idx >> 7, dd = idx & 127;
    wrowi[ni] = m * 512 + h * 128 + dd;
  }
  float4v acc[6][2];
#pragma unroll
  for (int ni = 0; ni < 6; ++ni)
#pragma unroll
    for (int mt = 0; mt < 2; ++mt) acc[ni][mt] = (float4v){0.f, 0.f, 0.f, 0.f};

  for (int ck = 0; ck < 4; ++ck) {
    __syncthreads();
    for (int i = tid; i < 1024; i += 256) {                // x quarter load
      int t = i >> 5, c4 = (i & 31) << 2;
      float4 e4 = *reinterpret_cast<const float4*>(
          g + (size_t)b * 16384 + t * 512 + ck * 128 + c4);
      short4v s; s[0] = f2us(e4.x); s[1] = f2us(e4.y); s[2] = f2us(e4.z); s[3] = f2us(e4.w);
      *reinterpret_cast<short4v*>(xs3 + t * 136 + c4) = s;
    }
    __syncthreads();
    short8v af2[2][4];
#pragma unroll
    for (int mt = 0; mt < 2; ++mt)
#pragma unroll
      for (int u = 0; u < 4; ++u)
        af2[mt][u] = *reinterpret_cast<const short8v*>(
            xs3 + (mt * 16 + l15) * 136 + u * 32 + quad * 8);
#pragma unroll
    for (int ni = 0; ni < 6; ++ni) {
      const unsigned short* wrow = twb + (size_t)wrowi[ni] * 512 + ck * 128;
#pragma unroll
      for (int u = 0; u < 4; ++u) {
        short8v bfr = *reinterpret_cast<const short8v*>(wrow + u * 32 + quad * 8);
        acc[ni][0] = MFMA16(af2[0][u], bfr, acc[ni][0], 0, 0, 0);
        acc[ni][1] = MFMA16(af2[1][u], bfr, acc[ni][1], 0, 0, 0);
      }
    }
  }
  __syncthreads();                                         // xs3 reads done
#pragma unroll
  for (int ni = 0; ni < 6; ++ni) {
    int idx = (wave + ni * 4) * 16 + l15;
    int m = idx >> 7, dd = idx & 127;
    float bj = Bv[wrowi[ni]];
    if (m < 2) {
      unsigned short* dst = (m == 0) ? qs : ks;
#pragma unroll
      for (int r = 0; r < 4; ++r) {
        int t0 = quad * 4 + r;
        dst[t0 * 136 + dd] = f2us(acc[ni][0][r] + bj);
        dst[(t0 + 16) * 136 + dd] = f2us(acc[ni][1][r] + bj);
      }
    } else {
      short4v s0, s1;
#pragma unroll
      for (int r = 0; r < 4; ++r) { s0[r] = f2us(acc[ni][0][r] + bj); s1[r] = f2us(acc[ni][1][r] + bj); }
      *reinterpret_cast<short4v*>(vT + dd * 40 + quad * 4) = s0;
      *reinterpret_cast<short4v*>(vT + dd * 40 + 16 + quad * 4) = s1;
    }
  }
  __syncthreads();
  // ---- scores MFMA -> P = exp(s) bf16 directly (no max: |s| <~ 7) ----
  {
    const float scale2 = 0.08838834764831845f;            // 1/sqrt(128)
    const int mt = wave >> 1, nt = wave & 1;
    float4v a = {0.f, 0.f, 0.f, 0.f};
#pragma unroll
    for (int kc = 0; kc < 4; ++kc) {
      short8v qf = *reinterpret_cast<const short8v*>(qs + (mt * 16 + l15) * 136 + kc * 32 + quad * 8);
      short8v kf = *reinterpret_cast<const short8v*>(ks + (nt * 16 + l15) * 136 + kc * 32 + quad * 8);
      a = MFMA16(qf, kf, a, 0, 0, 0);
    }
#pragma unroll
    for (int r = 0; r < 4; ++r) {
      int row = mt * 16 + quad * 4 + r;
      pb[row * 32 + nt * 16 + l15] = f2us(__expf(a[r] * scale2));
    }
  }
  __syncthreads();
  // ---- PV MFMA + ones-rowsum; scale by 1/sum in epilogue ----
  {
    short8v ones;
#pragma unroll
    for (int i = 0; i < 8; ++i) ones[i] = (short)0x3F80;  // bf16 1.0
    short8v pf[2], vf[2];
#pragma unroll
    for (int mt = 0; mt < 2; ++mt)
      pf[mt] = *reinterpret_cast<const short8v*>(pb + (mt * 16 + l15) * 32 + quad * 8);
    float4v sums[2];
#pragma unroll
    for (int mt = 0; mt < 2; ++mt) {
      sums[mt] = (float4v){0.f, 0.f, 0.f, 0.f};
      sums[mt] = MFMA16(pf[mt], ones, sums[mt], 0, 0, 0);
    }
#pragma unroll
    for (int ntl = 0; ntl < 2; ++ntl)
      vf[ntl] = *reinterpret_cast<const short8v*>(vT + ((2 * wave + ntl) * 16 + l15) * 40 + quad * 8);
    float4v oacc[2][2];
#pragma unroll
    for (int mt = 0; mt < 2; ++mt)
#pragma unroll
      for (int ntl = 0; ntl < 2; ++ntl) {
        oacc[mt][ntl] = (float4v){0.f, 0.f, 0.f, 0.f};
        oacc[mt][ntl] = MFMA16(pf[mt], vf[ntl], oacc[mt][ntl], 0, 0, 0);
      }
#pragma unroll
    for (int mt = 0; mt < 2; ++mt)
#pragma unroll
      for (int r = 0; r < 4; ++r) {
        int q = mt * 16 + quad * 4 + r;
        float inv = 1.f / sums[mt][r];
#pragma unroll
        for (int ntl = 0; ntl < 2; ++ntl)
          attn[((size_t)b * 32 + q) * 512 + h * 128 + (2 * wave + ntl) * 16 + l15] =
              oacc[mt][ntl][r] * inv;
      }
  }
}

// ---------------------------------------------------------------------------
// proj GEMM via MFMA, 512 threads (8 waves): M=16, N=512, K=512.
// W-row fragments double-buffered across the ni loop (ILP over L2 latency).
// + bias + residual + LN (32 thr/row).
// ---------------------------------------------------------------------------
__global__ __launch_bounds__(512, 2) void k_projln_mfma(
    const float* __restrict__ X, const unsigned short* __restrict__ Wb,
    const float* __restrict__ bias, const float* __restrict__ res,
    const float* __restrict__ gam, const float* __restrict__ bet,
    float* __restrict__ Y)
{
  const int row0 = blockIdx.x * 16, tid = threadIdx.x;
  __shared__ alignas(16) unsigned short xs[16 * 520];
  __shared__ float ys[16 * 516];
  for (int i = tid; i < 16 * 512; i += 512) {
    int t = i >> 9, c = i & 511;
    xs[t * 520 + c] = f2us(X[(size_t)(row0 + t) * 512 + c]);
  }
  __syncthreads();
  {
    const int lane = tid & 63, wave = tid >> 6;           // wave 0..7
    const int l15 = lane & 15, quad = lane >> 4;
    short8v af[16];
#pragma unroll
    for (int kc = 0; kc < 16; ++kc)
      af[kc] = *reinterpret_cast<const short8v*>(xs + l15 * 520 + kc * 32 + quad * 8);
    short8v bufA[16], bufB[16];
    {
      const unsigned short* w0 = Wb + (size_t)((wave + 0 * 8) * 16 + l15) * 512;
#pragma unroll
      for (int kc = 0; kc < 16; ++kc)
        bufA[kc] = *reinterpret_cast<const short8v*>(w0 + kc * 32 + quad * 8);
    }
#pragma unroll
    for (int ni = 0; ni < 4; ++ni) {
      short8v* cur = (ni & 1) ? bufB : bufA;
      short8v* nxt = (ni & 1) ? bufA : bufB;
      if (ni < 3) {
        const unsigned short* wn = Wb + (size_t)((wave + (ni + 1) * 8) * 16 + l15) * 512;
#pragma unroll
        for (int kc = 0; kc < 16; ++kc)
          nxt[kc] = *reinterpret_cast<const short8v*>(wn + kc * 32 + quad * 8);
      }
      float4v acc = {0.f,0.f,0.f,0.f};
#pragma unroll
      for (int kc = 0; kc < 16; ++kc)
        acc = MFMA16(af[kc], cur[kc], acc, 0, 0, 0);
      int col = (wave + ni * 8) * 16 + l15;
      float bj = bias[col];
#pragma unroll
      for (int r = 0; r < 4; ++r)
        ys[(quad * 4 + r) * 516 + col] = acc[r] + bj;
    }
  }
  __syncthreads();
  for (int i = tid; i < 16 * 512; i += 512) {
    int t = i >> 9, c = i & 511;
    ys[t * 516 + c] += res[(size_t)(row0 + t) * 512 + c];
  }
  __syncthreads();
  {
    int row = tid >> 5, l32 = tid & 31;                   // 32 threads/row
    const float* yr = ys + row * 516;
    float part = 0.f;
#pragma unroll
    for (int k = 0; k < 16; ++k) part += yr[l32 + 32 * k];
#pragma unroll
    for (int off = 16; off; off >>= 1) part += __shfl_xor(part, off, 32);
    float mean = part * (1.f / 512.f);
    float var = 0.f;
#pragma unroll
    for (int k = 0; k < 16; ++k) { float d = yr[l32 + 32 * k] - mean; var += d * d; }
#pragma unroll
    for (int off = 16; off; off >>= 1) var += __shfl_xor(var, off, 32);
    float rs = rsqrtf(var * (1.f / 512.f) + 1e-5f);
    for (int k = 0; k < 16; ++k) {
      int c = l32 + 32 * k;
      Y[(size_t)(row0 + row) * 512 + c] = (yr[c] - mean) * rs * gam[c] + bet[c];
    }
  }
}

// ---------------------------------------------------------------------------
// FUSED ff1+relu+ff2+residual+LN, 512 threads (8 waves), software-pipelined:
// A-fragments hoisted to registers (loop-invariant across ni), W-row
// fragments double-buffered so next ni's 16 global loads overlap current
// ni's MFMAs. In-place Y. LDS: xs 16,640 + f1L 33,024 = 49,664 B.
// ---------------------------------------------------------------------------
__global__ __launch_bounds__(512, 2) void k_ffln(
    const float* __restrict__ X, const unsigned short* __restrict__ W1,
    const float* __restrict__ b1, const unsigned short* __restrict__ W2,
    const float* __restrict__ b2, const float* __restrict__ res,
    const float* __restrict__ gam, const float* __restrict__ bet,
    float* __restrict__ Y)
{
  const int row0 = blockIdx.x * 16, tid = threadIdx.x;
  __shared__ alignas(16) unsigned short xs[16 * 520];
  __shared__ alignas(16) unsigned short f1L[16 * 1032];   // ys [16][516] fp32 overlays
  float* ys = reinterpret_cast<float*>(f1L);
  const int lane = tid & 63, wave = tid >> 6;             // wave 0..7
  const int l15 = lane & 15, quad = lane >> 4;
  for (int i = tid; i < 16 * 512; i += 512) {
    int t = i >> 9, c = i & 511;
    xs[t * 520 + c] = f2us(X[(size_t)(row0 + t) * 512 + c]);
  }
  __syncthreads();
  // ff1: N=1024, K=512 -> relu -> f1L bf16. af hoisted; W1 double-buffered.
  {
    short8v af[16];
#pragma unroll
    for (int kc = 0; kc < 16; ++kc)
      af[kc] = *reinterpret_cast<const short8v*>(xs + l15 * 520 + kc * 32 + quad * 8);
    short8v bufA[16], bufB[16];
    {
      const unsigned short* w0 = W1 + (size_t)((wave + 0 * 8) * 16 + l15) * 512;
#pragma unroll
      for (int kc = 0; kc < 16; ++kc)
        bufA[kc] = *reinterpret_cast<const short8v*>(w0 + kc * 32 + quad * 8);
    }
#pragma unroll
    for (int ni = 0; ni < 8; ++ni) {
      short8v* cur = (ni & 1) ? bufB : bufA;
      short8v* nxt = (ni & 1) ? bufA : bufB;
      if (ni < 7) {
        const unsigned short* wn = W1 + (size_t)((wave + (ni + 1) * 8) * 16 + l15) * 512;
#pragma unroll
        for (int kc = 0; kc < 16; ++kc)
          nxt[kc] = *reinterpret_cast<const short8v*>(wn + kc * 32 + quad * 8);
      }
      float4v acc = {0.f,0.f,0.f,0.f};
#pragma unroll
      for (int kc = 0; kc < 16; ++kc)
        acc = MFMA16(af[kc], cur[kc], acc, 0, 0, 0);
      int col = (wave + ni * 8) * 16 + l15;
      float bj = b1[col];
#pragma unroll
      for (int r = 0; r < 4; ++r)
        f1L[(quad * 4 + r) * 1032 + col] = f2us(fmaxf(acc[r] + bj, 0.f));
    }
  }
  __syncthreads();
  // ff2: N=512, K=1024 from f1L. Per half: af2 hoisted; W2 double-buffered.
  float4v acc2[4];
#pragma unroll
  for (int ni = 0; ni < 4; ++ni) acc2[ni] = (float4v){0.f,0.f,0.f,0.f};
  int cols2[4];
#pragma unroll
  for (int ni = 0; ni < 4; ++ni) cols2[ni] = (wave + ni * 8) * 16 + l15;
#pragma unroll
  for (int half = 0; half < 2; ++half) {
    short8v af2[16];
#pragma unroll
    for (int kc = 0; kc < 16; ++kc)
      af2[kc] = *reinterpret_cast<const short8v*>(
          f1L + l15 * 1032 + half * 512 + kc * 32 + quad * 8);
    short8v bufA[16], bufB[16];
    {
      const unsigned short* w0 = W2 + (size_t)cols2[0] * 1024 + half * 512;
#pragma unroll
      for (int kc = 0; kc < 16; ++kc)
        bufA[kc] = *reinterpret_cast<const short8v*>(w0 + kc * 32 + quad * 8);
    }
#pragma unroll
    for (int ni = 0; ni < 4; ++ni) {
      short8v* cur = (ni & 1) ? bufB : bufA;
      short8v* nxt = (ni & 1) ? bufA : bufB;
      if (ni < 3) {
        const unsigned short* wn = W2 + (size_t)cols2[ni + 1] * 1024 + half * 512;
#pragma unroll
        for (int kc = 0; kc < 16; ++kc)
          nxt[kc] = *reinterpret_cast<const short8v*>(wn + kc * 32 + quad * 8);
      }
#pragma unroll
      for (int kc = 0; kc < 16; ++kc)
        acc2[ni] = MFMA16(af2[kc], cur[kc], acc2[ni], 0, 0, 0);
    }
  }
  __syncthreads();                                        // f1L dead -> ys
#pragma unroll
  for (int ni = 0; ni < 4; ++ni) {
    int col = cols2[ni];
    float bj = b2[col];
#pragma unroll
    for (int r = 0; r < 4; ++r)
      ys[(quad * 4 + r) * 516 + col] = acc2[ni][r] + bj;
  }
  __syncthreads();
  for (int i = tid; i < 16 * 512; i += 512) {
    int t = i >> 9, c = i & 511;
    ys[t * 516 + c] += res[(size_t)(row0 + t) * 512 + c];
  }
  __syncthreads();
  {
    int row = tid >> 5, l32 = tid & 31;                   // 32 threads/row
    const float* yr = ys + row * 516;
    float part = 0.f;
#pragma unroll
    for (int k = 0; k < 16; ++k) part += yr[l32 + 32 * k];
#pragma unroll
    for (int off = 16; off; off >>= 1) part += __shfl_xor(part, off, 32);
    float mean = part * (1.f / 512.f);
    float var = 0.f;
#pragma unroll
    for (int k = 0; k < 16; ++k) { float d = yr[l32 + 32 * k] - mean; var += d * d; }
#pragma unroll
    for (int off = 16; off; off >>= 1) var += __shfl_xor(var, off, 32);
    float rs = rsqrtf(var * (1.f / 512.f) + 1e-5f);
    for (int k = 0; k < 16; ++k) {
      int c = l32 + 32 * k;
      Y[(size_t)(row0 + row) * 512 + c] = (yr[c] - mean) * rs * gam[c] + bet[c];
    }
  }
}

// ---------------------------------------------------------------------------
// Final: mean-pool, temporal MLP, concat, classifier, LN, relu -> fp32
// ---------------------------------------------------------------------------
__global__ __launch_bounds__(256) void k_final(
    const float* __restrict__ g2,
    const float* __restrict__ db, const float* __restrict__ dsl,
    const float* __restrict__ te1_w, const float* __restrict__ te1_b,
    const float* __restrict__ l1g, const float* __restrict__ l1b,
    const float* __restrict__ te2_w, const float* __restrict__ te2_b,
    const float* __restrict__ l2g, const float* __restrict__ l2b,
    const float* __restrict__ c_w, const float* __restrict__ c_b,
    const float* __restrict__ clg, const float* __restrict__ clb,
    float* __restrict__ out)
{
  const int b = blockIdx.x, tid = threadIdx.x;
  __shared__ float cat[640];
  __shared__ float t1[64];
  __shared__ float t2[128];
  __shared__ float pre[256];
  __shared__ float red[256];
  __shared__ float st[2];
  for (int i = tid; i < 512; i += 256) {
    float acc = 0.f;
#pragma unroll
    for (int t = 0; t < 32; ++t) acc += g2[((size_t)b * 32 + t) * 512 + i];
    cat[i] = acc * (1.f / 32.f);
  }
  if (tid == 0) {
    float s = 0.f;
    for (int i = 0; i < 31; ++i) s += db[b * 31 + i];
    st[0] = s / 31.f;
    st[1] = dsl[b];
  }
  __syncthreads();
  const float f0 = st[0], f1v = st[1];
  if (tid < 64)
    t1[tid] = f0 * te1_w[tid * 2] + f1v * te1_w[tid * 2 + 1] + te1_b[tid];
  __syncthreads();
  if (tid == 0) {
    float m = 0.f; for (int i = 0; i < 64; ++i) m += t1[i]; m *= (1.f / 64.f);
    float v = 0.f; for (int i = 0; i < 64; ++i) { float d = t1[i] - m; v += d * d; }
    st[0] = m; st[1] = rsqrtf(v * (1.f / 64.f) + 1e-5f);
  }
  __syncthreads();
  if (tid < 64) {
    float v = (t1[tid] - st[0]) * st[1] * l1g[tid] + l1b[tid];
    t1[tid] = fmaxf(v, 0.f);
  }
  __syncthreads();
  if (tid < 128)
    t2[tid] = dot_ff(t1, te2_w + (size_t)tid * 64, 64) + te2_b[tid];
  __syncthreads();
  if (tid == 0) {
    float m = 0.f; for (int i = 0; i < 128; ++i) m += t2[i]; m *= (1.f / 128.f);
    float v = 0.f; for (int i = 0; i < 128; ++i) { float d = t2[i] - m; v += d * d; }
    st[0] = m; st[1] = rsqrtf(v * (1.f / 128.f) + 1e-5f);
  }
  __syncthreads();
  if (tid < 128) {
    float v = (t2[tid] - st[0]) * st[1] * l2g[tid] + l2b[tid];
    cat[512 + tid] = fmaxf(v, 0.f);
  }
  __syncthreads();
  pre[tid] = dot_ff(cat, c_w + (size_t)tid * 640, 640) + c_b[tid];
  red[tid] = pre[tid];
  __syncthreads();
  for (int s = 128; s > 0; s >>= 1) { if (tid < s) red[tid] += red[tid + s]; __syncthreads(); }
  const float m = red[0] * (1.f / 256.f);
  __syncthreads();
  const float d = pre[tid] - m;
  red[tid] = d * d;
  __syncthreads();
  for (int s = 128; s > 0; s >>= 1) { if (tid < s) red[tid] += red[tid + s]; __syncthreads(); }
  const float rs = rsqrtf(red[0] * (1.f / 256.f) + 1e-5f);
  float v = d * rs * clg[tid] + clb[tid];
  out[(size_t)b * 256 + tid] = fmaxf(v, 0.f);
}

// ---------------------------------------------------------------------------
extern "C" void kernel_launch(void* const* d_in, const int* in_sizes, int n_in,
                              void* d_out, int out_size, void* d_ws, size_t ws_size,
                              hipStream_t stream) {
  (void)in_sizes; (void)n_in; (void)out_size; (void)ws_size;
  const int*   oh     = (const int*)  d_in[0];
  const float* db     = (const float*)d_in[1];
  const float* dsl    = (const float*)d_in[2];
  const float* emb    = (const float*)d_in[3];
  const float* a_in_w = (const float*)d_in[4];
  const float* a_in_b = (const float*)d_in[5];
  const float* a_out_w= (const float*)d_in[6];
  const float* a_out_b= (const float*)d_in[7];
  const float* wih_f  = (const float*)d_in[8];
  const float* whh_f  = (const float*)d_in[9];
  const float* bih_f  = (const float*)d_in[10];
  const float* bhh_f  = (const float*)d_in[11];
  const float* wih_b  = (const float*)d_in[12];
  const float* whh_b  = (const float*)d_in[13];
  const float* bih_b  = (const float*)d_in[14];
  const float* bhh_b  = (const float*)d_in[15];
  const float* t_in_w = (const float*)d_in[16];
  const float* t_in_b = (const float*)d_in[17];
  const float* t_out_w= (const float*)d_in[18];
  const float* t_out_b= (const float*)d_in[19];
  const float* t_ln1g = (const float*)d_in[20];
  const float* t_ln1b = (const float*)d_in[21];
  const float* t_ff1w = (const float*)d_in[22];
  const float* t_ff1b = (const float*)d_in[23];
  const float* t_ff2w = (const float*)d_in[24];
  const float* t_ff2b = (const float*)d_in[25];
  const float* t_ln2g = (const float*)d_in[26];
  const float* t_ln2b = (const float*)d_in[27];
  const float* te1_w  = (const float*)d_in[28];
  const float* te1_b  = (const float*)d_in[29];
  const float* tl1g   = (const float*)d_in[30];
  const float* tl1b   = (const float*)d_in[31];
  const float* te2_w  = (const float*)d_in[32];
  const float* te2_b  = (const float*)d_in[33];
  const float* tl2g   = (const float*)d_in[34];
  const float* tl2b   = (const float*)d_in[35];
  const float* c_w    = (const float*)d_in[36];
  const float* c_b    = (const float*)d_in[37];
  const float* clng   = (const float*)d_in[38];
  const float* clnb   = (const float*)d_in[39];

  float* ws = (float*)d_ws;
  // Workspace (float slots), max index 17,391,616 (~69.6 MB):
  //   A [0,        524288):  oeb bf16 [8192][128]
  //   B∪C [1048576, 7409664): qkt bf16 [49696][256] (dead after order_attn)
  //       then g fp32 [1048576,5242880) + attn/g1/g2 fp32 [5242880,9437184)
  //   D [9437184,  9633792): whhb bf16 [2][768][256]
  //   D2[9633792,  9732096): wihb bf16 [2][768][128]
  //   D3[9732096,  9740288): awb2 bf16 [128*128]
  //   E [10027008,10051584): awb bf16 [384*128]
  //   F [10051584,10444800): twb bf16 [1536*512]
  //   G [10444800,10575872): pwb bf16 [512*512]
  //   G2[10575872,10838016): f1wb bf16 [1024*512]
  //   G3[10838016,11100160): f2wb bf16 [512*1024]
  //   H [11100160,17391616): vt bf16 [49696][128] (dead after order_attn)
  //       then gi bf16 [8192*1536]
  unsigned short* oeb  = (unsigned short*)ws;
  unsigned short* qkt  = (unsigned short*)(ws + 1048576);
  float* g    = ws + 1048576;                           // over dead qkt
  float* attn = ws + 5242880;
  float* g1   = attn;                                   // in-place LN out
  float* g2   = attn;                                   // in-place ffln out
  unsigned short* whhb = (unsigned short*)(ws + 9437184);
  unsigned short* wihb = (unsigned short*)(ws + 9633792);
  unsigned short* awb2 = (unsigned short*)(ws + 9732096);
  unsigned short* awb  = (unsigned short*)(ws + 10027008);
  unsigned short* twb  = (unsigned short*)(ws + 10051584);
  unsigned short* pwb  = (unsigned short*)(ws + 10444800);
  unsigned short* f1wb = (unsigned short*)(ws + 10575872);
  unsigned short* f2wb = (unsigned short*)(ws + 10838016);
  unsigned short* vt   = (unsigned short*)(ws + 11100160);
  unsigned short* gi   = (unsigned short*)(ws + 11100160); // over dead vt

  k_canary<<<256, 256, 0, stream>>>((float*)d_out);
  k_cvt<<<3072, 256, 0, stream>>>(a_in_w, t_in_w, t_out_w, t_ff1w, t_ff2w, a_out_w,
                                  awb, twb, pwb, f1wb, f2wb, awb2);
  k_gru_wb<<<1536, 256, 0, stream>>>(wih_f, whh_f, wih_b, whh_b, whhb, wihb);
  k_qkvpre<<<1553, 256, 0, stream>>>(emb, awb, a_in_b, qkt, vt);
  k_order_attn<<<8192, 256, 0, stream>>>(oh, qkt, vt, awb2, a_out_b, oeb);
  k_gru_gi<<<256, 256, 0, stream>>>(oeb, wihb, gi);
  k_gru_rec<<<dim3(128, 2), 512, 0, stream>>>(gi, whhb, bih_f, bhh_f, bih_b, bhh_b, g);
  k_mha2f<<<dim3(256, 4), 256, 0, stream>>>(g, twb, t_in_b, attn);
  k_projln_mfma<<<512, 512, 0, stream>>>(attn, pwb, t_out_b, g, t_ln1g, t_ln1b, g1);
  k_ffln<<<512, 512, 0, stream>>>(g1, f1wb, t_ff1b, f2wb, t_ff2b, g1,
                                  t_ln2g, t_ln2b, g2);
  k_final<<<256, 256, 0, stream>>>(g2, db, dsl, te1_w, te1_b, tl1g, tl1b,
                                   te2_w, te2_b, tl2g, tl2b, c_w, c_b, clng, clnb,
                                   (float*)d_out);
}

// Round 14
// 547.657 us; speedup vs baseline: 1.2018x; 1.0440x over previous
//
#include <hip/hip_runtime.h>
#include <hip/hip_bf16.h>
#include <math.h>

typedef __hip_bfloat16 bf16;
typedef __attribute__((ext_vector_type(8))) short short8v;   // 8 bf16 (4 VGPRs)
typedef __attribute__((ext_vector_type(4))) short short4v;   // 4 bf16 (2 VGPRs)
typedef __attribute__((ext_vector_type(4))) float float4v;   // 4 fp32 acc
#define MFMA16 __builtin_amdgcn_mfma_f32_16x16x32_bf16

__device__ __forceinline__ float us2f(unsigned short u) {
  union { unsigned u; float f; } c; c.u = ((unsigned)u) << 16; return c.f;
}
__device__ __forceinline__ unsigned short f2us(float f) {
  return __bfloat16_as_ushort(__float2bfloat16(f));
}

// fp32 x . fp32 w, K % 8 == 0, 16B-aligned
__device__ __forceinline__ float dot_ff(const float* __restrict__ x,
                                        const float* __restrict__ w, int K) {
  const float4* xp = reinterpret_cast<const float4*>(x);
  const float4* wp = reinterpret_cast<const float4*>(w);
  float acc = 0.f;
  const int n = K >> 2;
  for (int i = 0; i < n; ++i) {
    float4 a = xp[i], b = wp[i];
    acc += a.x*b.x + a.y*b.y + a.z*b.z + a.w*b.w;
  }
  return acc;
}

// native-exp sigmoid / tanh (clamped; serial-path hot in GRU)
__device__ __forceinline__ float sigm(float x) { return 1.f / (1.f + __expf(-x)); }
__device__ __forceinline__ float tanh_fast(float x) {
  x = fminf(fmaxf(x, -15.f), 15.f);
  float e = __expf(2.f * x);
  return (e - 1.f) / (e + 1.f);
}

// ---------------------------------------------------------------------------
__global__ void k_canary(float* __restrict__ out) {
  out[blockIdx.x * 256 + threadIdx.x] = 100.0f;
}

// ---------------------------------------------------------------------------
// One-shot: convert MFMA-consumed weights to bf16 in ws.
// ---------------------------------------------------------------------------
__global__ __launch_bounds__(256) void k_cvt(
    const float* __restrict__ a_in_w, const float* __restrict__ t_in_w,
    const float* __restrict__ t_out_w, const float* __restrict__ t_ff1w,
    const float* __restrict__ t_ff2w, const float* __restrict__ a_out_w,
    unsigned short* __restrict__ awb, unsigned short* __restrict__ twb,
    unsigned short* __restrict__ pwb, unsigned short* __restrict__ f1wb,
    unsigned short* __restrict__ f2wb, unsigned short* __restrict__ awb2)
{
  int i = blockIdx.x * 256 + threadIdx.x;
  if (i < 49152)  awb[i] = f2us(a_in_w[i]);
  if (i < 786432) twb[i] = f2us(t_in_w[i]);
  if (i < 262144) pwb[i] = f2us(t_out_w[i]);
  if (i < 524288) f1wb[i] = f2us(t_ff1w[i]);
  if (i < 524288) f2wb[i] = f2us(t_ff2w[i]);
  if (i < 16384)  awb2[i] = f2us(a_out_w[i]);
}

// ---------------------------------------------------------------------------
// GRU weight prep: row-major bf16 copies. whhb [dir][768][256],
// wihb [dir][768][128] (for gi GEMM).
// ---------------------------------------------------------------------------
__global__ __launch_bounds__(256) void k_gru_wb(
    const float* __restrict__ wih_f, const float* __restrict__ whh_f,
    const float* __restrict__ wih_b, const float* __restrict__ whh_b,
    unsigned short* __restrict__ whhb, unsigned short* __restrict__ wihb)
{
  int i = blockIdx.x * 256 + threadIdx.x;   // < 393216
  if (i >= 393216) return;
  int dir = i / 196608, r = i % 196608;
  whhb[i] = f2us((dir ? whh_b : whh_f)[r]);
  if (r < 98304) wihb[dir * 98304 + r] = f2us((dir ? wih_b : wih_f)[r]);
}

// ---------------------------------------------------------------------------
// QKV precompute over the VOCAB. qkt[49689][256] = q,k with bias;
// vt[49689][128] = v with bias. M=32 rows/block, grid 1553.
// ---------------------------------------------------------------------------
__global__ __launch_bounds__(256, 2) void k_qkvpre(
    const float* __restrict__ emb, const unsigned short* __restrict__ awb,
    const float* __restrict__ in_b,
    unsigned short* __restrict__ qkt, unsigned short* __restrict__ vt)
{
  const int row0 = blockIdx.x * 32, tid = threadIdx.x;
  __shared__ alignas(16) unsigned short xs[32 * 136];
  for (int i = tid; i < 1024; i += 256) {
    int t = i >> 5, c4 = (i & 31) << 2;
    int grow = row0 + t; if (grow > 49688) grow = 49688;
    float4 e4 = *reinterpret_cast<const float4*>(emb + (size_t)grow * 128 + c4);
    short4v s; s[0] = f2us(e4.x); s[1] = f2us(e4.y); s[2] = f2us(e4.z); s[3] = f2us(e4.w);
    *reinterpret_cast<short4v*>(xs + t * 136 + c4) = s;
  }
  __syncthreads();
  const int lane = tid & 63, wave = tid >> 6;
  const int l15 = lane & 15, quad = lane >> 4;
  short8v af[2][4];
#pragma unroll
  for (int mt = 0; mt < 2; ++mt)
#pragma unroll
    for (int kc = 0; kc < 4; ++kc)
      af[mt][kc] = *reinterpret_cast<const short8v*>(
          xs + (mt * 16 + l15) * 136 + kc * 32 + quad * 8);
  for (int ni = 0; ni < 6; ++ni) {
    const int j = (wave + ni * 4) * 16 + l15;
    const unsigned short* wrow = awb + (size_t)j * 128;
    float4v acc0 = {0.f, 0.f, 0.f, 0.f}, acc1 = {0.f, 0.f, 0.f, 0.f};
#pragma unroll
    for (int kc = 0; kc < 4; ++kc) {
      short8v bfr = *reinterpret_cast<const short8v*>(wrow + kc * 32 + quad * 8);
      acc0 = MFMA16(af[0][kc], bfr, acc0, 0, 0, 0);
      acc1 = MFMA16(af[1][kc], bfr, acc1, 0, 0, 0);
    }
    const float bj = in_b[j];
#pragma unroll
    for (int r = 0; r < 4; ++r) {
      int g0 = row0 + quad * 4 + r, g1 = g0 + 16;
      if (j < 256) {
        if (g0 <= 49688) qkt[(size_t)g0 * 256 + j] = f2us(acc0[r] + bj);
        if (g1 <= 49688) qkt[(size_t)g1 * 256 + j] = f2us(acc1[r] + bj);
      } else {
        int jj = j - 256;
        if (g0 <= 49688) vt[(size_t)g0 * 128 + jj] = f2us(acc0[r] + bj);
        if (g1 <= 49688) vt[(size_t)g1 * 128 + jj] = f2us(acc1[r] + bj);
      }
    }
  }
}

// ---------------------------------------------------------------------------
// Stage 1: gather precomputed q/k/vT + fused attention + proj-then-mean.
// LDS: qb 8704 (O overlay) + kb 8704 (P overlay) + vTb 8192 = 25,600 B.
// ---------------------------------------------------------------------------
__global__ __launch_bounds__(256, 5) void k_order_attn(
    const int* __restrict__ oh, const unsigned short* __restrict__ qkt,
    const unsigned short* __restrict__ vt,
    const unsigned short* __restrict__ awb2, const float* __restrict__ out_b,
    unsigned short* __restrict__ oeb)
{
  const int bo = blockIdx.x;            // 0..8191
  const int tid = threadIdx.x;
  __shared__ alignas(16) unsigned short qb[32 * 136];     // q -> O
  __shared__ alignas(16) unsigned short kb[32 * 136];     // k -> P [128][32]
  __shared__ alignas(16) unsigned short vTb[128 * 32];    // vT[d][t]
  unsigned short* ob = qb;
  unsigned short* pb = kb;

  const int lane = tid & 63, wave = tid >> 6;
  const int l15 = lane & 15, quad = lane >> 4;

  // gather q,k (16B/lane, 512B contiguous per token)
  for (int i = tid; i < 1024; i += 256) {
    int t = i >> 5, c8 = (i & 31) << 3;
    int id = oh[bo * 32 + t];
    short8v v8 = *reinterpret_cast<const short8v*>(qkt + (size_t)id * 256 + c8);
    if (c8 < 128) *reinterpret_cast<short8v*>(qb + t * 136 + c8) = v8;
    else          *reinterpret_cast<short8v*>(kb + t * 136 + (c8 - 128)) = v8;
  }
  // gather v, transpose into vTb via scalar LDS scatter
  for (int i = tid; i < 512; i += 256) {
    int t = i >> 4, c8 = (i & 15) << 3;
    int id = oh[bo * 32 + t];
    short8v v8 = *reinterpret_cast<const short8v*>(vt + (size_t)id * 128 + c8);
#pragma unroll
    for (int j2 = 0; j2 < 8; ++j2) vTb[(c8 + j2) * 32 + t] = v8[j2];
  }
  __syncthreads();
  // ---- FUSED: scores + exp + PV + ones-rowsum + O write (wave = head) ----
  {
    const int h = wave;
    const float scale1 = 0.17677669529663687f;            // 1/sqrt(32)
    short8v qf[2], kf[2];
#pragma unroll
    for (int mt = 0; mt < 2; ++mt)
      qf[mt] = *reinterpret_cast<const short8v*>(qb + (mt * 16 + l15) * 136 + h * 32 + quad * 8);
#pragma unroll
    for (int nt = 0; nt < 2; ++nt)
      kf[nt] = *reinterpret_cast<const short8v*>(kb + (nt * 16 + l15) * 136 + h * 32 + quad * 8);
    float4v sacc[2][2];
#pragma unroll
    for (int mt = 0; mt < 2; ++mt)
#pragma unroll
      for (int nt = 0; nt < 2; ++nt) {
        sacc[mt][nt] = (float4v){0.f, 0.f, 0.f, 0.f};
        sacc[mt][nt] = MFMA16(qf[mt], kf[nt], sacc[mt][nt], 0, 0, 0);
      }
    __syncthreads();                     // all qb/kb reg-reads done -> P/O writes ok
    // P = exp(s) (no max subtraction: |s| <~ 2, safe)
#pragma unroll
    for (int mt = 0; mt < 2; ++mt)
#pragma unroll
      for (int r = 0; r < 4; ++r) {
        float e0 = __expf(sacc[mt][0][r] * scale1);
        float e1 = __expf(sacc[mt][1][r] * scale1);
        int row = h * 32 + mt * 16 + quad * 4 + r;
        pb[row * 32 + l15] = f2us(e0);
        pb[row * 32 + 16 + l15] = f2us(e1);
      }
    // ones fragment for rowsum MFMA
    short8v ones;
#pragma unroll
    for (int i = 0; i < 8; ++i) ones[i] = (short)0x3F80;  // bf16 1.0
    short8v pf[2], vf[2];
#pragma unroll
    for (int mt = 0; mt < 2; ++mt)
      pf[mt] = *reinterpret_cast<const short8v*>(pb + (h * 32 + mt * 16 + l15) * 32 + quad * 8);
    float4v sums[2];
#pragma unroll
    for (int mt = 0; mt < 2; ++mt) {
      sums[mt] = (float4v){0.f, 0.f, 0.f, 0.f};
      sums[mt] = MFMA16(pf[mt], ones, sums[mt], 0, 0, 0);  // rowsums in C layout
    }
#pragma unroll
    for (int nt = 0; nt < 2; ++nt)
      vf[nt] = *reinterpret_cast<const short8v*>(vTb + (h * 32 + nt * 16 + l15) * 32 + quad * 8);
    float4v oacc[2][2];
#pragma unroll
    for (int mt = 0; mt < 2; ++mt)
#pragma unroll
      for (int nt = 0; nt < 2; ++nt) {
        oacc[mt][nt] = (float4v){0.f, 0.f, 0.f, 0.f};
        oacc[mt][nt] = MFMA16(pf[mt], vf[nt], oacc[mt][nt], 0, 0, 0);
      }
    // write O bf16 into ob (qb overlay): this wave's head-col stripe
#pragma unroll
    for (int mt = 0; mt < 2; ++mt)
#pragma unroll
      for (int r = 0; r < 4; ++r) {
        int t = mt * 16 + quad * 4 + r;
        float inv = 1.f / sums[mt][r];
#pragma unroll
        for (int nt = 0; nt < 2; ++nt)
          ob[t * 136 + h * 32 + nt * 16 + l15] = f2us(oacc[mt][nt][r] * inv);
      }
  }
  __syncthreads();
  // ---- out-proj MFMA: proj[t][j] = O[t][.] . W[j][.]; then mean over t ----
  {
    float4v acc[2][2];
#pragma unroll
    for (int mt = 0; mt < 2; ++mt)
#pragma unroll
      for (int nt = 0; nt < 2; ++nt) acc[mt][nt] = (float4v){0.f, 0.f, 0.f, 0.f};
#pragma unroll
    for (int kc = 0; kc < 4; ++kc) {
      short8v af0 = *reinterpret_cast<const short8v*>(ob + l15 * 136 + kc * 32 + quad * 8);
      short8v af1 = *reinterpret_cast<const short8v*>(ob + (16 + l15) * 136 + kc * 32 + quad * 8);
#pragma unroll
      for (int nt = 0; nt < 2; ++nt) {
        int j = (wave * 2 + nt) * 16 + l15;
        short8v bfr = *reinterpret_cast<const short8v*>(awb2 + (size_t)j * 128 + kc * 32 + quad * 8);
        acc[0][nt] = MFMA16(af0, bfr, acc[0][nt], 0, 0, 0);
        acc[1][nt] = MFMA16(af1, bfr, acc[1][nt], 0, 0, 0);
      }
    }
#pragma unroll
    for (int nt = 0; nt < 2; ++nt) {
      float part = 0.f;
#pragma unroll
      for (int mt = 0; mt < 2; ++mt)
#pragma unroll
        for (int r = 0; r < 4; ++r) part += acc[mt][nt][r];
      part += __shfl_xor(part, 16);
      part += __shfl_xor(part, 32);
      if (quad == 0) {
        int j = (wave * 2 + nt) * 16 + l15;
        oeb[(size_t)bo * 128 + j] = f2us(part * (1.f / 32.f) + out_b[j]);
      }
    }
  }
}

// ---------------------------------------------------------------------------
// gi GEMM (MFMA): gi[8192][1536] bf16 = oe @ wih^T (both dirs). oe is bf16.
// ---------------------------------------------------------------------------
__global__ __launch_bounds__(256, 2) void k_gru_gi(
    const unsigned short* __restrict__ oeb, const unsigned short* __restrict__ wihb,
    unsigned short* __restrict__ gi)
{
  const int row0 = blockIdx.x * 32, tid = threadIdx.x;
  __shared__ alignas(16) unsigned short xs[32 * 136];
  for (int i = tid; i < 512; i += 256) {
    int t = i >> 4, c8 = (i & 15) << 3;
    *reinterpret_cast<short8v*>(xs + t * 136 + c8) =
        *reinterpret_cast<const short8v*>(oeb + (size_t)(row0 + t) * 128 + c8);
  }
  __syncthreads();
  const int lane = tid & 63, wave = tid >> 6;
  const int l15 = lane & 15, quad = lane >> 4;
  short8v af[2][4];
#pragma unroll
  for (int mt = 0; mt < 2; ++mt)
#pragma unroll
    for (int kc = 0; kc < 4; ++kc)
      af[mt][kc] = *reinterpret_cast<const short8v*>(
          xs + (mt * 16 + l15) * 136 + kc * 32 + quad * 8);
  for (int ni = 0; ni < 24; ++ni) {
    int col = (wave + ni * 4) * 16 + l15;
    const unsigned short* wrow = wihb + (size_t)col * 128;
    float4v a0 = {0.f,0.f,0.f,0.f}, a1 = {0.f,0.f,0.f,0.f};
#pragma unroll
    for (int kc = 0; kc < 4; ++kc) {
      short8v bfr = *reinterpret_cast<const short8v*>(wrow + kc * 32 + quad * 8);
      a0 = MFMA16(af[0][kc], bfr, a0, 0, 0, 0);
      a1 = MFMA16(af[1][kc], bfr, a1, 0, 0, 0);
    }
#pragma unroll
    for (int r = 0; r < 4; ++r) {
      gi[(size_t)(row0 + quad * 4 + r) * 1536 + col] = f2us(a0[r]);
      gi[(size_t)(row0 + quad * 4 + r + 16) * 1536 + col] = f2us(a1[r]);
    }
  }
}

// ---------------------------------------------------------------------------
// GRU recurrence via MFMA. 2 batches/block, grid (128,2) = 256 blocks,
// 512 threads (8 waves). whh register-resident. gi prefetched.
// LDS: hb 8448 + pg 6176 = 14,624 B.
// ---------------------------------------------------------------------------
__global__ __launch_bounds__(512, 2) void k_gru_rec(
    const unsigned short* __restrict__ gi, const unsigned short* __restrict__ whhb,
    const float* __restrict__ bih_f, const float* __restrict__ bhh_f,
    const float* __restrict__ bih_b, const float* __restrict__ bhh_b,
    float* __restrict__ g)
{
  const int b0 = blockIdx.x * 2, dir = blockIdx.y;
  const int tid = threadIdx.x;           // 0..511
  const unsigned short* wb = whhb + (size_t)dir * 196608;   // [768][256] bf16
  const float* bih = dir ? bih_b : bih_f;
  const float* bhh = dir ? bhh_b : bhh_f;
  __shared__ alignas(16) unsigned short hb[16 * 264];   // h bf16 (A operand)
  __shared__ float pg[2 * 772];                         // gh fp32 (rows 0-1)
  const int lane = tid & 63, wave = tid >> 6;
  const int l15 = lane & 15, quad = lane >> 4;
  const int j = tid & 255, mb = tid >> 8;               // pointwise: (m=mb, j)
  const float bir = bih[j], biz = bih[256 + j], bin_ = bih[512 + j];
  const float bhr = bhh[j], bhz = bhh[256 + j], bhn  = bhh[512 + j];
  short8v wf[6][8];
  int cols[6];
#pragma unroll
  for (int ni = 0; ni < 6; ++ni) {
    cols[ni] = (wave + ni * 8) * 16 + l15;
#pragma unroll
    for (int kc = 0; kc < 8; ++kc)
      wf[ni][kc] = *reinterpret_cast<const short8v*>(
          wb + (size_t)cols[ni] * 256 + kc * 32 + quad * 8);
  }
  for (int i = tid; i < 16 * 264; i += 512) hb[i] = 0;
  int tcur = dir ? 31 : 0;
  size_t gbase = ((size_t)(b0 + mb) * 32 + tcur) * 1536 + dir * 768;
  float gr = us2f(gi[gbase + j]);
  float gz = us2f(gi[gbase + 256 + j]);
  float gn = us2f(gi[gbase + 512 + j]);
  __syncthreads();
  for (int s = 0; s < 32; ++s) {
    float4v acc[6];
#pragma unroll
    for (int ni = 0; ni < 6; ++ni) acc[ni] = (float4v){0.f, 0.f, 0.f, 0.f};
#pragma unroll
    for (int kc = 0; kc < 8; ++kc) {
      short8v af = *reinterpret_cast<const short8v*>(hb + l15 * 264 + kc * 32 + quad * 8);
#pragma unroll
      for (int ni = 0; ni < 6; ++ni)
        acc[ni] = MFMA16(af, wf[ni][kc], acc[ni], 0, 0, 0);
    }
    if (quad == 0) {
#pragma unroll
      for (int ni = 0; ni < 6; ++ni) {
        pg[cols[ni]] = acc[ni][0];
        pg[772 + cols[ni]] = acc[ni][1];
      }
    }
    float gr2 = 0.f, gz2 = 0.f, gn2 = 0.f;
    if (s < 31) {
      int t2 = dir ? (30 - s) : (s + 1);
      size_t gb2 = ((size_t)(b0 + mb) * 32 + t2) * 1536 + dir * 768;
      gr2 = us2f(gi[gb2 + j]);
      gz2 = us2f(gi[gb2 + 256 + j]);
      gn2 = us2f(gi[gb2 + 512 + j]);
    }
    __syncthreads();
    {
      const int tt = dir ? (31 - s) : s;
      float hprev = us2f(hb[mb * 264 + j]);
      float r = sigm(gr + bir + pg[mb * 772 + j] + bhr);
      float z = sigm(gz + biz + pg[mb * 772 + 256 + j] + bhz);
      float n = tanh_fast(gn + bin_ + r * (pg[mb * 772 + 512 + j] + bhn));
      float nh = (1.f - z) * n + z * hprev;
      hb[mb * 264 + j] = f2us(nh);
      g[((size_t)(b0 + mb) * 32 + tt) * 512 + dir * 256 + j] = nh;
    }
    gr = gr2; gz = gz2; gn = gn2;
    __syncthreads();
  }
}

// ---------------------------------------------------------------------------
// Stage 3 fused attention, one block per (b, head). x staged in K=128
// quarter-chunks (xs3 8,704 B) -> LDS 36,352 B -> 4 blocks/CU.
// ---------------------------------------------------------------------------
__global__ __launch_bounds__(256, 4) void k_mha2f(
    const float* __restrict__ g, const unsigned short* __restrict__ twb,
    const float* __restrict__ Bv, float* __restrict__ attn)
{
  const int b = blockIdx.x, h = blockIdx.y, tid = threadIdx.x;
  __shared__ alignas(16) unsigned short xs3[32 * 136];     // x chunk; P overlay
  __shared__ alignas(16) unsigned short qk[2 * 32 * 136];
  __shared__ alignas(16) unsigned short vT[128 * 40];      // vT[d][k]
  unsigned short* qs = qk;
  unsigned short* ks = qk + 32 * 136;
  unsigned short* pb = xs3;                                // P bf16 [32][32]
  const int lane = tid & 63, wave = tid >> 6;
  const int l15 = lane & 15, quad = lane >> 4;

  int wrowi[6];
#pragma unroll
  for (int ni = 0; ni < 6; ++ni) {
    int idx = (wave + ni * 4) * 16 + l15;
    int m = idx >> 7, dd = idx & 127;
    wrowi[ni] = m * 512 + h * 128 + dd;
  }
  float4v acc[6][2];
#pragma unroll
  for (int ni = 0; ni < 6; ++ni)
#pragma unroll
    for (int mt = 0; mt < 2; ++mt) acc[ni][mt] = (float4v){0.f, 0.f, 0.f, 0.f};

  for (int ck = 0; ck < 4; ++ck) {
    __syncthreads();
    for (int i = tid; i < 1024; i += 256) {                // x quarter load
      int t = i >> 5, c4 = (i & 31) << 2;
      float4 e4 = *reinterpret_cast<const float4*>(
          g + (size_t)b * 16384 + t * 512 + ck * 128 + c4);
      short4v s; s[0] = f2us(e4.x); s[1] = f2us(e4.y); s[2] = f2us(e4.z); s[3] = f2us(e4.w);
      *reinterpret_cast<short4v*>(xs3 + t * 136 + c4) = s;
    }
    __syncthreads();
    short8v af2[2][4];
#pragma unroll
    for (int mt = 0; mt < 2; ++mt)
#pragma unroll
      for (int u = 0; u < 4; ++u)
        af2[mt][u] = *reinterpret_cast<const short8v*>(
            xs3 + (mt * 16 + l15) * 136 + u * 32 + quad * 8);
#pragma unroll
    for (int ni = 0; ni < 6; ++ni) {
      const unsigned short* wrow = twb + (size_t)wrowi[ni] * 512 + ck * 128;
#pragma unroll
      for (int u = 0; u < 4; ++u) {
        short8v bfr = *reinterpret_cast<const short8v*>(wrow + u * 32 + quad * 8);
        acc[ni][0] = MFMA16(af2[0][u], bfr, acc[ni][0], 0, 0, 0);
        acc[ni][1] = MFMA16(af2[1][u], bfr, acc[ni][1], 0, 0, 0);
      }
    }
  }
  __syncthreads();                                         // xs3 reads done
#pragma unroll
  for (int ni = 0; ni < 6; ++ni) {
    int idx = (wave + ni * 4) * 16 + l15;
    int m = idx >> 7, dd = idx & 127;
    float bj = Bv[wrowi[ni]];
    if (m < 2) {
      unsigned short* dst = (m == 0) ? qs : ks;
#pragma unroll
      for (int r = 0; r < 4; ++r) {
        int t0 = quad * 4 + r;
        dst[t0 * 136 + dd] = f2us(acc[ni][0][r] + bj);
        dst[(t0 + 16) * 136 + dd] = f2us(acc[ni][1][r] + bj);
      }
    } else {
      short4v s0, s1;
#pragma unroll
      for (int r = 0; r < 4; ++r) { s0[r] = f2us(acc[ni][0][r] + bj); s1[r] = f2us(acc[ni][1][r] + bj); }
      *reinterpret_cast<short4v*>(vT + dd * 40 + quad * 4) = s0;
      *reinterpret_cast<short4v*>(vT + dd * 40 + 16 + quad * 4) = s1;
    }
  }
  __syncthreads();
  // ---- scores MFMA -> P = exp(s) bf16 directly (no max: |s| <~ 7) ----
  {
    const float scale2 = 0.08838834764831845f;            // 1/sqrt(128)
    const int mt = wave >> 1, nt = wave & 1;
    float4v a = {0.f, 0.f, 0.f, 0.f};
#pragma unroll
    for (int kc = 0; kc < 4; ++kc) {
      short8v qf = *reinterpret_cast<const short8v*>(qs + (mt * 16 + l15) * 136 + kc * 32 + quad * 8);
      short8v kf = *reinterpret_cast<const short8v*>(ks + (nt * 16 + l15) * 136 + kc * 32 + quad * 8);
      a = MFMA16(qf, kf, a, 0, 0, 0);
    }
#pragma unroll
    for (int r = 0; r < 4; ++r) {
      int row = mt * 16 + quad * 4 + r;
      pb[row * 32 + nt * 16 + l15] = f2us(__expf(a[r] * scale2));
    }
  }
  __syncthreads();
  // ---- PV MFMA + ones-rowsum; scale by 1/sum in epilogue ----
  {
    short8v ones;
#pragma unroll
    for (int i = 0; i < 8; ++i) ones[i] = (short)0x3F80;  // bf16 1.0
    short8v pf[2], vf[2];
#pragma unroll
    for (int mt = 0; mt < 2; ++mt)
      pf[mt] = *reinterpret_cast<const short8v*>(pb + (mt * 16 + l15) * 32 + quad * 8);
    float4v sums[2];
#pragma unroll
    for (int mt = 0; mt < 2; ++mt) {
      sums[mt] = (float4v){0.f, 0.f, 0.f, 0.f};
      sums[mt] = MFMA16(pf[mt], ones, sums[mt], 0, 0, 0);
    }
#pragma unroll
    for (int ntl = 0; ntl < 2; ++ntl)
      vf[ntl] = *reinterpret_cast<const short8v*>(vT + ((2 * wave + ntl) * 16 + l15) * 40 + quad * 8);
    float4v oacc[2][2];
#pragma unroll
    for (int mt = 0; mt < 2; ++mt)
#pragma unroll
      for (int ntl = 0; ntl < 2; ++ntl) {
        oacc[mt][ntl] = (float4v){0.f, 0.f, 0.f, 0.f};
        oacc[mt][ntl] = MFMA16(pf[mt], vf[ntl], oacc[mt][ntl], 0, 0, 0);
      }
#pragma unroll
    for (int mt = 0; mt < 2; ++mt)
#pragma unroll
      for (int r = 0; r < 4; ++r) {
        int q = mt * 16 + quad * 4 + r;
        float inv = 1.f / sums[mt][r];
#pragma unroll
        for (int ntl = 0; ntl < 2; ++ntl)
          attn[((size_t)b * 32 + q) * 512 + h * 128 + (2 * wave + ntl) * 16 + l15] =
              oacc[mt][ntl][r] * inv;
      }
  }
}

// ---------------------------------------------------------------------------
// proj GEMM via MFMA, 512 threads (8 waves): M=16, N=512, K=512.
// W-row fragments double-buffered. + bias + residual + LN (32 thr/row).
// ---------------------------------------------------------------------------
__global__ __launch_bounds__(512, 2) void k_projln_mfma(
    const float* __restrict__ X, const unsigned short* __restrict__ Wb,
    const float* __restrict__ bias, const float* __restrict__ res,
    const float* __restrict__ gam, const float* __restrict__ bet,
    float* __restrict__ Y)
{
  const int row0 = blockIdx.x * 16, tid = threadIdx.x;
  __shared__ alignas(16) unsigned short xs[16 * 520];
  __shared__ float ys[16 * 516];
  for (int i = tid; i < 16 * 512; i += 512) {
    int t = i >> 9, c = i & 511;
    xs[t * 520 + c] = f2us(X[(size_t)(row0 + t) * 512 + c]);
  }
  __syncthreads();
  {
    const int lane = tid & 63, wave = tid >> 6;           // wave 0..7
    const int l15 = lane & 15, quad = lane >> 4;
    short8v af[16];
#pragma unroll
    for (int kc = 0; kc < 16; ++kc)
      af[kc] = *reinterpret_cast<const short8v*>(xs + l15 * 520 + kc * 32 + quad * 8);
    short8v bufA[16], bufB[16];
    {
      const unsigned short* w0 = Wb + (size_t)((wave + 0 * 8) * 16 + l15) * 512;
#pragma unroll
      for (int kc = 0; kc < 16; ++kc)
        bufA[kc] = *reinterpret_cast<const short8v*>(w0 + kc * 32 + quad * 8);
    }
#pragma unroll
    for (int ni = 0; ni < 4; ++ni) {
      short8v* cur = (ni & 1) ? bufB : bufA;
      short8v* nxt = (ni & 1) ? bufA : bufB;
      if (ni < 3) {
        const unsigned short* wn = Wb + (size_t)((wave + (ni + 1) * 8) * 16 + l15) * 512;
#pragma unroll
        for (int kc = 0; kc < 16; ++kc)
          nxt[kc] = *reinterpret_cast<const short8v*>(wn + kc * 32 + quad * 8);
      }
      float4v acc = {0.f,0.f,0.f,0.f};
#pragma unroll
      for (int kc = 0; kc < 16; ++kc)
        acc = MFMA16(af[kc], cur[kc], acc, 0, 0, 0);
      int col = (wave + ni * 8) * 16 + l15;
      float bj = bias[col];
#pragma unroll
      for (int r = 0; r < 4; ++r)
        ys[(quad * 4 + r) * 516 + col] = acc[r] + bj;
    }
  }
  __syncthreads();
  for (int i = tid; i < 16 * 512; i += 512) {
    int t = i >> 9, c = i & 511;
    ys[t * 516 + c] += res[(size_t)(row0 + t) * 512 + c];
  }
  __syncthreads();
  {
    int row = tid >> 5, l32 = tid & 31;                   // 32 threads/row
    const float* yr = ys + row * 516;
    float part = 0.f;
#pragma unroll
    for (int k = 0; k < 16; ++k) part += yr[l32 + 32 * k];
#pragma unroll
    for (int off = 16; off; off >>= 1) part += __shfl_xor(part, off, 32);
    float mean = part * (1.f / 512.f);
    float var = 0.f;
#pragma unroll
    for (int k = 0; k < 16; ++k) { float d = yr[l32 + 32 * k] - mean; var += d * d; }
#pragma unroll
    for (int off = 16; off; off >>= 1) var += __shfl_xor(var, off, 32);
    float rs = rsqrtf(var * (1.f / 512.f) + 1e-5f);
    for (int k = 0; k < 16; ++k) {
      int c = l32 + 32 * k;
      Y[(size_t)(row0 + row) * 512 + c] = (yr[c] - mean) * rs * gam[c] + bet[c];
    }
  }
}

// ---------------------------------------------------------------------------
// FF pair, M=32/block (grid 256): HALVES the per-block weight re-streaming
// (L2 request-rate was the wall: 512 blocks x 2 MB of identical weights).
// ff1 and ff2 fused at 128-col CHUNK granularity: f1 chunk lives in a small
// LDS buffer, ff2 accumulates that K-chunk into persistent regs. Writes
// yraw = ff2 + bias (fp32); residual+LN done by k_resln.
// LDS: xs 33,280 + f1c 8,704 = 41,984 B. 512 threads (8 waves).
// ---------------------------------------------------------------------------
__global__ __launch_bounds__(512, 2) void k_ff(
    const float* __restrict__ X, const unsigned short* __restrict__ W1,
    const float* __restrict__ b1, const unsigned short* __restrict__ W2,
    const float* __restrict__ b2, float* __restrict__ yraw)
{
  const int row0 = blockIdx.x * 32, tid = threadIdx.x;
  __shared__ alignas(16) unsigned short xs[32 * 520];     // X bf16 [32][520]
  __shared__ alignas(16) unsigned short f1c[32 * 136];    // f1 chunk [32][136]
  const int lane = tid & 63, wave = tid >> 6;             // wave 0..7
  const int l15 = lane & 15, quad = lane >> 4;
  for (int i = tid; i < 4096; i += 512) {                 // X load (float4)
    int t = i >> 7, c4 = (i & 127) << 2;
    float4 e4 = *reinterpret_cast<const float4*>(X + (size_t)(row0 + t) * 512 + c4);
    short4v s; s[0] = f2us(e4.x); s[1] = f2us(e4.y); s[2] = f2us(e4.z); s[3] = f2us(e4.w);
    *reinterpret_cast<short4v*>(xs + t * 520 + c4) = s;
  }
  __syncthreads();
  float4v acc2[2][4];                                     // ff2 accum (persist)
#pragma unroll
  for (int mt = 0; mt < 2; ++mt)
#pragma unroll
    for (int ni = 0; ni < 4; ++ni) acc2[mt][ni] = (float4v){0.f,0.f,0.f,0.f};
  int cols2[4];
#pragma unroll
  for (int ni = 0; ni < 4; ++ni) cols2[ni] = (wave + ni * 8) * 16 + l15;

  for (int ck = 0; ck < 8; ++ck) {                        // 8 chunks of 128 f1-cols
    // ---- ff1 for this chunk: col = ck*128 + wave*16 + l15 ----
    {
      const int col = ck * 128 + wave * 16 + l15;
      const unsigned short* wrow = W1 + (size_t)col * 512;
      float4v a0 = {0.f,0.f,0.f,0.f}, a1 = {0.f,0.f,0.f,0.f};
#pragma unroll
      for (int kc = 0; kc < 16; ++kc) {
        short8v b = *reinterpret_cast<const short8v*>(wrow + kc * 32 + quad * 8);
        short8v x0 = *reinterpret_cast<const short8v*>(xs + l15 * 520 + kc * 32 + quad * 8);
        short8v x1 = *reinterpret_cast<const short8v*>(xs + (16 + l15) * 520 + kc * 32 + quad * 8);
        a0 = MFMA16(x0, b, a0, 0, 0, 0);
        a1 = MFMA16(x1, b, a1, 0, 0, 0);
      }
      const float bj = b1[col];
      const int cl = wave * 16 + l15;                     // chunk-local col
#pragma unroll
      for (int r = 0; r < 4; ++r) {
        f1c[(quad * 4 + r) * 136 + cl] = f2us(fmaxf(a0[r] + bj, 0.f));
        f1c[(16 + quad * 4 + r) * 136 + cl] = f2us(fmaxf(a1[r] + bj, 0.f));
      }
    }
    __syncthreads();
    // ---- ff2 accumulate this K-chunk (128 elems = 4 kc) ----
#pragma unroll
    for (int ni = 0; ni < 4; ++ni) {
      const unsigned short* wrow2 = W2 + (size_t)cols2[ni] * 1024 + ck * 128;
#pragma unroll
      for (int kc = 0; kc < 4; ++kc) {
        short8v b = *reinterpret_cast<const short8v*>(wrow2 + kc * 32 + quad * 8);
        short8v a0 = *reinterpret_cast<const short8v*>(f1c + l15 * 136 + kc * 32 + quad * 8);
        short8v a1 = *reinterpret_cast<const short8v*>(f1c + (16 + l15) * 136 + kc * 32 + quad * 8);
        acc2[0][ni] = MFMA16(a0, b, acc2[0][ni], 0, 0, 0);
        acc2[1][ni] = MFMA16(a1, b, acc2[1][ni], 0, 0, 0);
      }
    }
    __syncthreads();                                      // f1c reusable
  }
  // ---- epilogue: yraw = ff2 + bias (fp32) ----
#pragma unroll
  for (int mt = 0; mt < 2; ++mt)
#pragma unroll
    for (int ni = 0; ni < 4; ++ni) {
      int col = cols2[ni];
      float bj = b2[col];
#pragma unroll
      for (int r = 0; r < 4; ++r)
        yraw[(size_t)(row0 + mt * 16 + quad * 4 + r) * 512 + col] = acc2[mt][ni][r] + bj;
    }
}

// ---------------------------------------------------------------------------
// residual + LN (proven projln-tail pattern): Y = LN(yraw + res).
// M=16/block, grid 512, 256 threads.
// ---------------------------------------------------------------------------
__global__ __launch_bounds__(256, 2) void k_resln(
    const float* __restrict__ yraw, const float* __restrict__ res,
    const float* __restrict__ gam, const float* __restrict__ bet,
    float* __restrict__ Y)
{
  const int row0 = blockIdx.x * 16, tid = threadIdx.x;
  __shared__ float ys[16 * 516];
  for (int i = tid; i < 16 * 512; i += 256) {
    int t = i >> 9, c = i & 511;
    ys[t * 516 + c] = yraw[(size_t)(row0 + t) * 512 + c] +
                      res[(size_t)(row0 + t) * 512 + c];
  }
  __syncthreads();
  {
    int row = tid >> 4, l16 = tid & 15;
    const float* yr = ys + row * 516;
    float part = 0.f;
#pragma unroll
    for (int k = 0; k < 32; ++k) part += yr[l16 + 16 * k];
#pragma unroll
    for (int off = 8; off; off >>= 1) part += __shfl_xor(part, off, 16);
    float mean = part * (1.f / 512.f);
    float var = 0.f;
#pragma unroll
    for (int k = 0; k < 32; ++k) { float d = yr[l16 + 16 * k] - mean; var += d * d; }
#pragma unroll
    for (int off = 8; off; off >>= 1) var += __shfl_xor(var, off, 16);
    float rs = rsqrtf(var * (1.f / 512.f) + 1e-5f);
    for (int k = 0; k < 32; ++k) {
      int c = l16 + 16 * k;
      Y[(size_t)(row0 + row) * 512 + c] = (yr[c] - mean) * rs * gam[c] + bet[c];
    }
  }
}

// ---------------------------------------------------------------------------
// Final: mean-pool, temporal MLP, concat, classifier, LN, relu -> fp32
// ---------------------------------------------------------------------------
__global__ __launch_bounds__(256) void k_final(
    const float* __restrict__ g2,
    const float* __restrict__ db, const float* __restrict__ dsl,
    const float* __restrict__ te1_w, const float* __restrict__ te1_b,
    const float* __restrict__ l1g, const float* __restrict__ l1b,
    const float* __restrict__ te2_w, const float* __restrict__ te2_b,
    const float* __restrict__ l2g, const float* __restrict__ l2b,
    const float* __restrict__ c_w, const float* __restrict__ c_b,
    const float* __restrict__ clg, const float* __restrict__ clb,
    float* __restrict__ out)
{
  const int b = blockIdx.x, tid = threadIdx.x;
  __shared__ float cat[640];
  __shared__ float t1[64];
  __shared__ float t2[128];
  __shared__ float pre[256];
  __shared__ float red[256];
  __shared__ float st[2];
  for (int i = tid; i < 512; i += 256) {
    float acc = 0.f;
#pragma unroll
    for (int t = 0; t < 32; ++t) acc += g2[((size_t)b * 32 + t) * 512 + i];
    cat[i] = acc * (1.f / 32.f);
  }
  if (tid == 0) {
    float s = 0.f;
    for (int i = 0; i < 31; ++i) s += db[b * 31 + i];
    st[0] = s / 31.f;
    st[1] = dsl[b];
  }
  __syncthreads();
  const float f0 = st[0], f1v = st[1];
  if (tid < 64)
    t1[tid] = f0 * te1_w[tid * 2] + f1v * te1_w[tid * 2 + 1] + te1_b[tid];
  __syncthreads();
  if (tid == 0) {
    float m = 0.f; for (int i = 0; i < 64; ++i) m += t1[i]; m *= (1.f / 64.f);
    float v = 0.f; for (int i = 0; i < 64; ++i) { float d = t1[i] - m; v += d * d; }
    st[0] = m; st[1] = rsqrtf(v * (1.f / 64.f) + 1e-5f);
  }
  __syncthreads();
  if (tid < 64) {
    float v = (t1[tid] - st[0]) * st[1] * l1g[tid] + l1b[tid];
    t1[tid] = fmaxf(v, 0.f);
  }
  __syncthreads();
  if (tid < 128)
    t2[tid] = dot_ff(t1, te2_w + (size_t)tid * 64, 64) + te2_b[tid];
  __syncthreads();
  if (tid == 0) {
    float m = 0.f; for (int i = 0; i < 128; ++i) m += t2[i]; m *= (1.f / 128.f);
    float v = 0.f; for (int i = 0; i < 128; ++i) { float d = t2[i] - m; v += d * d; }
    st[0] = m; st[1] = rsqrtf(v * (1.f / 128.f) + 1e-5f);
  }
  __syncthreads();
  if (tid < 128) {
    float v = (t2[tid] - st[0]) * st[1] * l2g[tid] + l2b[tid];
    cat[512 + tid] = fmaxf(v, 0.f);
  }
  __syncthreads();
  pre[tid] = dot_ff(cat, c_w + (size_t)tid * 640, 640) + c_b[tid];
  red[tid] = pre[tid];
  __syncthreads();
  for (int s = 128; s > 0; s >>= 1) { if (tid < s) red[tid] += red[tid + s]; __syncthreads(); }
  const float m = red[0] * (1.f / 256.f);
  __syncthreads();
  const float d = pre[tid] - m;
  red[tid] = d * d;
  __syncthreads();
  for (int s = 128; s > 0; s >>= 1) { if (tid < s) red[tid] += red[tid + s]; __syncthreads(); }
  const float rs = rsqrtf(red[0] * (1.f / 256.f) + 1e-5f);
  float v = d * rs * clg[tid] + clb[tid];
  out[(size_t)b * 256 + tid] = fmaxf(v, 0.f);
}

// ---------------------------------------------------------------------------
extern "C" void kernel_launch(void* const* d_in, const int* in_sizes, int n_in,
                              void* d_out, int out_size, void* d_ws, size_t ws_size,
                              hipStream_t stream) {
  (void)in_sizes; (void)n_in; (void)out_size; (void)ws_size;
  const int*   oh     = (const int*)  d_in[0];
  const float* db     = (const float*)d_in[1];
  const float* dsl    = (const float*)d_in[2];
  const float* emb    = (const float*)d_in[3];
  const float* a_in_w = (const float*)d_in[4];
  const float* a_in_b = (const float*)d_in[5];
  const float* a_out_w= (const float*)d_in[6];
  const float* a_out_b= (const float*)d_in[7];
  const float* wih_f  = (const float*)d_in[8];
  const float* whh_f  = (const float*)d_in[9];
  const float* bih_f  = (const float*)d_in[10];
  const float* bhh_f  = (const float*)d_in[11];
  const float* wih_b  = (const float*)d_in[12];
  const float* whh_b  = (const float*)d_in[13];
  const float* bih_b  = (const float*)d_in[14];
  const float* bhh_b  = (const float*)d_in[15];
  const float* t_in_w = (const float*)d_in[16];
  const float* t_in_b = (const float*)d_in[17];
  const float* t_out_w= (const float*)d_in[18];
  const float* t_out_b= (const float*)d_in[19];
  const float* t_ln1g = (const float*)d_in[20];
  const float* t_ln1b = (const float*)d_in[21];
  const float* t_ff1w = (const float*)d_in[22];
  const float* t_ff1b = (const float*)d_in[23];
  const float* t_ff2w = (const float*)d_in[24];
  const float* t_ff2b = (const float*)d_in[25];
  const float* t_ln2g = (const float*)d_in[26];
  const float* t_ln2b = (const float*)d_in[27];
  const float* te1_w  = (const float*)d_in[28];
  const float* te1_b  = (const float*)d_in[29];
  const float* tl1g   = (const float*)d_in[30];
  const float* tl1b   = (const float*)d_in[31];
  const float* te2_w  = (const float*)d_in[32];
  const float* te2_b  = (const float*)d_in[33];
  const float* tl2g   = (const float*)d_in[34];
  const float* tl2b   = (const float*)d_in[35];
  const float* c_w    = (const float*)d_in[36];
  const float* c_b    = (const float*)d_in[37];
  const float* clng   = (const float*)d_in[38];
  const float* clnb   = (const float*)d_in[39];

  float* ws = (float*)d_ws;
  // Workspace (float slots), max index 17,391,616 (~69.6 MB):
  //   A [0,        524288):  oeb bf16 [8192][128]
  //   B [1048576,  5242880): qkt bf16 (dead after order_attn) -> g fp32
  //       -> yraw fp32 (after projln; g dead)
  //   C [5242880,  9437184): attn fp32; g1 LN in-place; g2 resln in-place
  //   D [9437184,  9633792): whhb bf16 [2][768][256]
  //   D2[9633792,  9732096): wihb bf16 [2][768][128]
  //   D3[9732096,  9740288): awb2 bf16 [128*128]
  //   E [10027008,10051584): awb bf16 [384*128]
  //   F [10051584,10444800): twb bf16 [1536*512]
  //   G [10444800,10575872): pwb bf16 [512*512]
  //   G2[10575872,10838016): f1wb bf16 [1024*512]
  //   G3[10838016,11100160): f2wb bf16 [512*1024]
  //   H [11100160,17391616): vt bf16 (dead after order_attn) -> gi bf16
  unsigned short* oeb  = (unsigned short*)ws;
  unsigned short* qkt  = (unsigned short*)(ws + 1048576);
  float* g    = ws + 1048576;                           // over dead qkt
  float* yraw = ws + 1048576;                           // over dead g (post-projln)
  float* attn = ws + 5242880;
  float* g1   = attn;                                   // in-place LN out
  float* g2   = attn;                                   // in-place resln out
  unsigned short* whhb = (unsigned short*)(ws + 9437184);
  unsigned short* wihb = (unsigned short*)(ws + 9633792);
  unsigned short* awb2 = (unsigned short*)(ws + 9732096);
  unsigned short* awb  = (unsigned short*)(ws + 10027008);
  unsigned short* twb  = (unsigned short*)(ws + 10051584);
  unsigned short* pwb  = (unsigned short*)(ws + 10444800);
  unsigned short* f1wb = (unsigned short*)(ws + 10575872);
  unsigned short* f2wb = (unsigned short*)(ws + 10838016);
  unsigned short* vt   = (unsigned short*)(ws + 11100160);
  unsigned short* gi   = (unsigned short*)(ws + 11100160); // over dead vt

  k_canary<<<256, 256, 0, stream>>>((float*)d_out);
  k_cvt<<<3072, 256, 0, stream>>>(a_in_w, t_in_w, t_out_w, t_ff1w, t_ff2w, a_out_w,
                                  awb, twb, pwb, f1wb, f2wb, awb2);
  k_gru_wb<<<1536, 256, 0, stream>>>(wih_f, whh_f, wih_b, whh_b, whhb, wihb);
  k_qkvpre<<<1553, 256, 0, stream>>>(emb, awb, a_in_b, qkt, vt);
  k_order_attn<<<8192, 256, 0, stream>>>(oh, qkt, vt, awb2, a_out_b, oeb);
  k_gru_gi<<<256, 256, 0, stream>>>(oeb, wihb, gi);
  k_gru_rec<<<dim3(128, 2), 512, 0, stream>>>(gi, whhb, bih_f, bhh_f, bih_b, bhh_b, g);
  k_mha2f<<<dim3(256, 4), 256, 0, stream>>>(g, twb, t_in_b, attn);
  k_projln_mfma<<<512, 512, 0, stream>>>(attn, pwb, t_out_b, g, t_ln1g, t_ln1b, g1);
  k_ff<<<256, 512, 0, stream>>>(g1, f1wb, t_ff1b, f2wb, t_ff2b, yraw);
  k_resln<<<512, 256, 0, stream>>>(yraw, g1, t_ln2g, t_ln2b, g2);
  k_final<<<256, 256, 0, stream>>>(g2, db, dsl, te1_w, te1_b, tl1g, tl1b,
                                   te2_w, te2_b, tl2g, tl2b, c_w, c_b, clng, clnb,
                                   (float*)d_out);
}

// Round 15
// 526.331 us; speedup vs baseline: 1.2505x; 1.0405x over previous
//
#include <hip/hip_runtime.h>
#include <hip/hip_bf16.h>
#include <math.h>

typedef __hip_bfloat16 bf16;
typedef __attribute__((ext_vector_type(8))) short short8v;   // 8 bf16 (4 VGPRs)
typedef __attribute__((ext_vector_type(4))) short short4v;   // 4 bf16 (2 VGPRs)
typedef __attribute__((ext_vector_type(4))) float float4v;   // 4 fp32 acc
#define MFMA16 __builtin_amdgcn_mfma_f32_16x16x32_bf16

__device__ __forceinline__ float us2f(unsigned short u) {
  union { unsigned u; float f; } c; c.u = ((unsigned)u) << 16; return c.f;
}
__device__ __forceinline__ unsigned short f2us(float f) {
  return __bfloat16_as_ushort(__float2bfloat16(f));
}

// fp32 x . fp32 w, K % 8 == 0, 16B-aligned
__device__ __forceinline__ float dot_ff(const float* __restrict__ x,
                                        const float* __restrict__ w, int K) {
  const float4* xp = reinterpret_cast<const float4*>(x);
  const float4* wp = reinterpret_cast<const float4*>(w);
  float acc = 0.f;
  const int n = K >> 2;
  for (int i = 0; i < n; ++i) {
    float4 a = xp[i], b = wp[i];
    acc += a.x*b.x + a.y*b.y + a.z*b.z + a.w*b.w;
  }
  return acc;
}

// native-exp sigmoid / tanh (clamped; serial-path hot in GRU)
__device__ __forceinline__ float sigm(float x) { return 1.f / (1.f + __expf(-x)); }
__device__ __forceinline__ float tanh_fast(float x) {
  x = fminf(fmaxf(x, -15.f), 15.f);
  float e = __expf(2.f * x);
  return (e - 1.f) / (e + 1.f);
}

// ---------------------------------------------------------------------------
__global__ void k_canary(float* __restrict__ out) {
  out[blockIdx.x * 256 + threadIdx.x] = 100.0f;
}

// ---------------------------------------------------------------------------
// One-shot: convert MFMA-consumed weights to bf16 in ws.
// ---------------------------------------------------------------------------
__global__ __launch_bounds__(256) void k_cvt(
    const float* __restrict__ a_in_w, const float* __restrict__ t_in_w,
    const float* __restrict__ t_out_w, const float* __restrict__ t_ff1w,
    const float* __restrict__ t_ff2w, const float* __restrict__ a_out_w,
    unsigned short* __restrict__ awb, unsigned short* __restrict__ twb,
    unsigned short* __restrict__ pwb, unsigned short* __restrict__ f1wb,
    unsigned short* __restrict__ f2wb, unsigned short* __restrict__ awb2)
{
  int i = blockIdx.x * 256 + threadIdx.x;
  if (i < 49152)  awb[i] = f2us(a_in_w[i]);
  if (i < 786432) twb[i] = f2us(t_in_w[i]);
  if (i < 262144) pwb[i] = f2us(t_out_w[i]);
  if (i < 524288) f1wb[i] = f2us(t_ff1w[i]);
  if (i < 524288) f2wb[i] = f2us(t_ff2w[i]);
  if (i < 16384)  awb2[i] = f2us(a_out_w[i]);
}

// ---------------------------------------------------------------------------
// GRU weight prep: row-major bf16 copies. whhb [dir][768][256],
// wihb [dir][768][128] (for gi GEMM).
// ---------------------------------------------------------------------------
__global__ __launch_bounds__(256) void k_gru_wb(
    const float* __restrict__ wih_f, const float* __restrict__ whh_f,
    const float* __restrict__ wih_b, const float* __restrict__ whh_b,
    unsigned short* __restrict__ whhb, unsigned short* __restrict__ wihb)
{
  int i = blockIdx.x * 256 + threadIdx.x;   // < 393216
  if (i >= 393216) return;
  int dir = i / 196608, r = i % 196608;
  whhb[i] = f2us((dir ? whh_b : whh_f)[r]);
  if (r < 98304) wihb[dir * 98304 + r] = f2us((dir ? wih_b : wih_f)[r]);
}

// ---------------------------------------------------------------------------
// QKV precompute over the VOCAB. qkt[49689][256] = q,k with bias;
// vt[49689][128] = v with bias. M=32 rows/block, grid 1553.
// ---------------------------------------------------------------------------
__global__ __launch_bounds__(256, 2) void k_qkvpre(
    const float* __restrict__ emb, const unsigned short* __restrict__ awb,
    const float* __restrict__ in_b,
    unsigned short* __restrict__ qkt, unsigned short* __restrict__ vt)
{
  const int row0 = blockIdx.x * 32, tid = threadIdx.x;
  __shared__ alignas(16) unsigned short xs[32 * 136];
  for (int i = tid; i < 1024; i += 256) {
    int t = i >> 5, c4 = (i & 31) << 2;
    int grow = row0 + t; if (grow > 49688) grow = 49688;
    float4 e4 = *reinterpret_cast<const float4*>(emb + (size_t)grow * 128 + c4);
    short4v s; s[0] = f2us(e4.x); s[1] = f2us(e4.y); s[2] = f2us(e4.z); s[3] = f2us(e4.w);
    *reinterpret_cast<short4v*>(xs + t * 136 + c4) = s;
  }
  __syncthreads();
  const int lane = tid & 63, wave = tid >> 6;
  const int l15 = lane & 15, quad = lane >> 4;
  short8v af[2][4];
#pragma unroll
  for (int mt = 0; mt < 2; ++mt)
#pragma unroll
    for (int kc = 0; kc < 4; ++kc)
      af[mt][kc] = *reinterpret_cast<const short8v*>(
          xs + (mt * 16 + l15) * 136 + kc * 32 + quad * 8);
  for (int ni = 0; ni < 6; ++ni) {
    const int j = (wave + ni * 4) * 16 + l15;
    const unsigned short* wrow = awb + (size_t)j * 128;
    float4v acc0 = {0.f, 0.f, 0.f, 0.f}, acc1 = {0.f, 0.f, 0.f, 0.f};
#pragma unroll
    for (int kc = 0; kc < 4; ++kc) {
      short8v bfr = *reinterpret_cast<const short8v*>(wrow + kc * 32 + quad * 8);
      acc0 = MFMA16(af[0][kc], bfr, acc0, 0, 0, 0);
      acc1 = MFMA16(af[1][kc], bfr, acc1, 0, 0, 0);
    }
    const float bj = in_b[j];
#pragma unroll
    for (int r = 0; r < 4; ++r) {
      int g0 = row0 + quad * 4 + r, g1 = g0 + 16;
      if (j < 256) {
        if (g0 <= 49688) qkt[(size_t)g0 * 256 + j] = f2us(acc0[r] + bj);
        if (g1 <= 49688) qkt[(size_t)g1 * 256 + j] = f2us(acc1[r] + bj);
      } else {
        int jj = j - 256;
        if (g0 <= 49688) vt[(size_t)g0 * 128 + jj] = f2us(acc0[r] + bj);
        if (g1 <= 49688) vt[(size_t)g1 * 128 + jj] = f2us(acc1[r] + bj);
      }
    }
  }
}

// ---------------------------------------------------------------------------
// Stage 1: gather precomputed q/k/vT + fused attention + proj-then-mean.
// LDS: qb 8704 (O overlay) + kb 8704 (P overlay) + vTb 8192 = 25,600 B.
// ---------------------------------------------------------------------------
__global__ __launch_bounds__(256, 5) void k_order_attn(
    const int* __restrict__ oh, const unsigned short* __restrict__ qkt,
    const unsigned short* __restrict__ vt,
    const unsigned short* __restrict__ awb2, const float* __restrict__ out_b,
    unsigned short* __restrict__ oeb)
{
  const int bo = blockIdx.x;            // 0..8191
  const int tid = threadIdx.x;
  __shared__ alignas(16) unsigned short qb[32 * 136];     // q -> O
  __shared__ alignas(16) unsigned short kb[32 * 136];     // k -> P [128][32]
  __shared__ alignas(16) unsigned short vTb[128 * 32];    // vT[d][t]
  unsigned short* ob = qb;
  unsigned short* pb = kb;

  const int lane = tid & 63, wave = tid >> 6;
  const int l15 = lane & 15, quad = lane >> 4;

  // gather q,k (16B/lane, 512B contiguous per token)
  for (int i = tid; i < 1024; i += 256) {
    int t = i >> 5, c8 = (i & 31) << 3;
    int id = oh[bo * 32 + t];
    short8v v8 = *reinterpret_cast<const short8v*>(qkt + (size_t)id * 256 + c8);
    if (c8 < 128) *reinterpret_cast<short8v*>(qb + t * 136 + c8) = v8;
    else          *reinterpret_cast<short8v*>(kb + t * 136 + (c8 - 128)) = v8;
  }
  // gather v, transpose into vTb via scalar LDS scatter
  for (int i = tid; i < 512; i += 256) {
    int t = i >> 4, c8 = (i & 15) << 3;
    int id = oh[bo * 32 + t];
    short8v v8 = *reinterpret_cast<const short8v*>(vt + (size_t)id * 128 + c8);
#pragma unroll
    for (int j2 = 0; j2 < 8; ++j2) vTb[(c8 + j2) * 32 + t] = v8[j2];
  }
  __syncthreads();
  // ---- FUSED: scores + exp + PV + ones-rowsum + O write (wave = head) ----
  {
    const int h = wave;
    const float scale1 = 0.17677669529663687f;            // 1/sqrt(32)
    short8v qf[2], kf[2];
#pragma unroll
    for (int mt = 0; mt < 2; ++mt)
      qf[mt] = *reinterpret_cast<const short8v*>(qb + (mt * 16 + l15) * 136 + h * 32 + quad * 8);
#pragma unroll
    for (int nt = 0; nt < 2; ++nt)
      kf[nt] = *reinterpret_cast<const short8v*>(kb + (nt * 16 + l15) * 136 + h * 32 + quad * 8);
    float4v sacc[2][2];
#pragma unroll
    for (int mt = 0; mt < 2; ++mt)
#pragma unroll
      for (int nt = 0; nt < 2; ++nt) {
        sacc[mt][nt] = (float4v){0.f, 0.f, 0.f, 0.f};
        sacc[mt][nt] = MFMA16(qf[mt], kf[nt], sacc[mt][nt], 0, 0, 0);
      }
    __syncthreads();                     // all qb/kb reg-reads done -> P/O writes ok
    // P = exp(s) (no max subtraction: |s| <~ 2, safe)
#pragma unroll
    for (int mt = 0; mt < 2; ++mt)
#pragma unroll
      for (int r = 0; r < 4; ++r) {
        float e0 = __expf(sacc[mt][0][r] * scale1);
        float e1 = __expf(sacc[mt][1][r] * scale1);
        int row = h * 32 + mt * 16 + quad * 4 + r;
        pb[row * 32 + l15] = f2us(e0);
        pb[row * 32 + 16 + l15] = f2us(e1);
      }
    // ones fragment for rowsum MFMA
    short8v ones;
#pragma unroll
    for (int i = 0; i < 8; ++i) ones[i] = (short)0x3F80;  // bf16 1.0
    short8v pf[2], vf[2];
#pragma unroll
    for (int mt = 0; mt < 2; ++mt)
      pf[mt] = *reinterpret_cast<const short8v*>(pb + (h * 32 + mt * 16 + l15) * 32 + quad * 8);
    float4v sums[2];
#pragma unroll
    for (int mt = 0; mt < 2; ++mt) {
      sums[mt] = (float4v){0.f, 0.f, 0.f, 0.f};
      sums[mt] = MFMA16(pf[mt], ones, sums[mt], 0, 0, 0);  // rowsums in C layout
    }
#pragma unroll
    for (int nt = 0; nt < 2; ++nt)
      vf[nt] = *reinterpret_cast<const short8v*>(vTb + (h * 32 + nt * 16 + l15) * 32 + quad * 8);
    float4v oacc[2][2];
#pragma unroll
    for (int mt = 0; mt < 2; ++mt)
#pragma unroll
      for (int nt = 0; nt < 2; ++nt) {
        oacc[mt][nt] = (float4v){0.f, 0.f, 0.f, 0.f};
        oacc[mt][nt] = MFMA16(pf[mt], vf[nt], oacc[mt][nt], 0, 0, 0);
      }
    // write O bf16 into ob (qb overlay): this wave's head-col stripe
#pragma unroll
    for (int mt = 0; mt < 2; ++mt)
#pragma unroll
      for (int r = 0; r < 4; ++r) {
        int t = mt * 16 + quad * 4 + r;
        float inv = 1.f / sums[mt][r];
#pragma unroll
        for (int nt = 0; nt < 2; ++nt)
          ob[t * 136 + h * 32 + nt * 16 + l15] = f2us(oacc[mt][nt][r] * inv);
      }
  }
  __syncthreads();
  // ---- out-proj MFMA: proj[t][j] = O[t][.] . W[j][.]; then mean over t ----
  {
    float4v acc[2][2];
#pragma unroll
    for (int mt = 0; mt < 2; ++mt)
#pragma unroll
      for (int nt = 0; nt < 2; ++nt) acc[mt][nt] = (float4v){0.f, 0.f, 0.f, 0.f};
#pragma unroll
    for (int kc = 0; kc < 4; ++kc) {
      short8v af0 = *reinterpret_cast<const short8v*>(ob + l15 * 136 + kc * 32 + quad * 8);
      short8v af1 = *reinterpret_cast<const short8v*>(ob + (16 + l15) * 136 + kc * 32 + quad * 8);
#pragma unroll
      for (int nt = 0; nt < 2; ++nt) {
        int j = (wave * 2 + nt) * 16 + l15;
        short8v bfr = *reinterpret_cast<const short8v*>(awb2 + (size_t)j * 128 + kc * 32 + quad * 8);
        acc[0][nt] = MFMA16(af0, bfr, acc[0][nt], 0, 0, 0);
        acc[1][nt] = MFMA16(af1, bfr, acc[1][nt], 0, 0, 0);
      }
    }
#pragma unroll
    for (int nt = 0; nt < 2; ++nt) {
      float part = 0.f;
#pragma unroll
      for (int mt = 0; mt < 2; ++mt)
#pragma unroll
        for (int r = 0; r < 4; ++r) part += acc[mt][nt][r];
      part += __shfl_xor(part, 16);
      part += __shfl_xor(part, 32);
      if (quad == 0) {
        int j = (wave * 2 + nt) * 16 + l15;
        oeb[(size_t)bo * 128 + j] = f2us(part * (1.f / 32.f) + out_b[j]);
      }
    }
  }
}

// ---------------------------------------------------------------------------
// gi GEMM (MFMA): gi[8192][1536] bf16 = oe @ wih^T (both dirs). oe is bf16.
// ---------------------------------------------------------------------------
__global__ __launch_bounds__(256, 2) void k_gru_gi(
    const unsigned short* __restrict__ oeb, const unsigned short* __restrict__ wihb,
    unsigned short* __restrict__ gi)
{
  const int row0 = blockIdx.x * 32, tid = threadIdx.x;
  __shared__ alignas(16) unsigned short xs[32 * 136];
  for (int i = tid; i < 512; i += 256) {
    int t = i >> 4, c8 = (i & 15) << 3;
    *reinterpret_cast<short8v*>(xs + t * 136 + c8) =
        *reinterpret_cast<const short8v*>(oeb + (size_t)(row0 + t) * 128 + c8);
  }
  __syncthreads();
  const int lane = tid & 63, wave = tid >> 6;
  const int l15 = lane & 15, quad = lane >> 4;
  short8v af[2][4];
#pragma unroll
  for (int mt = 0; mt < 2; ++mt)
#pragma unroll
    for (int kc = 0; kc < 4; ++kc)
      af[mt][kc] = *reinterpret_cast<const short8v*>(
          xs + (mt * 16 + l15) * 136 + kc * 32 + quad * 8);
  for (int ni = 0; ni < 24; ++ni) {
    int col = (wave + ni * 4) * 16 + l15;
    const unsigned short* wrow = wihb + (size_t)col * 128;
    float4v a0 = {0.f,0.f,0.f,0.f}, a1 = {0.f,0.f,0.f,0.f};
#pragma unroll
    for (int kc = 0; kc < 4; ++kc) {
      short8v bfr = *reinterpret_cast<const short8v*>(wrow + kc * 32 + quad * 8);
      a0 = MFMA16(af[0][kc], bfr, a0, 0, 0, 0);
      a1 = MFMA16(af[1][kc], bfr, a1, 0, 0, 0);
    }
#pragma unroll
    for (int r = 0; r < 4; ++r) {
      gi[(size_t)(row0 + quad * 4 + r) * 1536 + col] = f2us(a0[r]);
      gi[(size_t)(row0 + quad * 4 + r + 16) * 1536 + col] = f2us(a1[r]);
    }
  }
}

// ---------------------------------------------------------------------------
// GRU recurrence via MFMA. 2 batches/block, grid (128,2) = 256 blocks,
// 512 threads (8 waves). whh register-resident. gi prefetched.
// LDS: hb 8448 + pg 6176 = 14,624 B.
// ---------------------------------------------------------------------------
__global__ __launch_bounds__(512, 2) void k_gru_rec(
    const unsigned short* __restrict__ gi, const unsigned short* __restrict__ whhb,
    const float* __restrict__ bih_f, const float* __restrict__ bhh_f,
    const float* __restrict__ bih_b, const float* __restrict__ bhh_b,
    float* __restrict__ g)
{
  const int b0 = blockIdx.x * 2, dir = blockIdx.y;
  const int tid = threadIdx.x;           // 0..511
  const unsigned short* wb = whhb + (size_t)dir * 196608;   // [768][256] bf16
  const float* bih = dir ? bih_b : bih_f;
  const float* bhh = dir ? bhh_b : bhh_f;
  __shared__ alignas(16) unsigned short hb[16 * 264];   // h bf16 (A operand)
  __shared__ float pg[2 * 772];                         // gh fp32 (rows 0-1)
  const int lane = tid & 63, wave = tid >> 6;
  const int l15 = lane & 15, quad = lane >> 4;
  const int j = tid & 255, mb = tid >> 8;               // pointwise: (m=mb, j)
  const float bir = bih[j], biz = bih[256 + j], bin_ = bih[512 + j];
  const float bhr = bhh[j], bhz = bhh[256 + j], bhn  = bhh[512 + j];
  short8v wf[6][8];
  int cols[6];
#pragma unroll
  for (int ni = 0; ni < 6; ++ni) {
    cols[ni] = (wave + ni * 8) * 16 + l15;
#pragma unroll
    for (int kc = 0; kc < 8; ++kc)
      wf[ni][kc] = *reinterpret_cast<const short8v*>(
          wb + (size_t)cols[ni] * 256 + kc * 32 + quad * 8);
  }
  for (int i = tid; i < 16 * 264; i += 512) hb[i] = 0;
  int tcur = dir ? 31 : 0;
  size_t gbase = ((size_t)(b0 + mb) * 32 + tcur) * 1536 + dir * 768;
  float gr = us2f(gi[gbase + j]);
  float gz = us2f(gi[gbase + 256 + j]);
  float gn = us2f(gi[gbase + 512 + j]);
  __syncthreads();
  for (int s = 0; s < 32; ++s) {
    float4v acc[6];
#pragma unroll
    for (int ni = 0; ni < 6; ++ni) acc[ni] = (float4v){0.f, 0.f, 0.f, 0.f};
#pragma unroll
    for (int kc = 0; kc < 8; ++kc) {
      short8v af = *reinterpret_cast<const short8v*>(hb + l15 * 264 + kc * 32 + quad * 8);
#pragma unroll
      for (int ni = 0; ni < 6; ++ni)
        acc[ni] = MFMA16(af, wf[ni][kc], acc[ni], 0, 0, 0);
    }
    if (quad == 0) {
#pragma unroll
      for (int ni = 0; ni < 6; ++ni) {
        pg[cols[ni]] = acc[ni][0];
        pg[772 + cols[ni]] = acc[ni][1];
      }
    }
    float gr2 = 0.f, gz2 = 0.f, gn2 = 0.f;
    if (s < 31) {
      int t2 = dir ? (30 - s) : (s + 1);
      size_t gb2 = ((size_t)(b0 + mb) * 32 + t2) * 1536 + dir * 768;
      gr2 = us2f(gi[gb2 + j]);
      gz2 = us2f(gi[gb2 + 256 + j]);
      gn2 = us2f(gi[gb2 + 512 + j]);
    }
    __syncthreads();
    {
      const int tt = dir ? (31 - s) : s;
      float hprev = us2f(hb[mb * 264 + j]);
      float r = sigm(gr + bir + pg[mb * 772 + j] + bhr);
      float z = sigm(gz + biz + pg[mb * 772 + 256 + j] + bhz);
      float n = tanh_fast(gn + bin_ + r * (pg[mb * 772 + 512 + j] + bhn));
      float nh = (1.f - z) * n + z * hprev;
      hb[mb * 264 + j] = f2us(nh);
      g[((size_t)(b0 + mb) * 32 + tt) * 512 + dir * 256 + j] = nh;
    }
    gr = gr2; gz = gz2; gn = gn2;
    __syncthreads();
  }
}

// ---------------------------------------------------------------------------
// Stage 3 fused attention, one block per (b, head). x staged in K=128
// quarter-chunks (xs3 8,704 B) -> LDS 36,352 B -> 4 blocks/CU.
// ---------------------------------------------------------------------------
__global__ __launch_bounds__(256, 4) void k_mha2f(
    const float* __restrict__ g, const unsigned short* __restrict__ twb,
    const float* __restrict__ Bv, float* __restrict__ attn)
{
  const int b = blockIdx.x, h = blockIdx.y, tid = threadIdx.x;
  __shared__ alignas(16) unsigned short xs3[32 * 136];     // x chunk; P overlay
  __shared__ alignas(16) unsigned short qk[2 * 32 * 136];
  __shared__ alignas(16) unsigned short vT[128 * 40];      // vT[d][k]
  unsigned short* qs = qk;
  unsigned short* ks = qk + 32 * 136;
  unsigned short* pb = xs3;                                // P bf16 [32][32]
  const int lane = tid & 63, wave = tid >> 6;
  const int l15 = lane & 15, quad = lane >> 4;

  int wrowi[6];
#pragma unroll
  for (int ni = 0; ni < 6; ++ni) {
    int idx = (wave + ni * 4) * 16 + l15;
    int m = idx >> 7, dd = idx & 127;
    wrowi[ni] = m * 512 + h * 128 + dd;
  }
  float4v acc[6][2];
#pragma unroll
  for (int ni = 0; ni < 6; ++ni)
#pragma unroll
    for (int mt = 0; mt < 2; ++mt) acc[ni][mt] = (float4v){0.f, 0.f, 0.f, 0.f};

  for (int ck = 0; ck < 4; ++ck) {
    __syncthreads();
    for (int i = tid; i < 1024; i += 256) {                // x quarter load
      int t = i >> 5, c4 = (i & 31) << 2;
      float4 e4 = *reinterpret_cast<const float4*>(
          g + (size_t)b * 16384 + t * 512 + ck * 128 + c4);
      short4v s; s[0] = f2us(e4.x); s[1] = f2us(e4.y); s[2] = f2us(e4.z); s[3] = f2us(e4.w);
      *reinterpret_cast<short4v*>(xs3 + t * 136 + c4) = s;
    }
    __syncthreads();
    short8v af2[2][4];
#pragma unroll
    for (int mt = 0; mt < 2; ++mt)
#pragma unroll
      for (int u = 0; u < 4; ++u)
        af2[mt][u] = *reinterpret_cast<const short8v*>(
            xs3 + (mt * 16 + l15) * 136 + u * 32 + quad * 8);
#pragma unroll
    for (int ni = 0; ni < 6; ++ni) {
      const unsigned short* wrow = twb + (size_t)wrowi[ni] * 512 + ck * 128;
#pragma unroll
      for (int u = 0; u < 4; ++u) {
        short8v bfr = *reinterpret_cast<const short8v*>(wrow + u * 32 + quad * 8);
        acc[ni][0] = MFMA16(af2[0][u], bfr, acc[ni][0], 0, 0, 0);
        acc[ni][1] = MFMA16(af2[1][u], bfr, acc[ni][1], 0, 0, 0);
      }
    }
  }
  __syncthreads();                                         // xs3 reads done
#pragma unroll
  for (int ni = 0; ni < 6; ++ni) {
    int idx = (wave + ni * 4) * 16 + l15;
    int m = idx >> 7, dd = idx & 127;
    float bj = Bv[wrowi[ni]];
    if (m < 2) {
      unsigned short* dst = (m == 0) ? qs : ks;
#pragma unroll
      for (int r = 0; r < 4; ++r) {
        int t0 = quad * 4 + r;
        dst[t0 * 136 + dd] = f2us(acc[ni][0][r] + bj);
        dst[(t0 + 16) * 136 + dd] = f2us(acc[ni][1][r] + bj);
      }
    } else {
      short4v s0, s1;
#pragma unroll
      for (int r = 0; r < 4; ++r) { s0[r] = f2us(acc[ni][0][r] + bj); s1[r] = f2us(acc[ni][1][r] + bj); }
      *reinterpret_cast<short4v*>(vT + dd * 40 + quad * 4) = s0;
      *reinterpret_cast<short4v*>(vT + dd * 40 + 16 + quad * 4) = s1;
    }
  }
  __syncthreads();
  // ---- scores MFMA -> P = exp(s) bf16 directly (no max: |s| <~ 7) ----
  {
    const float scale2 = 0.08838834764831845f;            // 1/sqrt(128)
    const int mt = wave >> 1, nt = wave & 1;
    float4v a = {0.f, 0.f, 0.f, 0.f};
#pragma unroll
    for (int kc = 0; kc < 4; ++kc) {
      short8v qf = *reinterpret_cast<const short8v*>(qs + (mt * 16 + l15) * 136 + kc * 32 + quad * 8);
      short8v kf = *reinterpret_cast<const short8v*>(ks + (nt * 16 + l15) * 136 + kc * 32 + quad * 8);
      a = MFMA16(qf, kf, a, 0, 0, 0);
    }
#pragma unroll
    for (int r = 0; r < 4; ++r) {
      int row = mt * 16 + quad * 4 + r;
      pb[row * 32 + nt * 16 + l15] = f2us(__expf(a[r] * scale2));
    }
  }
  __syncthreads();
  // ---- PV MFMA + ones-rowsum; scale by 1/sum in epilogue ----
  {
    short8v ones;
#pragma unroll
    for (int i = 0; i < 8; ++i) ones[i] = (short)0x3F80;  // bf16 1.0
    short8v pf[2], vf[2];
#pragma unroll
    for (int mt = 0; mt < 2; ++mt)
      pf[mt] = *reinterpret_cast<const short8v*>(pb + (mt * 16 + l15) * 32 + quad * 8);
    float4v sums[2];
#pragma unroll
    for (int mt = 0; mt < 2; ++mt) {
      sums[mt] = (float4v){0.f, 0.f, 0.f, 0.f};
      sums[mt] = MFMA16(pf[mt], ones, sums[mt], 0, 0, 0);
    }
#pragma unroll
    for (int ntl = 0; ntl < 2; ++ntl)
      vf[ntl] = *reinterpret_cast<const short8v*>(vT + ((2 * wave + ntl) * 16 + l15) * 40 + quad * 8);
    float4v oacc[2][2];
#pragma unroll
    for (int mt = 0; mt < 2; ++mt)
#pragma unroll
      for (int ntl = 0; ntl < 2; ++ntl) {
        oacc[mt][ntl] = (float4v){0.f, 0.f, 0.f, 0.f};
        oacc[mt][ntl] = MFMA16(pf[mt], vf[ntl], oacc[mt][ntl], 0, 0, 0);
      }
#pragma unroll
    for (int mt = 0; mt < 2; ++mt)
#pragma unroll
      for (int r = 0; r < 4; ++r) {
        int q = mt * 16 + quad * 4 + r;
        float inv = 1.f / sums[mt][r];
#pragma unroll
        for (int ntl = 0; ntl < 2; ++ntl)
          attn[((size_t)b * 32 + q) * 512 + h * 128 + (2 * wave + ntl) * 16 + l15] =
              oacc[mt][ntl][r] * inv;
      }
  }
}

// ---------------------------------------------------------------------------
// proj GEMM raw, M=32/block (grid 256, halves pwb streaming), 1024 threads
// (16 waves = 50% occ). Writes praw = X @ W^T + bias (fp32); residual+LN
// done by k_resln. LDS: xs 33,280 B.
// ---------------------------------------------------------------------------
__global__ __launch_bounds__(1024, 1) void k_proj(
    const float* __restrict__ X, const unsigned short* __restrict__ Wb,
    const float* __restrict__ bias, float* __restrict__ praw)
{
  const int row0 = blockIdx.x * 32, tid = threadIdx.x;
  __shared__ alignas(16) unsigned short xs[32 * 520];
  const int lane = tid & 63, wave = tid >> 6;             // wave 0..15
  const int l15 = lane & 15, quad = lane >> 4;
  for (int i = tid; i < 4096; i += 1024) {
    int t = i >> 7, c4 = (i & 127) << 2;
    float4 e4 = *reinterpret_cast<const float4*>(X + (size_t)(row0 + t) * 512 + c4);
    short4v s; s[0] = f2us(e4.x); s[1] = f2us(e4.y); s[2] = f2us(e4.z); s[3] = f2us(e4.w);
    *reinterpret_cast<short4v*>(xs + t * 520 + c4) = s;
  }
  __syncthreads();
#pragma unroll
  for (int ni = 0; ni < 2; ++ni) {
    const int col = (wave + ni * 16) * 16 + l15;
    const unsigned short* wrow = Wb + (size_t)col * 512;
    float4v a0 = {0.f,0.f,0.f,0.f}, a1 = {0.f,0.f,0.f,0.f};
#pragma unroll
    for (int kc = 0; kc < 16; ++kc) {
      short8v b = *reinterpret_cast<const short8v*>(wrow + kc * 32 + quad * 8);
      short8v x0 = *reinterpret_cast<const short8v*>(xs + l15 * 520 + kc * 32 + quad * 8);
      short8v x1 = *reinterpret_cast<const short8v*>(xs + (16 + l15) * 520 + kc * 32 + quad * 8);
      a0 = MFMA16(x0, b, a0, 0, 0, 0);
      a1 = MFMA16(x1, b, a1, 0, 0, 0);
    }
    const float bj = bias[col];
#pragma unroll
    for (int r = 0; r < 4; ++r) {
      praw[(size_t)(row0 + quad * 4 + r) * 512 + col] = a0[r] + bj;
      praw[(size_t)(row0 + 16 + quad * 4 + r) * 512 + col] = a1[r] + bj;
    }
  }
}

// ---------------------------------------------------------------------------
// FF pair, M=32/block (grid 256), 1024 threads (16 waves = 50% occ; was 8).
// 4 chunks of 256 f1-cols (8 barriers; was 16). f1 chunk in LDS, ff2
// accumulates each K-chunk into persistent regs. Writes yraw (fp32).
// LDS: xs 33,280 + f1c 16,896 = 50,176 B.
// ---------------------------------------------------------------------------
__global__ __launch_bounds__(1024, 1) void k_ff(
    const float* __restrict__ X, const unsigned short* __restrict__ W1,
    const float* __restrict__ b1, const unsigned short* __restrict__ W2,
    const float* __restrict__ b2, float* __restrict__ yraw)
{
  const int row0 = blockIdx.x * 32, tid = threadIdx.x;
  __shared__ alignas(16) unsigned short xs[32 * 520];     // X bf16 [32][520]
  __shared__ alignas(16) unsigned short f1c[32 * 264];    // f1 chunk [32][264]
  const int lane = tid & 63, wave = tid >> 6;             // wave 0..15
  const int l15 = lane & 15, quad = lane >> 4;
  for (int i = tid; i < 4096; i += 1024) {                // X load (float4)
    int t = i >> 7, c4 = (i & 127) << 2;
    float4 e4 = *reinterpret_cast<const float4*>(X + (size_t)(row0 + t) * 512 + c4);
    short4v s; s[0] = f2us(e4.x); s[1] = f2us(e4.y); s[2] = f2us(e4.z); s[3] = f2us(e4.w);
    *reinterpret_cast<short4v*>(xs + t * 520 + c4) = s;
  }
  __syncthreads();
  float4v acc2[2][2];                                     // ff2 accum (persist)
#pragma unroll
  for (int mt = 0; mt < 2; ++mt)
#pragma unroll
    for (int ni = 0; ni < 2; ++ni) acc2[mt][ni] = (float4v){0.f,0.f,0.f,0.f};
  int cols2[2];
#pragma unroll
  for (int ni = 0; ni < 2; ++ni) cols2[ni] = (wave + ni * 16) * 16 + l15;

  for (int ck = 0; ck < 4; ++ck) {                        // 4 chunks of 256 f1-cols
    // ---- ff1 for this chunk: col = ck*256 + wave*16 + l15 ----
    {
      const int col = ck * 256 + wave * 16 + l15;
      const unsigned short* wrow = W1 + (size_t)col * 512;
      float4v a0 = {0.f,0.f,0.f,0.f}, a1 = {0.f,0.f,0.f,0.f};
#pragma unroll
      for (int kc = 0; kc < 16; ++kc) {
        short8v b = *reinterpret_cast<const short8v*>(wrow + kc * 32 + quad * 8);
        short8v x0 = *reinterpret_cast<const short8v*>(xs + l15 * 520 + kc * 32 + quad * 8);
        short8v x1 = *reinterpret_cast<const short8v*>(xs + (16 + l15) * 520 + kc * 32 + quad * 8);
        a0 = MFMA16(x0, b, a0, 0, 0, 0);
        a1 = MFMA16(x1, b, a1, 0, 0, 0);
      }
      const float bj = b1[col];
      const int cl = wave * 16 + l15;                     // chunk-local col
#pragma unroll
      for (int r = 0; r < 4; ++r) {
        f1c[(quad * 4 + r) * 264 + cl] = f2us(fmaxf(a0[r] + bj, 0.f));
        f1c[(16 + quad * 4 + r) * 264 + cl] = f2us(fmaxf(a1[r] + bj, 0.f));
      }
    }
    __syncthreads();
    // ---- ff2 accumulate this K-chunk (256 elems = 8 kc) ----
#pragma unroll
    for (int ni = 0; ni < 2; ++ni) {
      const unsigned short* wrow2 = W2 + (size_t)cols2[ni] * 1024 + ck * 256;
#pragma unroll
      for (int kc = 0; kc < 8; ++kc) {
        short8v b = *reinterpret_cast<const short8v*>(wrow2 + kc * 32 + quad * 8);
        short8v a0 = *reinterpret_cast<const short8v*>(f1c + l15 * 264 + kc * 32 + quad * 8);
        short8v a1 = *reinterpret_cast<const short8v*>(f1c + (16 + l15) * 264 + kc * 32 + quad * 8);
        acc2[0][ni] = MFMA16(a0, b, acc2[0][ni], 0, 0, 0);
        acc2[1][ni] = MFMA16(a1, b, acc2[1][ni], 0, 0, 0);
      }
    }
    __syncthreads();                                      // f1c reusable
  }
  // ---- epilogue: yraw = ff2 + bias (fp32) ----
#pragma unroll
  for (int mt = 0; mt < 2; ++mt)
#pragma unroll
    for (int ni = 0; ni < 2; ++ni) {
      int col = cols2[ni];
      float bj = b2[col];
#pragma unroll
      for (int r = 0; r < 4; ++r)
        yraw[(size_t)(row0 + mt * 16 + quad * 4 + r) * 512 + col] = acc2[mt][ni][r] + bj;
    }
}

// ---------------------------------------------------------------------------
// residual + LN: Y = LN(yraw + res). M=16/block, grid 512, 256 threads.
// ---------------------------------------------------------------------------
__global__ __launch_bounds__(256, 2) void k_resln(
    const float* __restrict__ yraw, const float* __restrict__ res,
    const float* __restrict__ gam, const float* __restrict__ bet,
    float* __restrict__ Y)
{
  const int row0 = blockIdx.x * 16, tid = threadIdx.x;
  __shared__ float ys[16 * 516];
  for (int i = tid; i < 16 * 512; i += 256) {
    int t = i >> 9, c = i & 511;
    ys[t * 516 + c] = yraw[(size_t)(row0 + t) * 512 + c] +
                      res[(size_t)(row0 + t) * 512 + c];
  }
  __syncthreads();
  {
    int row = tid >> 4, l16 = tid & 15;
    const float* yr = ys + row * 516;
    float part = 0.f;
#pragma unroll
    for (int k = 0; k < 32; ++k) part += yr[l16 + 16 * k];
#pragma unroll
    for (int off = 8; off; off >>= 1) part += __shfl_xor(part, off, 16);
    float mean = part * (1.f / 512.f);
    float var = 0.f;
#pragma unroll
    for (int k = 0; k < 32; ++k) { float d = yr[l16 + 16 * k] - mean; var += d * d; }
#pragma unroll
    for (int off = 8; off; off >>= 1) var += __shfl_xor(var, off, 16);
    float rs = rsqrtf(var * (1.f / 512.f) + 1e-5f);
    for (int k = 0; k < 32; ++k) {
      int c = l16 + 16 * k;
      Y[(size_t)(row0 + row) * 512 + c] = (yr[c] - mean) * rs * gam[c] + bet[c];
    }
  }
}

// ---------------------------------------------------------------------------
// Final: mean-pool, temporal MLP, concat, classifier, LN, relu -> fp32
// ---------------------------------------------------------------------------
__global__ __launch_bounds__(256) void k_final(
    const float* __restrict__ g2,
    const float* __restrict__ db, const float* __restrict__ dsl,
    const float* __restrict__ te1_w, const float* __restrict__ te1_b,
    const float* __restrict__ l1g, const float* __restrict__ l1b,
    const float* __restrict__ te2_w, const float* __restrict__ te2_b,
    const float* __restrict__ l2g, const float* __restrict__ l2b,
    const float* __restrict__ c_w, const float* __restrict__ c_b,
    const float* __restrict__ clg, const float* __restrict__ clb,
    float* __restrict__ out)
{
  const int b = blockIdx.x, tid = threadIdx.x;
  __shared__ float cat[640];
  __shared__ float t1[64];
  __shared__ float t2[128];
  __shared__ float pre[256];
  __shared__ float red[256];
  __shared__ float st[2];
  for (int i = tid; i < 512; i += 256) {
    float acc = 0.f;
#pragma unroll
    for (int t = 0; t < 32; ++t) acc += g2[((size_t)b * 32 + t) * 512 + i];
    cat[i] = acc * (1.f / 32.f);
  }
  if (tid == 0) {
    float s = 0.f;
    for (int i = 0; i < 31; ++i) s += db[b * 31 + i];
    st[0] = s / 31.f;
    st[1] = dsl[b];
  }
  __syncthreads();
  const float f0 = st[0], f1v = st[1];
  if (tid < 64)
    t1[tid] = f0 * te1_w[tid * 2] + f1v * te1_w[tid * 2 + 1] + te1_b[tid];
  __syncthreads();
  if (tid == 0) {
    float m = 0.f; for (int i = 0; i < 64; ++i) m += t1[i]; m *= (1.f / 64.f);
    float v = 0.f; for (int i = 0; i < 64; ++i) { float d = t1[i] - m; v += d * d; }
    st[0] = m; st[1] = rsqrtf(v * (1.f / 64.f) + 1e-5f);
  }
  __syncthreads();
  if (tid < 64) {
    float v = (t1[tid] - st[0]) * st[1] * l1g[tid] + l1b[tid];
    t1[tid] = fmaxf(v, 0.f);
  }
  __syncthreads();
  if (tid < 128)
    t2[tid] = dot_ff(t1, te2_w + (size_t)tid * 64, 64) + te2_b[tid];
  __syncthreads();
  if (tid == 0) {
    float m = 0.f; for (int i = 0; i < 128; ++i) m += t2[i]; m *= (1.f / 128.f);
    float v = 0.f; for (int i = 0; i < 128; ++i) { float d = t2[i] - m; v += d * d; }
    st[0] = m; st[1] = rsqrtf(v * (1.f / 128.f) + 1e-5f);
  }
  __syncthreads();
  if (tid < 128) {
    float v = (t2[tid] - st[0]) * st[1] * l2g[tid] + l2b[tid];
    cat[512 + tid] = fmaxf(v, 0.f);
  }
  __syncthreads();
  pre[tid] = dot_ff(cat, c_w + (size_t)tid * 640, 640) + c_b[tid];
  red[tid] = pre[tid];
  __syncthreads();
  for (int s = 128; s > 0; s >>= 1) { if (tid < s) red[tid] += red[tid + s]; __syncthreads(); }
  const float m = red[0] * (1.f / 256.f);
  __syncthreads();
  const float d = pre[tid] - m;
  red[tid] = d * d;
  __syncthreads();
  for (int s = 128; s > 0; s >>= 1) { if (tid < s) red[tid] += red[tid + s]; __syncthreads(); }
  const float rs = rsqrtf(red[0] * (1.f / 256.f) + 1e-5f);
  float v = d * rs * clg[tid] + clb[tid];
  out[(size_t)b * 256 + tid] = fmaxf(v, 0.f);
}

// ---------------------------------------------------------------------------
extern "C" void kernel_launch(void* const* d_in, const int* in_sizes, int n_in,
                              void* d_out, int out_size, void* d_ws, size_t ws_size,
                              hipStream_t stream) {
  (void)in_sizes; (void)n_in; (void)out_size; (void)ws_size;
  const int*   oh     = (const int*)  d_in[0];
  const float* db     = (const float*)d_in[1];
  const float* dsl    = (const float*)d_in[2];
  const float* emb    = (const float*)d_in[3];
  const float* a_in_w = (const float*)d_in[4];
  const float* a_in_b = (const float*)d_in[5];
  const float* a_out_w= (const float*)d_in[6];
  const float* a_out_b= (const float*)d_in[7];
  const float* wih_f  = (const float*)d_in[8];
  const float* whh_f  = (const float*)d_in[9];
  const float* bih_f  = (const float*)d_in[10];
  const float* bhh_f  = (const float*)d_in[11];
  const float* wih_b  = (const float*)d_in[12];
  const float* whh_b  = (const float*)d_in[13];
  const float* bih_b  = (const float*)d_in[14];
  const float* bhh_b  = (const float*)d_in[15];
  const float* t_in_w = (const float*)d_in[16];
  const float* t_in_b = (const float*)d_in[17];
  const float* t_out_w= (const float*)d_in[18];
  const float* t_out_b= (const float*)d_in[19];
  const float* t_ln1g = (const float*)d_in[20];
  const float* t_ln1b = (const float*)d_in[21];
  const float* t_ff1w = (const float*)d_in[22];
  const float* t_ff1b = (const float*)d_in[23];
  const float* t_ff2w = (const float*)d_in[24];
  const float* t_ff2b = (const float*)d_in[25];
  const float* t_ln2g = (const float*)d_in[26];
  const float* t_ln2b = (const float*)d_in[27];
  const float* te1_w  = (const float*)d_in[28];
  const float* te1_b  = (const float*)d_in[29];
  const float* tl1g   = (const float*)d_in[30];
  const float* tl1b   = (const float*)d_in[31];
  const float* te2_w  = (const float*)d_in[32];
  const float* te2_b  = (const float*)d_in[33];
  const float* tl2g   = (const float*)d_in[34];
  const float* tl2b   = (const float*)d_in[35];
  const float* c_w    = (const float*)d_in[36];
  const float* c_b    = (const float*)d_in[37];
  const float* clng   = (const float*)d_in[38];
  const float* clnb   = (const float*)d_in[39];

  float* ws = (float*)d_ws;
  // Workspace (float slots), max index 17,391,616 (~69.6 MB):
  //   A [0,        524288):  oeb bf16 [8192][128]
  //   B [1048576,  5242880): qkt bf16 (dead after order_attn) -> g fp32
  //       -> yraw fp32 (after resln#1; g dead)
  //   C [5242880,  9437184): attn fp32; g1 resln#1 in-place; g2 resln#2
  //   D [9437184,  9633792): whhb bf16 [2][768][256]
  //   D2[9633792,  9732096): wihb bf16 [2][768][128]
  //   D3[9732096,  9740288): awb2 bf16 [128*128]
  //   E [10027008,10051584): awb bf16 [384*128]
  //   F [10051584,10444800): twb bf16 [1536*512]
  //   G [10444800,10575872): pwb bf16 [512*512]
  //   G2[10575872,10838016): f1wb bf16 [1024*512]
  //   G3[10838016,11100160): f2wb bf16 [512*1024]
  //   H [11100160,17391616): vt bf16 -> gi bf16 (dead after gru_rec)
  //       -> praw fp32 [8192][512] (proj raw)
  unsigned short* oeb  = (unsigned short*)ws;
  unsigned short* qkt  = (unsigned short*)(ws + 1048576);
  float* g    = ws + 1048576;                           // over dead qkt
  float* yraw = ws + 1048576;                           // over dead g (post-resln#1)
  float* attn = ws + 5242880;
  float* g1   = attn;                                   // in-place resln#1 out
  float* g2   = attn;                                   // in-place resln#2 out
  unsigned short* whhb = (unsigned short*)(ws + 9437184);
  unsigned short* wihb = (unsigned short*)(ws + 9633792);
  unsigned short* awb2 = (unsigned short*)(ws + 9732096);
  unsigned short* awb  = (unsigned short*)(ws + 10027008);
  unsigned short* twb  = (unsigned short*)(ws + 10051584);
  unsigned short* pwb  = (unsigned short*)(ws + 10444800);
  unsigned short* f1wb = (unsigned short*)(ws + 10575872);
  unsigned short* f2wb = (unsigned short*)(ws + 10838016);
  unsigned short* vt   = (unsigned short*)(ws + 11100160);
  unsigned short* gi   = (unsigned short*)(ws + 11100160); // over dead vt
  float* praw = ws + 11100160;                          // over dead gi

  k_canary<<<256, 256, 0, stream>>>((float*)d_out);
  k_cvt<<<3072, 256, 0, stream>>>(a_in_w, t_in_w, t_out_w, t_ff1w, t_ff2w, a_out_w,
                                  awb, twb, pwb, f1wb, f2wb, awb2);
  k_gru_wb<<<1536, 256, 0, stream>>>(wih_f, whh_f, wih_b, whh_b, whhb, wihb);
  k_qkvpre<<<1553, 256, 0, stream>>>(emb, awb, a_in_b, qkt, vt);
  k_order_attn<<<8192, 256, 0, stream>>>(oh, qkt, vt, awb2, a_out_b, oeb);
  k_gru_gi<<<256, 256, 0, stream>>>(oeb, wihb, gi);
  k_gru_rec<<<dim3(128, 2), 512, 0, stream>>>(gi, whhb, bih_f, bhh_f, bih_b, bhh_b, g);
  k_mha2f<<<dim3(256, 4), 256, 0, stream>>>(g, twb, t_in_b, attn);
  k_proj<<<256, 1024, 0, stream>>>(attn, pwb, t_out_b, praw);
  k_resln<<<512, 256, 0, stream>>>(praw, g, t_ln1g, t_ln1b, g1);
  k_ff<<<256, 1024, 0, stream>>>(g1, f1wb, t_ff1b, f2wb, t_ff2b, yraw);
  k_resln<<<512, 256, 0, stream>>>(yraw, g1, t_ln2g, t_ln2b, g2);
  k_final<<<256, 256, 0, stream>>>(g2, db, dsl, te1_w, te1_b, tl1g, tl1b,
                                   te2_w, te2_b, tl2g, tl2b, c_w, c_b, clng, clnb,
                                   (float*)d_out);
}